// Round 1
// baseline (33088.068 us; speedup 1.0000x reference)
//
#include <hip/hip_runtime.h>
#include <math.h>

typedef unsigned short ushort_t;

// ---------------- helpers ----------------
__device__ __forceinline__ float geluf(float x){
  return 0.5f*x*(1.0f+erff(x*0.70710678118654752440f));
}
__device__ __forceinline__ float bfu(unsigned int u){
  union { unsigned int i; float f; } v; v.i = (u & 0xffffu) << 16; return v.f;
}
__device__ __forceinline__ unsigned short f2b(float f){
  union { float f; unsigned int i; } v; v.f = f;
  unsigned int r = v.i + 0x7fffu + ((v.i >> 16) & 1u);
  return (unsigned short)(r >> 16);
}

// Problem constants
// B=512, N=197, C=384, T=196 image tokens
// d_out layout (floats): out[512] | cosine[512] | query_class[512*384] | support_class[512*384]

// ---------------- A: token means (per tensor, b, c) ----------------
__global__ __launch_bounds__(384) void k_mean(
    const float* __restrict__ x0, const float* __restrict__ x1,
    const float* __restrict__ x2, const float* __restrict__ x3,
    float* __restrict__ meanb){
  int s = blockIdx.x >> 9, b = blockIdx.x & 511, c = threadIdx.x;
  const float* x = (s==0)?x0:(s==1)?x1:(s==2)?x2:x3;
  const float* p = x + ((size_t)b*197)*384 + c;
  float acc = 0.f;
  #pragma unroll 4
  for (int t=0;t<197;++t) acc += p[(size_t)t*384];
  meanb[((size_t)s*512+b)*384+c] = acc*(1.0f/197.0f);
}

// ---------------- B: fc1 tiny MLP on means ----------------
__global__ __launch_bounds__(384) void k_fc1(
    const float* __restrict__ meanb, const float* __restrict__ w1,
    const float* __restrict__ b1, const float* __restrict__ w2,
    const float* __restrict__ b2, float* __restrict__ mlp1){
  __shared__ float ms[384];
  __shared__ float hs[96];
  int row = blockIdx.x, tid = threadIdx.x;
  ms[tid] = meanb[(size_t)row*384 + tid];
  __syncthreads();
  if (tid < 96){
    float a = b1[tid];
    for (int c=0;c<384;++c) a += ms[c]*w1[c*96+tid];
    hs[tid] = geluf(a);
  }
  __syncthreads();
  float a = b2[tid];
  for (int j=0;j<96;++j) a += hs[j]*w2[j*384+tid];
  mlp1[(size_t)row*384 + tid] = a;
}

// ---------------- C: per-row LN stats of (x + mlp1) ----------------
__global__ __launch_bounds__(256) void k_stats(
    const float* __restrict__ x0, const float* __restrict__ x1,
    const float* __restrict__ x2, const float* __restrict__ x3,
    const float* __restrict__ mlp1, float* __restrict__ mu, float* __restrict__ rstd){
  int lane = threadIdx.x & 63, w = threadIdx.x >> 6;
  int row = blockIdx.x*4 + w;           // rows = 4*512*197 = 403456, grid exact
  int s = row / 100864;
  int rr = row % 100864;
  int b = rr / 197, t = rr % 197;
  const float* x = (s==0)?x0:(s==1)?x1:(s==2)?x2:x3;
  const float* xp = x + ((size_t)b*197 + t)*384;
  const float* mp = mlp1 + ((size_t)s*512 + b)*384;
  float sum=0.f, sq=0.f;
  for (int i=lane;i<384;i+=64){ float v = xp[i]+mp[i]; sum+=v; sq+=v*v; }
  #pragma unroll
  for (int o=32;o;o>>=1){ sum+=__shfl_down(sum,o); sq+=__shfl_down(sq,o); }
  if (lane==0){
    float m = sum*(1.0f/384.0f);
    mu[row] = m;
    rstd[row] = rsqrtf(sq*(1.0f/384.0f) - m*m + 1e-5f);
  }
}

// ---------------- D: class token rows -> d_out ----------------
__global__ __launch_bounds__(384) void k_class(
    const float* __restrict__ x0, const float* __restrict__ x1,
    const float* __restrict__ mlp1, const float* __restrict__ mu,
    const float* __restrict__ rstd, const float* __restrict__ g1,
    const float* __restrict__ bb1, float* __restrict__ dout){
  int s = blockIdx.x >> 9, b = blockIdx.x & 511, c = threadIdx.x;
  const float* x = s ? x1 : x0;
  int srow = (s*512 + b)*197;
  float v = x[((size_t)b*197)*384 + c] + mlp1[((size_t)s*512+b)*384 + c];
  float y = (v - mu[srow])*rstd[srow]*g1[c] + bb1[c];
  dout[1024 + (size_t)s*196608 + (size_t)b*384 + c] = y;
}

// ---------------- E: cosine head on class tokens ----------------
__global__ __launch_bounds__(384) void k_cosine(
    const float* __restrict__ w1, const float* __restrict__ b1,
    const float* __restrict__ w2, const float* __restrict__ b2,
    float* __restrict__ dout){
  __shared__ float qrow[384], srw[384], hq[96], hs[96];
  __shared__ float rd0[384], rd1[384], rd2[384];
  int b = blockIdx.x, tid = threadIdx.x;
  qrow[tid] = dout[1024   + (size_t)b*384 + tid];
  srw[tid]  = dout[197632 + (size_t)b*384 + tid];
  __syncthreads();
  if (tid < 96){
    float a = b1[tid];
    for (int c=0;c<384;++c) a += qrow[c]*w1[c*96+tid];
    hq[tid] = geluf(a);
  } else if (tid < 192){
    int j = tid - 96;
    float a = b1[j];
    for (int c=0;c<384;++c) a += srw[c]*w1[c*96+j];
    hs[j] = geluf(a);
  }
  __syncthreads();
  float qx = b2[tid], sy = b2[tid];
  for (int j=0;j<96;++j){ qx += hq[j]*w2[j*384+tid]; sy += hs[j]*w2[j*384+tid]; }
  rd0[tid] = qx*sy; rd1[tid] = qx*qx; rd2[tid] = sy*sy;
  __syncthreads();
  if (tid < 64){
    float d=0.f,nq=0.f,ns=0.f;
    for (int i=tid;i<384;i+=64){ d+=rd0[i]; nq+=rd1[i]; ns+=rd2[i]; }
    #pragma unroll
    for (int o=32;o;o>>=1){ d+=__shfl_down(d,o); nq+=__shfl_down(nq,o); ns+=__shfl_down(ns,o); }
    if (tid==0) dout[512 + b] = d / (fmaxf(sqrtf(nq),1e-8f)*fmaxf(sqrtf(ns),1e-8f));
  }
}

// ---------------- F: fc3 GEMM1  h = gelu(X^T @ w1 + b1) ----------------
// grid 512*6 (b, c-tile of 64), block 256
__global__ __launch_bounds__(256) void k_fc3a(
    const float* __restrict__ x, const float* __restrict__ mlp1t,
    const float* __restrict__ mut, const float* __restrict__ rstdt,
    const float* __restrict__ g1, const float* __restrict__ bb1,
    const float* __restrict__ w1, const float* __restrict__ b1,
    ushort_t* __restrict__ h3){
  __shared__ ushort_t A[196][64];     // bf16 LN'd x^T tile [t][c]
  __shared__ ushort_t W[196][128];    // bf16 w1
  int b = blockIdx.x/6, ct = blockIdx.x%6, c0 = ct*64;
  int tid = threadIdx.x;
  for (int i = tid; i < 196*128; i += 256) (&W[0][0])[i] = f2b(w1[i]);
  {
    int cl = tid & 63, tg = tid >> 6;
    const float* mrow = mlp1t + (size_t)b*384;
    for (int t = tg; t < 196; t += 4){
      int c = c0 + cl;
      int srow = b*197 + (t+1);
      float v = x[((size_t)b*197 + (t+1))*384 + c] + mrow[c];
      float y = (v - mut[srow])*rstdt[srow]*g1[c] + bb1[c];
      A[t][cl] = f2b(y);
    }
  }
  __syncthreads();
  int ci = tid >> 4, ji = tid & 15;
  float acc[4][8];
  #pragma unroll
  for (int i=0;i<4;++i)
    #pragma unroll
    for (int k=0;k<8;++k) acc[i][k]=0.f;
  for (int t = 0; t < 196; ++t){
    uint2 av = *reinterpret_cast<const uint2*>(&A[t][ci*4]);
    uint4 wv = *reinterpret_cast<const uint4*>(&W[t][ji*8]);
    float a[4] = { bfu(av.x), bfu(av.x>>16), bfu(av.y), bfu(av.y>>16) };
    float w[8] = { bfu(wv.x), bfu(wv.x>>16), bfu(wv.y), bfu(wv.y>>16),
                   bfu(wv.z), bfu(wv.z>>16), bfu(wv.w), bfu(wv.w>>16) };
    #pragma unroll
    for (int i=0;i<4;++i)
      #pragma unroll
      for (int k=0;k<8;++k) acc[i][k] += a[i]*w[k];
  }
  #pragma unroll
  for (int i=0;i<4;++i){
    int c = c0 + ci*4 + i;
    unsigned short hv[8];
    #pragma unroll
    for (int k=0;k<8;++k){
      int j = ji*8+k;
      hv[k] = f2b(geluf(acc[i][k] + b1[j]));
    }
    uint4 pk;
    pk.x = hv[0] | ((unsigned)hv[1]<<16);
    pk.y = hv[2] | ((unsigned)hv[3]<<16);
    pk.z = hv[4] | ((unsigned)hv[5]<<16);
    pk.w = hv[6] | ((unsigned)hv[7]<<16);
    *reinterpret_cast<uint4*>(&h3[((size_t)b*384 + c)*128 + ji*8]) = pk;
  }
}

// ---------------- G: fc3 GEMM2 + LN over t', write transposed ----------------
// grid 512*6 (b, c-tile of 64), block 256
__global__ __launch_bounds__(256) void k_fc3b(
    const ushort_t* __restrict__ h3, const float* __restrict__ w2,
    const float* __restrict__ b2, const float* __restrict__ g3,
    const float* __restrict__ b3, ushort_t* __restrict__ Qout){
  __shared__ ushort_t H[128][68];     // bf16 h transposed [j][c], padded
  __shared__ ushort_t W[128][196];    // bf16 w2
  __shared__ float red[2][64][16];
  int b = blockIdx.x/6, ct = blockIdx.x%6, c0 = ct*64;
  int tid = threadIdx.x;
  for (int i = tid; i < 64*32; i += 256){
    int c = i >> 5, jq = i & 31;
    uint2 v = *reinterpret_cast<const uint2*>(&h3[((size_t)b*384 + c0 + c)*128 + jq*4]);
    H[jq*4+0][c] = (ushort_t)(v.x & 0xffffu);
    H[jq*4+1][c] = (ushort_t)(v.x >> 16);
    H[jq*4+2][c] = (ushort_t)(v.y & 0xffffu);
    H[jq*4+3][c] = (ushort_t)(v.y >> 16);
  }
  for (int i = tid; i < 128*196; i += 256) (&W[0][0])[i] = f2b(w2[i]);
  __syncthreads();
  int cg = tid >> 4, tg = tid & 15;
  float acc[4][14];
  #pragma unroll
  for (int i=0;i<4;++i)
    #pragma unroll
    for (int k=0;k<14;++k) acc[i][k]=0.f;
  for (int j = 0; j < 128; ++j){
    uint2 hv = *reinterpret_cast<const uint2*>(&H[j][cg*4]);
    float h[4] = { bfu(hv.x), bfu(hv.x>>16), bfu(hv.y), bfu(hv.y>>16) };
    #pragma unroll
    for (int k = 0; k < 7; ++k){
      if (k < 6 || tg < 2){    // k=6 valid only for tg<2 (t'=192..195)
        unsigned int wv = *reinterpret_cast<const unsigned int*>(&W[j][2*tg + 32*k]);
        float w0 = bfu(wv), w1v = bfu(wv>>16);
        #pragma unroll
        for (int i=0;i<4;++i){
          acc[i][2*k]   += h[i]*w0;
          acc[i][2*k+1] += h[i]*w1v;
        }
      }
    }
  }
  // bias + LN stats over t' (per c-row)
  float psum[4]={0,0,0,0}, psq[4]={0,0,0,0};
  #pragma unroll
  for (int sl=0; sl<14; ++sl){
    int t = 2*tg + 32*(sl>>1) + (sl&1);
    if (t < 196){
      #pragma unroll
      for (int i=0;i<4;++i){
        float y = acc[i][sl] + b2[t];
        acc[i][sl] = y;
        psum[i] += y; psq[i] += y*y;
      }
    }
  }
  #pragma unroll
  for (int i=0;i<4;++i){ red[0][cg*4+i][tg]=psum[i]; red[1][cg*4+i][tg]=psq[i]; }
  __syncthreads();
  float mu4[4], rs4[4];
  #pragma unroll
  for (int i=0;i<4;++i){
    float ssv=0.f, qv=0.f;
    #pragma unroll
    for (int u=0;u<16;++u){ ssv += red[0][cg*4+i][u]; qv += red[1][cg*4+i][u]; }
    float m = ssv*(1.0f/196.0f);
    mu4[i]=m; rs4[i]=rsqrtf(qv*(1.0f/196.0f)-m*m+1e-5f);
  }
  #pragma unroll
  for (int sl=0; sl<14; ++sl){
    int t = 2*tg + 32*(sl>>1) + (sl&1);
    if (t < 196){
      float g = g3[t], bb = b3[t];
      unsigned short o0 = f2b((acc[0][sl]-mu4[0])*rs4[0]*g + bb);
      unsigned short o1 = f2b((acc[1][sl]-mu4[1])*rs4[1]*g + bb);
      unsigned short o2 = f2b((acc[2][sl]-mu4[2])*rs4[2]*g + bb);
      unsigned short o3 = f2b((acc[3][sl]-mu4[3])*rs4[3]*g + bb);
      uint2 pk; pk.x = o0 | ((unsigned)o1<<16); pk.y = o2 | ((unsigned)o3<<16);
      *reinterpret_cast<uint2*>(&Qout[((size_t)b*196 + t)*384 + c0 + cg*4]) = pk;
    }
  }
}

// ---------------- H: fc4 fused (mul, MLP, LN, +0.5*class, l2norm, center) ----------------
// grid 2*512*13 (s, b, t-tile of 16), block 256
__global__ __launch_bounds__(256) void k_fc4(
    const float* __restrict__ xq, const float* __restrict__ xs,
    const float* __restrict__ mlp1, const float* __restrict__ mu,
    const float* __restrict__ rstd,
    const float* __restrict__ g1, const float* __restrict__ bb1,
    const ushort_t* __restrict__ Qq_in, const ushort_t* __restrict__ Qs_in,
    const float* __restrict__ w1, const float* __restrict__ b1,
    const float* __restrict__ w2, const float* __restrict__ b2,
    const float* __restrict__ g4, const float* __restrict__ bb4,
    const float* __restrict__ dout,
    ushort_t* __restrict__ Qq_out, ushort_t* __restrict__ Qs_out){
  __shared__ float Z[16][385];
  __shared__ float H[16][97];
  __shared__ float WS[96*64];
  int bid = blockIdx.x;
  int s = bid / (512*13); int r = bid % (512*13); int b = r/13; int tt0 = (r%13)*16;
  const float* x = s ? xs : xq;
  const ushort_t* Qin = s ? Qs_in : Qq_in;
  ushort_t* Qo = s ? Qs_out : Qq_out;
  const float* m1 = mlp1 + ((size_t)s*512 + b)*384;
  int tid = threadIdx.x;
  // phase 1: Z = LN1(x)+... elementwise product
  for (int idx = tid; idx < 16*384; idx += 256){
    int tt = idx / 384, c = idx % 384;
    int t = tt0 + tt;
    float z = 0.f;
    if (t < 196){
      int srow = (s*512 + b)*197 + (t+1);
      float v = x[((size_t)b*197 + (t+1))*384 + c] + m1[c];
      float qi = (v - mu[srow])*rstd[srow]*g1[c] + bb1[c];
      float qis = bfu((unsigned)Qin[((size_t)b*196 + t)*384 + c]);
      z = qi*qis;
    }
    Z[tt][c] = z;
  }
  int tt = tid >> 4, lg = tid & 15;
  // phase 2: GEMM1 (384 -> 96), gelu
  float a1[6] = {0,0,0,0,0,0};
  for (int cb = 0; cb < 384; cb += 64){
    __syncthreads();
    for (int i = tid; i < 64*96; i += 256) WS[i] = w1[(size_t)(cb + i/96)*96 + (i%96)];
    __syncthreads();
    for (int cc = 0; cc < 64; ++cc){
      float z = Z[tt][cb+cc];
      #pragma unroll
      for (int m=0;m<6;++m) a1[m] += z * WS[cc*96 + lg + 16*m];
    }
  }
  __syncthreads();
  #pragma unroll
  for (int m=0;m<6;++m){ int j = lg + 16*m; H[tt][j] = geluf(a1[m] + b1[j]); }
  // phase 3: GEMM2 (96 -> 384)
  float a2[24];
  #pragma unroll
  for (int k=0;k<24;++k) a2[k]=0.f;
  #pragma unroll
  for (int n = 0; n < 6; ++n){
    __syncthreads();
    for (int i = tid; i < 96*64; i += 256) WS[i] = w2[(size_t)(i/64)*384 + n*64 + (i%64)];
    __syncthreads();
    for (int j = 0; j < 96; ++j){
      float h = H[tt][j];
      #pragma unroll
      for (int q=0;q<4;++q) a2[n*4+q] += h * WS[j*64 + lg + 16*q];
    }
  }
  // epilogue: bias, LN4, +0.5*class, l2norm, center; 16-lane shuffle reductions
  int t = tt0 + tt; bool valid = (t < 196);
  float sum=0.f, sq=0.f;
  #pragma unroll
  for (int k=0;k<24;++k){
    int c = lg + 16*k;
    a2[k] += b2[c];
    sum += a2[k]; sq += a2[k]*a2[k];
  }
  #pragma unroll
  for (int o=1;o<16;o<<=1){ sum += __shfl_xor(sum,o); sq += __shfl_xor(sq,o); }
  float m4 = sum*(1.0f/384.0f);
  float rs = rsqrtf(sq*(1.0f/384.0f) - m4*m4 + 1e-5f);
  const float* cls = dout + 1024 + (size_t)s*196608 + (size_t)b*384;
  float s2 = 0.f;
  #pragma unroll
  for (int k=0;k<24;++k){
    int c = lg + 16*k;
    float v = (a2[k]-m4)*rs*g4[c] + bb4[c];
    v += 0.5f*cls[c];
    a2[k] = v; s2 += v*v;
  }
  #pragma unroll
  for (int o=1;o<16;o<<=1) s2 += __shfl_xor(s2,o);
  float inv = 1.0f/fmaxf(sqrtf(s2), 1e-12f);
  float sm = 0.f;
  #pragma unroll
  for (int k=0;k<24;++k){ a2[k]*=inv; sm += a2[k]; }
  #pragma unroll
  for (int o=1;o<16;o<<=1) sm += __shfl_xor(sm,o);
  sm *= (1.0f/384.0f);
  if (valid){
    #pragma unroll
    for (int k=0;k<24;++k) Qo[((size_t)b*196 + t)*384 + lg + 16*k] = f2b(a2[k]-sm);
  }
}

// ---------------- I: batched einsum + fused 2x2 pooling ----------------
// grid 512*16 (b, qt, st), block 256
__global__ __launch_bounds__(256) void k_sim(
    const ushort_t* __restrict__ Q, const ushort_t* __restrict__ S,
    float* __restrict__ P){
  __shared__ ushort_t As[32][68];
  __shared__ ushort_t Bs[32][68];
  int bx = blockIdx.x;
  int b = bx >> 4, qt = (bx >> 2) & 3, st = bx & 3;
  int q0 = qt*64, s0 = st*64;
  int tid = threadIdx.x, ty = tid >> 4, tx = tid & 15;
  float acc[4][4];
  #pragma unroll
  for (int i=0;i<4;++i)
    #pragma unroll
    for (int j=0;j<4;++j) acc[i][j]=0.f;
  for (int kc = 0; kc < 384; kc += 32){
    __syncthreads();
    #pragma unroll
    for (int l = 0; l < 2; ++l){
      int idx = tid + l*256;
      int rr = idx >> 3, g = idx & 7;
      uint2 va; va.x=0u; va.y=0u;
      uint2 vb; vb.x=0u; vb.y=0u;
      int q = q0 + rr, ss = s0 + rr;
      if (q  < 196) va = *reinterpret_cast<const uint2*>(&Q[((size_t)b*196+q )*384 + kc + g*4]);
      if (ss < 196) vb = *reinterpret_cast<const uint2*>(&S[((size_t)b*196+ss)*384 + kc + g*4]);
      As[g*4+0][rr] = (ushort_t)(va.x&0xffffu); As[g*4+1][rr]=(ushort_t)(va.x>>16);
      As[g*4+2][rr] = (ushort_t)(va.y&0xffffu); As[g*4+3][rr]=(ushort_t)(va.y>>16);
      Bs[g*4+0][rr] = (ushort_t)(vb.x&0xffffu); Bs[g*4+1][rr]=(ushort_t)(vb.x>>16);
      Bs[g*4+2][rr] = (ushort_t)(vb.y&0xffffu); Bs[g*4+3][rr]=(ushort_t)(vb.y>>16);
    }
    __syncthreads();
    for (int k = 0; k < 32; ++k){
      uint2 ua = *reinterpret_cast<const uint2*>(&As[k][ty*4]);
      uint2 ub = *reinterpret_cast<const uint2*>(&Bs[k][tx*4]);
      float av[4] = {bfu(ua.x),bfu(ua.x>>16),bfu(ua.y),bfu(ua.y>>16)};
      float bv[4] = {bfu(ub.x),bfu(ub.x>>16),bfu(ub.y),bfu(ub.y>>16)};
      #pragma unroll
      for (int i=0;i<4;++i)
        #pragma unroll
        for (int j=0;j<4;++j) acc[i][j] += av[i]*bv[j];
    }
  }
  int qb = q0 + ty*4, sb = s0 + tx*4;
  #pragma unroll
  for (int i=0;i<2;++i)
    #pragma unroll
    for (int j=0;j<2;++j){
      int qp = (qb>>1) + i, sp = (sb>>1) + j;
      if (qp < 98 && sp < 98){
        float v = 0.25f*(acc[2*i][2*j]+acc[2*i][2*j+1]+acc[2*i+1][2*j]+acc[2*i+1][2*j+1]);
        P[((size_t)b*98 + qp)*98 + sp] = v;
      }
    }
}

// ---------------- J: fc2 head (square -> 9604->256 gelu -> 1) ----------------
// grid 64 (8 batch rows each), block 256
__global__ __launch_bounds__(256) void k_fc2(
    const float* __restrict__ P, const float* __restrict__ w1,
    const float* __restrict__ b1, const float* __restrict__ w2,
    const float* __restrict__ b2, float* __restrict__ outp){
  __shared__ float p2[8][257];
  int b0 = blockIdx.x*8, tid = threadIdx.x;
  float acc[8];
  #pragma unroll
  for (int r=0;r<8;++r) acc[r]=0.f;
  for (int ic = 0; ic < 9604; ic += 256){
    __syncthreads();
    int iend = min(256, 9604-ic);
    #pragma unroll
    for (int l=0;l<8;++l){
      float v = 0.f;
      if (tid < iend) v = P[(size_t)(b0+l)*9604 + ic + tid];
      p2[l][tid] = v*v;
    }
    __syncthreads();
    for (int ii=0; ii<iend; ++ii){
      float w = w1[(size_t)(ic+ii)*256 + tid];
      #pragma unroll
      for (int r=0;r<8;++r) acc[r] += p2[r][ii]*w;
    }
  }
  float wv = w2[tid];
  __syncthreads();
  #pragma unroll
  for (int r=0;r<8;++r) p2[r][tid] = geluf(acc[r] + b1[tid]) * wv;
  __syncthreads();
  if (tid < 8){
    float s = b2[0];
    for (int j=0;j<256;++j) s += p2[tid][j];
    outp[b0+tid] = s;
  }
}

// ---------------- launch ----------------
extern "C" void kernel_launch(void* const* d_in, const int* in_sizes, int n_in,
                              void* d_out, int out_size, void* d_ws, size_t ws_size,
                              hipStream_t stream){
  const float* fq  = (const float*)d_in[0];
  const float* fs  = (const float*)d_in[1];
  const float* fqs = (const float*)d_in[2];
  const float* fss = (const float*)d_in[3];
  const float* fc1_w1 = (const float*)d_in[4];
  const float* fc1_b1 = (const float*)d_in[5];
  const float* fc1_w2 = (const float*)d_in[6];
  const float* fc1_b2 = (const float*)d_in[7];
  const float* ln1_g = (const float*)d_in[8];
  const float* ln1_b = (const float*)d_in[9];
  const float* fc3_w1 = (const float*)d_in[10];
  const float* fc3_b1 = (const float*)d_in[11];
  const float* fc3_w2 = (const float*)d_in[12];
  const float* fc3_b2 = (const float*)d_in[13];
  const float* ln3_g = (const float*)d_in[14];
  const float* ln3_b = (const float*)d_in[15];
  const float* fc4_w1 = (const float*)d_in[16];
  const float* fc4_b1 = (const float*)d_in[17];
  const float* fc4_w2 = (const float*)d_in[18];
  const float* fc4_b2 = (const float*)d_in[19];
  const float* ln4_g = (const float*)d_in[20];
  const float* ln4_b = (const float*)d_in[21];
  const float* fc2_w1 = (const float*)d_in[22];
  const float* fc2_b1 = (const float*)d_in[23];
  const float* fc2_w2 = (const float*)d_in[24];
  const float* fc2_b2 = (const float*)d_in[25];
  const float* cs_w1 = (const float*)d_in[26];
  const float* cs_b1 = (const float*)d_in[27];
  const float* cs_w2 = (const float*)d_in[28];
  const float* cs_b2 = (const float*)d_in[29];
  float* out = (float*)d_out;
  char* ws = (char*)d_ws;
  // ws layout (bytes):
  //   meanb f32 @0           (3,145,728)
  //   mlp1  f32 @3145728     (3,145,728)
  //   mu    f32 @6291456     (1,613,824)
  //   rstd  f32 @7905280     (1,613,824)
  //   h3    bf16 @9519104    (50,331,648)  [also reused later for P f32 19.7MB]
  //   Qb    bf16 @59850752   (77,070,336)
  //   Sb    bf16 @136921088  (77,070,336)
  //   total 213,991,424 B
  float* meanb  = (float*)(ws + 0);
  float* mlp1   = (float*)(ws + 3145728);
  float* mu     = (float*)(ws + 6291456);
  float* rstd   = (float*)(ws + 7905280);
  ushort_t* h3  = (ushort_t*)(ws + 9519104);
  float* P      = (float*)(ws + 9519104);   // overlays h3 (dead by k_sim)
  ushort_t* Qb  = (ushort_t*)(ws + 59850752);
  ushort_t* Sb  = (ushort_t*)(ws + 136921088);

  k_mean<<<2048, 384, 0, stream>>>(fq, fs, fqs, fss, meanb);
  k_fc1<<<2048, 384, 0, stream>>>(meanb, fc1_w1, fc1_b1, fc1_w2, fc1_b2, mlp1);
  k_stats<<<100864, 256, 0, stream>>>(fq, fs, fqs, fss, mlp1, mu, rstd);
  k_class<<<1024, 384, 0, stream>>>(fq, fs, mlp1, mu, rstd, ln1_g, ln1_b, out);
  k_cosine<<<512, 384, 0, stream>>>(cs_w1, cs_b1, cs_w2, cs_b2, out);
  k_fc3a<<<3072, 256, 0, stream>>>(fqs, mlp1 + (size_t)2*512*384, mu + 2*100864, rstd + 2*100864,
                                   ln1_g, ln1_b, fc3_w1, fc3_b1, h3);
  k_fc3b<<<3072, 256, 0, stream>>>(h3, fc3_w2, fc3_b2, ln3_g, ln3_b, Qb);
  k_fc3a<<<3072, 256, 0, stream>>>(fss, mlp1 + (size_t)3*512*384, mu + 3*100864, rstd + 3*100864,
                                   ln1_g, ln1_b, fc3_w1, fc3_b1, h3);
  k_fc3b<<<3072, 256, 0, stream>>>(h3, fc3_w2, fc3_b2, ln3_g, ln3_b, Sb);
  k_fc4<<<13312, 256, 0, stream>>>(fq, fs, mlp1, mu, rstd, ln1_g, ln1_b, Qb, Sb,
                                   fc4_w1, fc4_b1, fc4_w2, fc4_b2, ln4_g, ln4_b,
                                   out, Qb, Sb);
  k_sim<<<8192, 256, 0, stream>>>(Qb, Sb, P);
  k_fc2<<<64, 256, 0, stream>>>(P, fc2_w1, fc2_b1, fc2_w2, fc2_b2, out);
}

// Round 2
// 32747.186 us; speedup vs baseline: 1.0104x; 1.0104x over previous
//
#include <hip/hip_runtime.h>
#include <math.h>

typedef unsigned short ushort_t;

// ---------------- helpers ----------------
__device__ __forceinline__ float geluf(float x){
  return 0.5f*x*(1.0f+erff(x*0.70710678118654752440f));
}
__device__ __forceinline__ float bfu(unsigned int u){
  union { unsigned int i; float f; } v; v.i = (u & 0xffffu) << 16; return v.f;
}
__device__ __forceinline__ unsigned short f2b(float f){
  union { float f; unsigned int i; } v; v.f = f;
  unsigned int r = v.i + 0x7fffu + ((v.i >> 16) & 1u);
  return (unsigned short)(r >> 16);
}

// Problem constants
// B=512, N=197, C=384, T=196 image tokens
// d_out layout (floats): out[512] | cosine[512] | query_class[512*384] | support_class[512*384]

// ---------------- A: token means (per tensor, b, c) ----------------
__global__ __launch_bounds__(384) void k_mean(
    const float* __restrict__ x0, const float* __restrict__ x1,
    const float* __restrict__ x2, const float* __restrict__ x3,
    float* __restrict__ meanb){
  int s = blockIdx.x >> 9, b = blockIdx.x & 511, c = threadIdx.x;
  const float* x = (s==0)?x0:(s==1)?x1:(s==2)?x2:x3;
  const float* p = x + ((size_t)b*197)*384 + c;
  float acc = 0.f;
  #pragma unroll 4
  for (int t=0;t<197;++t) acc += p[(size_t)t*384];
  meanb[((size_t)s*512+b)*384+c] = acc*(1.0f/197.0f);
}

// ---------------- B: fc1 tiny MLP on means ----------------
__global__ __launch_bounds__(384) void k_fc1(
    const float* __restrict__ meanb, const float* __restrict__ w1,
    const float* __restrict__ b1, const float* __restrict__ w2,
    const float* __restrict__ b2, float* __restrict__ mlp1){
  __shared__ float ms[384];
  __shared__ float hs[96];
  int row = blockIdx.x, tid = threadIdx.x;
  ms[tid] = meanb[(size_t)row*384 + tid];
  __syncthreads();
  if (tid < 96){
    float a = b1[tid];
    for (int c=0;c<384;++c) a += ms[c]*w1[c*96+tid];
    hs[tid] = geluf(a);
  }
  __syncthreads();
  float a = b2[tid];
  for (int j=0;j<96;++j) a += hs[j]*w2[j*384+tid];
  mlp1[(size_t)row*384 + tid] = a;
}

// ---------------- C: per-row LN stats of (x + mlp1) ----------------
__global__ __launch_bounds__(256) void k_stats(
    const float* __restrict__ x0, const float* __restrict__ x1,
    const float* __restrict__ x2, const float* __restrict__ x3,
    const float* __restrict__ mlp1, float* __restrict__ mu, float* __restrict__ rstd){
  int lane = threadIdx.x & 63, w = threadIdx.x >> 6;
  int row = blockIdx.x*4 + w;           // rows = 4*512*197 = 403456, grid exact
  int s = row / 100864;
  int rr = row % 100864;
  int b = rr / 197, t = rr % 197;
  const float* x = (s==0)?x0:(s==1)?x1:(s==2)?x2:x3;
  const float* xp = x + ((size_t)b*197 + t)*384;
  const float* mp = mlp1 + ((size_t)s*512 + b)*384;
  float sum=0.f, sq=0.f;
  for (int i=lane;i<384;i+=64){ float v = xp[i]+mp[i]; sum+=v; sq+=v*v; }
  #pragma unroll
  for (int o=32;o;o>>=1){ sum+=__shfl_down(sum,o); sq+=__shfl_down(sq,o); }
  if (lane==0){
    float m = sum*(1.0f/384.0f);
    mu[row] = m;
    rstd[row] = rsqrtf(sq*(1.0f/384.0f) - m*m + 1e-5f);
  }
}

// ---------------- D: class token rows -> d_out ----------------
__global__ __launch_bounds__(384) void k_class(
    const float* __restrict__ x0, const float* __restrict__ x1,
    const float* __restrict__ mlp1, const float* __restrict__ mu,
    const float* __restrict__ rstd, const float* __restrict__ g1,
    const float* __restrict__ bb1, float* __restrict__ dout){
  int s = blockIdx.x >> 9, b = blockIdx.x & 511, c = threadIdx.x;
  const float* x = s ? x1 : x0;
  int srow = (s*512 + b)*197;
  float v = x[((size_t)b*197)*384 + c] + mlp1[((size_t)s*512+b)*384 + c];
  float y = (v - mu[srow])*rstd[srow]*g1[c] + bb1[c];
  dout[1024 + (size_t)s*196608 + (size_t)b*384 + c] = y;
}

// ---------------- E: cosine head on class tokens ----------------
__global__ __launch_bounds__(384) void k_cosine(
    const float* __restrict__ w1, const float* __restrict__ b1,
    const float* __restrict__ w2, const float* __restrict__ b2,
    float* __restrict__ dout){
  __shared__ float qrow[384], srw[384], hq[96], hs[96];
  __shared__ float rd0[384], rd1[384], rd2[384];
  int b = blockIdx.x, tid = threadIdx.x;
  qrow[tid] = dout[1024   + (size_t)b*384 + tid];
  srw[tid]  = dout[197632 + (size_t)b*384 + tid];
  __syncthreads();
  if (tid < 96){
    float a = b1[tid];
    for (int c=0;c<384;++c) a += qrow[c]*w1[c*96+tid];
    hq[tid] = geluf(a);
  } else if (tid < 192){
    int j = tid - 96;
    float a = b1[j];
    for (int c=0;c<384;++c) a += srw[c]*w1[c*96+j];
    hs[j] = geluf(a);
  }
  __syncthreads();
  float qx = b2[tid], sy = b2[tid];
  for (int j=0;j<96;++j){ qx += hq[j]*w2[j*384+tid]; sy += hs[j]*w2[j*384+tid]; }
  rd0[tid] = qx*sy; rd1[tid] = qx*qx; rd2[tid] = sy*sy;
  __syncthreads();
  if (tid < 64){
    float d=0.f,nq=0.f,ns=0.f;
    for (int i=tid;i<384;i+=64){ d+=rd0[i]; nq+=rd1[i]; ns+=rd2[i]; }
    #pragma unroll
    for (int o=32;o;o>>=1){ d+=__shfl_down(d,o); nq+=__shfl_down(nq,o); ns+=__shfl_down(ns,o); }
    if (tid==0) dout[512 + b] = d / (fmaxf(sqrtf(nq),1e-8f)*fmaxf(sqrtf(ns),1e-8f));
  }
}

// ---------------- F: fc3 GEMM1  h = gelu(X^T @ w1 + b1) ----------------
// grid 512*6 (b, c-tile of 64), block 256
__global__ __launch_bounds__(256) void k_fc3a(
    const float* __restrict__ x, const float* __restrict__ mlp1t,
    const float* __restrict__ mut, const float* __restrict__ rstdt,
    const float* __restrict__ g1, const float* __restrict__ bb1,
    const float* __restrict__ w1, const float* __restrict__ b1,
    ushort_t* __restrict__ h3){
  __shared__ ushort_t A[196][64];     // bf16 LN'd x^T tile [t][c]
  __shared__ ushort_t W[196][128];    // bf16 w1
  int b = blockIdx.x/6, ct = blockIdx.x%6, c0 = ct*64;
  int tid = threadIdx.x;
  for (int i = tid; i < 196*128; i += 256) (&W[0][0])[i] = f2b(w1[i]);
  {
    int cl = tid & 63, tg = tid >> 6;
    const float* mrow = mlp1t + (size_t)b*384;
    for (int t = tg; t < 196; t += 4){
      int c = c0 + cl;
      int srow = b*197 + (t+1);
      float v = x[((size_t)b*197 + (t+1))*384 + c] + mrow[c];
      float y = (v - mut[srow])*rstdt[srow]*g1[c] + bb1[c];
      A[t][cl] = f2b(y);
    }
  }
  __syncthreads();
  int ci = tid >> 4, ji = tid & 15;
  float acc[4][8];
  #pragma unroll
  for (int i=0;i<4;++i)
    #pragma unroll
    for (int k=0;k<8;++k) acc[i][k]=0.f;
  for (int t = 0; t < 196; ++t){
    uint2 av = *reinterpret_cast<const uint2*>(&A[t][ci*4]);
    uint4 wv = *reinterpret_cast<const uint4*>(&W[t][ji*8]);
    float a[4] = { bfu(av.x), bfu(av.x>>16), bfu(av.y), bfu(av.y>>16) };
    float w[8] = { bfu(wv.x), bfu(wv.x>>16), bfu(wv.y), bfu(wv.y>>16),
                   bfu(wv.z), bfu(wv.z>>16), bfu(wv.w), bfu(wv.w>>16) };
    #pragma unroll
    for (int i=0;i<4;++i)
      #pragma unroll
      for (int k=0;k<8;++k) acc[i][k] += a[i]*w[k];
  }
  #pragma unroll
  for (int i=0;i<4;++i){
    int c = c0 + ci*4 + i;
    unsigned short hv[8];
    #pragma unroll
    for (int k=0;k<8;++k){
      int j = ji*8+k;
      hv[k] = f2b(geluf(acc[i][k] + b1[j]));
    }
    uint4 pk;
    pk.x = hv[0] | ((unsigned)hv[1]<<16);
    pk.y = hv[2] | ((unsigned)hv[3]<<16);
    pk.z = hv[4] | ((unsigned)hv[5]<<16);
    pk.w = hv[6] | ((unsigned)hv[7]<<16);
    *reinterpret_cast<uint4*>(&h3[((size_t)b*384 + c)*128 + ji*8]) = pk;
  }
}

// ---------------- G: fc3 GEMM2 + LN over t', write transposed ----------------
// grid 512*6 (b, c-tile of 64), block 256
__global__ __launch_bounds__(256) void k_fc3b(
    const ushort_t* __restrict__ h3, const float* __restrict__ w2,
    const float* __restrict__ b2, const float* __restrict__ g3,
    const float* __restrict__ b3, ushort_t* __restrict__ Qout){
  __shared__ ushort_t H[128][68];     // bf16 h transposed [j][c], padded
  __shared__ ushort_t W[128][196];    // bf16 w2
  __shared__ float red[2][64][16];
  int b = blockIdx.x/6, ct = blockIdx.x%6, c0 = ct*64;
  int tid = threadIdx.x;
  for (int i = tid; i < 64*32; i += 256){
    int c = i >> 5, jq = i & 31;
    uint2 v = *reinterpret_cast<const uint2*>(&h3[((size_t)b*384 + c0 + c)*128 + jq*4]);
    H[jq*4+0][c] = (ushort_t)(v.x & 0xffffu);
    H[jq*4+1][c] = (ushort_t)(v.x >> 16);
    H[jq*4+2][c] = (ushort_t)(v.y & 0xffffu);
    H[jq*4+3][c] = (ushort_t)(v.y >> 16);
  }
  for (int i = tid; i < 128*196; i += 256) (&W[0][0])[i] = f2b(w2[i]);
  __syncthreads();
  int cg = tid >> 4, tg = tid & 15;
  float acc[4][14];
  #pragma unroll
  for (int i=0;i<4;++i)
    #pragma unroll
    for (int k=0;k<14;++k) acc[i][k]=0.f;
  for (int j = 0; j < 128; ++j){
    uint2 hv = *reinterpret_cast<const uint2*>(&H[j][cg*4]);
    float h[4] = { bfu(hv.x), bfu(hv.x>>16), bfu(hv.y), bfu(hv.y>>16) };
    #pragma unroll
    for (int k = 0; k < 7; ++k){
      if (k < 6 || tg < 2){    // k=6 valid only for tg<2 (t'=192..195)
        unsigned int wv = *reinterpret_cast<const unsigned int*>(&W[j][2*tg + 32*k]);
        float w0 = bfu(wv), w1v = bfu(wv>>16);
        #pragma unroll
        for (int i=0;i<4;++i){
          acc[i][2*k]   += h[i]*w0;
          acc[i][2*k+1] += h[i]*w1v;
        }
      }
    }
  }
  // bias + LN stats over t' (per c-row)
  float psum[4]={0,0,0,0}, psq[4]={0,0,0,0};
  #pragma unroll
  for (int sl=0; sl<14; ++sl){
    int t = 2*tg + 32*(sl>>1) + (sl&1);
    if (t < 196){
      #pragma unroll
      for (int i=0;i<4;++i){
        float y = acc[i][sl] + b2[t];
        acc[i][sl] = y;
        psum[i] += y; psq[i] += y*y;
      }
    }
  }
  #pragma unroll
  for (int i=0;i<4;++i){ red[0][cg*4+i][tg]=psum[i]; red[1][cg*4+i][tg]=psq[i]; }
  __syncthreads();
  float mu4[4], rs4[4];
  #pragma unroll
  for (int i=0;i<4;++i){
    float ssv=0.f, qv=0.f;
    #pragma unroll
    for (int u=0;u<16;++u){ ssv += red[0][cg*4+i][u]; qv += red[1][cg*4+i][u]; }
    float m = ssv*(1.0f/196.0f);
    mu4[i]=m; rs4[i]=rsqrtf(qv*(1.0f/196.0f)-m*m+1e-5f);
  }
  #pragma unroll
  for (int sl=0; sl<14; ++sl){
    int t = 2*tg + 32*(sl>>1) + (sl&1);
    if (t < 196){
      float g = g3[t], bb = b3[t];
      unsigned short o0 = f2b((acc[0][sl]-mu4[0])*rs4[0]*g + bb);
      unsigned short o1 = f2b((acc[1][sl]-mu4[1])*rs4[1]*g + bb);
      unsigned short o2 = f2b((acc[2][sl]-mu4[2])*rs4[2]*g + bb);
      unsigned short o3 = f2b((acc[3][sl]-mu4[3])*rs4[3]*g + bb);
      uint2 pk; pk.x = o0 | ((unsigned)o1<<16); pk.y = o2 | ((unsigned)o3<<16);
      *reinterpret_cast<uint2*>(&Qout[((size_t)b*196 + t)*384 + c0 + cg*4]) = pk;
    }
  }
}

// ---------------- H1: fc4 stage A — Z = LN1(x)*Qin, h = gelu(Z@w1+b1) ----------------
// grid 2*512*13 (s, b, t-tile of 16), block 256
__global__ __launch_bounds__(256) void k_fc4a(
    const float* __restrict__ xq, const float* __restrict__ xs,
    const float* __restrict__ mlp1, const float* __restrict__ mu,
    const float* __restrict__ rstd,
    const float* __restrict__ g1, const float* __restrict__ bb1,
    const ushort_t* __restrict__ Qq_in, const ushort_t* __restrict__ Qs_in,
    const float* __restrict__ w1, const float* __restrict__ b1,
    ushort_t* __restrict__ h4){
  __shared__ float Z[16][385];
  __shared__ float WS[64*96];
  int bid = blockIdx.x;
  int s = bid / (512*13); int r = bid % (512*13); int b = r/13; int tt0 = (r%13)*16;
  const float* x = s ? xs : xq;
  const ushort_t* Qin = s ? Qs_in : Qq_in;
  const float* m1 = mlp1 + ((size_t)s*512 + b)*384;
  int tid = threadIdx.x;
  // phase 1: Z = LN1(x) * Qin elementwise
  for (int idx = tid; idx < 16*384; idx += 256){
    int tt = idx / 384, c = idx % 384;
    int t = tt0 + tt;
    float z = 0.f;
    if (t < 196){
      int srow = (s*512 + b)*197 + (t+1);
      float v = x[((size_t)b*197 + (t+1))*384 + c] + m1[c];
      float qi = (v - mu[srow])*rstd[srow]*g1[c] + bb1[c];
      float qis = bfu((unsigned)Qin[((size_t)b*196 + t)*384 + c]);
      z = qi*qis;
    }
    Z[tt][c] = z;
  }
  // phase 2: GEMM1 (384 -> 96), gelu -> h4 (bf16)
  int tt = tid >> 4, lg = tid & 15;
  float a1[6] = {0,0,0,0,0,0};
  for (int cb = 0; cb < 6; ++cb){                 // runtime loop: do NOT unroll
    __syncthreads();
    for (int i = tid; i < 64*96; i += 256) WS[i] = w1[(size_t)(cb*64 + i/96)*96 + (i%96)];
    __syncthreads();
    for (int cc = 0; cc < 64; ++cc){
      float z = Z[tt][cb*64+cc];
      #pragma unroll
      for (int m=0;m<6;++m) a1[m] += z * WS[cc*96 + lg + 16*m];
    }
  }
  int t = tt0 + tt;
  if (t < 196){
    #pragma unroll
    for (int m=0;m<6;++m){
      int j = lg + 16*m;
      h4[((size_t)((size_t)s*512+b)*196 + t)*96 + j] = f2b(geluf(a1[m] + b1[j]));
    }
  }
}

// ---------------- H2: fc4 stage B — y = h@w2+b2, LN4, +0.5*class, l2norm, center ----------------
// grid 2*512*13 (s, b, t-tile of 16), block 256
__global__ __launch_bounds__(256) void k_fc4b(
    const ushort_t* __restrict__ h4,
    const float* __restrict__ w2, const float* __restrict__ b2,
    const float* __restrict__ g4, const float* __restrict__ bb4,
    const float* __restrict__ dout,
    ushort_t* __restrict__ Qq_out, ushort_t* __restrict__ Qs_out){
  __shared__ float Hs[16][97];
  __shared__ float WS[24*384];
  int bid = blockIdx.x;
  int s = bid / (512*13); int r = bid % (512*13); int b = r/13; int tt0 = (r%13)*16;
  ushort_t* Qo = s ? Qs_out : Qq_out;
  int tid = threadIdx.x;
  // load h tile (invalid rows -> 0; their lanes never write out)
  for (int idx = tid; idx < 16*96; idx += 256){
    int tt = idx / 96, j = idx % 96;
    int t = tt0 + tt;
    float v = 0.f;
    if (t < 196) v = bfu((unsigned)h4[((size_t)((size_t)s*512+b)*196 + t)*96 + j]);
    Hs[tt][j] = v;
  }
  int tt = tid >> 4, lg = tid & 15;
  float a2[24];
  #pragma unroll
  for (int k=0;k<24;++k) a2[k]=0.f;
  for (int n = 0; n < 4; ++n){                    // runtime loop: do NOT unroll
    __syncthreads();
    for (int i = tid; i < 24*384; i += 256) WS[i] = w2[(size_t)(n*24 + i/384)*384 + (i%384)];
    __syncthreads();
    for (int jj = 0; jj < 24; ++jj){
      float h = Hs[tt][n*24+jj];
      #pragma unroll
      for (int k=0;k<24;++k) a2[k] += h * WS[jj*384 + lg + 16*k];
    }
  }
  // epilogue: bias, LN4, +0.5*class, l2norm, center; 16-lane shuffle reductions
  int t = tt0 + tt; bool valid = (t < 196);
  float sum=0.f, sq=0.f;
  #pragma unroll
  for (int k=0;k<24;++k){
    int c = lg + 16*k;
    a2[k] += b2[c];
    sum += a2[k]; sq += a2[k]*a2[k];
  }
  #pragma unroll
  for (int o=1;o<16;o<<=1){ sum += __shfl_xor(sum,o); sq += __shfl_xor(sq,o); }
  float m4 = sum*(1.0f/384.0f);
  float rs = rsqrtf(sq*(1.0f/384.0f) - m4*m4 + 1e-5f);
  const float* cls = dout + 1024 + (size_t)s*196608 + (size_t)b*384;
  float s2 = 0.f;
  #pragma unroll
  for (int k=0;k<24;++k){
    int c = lg + 16*k;
    float v = (a2[k]-m4)*rs*g4[c] + bb4[c];
    v += 0.5f*cls[c];
    a2[k] = v; s2 += v*v;
  }
  #pragma unroll
  for (int o=1;o<16;o<<=1) s2 += __shfl_xor(s2,o);
  float inv = 1.0f/fmaxf(sqrtf(s2), 1e-12f);
  float sm = 0.f;
  #pragma unroll
  for (int k=0;k<24;++k){ a2[k]*=inv; sm += a2[k]; }
  #pragma unroll
  for (int o=1;o<16;o<<=1) sm += __shfl_xor(sm,o);
  sm *= (1.0f/384.0f);
  if (valid){
    #pragma unroll
    for (int k=0;k<24;++k) Qo[((size_t)b*196 + t)*384 + lg + 16*k] = f2b(a2[k]-sm);
  }
}

// ---------------- I: batched einsum + fused 2x2 pooling ----------------
// grid 512*16 (b, qt, st), block 256
__global__ __launch_bounds__(256) void k_sim(
    const ushort_t* __restrict__ Q, const ushort_t* __restrict__ S,
    float* __restrict__ P){
  __shared__ ushort_t As[32][68];
  __shared__ ushort_t Bs[32][68];
  int bx = blockIdx.x;
  int b = bx >> 4, qt = (bx >> 2) & 3, st = bx & 3;
  int q0 = qt*64, s0 = st*64;
  int tid = threadIdx.x, ty = tid >> 4, tx = tid & 15;
  float acc[4][4];
  #pragma unroll
  for (int i=0;i<4;++i)
    #pragma unroll
    for (int j=0;j<4;++j) acc[i][j]=0.f;
  for (int kc = 0; kc < 384; kc += 32){
    __syncthreads();
    #pragma unroll
    for (int l = 0; l < 2; ++l){
      int idx = tid + l*256;
      int rr = idx >> 3, g = idx & 7;
      uint2 va; va.x=0u; va.y=0u;
      uint2 vb; vb.x=0u; vb.y=0u;
      int q = q0 + rr, ss = s0 + rr;
      if (q  < 196) va = *reinterpret_cast<const uint2*>(&Q[((size_t)b*196+q )*384 + kc + g*4]);
      if (ss < 196) vb = *reinterpret_cast<const uint2*>(&S[((size_t)b*196+ss)*384 + kc + g*4]);
      As[g*4+0][rr] = (ushort_t)(va.x&0xffffu); As[g*4+1][rr]=(ushort_t)(va.x>>16);
      As[g*4+2][rr] = (ushort_t)(va.y&0xffffu); As[g*4+3][rr]=(ushort_t)(va.y>>16);
      Bs[g*4+0][rr] = (ushort_t)(vb.x&0xffffu); Bs[g*4+1][rr]=(ushort_t)(vb.x>>16);
      Bs[g*4+2][rr] = (ushort_t)(vb.y&0xffffu); Bs[g*4+3][rr]=(ushort_t)(vb.y>>16);
    }
    __syncthreads();
    for (int k = 0; k < 32; ++k){
      uint2 ua = *reinterpret_cast<const uint2*>(&As[k][ty*4]);
      uint2 ub = *reinterpret_cast<const uint2*>(&Bs[k][tx*4]);
      float av[4] = {bfu(ua.x),bfu(ua.x>>16),bfu(ua.y),bfu(ua.y>>16)};
      float bv[4] = {bfu(ub.x),bfu(ub.x>>16),bfu(ub.y),bfu(ub.y>>16)};
      #pragma unroll
      for (int i=0;i<4;++i)
        #pragma unroll
        for (int j=0;j<4;++j) acc[i][j] += av[i]*bv[j];
    }
  }
  int qb = q0 + ty*4, sb = s0 + tx*4;
  #pragma unroll
  for (int i=0;i<2;++i)
    #pragma unroll
    for (int j=0;j<2;++j){
      int qp = (qb>>1) + i, sp = (sb>>1) + j;
      if (qp < 98 && sp < 98){
        float v = 0.25f*(acc[2*i][2*j]+acc[2*i][2*j+1]+acc[2*i+1][2*j]+acc[2*i+1][2*j+1]);
        P[((size_t)b*98 + qp)*98 + sp] = v;
      }
    }
}

// ---------------- J: fc2 head (square -> 9604->256 gelu -> 1) ----------------
// grid 64 (8 batch rows each), block 256
__global__ __launch_bounds__(256) void k_fc2(
    const float* __restrict__ P, const float* __restrict__ w1,
    const float* __restrict__ b1, const float* __restrict__ w2,
    const float* __restrict__ b2, float* __restrict__ outp){
  __shared__ float p2[8][257];
  int b0 = blockIdx.x*8, tid = threadIdx.x;
  float acc[8];
  #pragma unroll
  for (int r=0;r<8;++r) acc[r]=0.f;
  for (int ic = 0; ic < 9604; ic += 256){
    __syncthreads();
    int iend = min(256, 9604-ic);
    #pragma unroll
    for (int l=0;l<8;++l){
      float v = 0.f;
      if (tid < iend) v = P[(size_t)(b0+l)*9604 + ic + tid];
      p2[l][tid] = v*v;
    }
    __syncthreads();
    for (int ii=0; ii<iend; ++ii){
      float w = w1[(size_t)(ic+ii)*256 + tid];
      #pragma unroll
      for (int r=0;r<8;++r) acc[r] += p2[r][ii]*w;
    }
  }
  float wv = w2[tid];
  __syncthreads();
  #pragma unroll
  for (int r=0;r<8;++r) p2[r][tid] = geluf(acc[r] + b1[tid]) * wv;
  __syncthreads();
  if (tid < 8){
    float s = b2[0];
    for (int j=0;j<256;++j) s += p2[tid][j];
    outp[b0+tid] = s;
  }
}

// ---------------- launch ----------------
extern "C" void kernel_launch(void* const* d_in, const int* in_sizes, int n_in,
                              void* d_out, int out_size, void* d_ws, size_t ws_size,
                              hipStream_t stream){
  const float* fq  = (const float*)d_in[0];
  const float* fs  = (const float*)d_in[1];
  const float* fqs = (const float*)d_in[2];
  const float* fss = (const float*)d_in[3];
  const float* fc1_w1 = (const float*)d_in[4];
  const float* fc1_b1 = (const float*)d_in[5];
  const float* fc1_w2 = (const float*)d_in[6];
  const float* fc1_b2 = (const float*)d_in[7];
  const float* ln1_g = (const float*)d_in[8];
  const float* ln1_b = (const float*)d_in[9];
  const float* fc3_w1 = (const float*)d_in[10];
  const float* fc3_b1 = (const float*)d_in[11];
  const float* fc3_w2 = (const float*)d_in[12];
  const float* fc3_b2 = (const float*)d_in[13];
  const float* ln3_g = (const float*)d_in[14];
  const float* ln3_b = (const float*)d_in[15];
  const float* fc4_w1 = (const float*)d_in[16];
  const float* fc4_b1 = (const float*)d_in[17];
  const float* fc4_w2 = (const float*)d_in[18];
  const float* fc4_b2 = (const float*)d_in[19];
  const float* ln4_g = (const float*)d_in[20];
  const float* ln4_b = (const float*)d_in[21];
  const float* fc2_w1 = (const float*)d_in[22];
  const float* fc2_b1 = (const float*)d_in[23];
  const float* fc2_w2 = (const float*)d_in[24];
  const float* fc2_b2 = (const float*)d_in[25];
  const float* cs_w1 = (const float*)d_in[26];
  const float* cs_b1 = (const float*)d_in[27];
  const float* cs_w2 = (const float*)d_in[28];
  const float* cs_b2 = (const float*)d_in[29];
  float* out = (float*)d_out;
  char* ws = (char*)d_ws;
  // ws layout (bytes):
  //   meanb f32 @0           (3,145,728)
  //   mlp1  f32 @3145728     (3,145,728)
  //   mu    f32 @6291456     (1,613,824)
  //   rstd  f32 @7905280     (1,613,824)
  //   h3    bf16 @9519104    (50,331,648)  [reused for h4 bf16 38.5MB, then P f32 19.7MB]
  //   Qb    bf16 @59850752   (77,070,336)
  //   Sb    bf16 @136921088  (77,070,336)
  //   total 213,991,424 B
  float* meanb  = (float*)(ws + 0);
  float* mlp1   = (float*)(ws + 3145728);
  float* mu     = (float*)(ws + 6291456);
  float* rstd   = (float*)(ws + 7905280);
  ushort_t* h3  = (ushort_t*)(ws + 9519104);
  ushort_t* h4  = (ushort_t*)(ws + 9519104);  // overlays h3 (dead after 2nd fc3b)
  float* P      = (float*)(ws + 9519104);     // overlays h4 (dead after fc4b)
  ushort_t* Qb  = (ushort_t*)(ws + 59850752);
  ushort_t* Sb  = (ushort_t*)(ws + 136921088);

  k_mean<<<2048, 384, 0, stream>>>(fq, fs, fqs, fss, meanb);
  k_fc1<<<2048, 384, 0, stream>>>(meanb, fc1_w1, fc1_b1, fc1_w2, fc1_b2, mlp1);
  k_stats<<<100864, 256, 0, stream>>>(fq, fs, fqs, fss, mlp1, mu, rstd);
  k_class<<<1024, 384, 0, stream>>>(fq, fs, mlp1, mu, rstd, ln1_g, ln1_b, out);
  k_cosine<<<512, 384, 0, stream>>>(cs_w1, cs_b1, cs_w2, cs_b2, out);
  k_fc3a<<<3072, 256, 0, stream>>>(fqs, mlp1 + (size_t)2*512*384, mu + 2*100864, rstd + 2*100864,
                                   ln1_g, ln1_b, fc3_w1, fc3_b1, h3);
  k_fc3b<<<3072, 256, 0, stream>>>(h3, fc3_w2, fc3_b2, ln3_g, ln3_b, Qb);
  k_fc3a<<<3072, 256, 0, stream>>>(fss, mlp1 + (size_t)3*512*384, mu + 3*100864, rstd + 3*100864,
                                   ln1_g, ln1_b, fc3_w1, fc3_b1, h3);
  k_fc3b<<<3072, 256, 0, stream>>>(h3, fc3_w2, fc3_b2, ln3_g, ln3_b, Sb);
  k_fc4a<<<13312, 256, 0, stream>>>(fq, fs, mlp1, mu, rstd, ln1_g, ln1_b, Qb, Sb,
                                    fc4_w1, fc4_b1, h4);
  k_fc4b<<<13312, 256, 0, stream>>>(h4, fc4_w2, fc4_b2, ln4_g, ln4_b, out, Qb, Sb);
  k_sim<<<8192, 256, 0, stream>>>(Qb, Sb, P);
  k_fc2<<<64, 256, 0, stream>>>(P, fc2_w1, fc2_b1, fc2_w2, fc2_b2, out);
}

// Round 3
// 32567.862 us; speedup vs baseline: 1.0160x; 1.0055x over previous
//
#include <hip/hip_runtime.h>
#include <math.h>

typedef unsigned short ushort_t;

// ---------------- helpers ----------------
__device__ __forceinline__ float geluf(float x){
  return 0.5f*x*(1.0f+erff(x*0.70710678118654752440f));
}
__device__ __forceinline__ float bfu(unsigned int u){
  union { unsigned int i; float f; } v; v.i = (u & 0xffffu) << 16; return v.f;
}
__device__ __forceinline__ unsigned short f2b(float f){
  union { float f; unsigned int i; } v; v.f = f;
  unsigned int r = v.i + 0x7fffu + ((v.i >> 16) & 1u);
  return (unsigned short)(r >> 16);
}

// Problem constants
// B=512, N=197, C=384, T=196 image tokens
// d_out layout (floats): out[512] | cosine[512] | query_class[512*384] | support_class[512*384]

// ---------------- A: token means (per tensor, b, c) ----------------
__global__ __launch_bounds__(384) void k_mean(
    const float* __restrict__ x0, const float* __restrict__ x1,
    const float* __restrict__ x2, const float* __restrict__ x3,
    float* __restrict__ meanb){
  int s = blockIdx.x >> 9, b = blockIdx.x & 511, c = threadIdx.x;
  const float* x = (s==0)?x0:(s==1)?x1:(s==2)?x2:x3;
  const float* p = x + ((size_t)b*197)*384 + c;
  float acc = 0.f;
  #pragma unroll 4
  for (int t=0;t<197;++t) acc += p[(size_t)t*384];
  meanb[((size_t)s*512+b)*384+c] = acc*(1.0f/197.0f);
}

// ---------------- B: fc1 tiny MLP on means ----------------
__global__ __launch_bounds__(384) void k_fc1(
    const float* __restrict__ meanb, const float* __restrict__ w1,
    const float* __restrict__ b1, const float* __restrict__ w2,
    const float* __restrict__ b2, float* __restrict__ mlp1){
  __shared__ float ms[384];
  __shared__ float hs[96];
  int row = blockIdx.x, tid = threadIdx.x;
  ms[tid] = meanb[(size_t)row*384 + tid];
  __syncthreads();
  if (tid < 96){
    float a = b1[tid];
    for (int c=0;c<384;++c) a += ms[c]*w1[c*96+tid];
    hs[tid] = geluf(a);
  }
  __syncthreads();
  float a = b2[tid];
  for (int j=0;j<96;++j) a += hs[j]*w2[j*384+tid];
  mlp1[(size_t)row*384 + tid] = a;
}

// ---------------- C: per-row LN stats of (x + mlp1) ----------------
__global__ __launch_bounds__(256) void k_stats(
    const float* __restrict__ x0, const float* __restrict__ x1,
    const float* __restrict__ x2, const float* __restrict__ x3,
    const float* __restrict__ mlp1, float* __restrict__ mu, float* __restrict__ rstd){
  int lane = threadIdx.x & 63, w = threadIdx.x >> 6;
  int row = blockIdx.x*4 + w;           // rows = 4*512*197 = 403456, grid exact
  int s = row / 100864;
  int rr = row % 100864;
  int b = rr / 197, t = rr % 197;
  const float* x = (s==0)?x0:(s==1)?x1:(s==2)?x2:x3;
  const float* xp = x + ((size_t)b*197 + t)*384;
  const float* mp = mlp1 + ((size_t)s*512 + b)*384;
  float sum=0.f, sq=0.f;
  for (int i=lane;i<384;i+=64){ float v = xp[i]+mp[i]; sum+=v; sq+=v*v; }
  #pragma unroll
  for (int o=32;o;o>>=1){ sum+=__shfl_down(sum,o); sq+=__shfl_down(sq,o); }
  if (lane==0){
    float m = sum*(1.0f/384.0f);
    mu[row] = m;
    rstd[row] = rsqrtf(sq*(1.0f/384.0f) - m*m + 1e-5f);
  }
}

// ---------------- D: class token rows -> d_out ----------------
__global__ __launch_bounds__(384) void k_class(
    const float* __restrict__ x0, const float* __restrict__ x1,
    const float* __restrict__ mlp1, const float* __restrict__ mu,
    const float* __restrict__ rstd, const float* __restrict__ g1,
    const float* __restrict__ bb1, float* __restrict__ dout){
  int s = blockIdx.x >> 9, b = blockIdx.x & 511, c = threadIdx.x;
  const float* x = s ? x1 : x0;
  int srow = (s*512 + b)*197;
  float v = x[((size_t)b*197)*384 + c] + mlp1[((size_t)s*512+b)*384 + c];
  float y = (v - mu[srow])*rstd[srow]*g1[c] + bb1[c];
  dout[1024 + (size_t)s*196608 + (size_t)b*384 + c] = y;
}

// ---------------- E: cosine head on class tokens ----------------
__global__ __launch_bounds__(384) void k_cosine(
    const float* __restrict__ w1, const float* __restrict__ b1,
    const float* __restrict__ w2, const float* __restrict__ b2,
    float* __restrict__ dout){
  __shared__ float qrow[384], srw[384], hq[96], hs[96];
  __shared__ float rd0[384], rd1[384], rd2[384];
  int b = blockIdx.x, tid = threadIdx.x;
  qrow[tid] = dout[1024   + (size_t)b*384 + tid];
  srw[tid]  = dout[197632 + (size_t)b*384 + tid];
  __syncthreads();
  if (tid < 96){
    float a = b1[tid];
    for (int c=0;c<384;++c) a += qrow[c]*w1[c*96+tid];
    hq[tid] = geluf(a);
  } else if (tid < 192){
    int j = tid - 96;
    float a = b1[j];
    for (int c=0;c<384;++c) a += srw[c]*w1[c*96+j];
    hs[j] = geluf(a);
  }
  __syncthreads();
  float qx = b2[tid], sy = b2[tid];
  for (int j=0;j<96;++j){ qx += hq[j]*w2[j*384+tid]; sy += hs[j]*w2[j*384+tid]; }
  rd0[tid] = qx*sy; rd1[tid] = qx*qx; rd2[tid] = sy*sy;
  __syncthreads();
  if (tid < 64){
    float d=0.f,nq=0.f,ns=0.f;
    for (int i=tid;i<384;i+=64){ d+=rd0[i]; nq+=rd1[i]; ns+=rd2[i]; }
    #pragma unroll
    for (int o=32;o;o>>=1){ d+=__shfl_down(d,o); nq+=__shfl_down(nq,o); ns+=__shfl_down(ns,o); }
    if (tid==0) dout[512 + b] = d / (fmaxf(sqrtf(nq),1e-8f)*fmaxf(sqrtf(ns),1e-8f));
  }
}

// ---------------- F: fc3 GEMM1  h = gelu(X^T @ w1 + b1) ----------------
// grid 512*6 (b, c-tile of 64), block 256
__global__ __launch_bounds__(256) void k_fc3a(
    const float* __restrict__ x, const float* __restrict__ mlp1t,
    const float* __restrict__ mut, const float* __restrict__ rstdt,
    const float* __restrict__ g1, const float* __restrict__ bb1,
    const float* __restrict__ w1, const float* __restrict__ b1,
    ushort_t* __restrict__ h3){
  __shared__ ushort_t A[196][64];     // bf16 LN'd x^T tile [t][c]
  __shared__ ushort_t W[196][128];    // bf16 w1
  int b = blockIdx.x/6, ct = blockIdx.x%6, c0 = ct*64;
  int tid = threadIdx.x;
  for (int i = tid; i < 196*128; i += 256) (&W[0][0])[i] = f2b(w1[i]);
  {
    int cl = tid & 63, tg = tid >> 6;
    const float* mrow = mlp1t + (size_t)b*384;
    for (int t = tg; t < 196; t += 4){
      int c = c0 + cl;
      int srow = b*197 + (t+1);
      float v = x[((size_t)b*197 + (t+1))*384 + c] + mrow[c];
      float y = (v - mut[srow])*rstdt[srow]*g1[c] + bb1[c];
      A[t][cl] = f2b(y);
    }
  }
  __syncthreads();
  int ci = tid >> 4, ji = tid & 15;
  float acc[4][8];
  #pragma unroll
  for (int i=0;i<4;++i)
    #pragma unroll
    for (int k=0;k<8;++k) acc[i][k]=0.f;
  for (int t = 0; t < 196; ++t){
    uint2 av = *reinterpret_cast<const uint2*>(&A[t][ci*4]);
    uint4 wv = *reinterpret_cast<const uint4*>(&W[t][ji*8]);
    float a[4] = { bfu(av.x), bfu(av.x>>16), bfu(av.y), bfu(av.y>>16) };
    float w[8] = { bfu(wv.x), bfu(wv.x>>16), bfu(wv.y), bfu(wv.y>>16),
                   bfu(wv.z), bfu(wv.z>>16), bfu(wv.w), bfu(wv.w>>16) };
    #pragma unroll
    for (int i=0;i<4;++i)
      #pragma unroll
      for (int k=0;k<8;++k) acc[i][k] += a[i]*w[k];
  }
  #pragma unroll
  for (int i=0;i<4;++i){
    int c = c0 + ci*4 + i;
    unsigned short hv[8];
    #pragma unroll
    for (int k=0;k<8;++k){
      int j = ji*8+k;
      hv[k] = f2b(geluf(acc[i][k] + b1[j]));
    }
    uint4 pk;
    pk.x = hv[0] | ((unsigned)hv[1]<<16);
    pk.y = hv[2] | ((unsigned)hv[3]<<16);
    pk.z = hv[4] | ((unsigned)hv[5]<<16);
    pk.w = hv[6] | ((unsigned)hv[7]<<16);
    *reinterpret_cast<uint4*>(&h3[((size_t)b*384 + c)*128 + ji*8]) = pk;
  }
}

// ---------------- G: fc3 GEMM2 + LN over t', write transposed ----------------
// grid 512*6 (b, c-tile of 64), block 256
__global__ __launch_bounds__(256) void k_fc3b(
    const ushort_t* __restrict__ h3, const float* __restrict__ w2,
    const float* __restrict__ b2, const float* __restrict__ g3,
    const float* __restrict__ b3, ushort_t* __restrict__ Qout){
  __shared__ ushort_t H[128][68];     // bf16 h transposed [j][c], padded
  __shared__ ushort_t W[128][196];    // bf16 w2
  __shared__ float red[2][64][16];
  int b = blockIdx.x/6, ct = blockIdx.x%6, c0 = ct*64;
  int tid = threadIdx.x;
  for (int i = tid; i < 64*32; i += 256){
    int c = i >> 5, jq = i & 31;
    uint2 v = *reinterpret_cast<const uint2*>(&h3[((size_t)b*384 + c0 + c)*128 + jq*4]);
    H[jq*4+0][c] = (ushort_t)(v.x & 0xffffu);
    H[jq*4+1][c] = (ushort_t)(v.x >> 16);
    H[jq*4+2][c] = (ushort_t)(v.y & 0xffffu);
    H[jq*4+3][c] = (ushort_t)(v.y >> 16);
  }
  for (int i = tid; i < 128*196; i += 256) (&W[0][0])[i] = f2b(w2[i]);
  __syncthreads();
  int cg = tid >> 4, tg = tid & 15;
  float acc[4][14];
  #pragma unroll
  for (int i=0;i<4;++i)
    #pragma unroll
    for (int k=0;k<14;++k) acc[i][k]=0.f;
  for (int j = 0; j < 128; ++j){
    uint2 hv = *reinterpret_cast<const uint2*>(&H[j][cg*4]);
    float h[4] = { bfu(hv.x), bfu(hv.x>>16), bfu(hv.y), bfu(hv.y>>16) };
    #pragma unroll
    for (int k = 0; k < 7; ++k){
      if (k < 6 || tg < 2){    // k=6 valid only for tg<2 (t'=192..195)
        unsigned int wv = *reinterpret_cast<const unsigned int*>(&W[j][2*tg + 32*k]);
        float w0 = bfu(wv), w1v = bfu(wv>>16);
        #pragma unroll
        for (int i=0;i<4;++i){
          acc[i][2*k]   += h[i]*w0;
          acc[i][2*k+1] += h[i]*w1v;
        }
      }
    }
  }
  // bias + LN stats over t' (per c-row)
  float psum[4]={0,0,0,0}, psq[4]={0,0,0,0};
  #pragma unroll
  for (int sl=0; sl<14; ++sl){
    int t = 2*tg + 32*(sl>>1) + (sl&1);
    if (t < 196){
      #pragma unroll
      for (int i=0;i<4;++i){
        float y = acc[i][sl] + b2[t];
        acc[i][sl] = y;
        psum[i] += y; psq[i] += y*y;
      }
    }
  }
  #pragma unroll
  for (int i=0;i<4;++i){ red[0][cg*4+i][tg]=psum[i]; red[1][cg*4+i][tg]=psq[i]; }
  __syncthreads();
  float mu4[4], rs4[4];
  #pragma unroll
  for (int i=0;i<4;++i){
    float ssv=0.f, qv=0.f;
    #pragma unroll
    for (int u=0;u<16;++u){ ssv += red[0][cg*4+i][u]; qv += red[1][cg*4+i][u]; }
    float m = ssv*(1.0f/196.0f);
    mu4[i]=m; rs4[i]=rsqrtf(qv*(1.0f/196.0f)-m*m+1e-5f);
  }
  #pragma unroll
  for (int sl=0; sl<14; ++sl){
    int t = 2*tg + 32*(sl>>1) + (sl&1);
    if (t < 196){
      float g = g3[t], bb = b3[t];
      unsigned short o0 = f2b((acc[0][sl]-mu4[0])*rs4[0]*g + bb);
      unsigned short o1 = f2b((acc[1][sl]-mu4[1])*rs4[1]*g + bb);
      unsigned short o2 = f2b((acc[2][sl]-mu4[2])*rs4[2]*g + bb);
      unsigned short o3 = f2b((acc[3][sl]-mu4[3])*rs4[3]*g + bb);
      uint2 pk; pk.x = o0 | ((unsigned)o1<<16); pk.y = o2 | ((unsigned)o3<<16);
      *reinterpret_cast<uint2*>(&Qout[((size_t)b*196 + t)*384 + c0 + cg*4]) = pk;
    }
  }
}

// ---------------- H1: fc4 stage A — Z = LN1(x)*Qin, h = gelu(Z@w1+b1) ----------------
// grid 2*512*13 (s, b, t-tile of 16), block 256
// Phase-1 invariants (m1, g1, b1ln) staged in LDS (overlaid on WS, dead until
// first GEMM staging barrier) so the Z loop has only 2 global streams — the
// 7-stream version spilled past 256 VGPR (round-1/2 profiles: 50 GB scratch).
__global__ __launch_bounds__(256) void k_fc4a(
    const float* __restrict__ xq, const float* __restrict__ xs,
    const float* __restrict__ mlp1, const float* __restrict__ mu,
    const float* __restrict__ rstd,
    const float* __restrict__ g1, const float* __restrict__ bb1,
    const ushort_t* __restrict__ Qq_in, const ushort_t* __restrict__ Qs_in,
    const float* __restrict__ w1, const float* __restrict__ b1,
    ushort_t* __restrict__ h4){
  __shared__ float Z[16][385];
  __shared__ float WS[64*96];
  __shared__ float mus[16], rss[16];
  int bid = blockIdx.x;
  int s = bid / (512*13); int r = bid % (512*13); int b = r/13; int tt0 = (r%13)*16;
  const float* x = s ? xs : xq;
  const ushort_t* Qin = s ? Qs_in : Qq_in;
  const float* m1 = mlp1 + ((size_t)s*512 + b)*384;
  int tid = threadIdx.x;
  // stage per-c invariants into WS (dead until GEMM staging) + per-t stats
  float* m1s = WS; float* g1s = WS + 384; float* b1s = WS + 768;
  for (int i = tid; i < 384; i += 256){ m1s[i] = m1[i]; g1s[i] = g1[i]; b1s[i] = bb1[i]; }
  if (tid < 16){
    int t = tt0 + tid;
    float muv = 0.f, rsv = 0.f;
    if (t < 196){ int srow = (s*512 + b)*197 + (t+1); muv = mu[srow]; rsv = rstd[srow]; }
    mus[tid] = muv; rss[tid] = rsv;
  }
  __syncthreads();
  // phase 1: Z = LN1(x) * Qin elementwise (2 global streams only)
  #pragma unroll 4
  for (int e = 0; e < 24; ++e){
    int idx = e*256 + tid;
    int tt = idx / 384, c = idx - tt*384;
    int t = tt0 + tt;
    float z = 0.f;
    if (t < 196){
      float v = x[((size_t)b*197 + (t+1))*384 + c] + m1s[c];
      float qi = (v - mus[tt])*rss[tt]*g1s[c] + b1s[c];
      float qis = bfu((unsigned)Qin[((size_t)b*196 + t)*384 + c]);
      z = qi*qis;
    }
    Z[tt][c] = z;
  }
  // phase 2: GEMM1 (384 -> 96), gelu -> h4 (bf16)
  int tt = tid >> 4, lg = tid & 15;
  float a1[6] = {0,0,0,0,0,0};
  for (int cb = 0; cb < 6; ++cb){                 // runtime loop: do NOT unroll
    __syncthreads();
    for (int i = tid; i < 64*96; i += 256) WS[i] = w1[(size_t)(cb*64 + i/96)*96 + (i%96)];
    __syncthreads();
    for (int cc = 0; cc < 64; ++cc){
      float z = Z[tt][cb*64+cc];
      #pragma unroll
      for (int m=0;m<6;++m) a1[m] += z * WS[cc*96 + lg + 16*m];
    }
  }
  int t = tt0 + tt;
  if (t < 196){
    #pragma unroll
    for (int m=0;m<6;++m){
      int j = lg + 16*m;
      h4[((size_t)((size_t)s*512+b)*196 + t)*96 + j] = f2b(geluf(a1[m] + b1[j]));
    }
  }
}

// ---------------- H2: fc4 stage B — y = h@w2+b2, LN4, +0.5*class, l2norm, center ----------------
// grid 2*512*13 (s, b, t-tile of 16), block 256
__global__ __launch_bounds__(256) void k_fc4b(
    const ushort_t* __restrict__ h4,
    const float* __restrict__ w2, const float* __restrict__ b2,
    const float* __restrict__ g4, const float* __restrict__ bb4,
    const float* __restrict__ dout,
    ushort_t* __restrict__ Qq_out, ushort_t* __restrict__ Qs_out){
  __shared__ float Hs[16][97];
  __shared__ float WS[24*384];
  int bid = blockIdx.x;
  int s = bid / (512*13); int r = bid % (512*13); int b = r/13; int tt0 = (r%13)*16;
  ushort_t* Qo = s ? Qs_out : Qq_out;
  int tid = threadIdx.x;
  // load h tile (invalid rows -> 0; their lanes never write out)
  for (int idx = tid; idx < 16*96; idx += 256){
    int tt = idx / 96, j = idx % 96;
    int t = tt0 + tt;
    float v = 0.f;
    if (t < 196) v = bfu((unsigned)h4[((size_t)((size_t)s*512+b)*196 + t)*96 + j]);
    Hs[tt][j] = v;
  }
  int tt = tid >> 4, lg = tid & 15;
  float a2[24];
  #pragma unroll
  for (int k=0;k<24;++k) a2[k]=0.f;
  for (int n = 0; n < 4; ++n){                    // runtime loop: do NOT unroll
    __syncthreads();
    for (int i = tid; i < 24*384; i += 256) WS[i] = w2[(size_t)(n*24 + i/384)*384 + (i%384)];
    __syncthreads();
    for (int jj = 0; jj < 24; ++jj){
      float h = Hs[tt][n*24+jj];
      #pragma unroll
      for (int k=0;k<24;++k) a2[k] += h * WS[jj*384 + lg + 16*k];
    }
  }
  // epilogue: bias, LN4, +0.5*class, l2norm, center; 16-lane shuffle reductions
  int t = tt0 + tt; bool valid = (t < 196);
  float sum=0.f, sq=0.f;
  #pragma unroll
  for (int k=0;k<24;++k){
    int c = lg + 16*k;
    a2[k] += b2[c];
    sum += a2[k]; sq += a2[k]*a2[k];
  }
  #pragma unroll
  for (int o=1;o<16;o<<=1){ sum += __shfl_xor(sum,o); sq += __shfl_xor(sq,o); }
  float m4 = sum*(1.0f/384.0f);
  float rs = rsqrtf(sq*(1.0f/384.0f) - m4*m4 + 1e-5f);
  const float* cls = dout + 1024 + (size_t)s*196608 + (size_t)b*384;
  float s2 = 0.f;
  #pragma unroll
  for (int k=0;k<24;++k){
    int c = lg + 16*k;
    float v = (a2[k]-m4)*rs*g4[c] + bb4[c];
    v += 0.5f*cls[c];
    a2[k] = v; s2 += v*v;
  }
  #pragma unroll
  for (int o=1;o<16;o<<=1) s2 += __shfl_xor(s2,o);
  float inv = 1.0f/fmaxf(sqrtf(s2), 1e-12f);
  float sm = 0.f;
  #pragma unroll
  for (int k=0;k<24;++k){ a2[k]*=inv; sm += a2[k]; }
  #pragma unroll
  for (int o=1;o<16;o<<=1) sm += __shfl_xor(sm,o);
  sm *= (1.0f/384.0f);
  if (valid){
    #pragma unroll
    for (int k=0;k<24;++k) Qo[((size_t)b*196 + t)*384 + lg + 16*k] = f2b(a2[k]-sm);
  }
}

// ---------------- I: batched einsum + fused 2x2 pooling ----------------
// grid 512*16 (b, qt, st), block 256
__global__ __launch_bounds__(256) void k_sim(
    const ushort_t* __restrict__ Q, const ushort_t* __restrict__ S,
    float* __restrict__ P){
  __shared__ ushort_t As[32][68];
  __shared__ ushort_t Bs[32][68];
  int bx = blockIdx.x;
  int b = bx >> 4, qt = (bx >> 2) & 3, st = bx & 3;
  int q0 = qt*64, s0 = st*64;
  int tid = threadIdx.x, ty = tid >> 4, tx = tid & 15;
  float acc[4][4];
  #pragma unroll
  for (int i=0;i<4;++i)
    #pragma unroll
    for (int j=0;j<4;++j) acc[i][j]=0.f;
  for (int kc = 0; kc < 384; kc += 32){
    __syncthreads();
    #pragma unroll
    for (int l = 0; l < 2; ++l){
      int idx = tid + l*256;
      int rr = idx >> 3, g = idx & 7;
      uint2 va; va.x=0u; va.y=0u;
      uint2 vb; vb.x=0u; vb.y=0u;
      int q = q0 + rr, ss = s0 + rr;
      if (q  < 196) va = *reinterpret_cast<const uint2*>(&Q[((size_t)b*196+q )*384 + kc + g*4]);
      if (ss < 196) vb = *reinterpret_cast<const uint2*>(&S[((size_t)b*196+ss)*384 + kc + g*4]);
      As[g*4+0][rr] = (ushort_t)(va.x&0xffffu); As[g*4+1][rr]=(ushort_t)(va.x>>16);
      As[g*4+2][rr] = (ushort_t)(va.y&0xffffu); As[g*4+3][rr]=(ushort_t)(va.y>>16);
      Bs[g*4+0][rr] = (ushort_t)(vb.x&0xffffu); Bs[g*4+1][rr]=(ushort_t)(vb.x>>16);
      Bs[g*4+2][rr] = (ushort_t)(vb.y&0xffffu); Bs[g*4+3][rr]=(ushort_t)(vb.y>>16);
    }
    __syncthreads();
    for (int k = 0; k < 32; ++k){
      uint2 ua = *reinterpret_cast<const uint2*>(&As[k][ty*4]);
      uint2 ub = *reinterpret_cast<const uint2*>(&Bs[k][tx*4]);
      float av[4] = {bfu(ua.x),bfu(ua.x>>16),bfu(ua.y),bfu(ua.y>>16)};
      float bv[4] = {bfu(ub.x),bfu(ub.x>>16),bfu(ub.y),bfu(ub.y>>16)};
      #pragma unroll
      for (int i=0;i<4;++i)
        #pragma unroll
        for (int j=0;j<4;++j) acc[i][j] += av[i]*bv[j];
    }
  }
  int qb = q0 + ty*4, sb = s0 + tx*4;
  #pragma unroll
  for (int i=0;i<2;++i)
    #pragma unroll
    for (int j=0;j<2;++j){
      int qp = (qb>>1) + i, sp = (sb>>1) + j;
      if (qp < 98 && sp < 98){
        float v = 0.25f*(acc[2*i][2*j]+acc[2*i][2*j+1]+acc[2*i+1][2*j]+acc[2*i+1][2*j+1]);
        P[((size_t)b*98 + qp)*98 + sp] = v;
      }
    }
}

// ---------------- J: fc2 head (square -> 9604->256 gelu -> 1) ----------------
// grid 64 (8 batch rows each), block 256
__global__ __launch_bounds__(256) void k_fc2(
    const float* __restrict__ P, const float* __restrict__ w1,
    const float* __restrict__ b1, const float* __restrict__ w2,
    const float* __restrict__ b2, float* __restrict__ outp){
  __shared__ float p2[8][257];
  int b0 = blockIdx.x*8, tid = threadIdx.x;
  float acc[8];
  #pragma unroll
  for (int r=0;r<8;++r) acc[r]=0.f;
  for (int ic = 0; ic < 9604; ic += 256){
    __syncthreads();
    int iend = min(256, 9604-ic);
    #pragma unroll
    for (int l=0;l<8;++l){
      float v = 0.f;
      if (tid < iend) v = P[(size_t)(b0+l)*9604 + ic + tid];
      p2[l][tid] = v*v;
    }
    __syncthreads();
    for (int ii=0; ii<iend; ++ii){
      float w = w1[(size_t)(ic+ii)*256 + tid];
      #pragma unroll
      for (int r=0;r<8;++r) acc[r] += p2[r][ii]*w;
    }
  }
  float wv = w2[tid];
  __syncthreads();
  #pragma unroll
  for (int r=0;r<8;++r) p2[r][tid] = geluf(acc[r] + b1[tid]) * wv;
  __syncthreads();
  if (tid < 8){
    float s = b2[0];
    for (int j=0;j<256;++j) s += p2[tid][j];
    outp[b0+tid] = s;
  }
}

// ---------------- launch ----------------
extern "C" void kernel_launch(void* const* d_in, const int* in_sizes, int n_in,
                              void* d_out, int out_size, void* d_ws, size_t ws_size,
                              hipStream_t stream){
  const float* fq  = (const float*)d_in[0];
  const float* fs  = (const float*)d_in[1];
  const float* fqs = (const float*)d_in[2];
  const float* fss = (const float*)d_in[3];
  const float* fc1_w1 = (const float*)d_in[4];
  const float* fc1_b1 = (const float*)d_in[5];
  const float* fc1_w2 = (const float*)d_in[6];
  const float* fc1_b2 = (const float*)d_in[7];
  const float* ln1_g = (const float*)d_in[8];
  const float* ln1_b = (const float*)d_in[9];
  const float* fc3_w1 = (const float*)d_in[10];
  const float* fc3_b1 = (const float*)d_in[11];
  const float* fc3_w2 = (const float*)d_in[12];
  const float* fc3_b2 = (const float*)d_in[13];
  const float* ln3_g = (const float*)d_in[14];
  const float* ln3_b = (const float*)d_in[15];
  const float* fc4_w1 = (const float*)d_in[16];
  const float* fc4_b1 = (const float*)d_in[17];
  const float* fc4_w2 = (const float*)d_in[18];
  const float* fc4_b2 = (const float*)d_in[19];
  const float* ln4_g = (const float*)d_in[20];
  const float* ln4_b = (const float*)d_in[21];
  const float* fc2_w1 = (const float*)d_in[22];
  const float* fc2_b1 = (const float*)d_in[23];
  const float* fc2_w2 = (const float*)d_in[24];
  const float* fc2_b2 = (const float*)d_in[25];
  const float* cs_w1 = (const float*)d_in[26];
  const float* cs_b1 = (const float*)d_in[27];
  const float* cs_w2 = (const float*)d_in[28];
  const float* cs_b2 = (const float*)d_in[29];
  float* out = (float*)d_out;
  char* ws = (char*)d_ws;
  // ws layout (bytes):
  //   meanb f32 @0           (3,145,728)
  //   mlp1  f32 @3145728     (3,145,728)
  //   mu    f32 @6291456     (1,613,824)
  //   rstd  f32 @7905280     (1,613,824)
  //   h3    bf16 @9519104    (50,331,648)  [reused for h4 bf16 38.5MB, then P f32 19.7MB]
  //   Qb    bf16 @59850752   (77,070,336)
  //   Sb    bf16 @136921088  (77,070,336)
  //   total 213,991,424 B
  float* meanb  = (float*)(ws + 0);
  float* mlp1   = (float*)(ws + 3145728);
  float* mu     = (float*)(ws + 6291456);
  float* rstd   = (float*)(ws + 7905280);
  ushort_t* h3  = (ushort_t*)(ws + 9519104);
  ushort_t* h4  = (ushort_t*)(ws + 9519104);  // overlays h3 (dead after 2nd fc3b)
  float* P      = (float*)(ws + 9519104);     // overlays h4 (dead after fc4b)
  ushort_t* Qb  = (ushort_t*)(ws + 59850752);
  ushort_t* Sb  = (ushort_t*)(ws + 136921088);

  k_mean<<<2048, 384, 0, stream>>>(fq, fs, fqs, fss, meanb);
  k_fc1<<<2048, 384, 0, stream>>>(meanb, fc1_w1, fc1_b1, fc1_w2, fc1_b2, mlp1);
  k_stats<<<100864, 256, 0, stream>>>(fq, fs, fqs, fss, mlp1, mu, rstd);
  k_class<<<1024, 384, 0, stream>>>(fq, fs, mlp1, mu, rstd, ln1_g, ln1_b, out);
  k_cosine<<<512, 384, 0, stream>>>(cs_w1, cs_b1, cs_w2, cs_b2, out);
  k_fc3a<<<3072, 256, 0, stream>>>(fqs, mlp1 + (size_t)2*512*384, mu + 2*100864, rstd + 2*100864,
                                   ln1_g, ln1_b, fc3_w1, fc3_b1, h3);
  k_fc3b<<<3072, 256, 0, stream>>>(h3, fc3_w2, fc3_b2, ln3_g, ln3_b, Qb);
  k_fc3a<<<3072, 256, 0, stream>>>(fss, mlp1 + (size_t)3*512*384, mu + 3*100864, rstd + 3*100864,
                                   ln1_g, ln1_b, fc3_w1, fc3_b1, h3);
  k_fc3b<<<3072, 256, 0, stream>>>(h3, fc3_w2, fc3_b2, ln3_g, ln3_b, Sb);
  k_fc4a<<<13312, 256, 0, stream>>>(fq, fs, mlp1, mu, rstd, ln1_g, ln1_b, Qb, Sb,
                                    fc4_w1, fc4_b1, h4);
  k_fc4b<<<13312, 256, 0, stream>>>(h4, fc4_w2, fc4_b2, ln4_g, ln4_b, out, Qb, Sb);
  k_sim<<<8192, 256, 0, stream>>>(Qb, Sb, P);
  k_fc2<<<64, 256, 0, stream>>>(P, fc2_w1, fc2_b1, fc2_w2, fc2_b2, out);
}

// Round 4
// 3903.924 us; speedup vs baseline: 8.4756x; 8.3423x over previous
//
#include <hip/hip_runtime.h>
#include <math.h>

typedef unsigned short ushort_t;

// ---------------- helpers ----------------
__device__ __forceinline__ float geluf(float x){
  return 0.5f*x*(1.0f+erff(x*0.70710678118654752440f));
}
__device__ __forceinline__ float bfu(unsigned int u){
  union { unsigned int i; float f; } v; v.i = (u & 0xffffu) << 16; return v.f;
}
__device__ __forceinline__ unsigned int f2b(float f){
  union { float f; unsigned int i; } v; v.f = f;
  unsigned int r = v.i + 0x7fffu + ((v.i >> 16) & 1u);
  return (r >> 16);
}

// Problem constants
// B=512, N=197, C=384, T=196 image tokens
// d_out layout (floats): out[512] | cosine[512] | query_class[512*384] | support_class[512*384]

// ---------------- A: token means (per tensor, b, c) ----------------
__global__ __launch_bounds__(384) void k_mean(
    const float* __restrict__ x0, const float* __restrict__ x1,
    const float* __restrict__ x2, const float* __restrict__ x3,
    float* __restrict__ meanb){
  int s = blockIdx.x >> 9, b = blockIdx.x & 511, c = threadIdx.x;
  const float* x = (s==0)?x0:(s==1)?x1:(s==2)?x2:x3;
  const float* p = x + ((size_t)b*197)*384 + c;
  float acc = 0.f;
  #pragma unroll 4
  for (int t=0;t<197;++t) acc += p[(size_t)t*384];
  meanb[((size_t)s*512+b)*384+c] = acc*(1.0f/197.0f);
}

// ---------------- B: fc1 tiny MLP on means ----------------
__global__ __launch_bounds__(384) void k_fc1(
    const float* __restrict__ meanb, const float* __restrict__ w1,
    const float* __restrict__ b1, const float* __restrict__ w2,
    const float* __restrict__ b2, float* __restrict__ mlp1){
  __shared__ float ms[384];
  __shared__ float hs[96];
  int row = blockIdx.x, tid = threadIdx.x;
  ms[tid] = meanb[(size_t)row*384 + tid];
  __syncthreads();
  if (tid < 96){
    float a = b1[tid];
    for (int c=0;c<384;++c) a += ms[c]*w1[c*96+tid];
    hs[tid] = geluf(a);
  }
  __syncthreads();
  float a = b2[tid];
  for (int j=0;j<96;++j) a += hs[j]*w2[j*384+tid];
  mlp1[(size_t)row*384 + tid] = a;
}

// ---------------- C: per-row LN stats of (x + mlp1) ----------------
__global__ __launch_bounds__(256) void k_stats(
    const float* __restrict__ x0, const float* __restrict__ x1,
    const float* __restrict__ x2, const float* __restrict__ x3,
    const float* __restrict__ mlp1, float* __restrict__ mu, float* __restrict__ rstd){
  int lane = threadIdx.x & 63, w = threadIdx.x >> 6;
  int row = blockIdx.x*4 + w;           // rows = 4*512*197 = 403456, grid exact
  int s = row / 100864;
  int rr = row % 100864;
  int b = rr / 197, t = rr % 197;
  const float* x = (s==0)?x0:(s==1)?x1:(s==2)?x2:x3;
  const float* xp = x + ((size_t)b*197 + t)*384;
  const float* mp = mlp1 + ((size_t)s*512 + b)*384;
  float sum=0.f, sq=0.f;
  for (int i=lane;i<384;i+=64){ float v = xp[i]+mp[i]; sum+=v; sq+=v*v; }
  #pragma unroll
  for (int o=32;o;o>>=1){ sum+=__shfl_down(sum,o); sq+=__shfl_down(sq,o); }
  if (lane==0){
    float m = sum*(1.0f/384.0f);
    mu[row] = m;
    rstd[row] = rsqrtf(sq*(1.0f/384.0f) - m*m + 1e-5f);
  }
}

// ---------------- D: class token rows -> d_out ----------------
__global__ __launch_bounds__(384) void k_class(
    const float* __restrict__ x0, const float* __restrict__ x1,
    const float* __restrict__ mlp1, const float* __restrict__ mu,
    const float* __restrict__ rstd, const float* __restrict__ g1,
    const float* __restrict__ bb1, float* __restrict__ dout){
  int s = blockIdx.x >> 9, b = blockIdx.x & 511, c = threadIdx.x;
  const float* x = s ? x1 : x0;
  int srow = (s*512 + b)*197;
  float v = x[((size_t)b*197)*384 + c] + mlp1[((size_t)s*512+b)*384 + c];
  float y = (v - mu[srow])*rstd[srow]*g1[c] + bb1[c];
  dout[1024 + (size_t)s*196608 + (size_t)b*384 + c] = y;
}

// ---------------- E: cosine head on class tokens ----------------
__global__ __launch_bounds__(384) void k_cosine(
    const float* __restrict__ w1, const float* __restrict__ b1,
    const float* __restrict__ w2, const float* __restrict__ b2,
    float* __restrict__ dout){
  __shared__ float qrow[384], srw[384], hq[96], hs[96];
  __shared__ float rd0[384], rd1[384], rd2[384];
  int b = blockIdx.x, tid = threadIdx.x;
  qrow[tid] = dout[1024   + (size_t)b*384 + tid];
  srw[tid]  = dout[197632 + (size_t)b*384 + tid];
  __syncthreads();
  if (tid < 96){
    float a = b1[tid];
    for (int c=0;c<384;++c) a += qrow[c]*w1[c*96+tid];
    hq[tid] = geluf(a);
  } else if (tid < 192){
    int j = tid - 96;
    float a = b1[j];
    for (int c=0;c<384;++c) a += srw[c]*w1[c*96+j];
    hs[j] = geluf(a);
  }
  __syncthreads();
  float qx = b2[tid], sy = b2[tid];
  for (int j=0;j<96;++j){ qx += hq[j]*w2[j*384+tid]; sy += hs[j]*w2[j*384+tid]; }
  rd0[tid] = qx*sy; rd1[tid] = qx*qx; rd2[tid] = sy*sy;
  __syncthreads();
  if (tid < 64){
    float d=0.f,nq=0.f,ns=0.f;
    for (int i=tid;i<384;i+=64){ d+=rd0[i]; nq+=rd1[i]; ns+=rd2[i]; }
    #pragma unroll
    for (int o=32;o;o>>=1){ d+=__shfl_down(d,o); nq+=__shfl_down(nq,o); ns+=__shfl_down(ns,o); }
    if (tid==0) dout[512 + b] = d / (fmaxf(sqrtf(nq),1e-8f)*fmaxf(sqrtf(ns),1e-8f));
  }
}

// ---------------- F: fc3 GEMM1  h = gelu(X^T @ w1 + b1) ----------------
// grid 512*6 (b, c-tile of 64), block 256
__global__ __launch_bounds__(256) void k_fc3a(
    const float* __restrict__ x, const float* __restrict__ mlp1t,
    const float* __restrict__ mut, const float* __restrict__ rstdt,
    const float* __restrict__ g1, const float* __restrict__ bb1,
    const float* __restrict__ w1, const float* __restrict__ b1,
    ushort_t* __restrict__ h3){
  __shared__ ushort_t A[196][64];     // bf16 LN'd x^T tile [t][c]
  __shared__ ushort_t W[196][128];    // bf16 w1
  int b = blockIdx.x/6, ct = blockIdx.x%6, c0 = ct*64;
  int tid = threadIdx.x;
  for (int i = tid; i < 196*128; i += 256) (&W[0][0])[i] = (ushort_t)f2b(w1[i]);
  {
    int cl = tid & 63, tg = tid >> 6;
    const float* mrow = mlp1t + (size_t)b*384;
    for (int t = tg; t < 196; t += 4){
      int c = c0 + cl;
      int srow = b*197 + (t+1);
      float v = x[((size_t)b*197 + (t+1))*384 + c] + mrow[c];
      float y = (v - mut[srow])*rstdt[srow]*g1[c] + bb1[c];
      A[t][cl] = (ushort_t)f2b(y);
    }
  }
  __syncthreads();
  int ci = tid >> 4, ji = tid & 15;
  float acc[4][8];
  #pragma unroll
  for (int i=0;i<4;++i)
    #pragma unroll
    for (int k=0;k<8;++k) acc[i][k]=0.f;
  for (int t = 0; t < 196; ++t){
    uint2 av = *reinterpret_cast<const uint2*>(&A[t][ci*4]);
    uint4 wv = *reinterpret_cast<const uint4*>(&W[t][ji*8]);
    float a[4] = { bfu(av.x), bfu(av.x>>16), bfu(av.y), bfu(av.y>>16) };
    float w[8] = { bfu(wv.x), bfu(wv.x>>16), bfu(wv.y), bfu(wv.y>>16),
                   bfu(wv.z), bfu(wv.z>>16), bfu(wv.w), bfu(wv.w>>16) };
    #pragma unroll
    for (int i=0;i<4;++i)
      #pragma unroll
      for (int k=0;k<8;++k) acc[i][k] += a[i]*w[k];
  }
  #pragma unroll
  for (int i=0;i<4;++i){
    int c = c0 + ci*4 + i;
    unsigned int hv[8];
    #pragma unroll
    for (int k=0;k<8;++k){
      int j = ji*8+k;
      hv[k] = f2b(geluf(acc[i][k] + b1[j]));
    }
    uint4 pk;
    pk.x = hv[0] | (hv[1]<<16);
    pk.y = hv[2] | (hv[3]<<16);
    pk.z = hv[4] | (hv[5]<<16);
    pk.w = hv[6] | (hv[7]<<16);
    *reinterpret_cast<uint4*>(&h3[((size_t)b*384 + c)*128 + ji*8]) = pk;
  }
}

// ---------------- G: fc3 GEMM2 + LN over t', write transposed ----------------
// grid 512*6 (b, c-tile of 64), block 256
__global__ __launch_bounds__(256) void k_fc3b(
    const ushort_t* __restrict__ h3, const float* __restrict__ w2,
    const float* __restrict__ b2, const float* __restrict__ g3,
    const float* __restrict__ b3, ushort_t* __restrict__ Qout){
  __shared__ ushort_t H[128][68];     // bf16 h transposed [j][c], padded
  __shared__ ushort_t W[128][196];    // bf16 w2
  __shared__ float red[2][64][16];
  int b = blockIdx.x/6, ct = blockIdx.x%6, c0 = ct*64;
  int tid = threadIdx.x;
  for (int i = tid; i < 64*32; i += 256){
    int c = i >> 5, jq = i & 31;
    uint2 v = *reinterpret_cast<const uint2*>(&h3[((size_t)b*384 + c0 + c)*128 + jq*4]);
    H[jq*4+0][c] = (ushort_t)(v.x & 0xffffu);
    H[jq*4+1][c] = (ushort_t)(v.x >> 16);
    H[jq*4+2][c] = (ushort_t)(v.y & 0xffffu);
    H[jq*4+3][c] = (ushort_t)(v.y >> 16);
  }
  for (int i = tid; i < 128*196; i += 256) (&W[0][0])[i] = (ushort_t)f2b(w2[i]);
  __syncthreads();
  int cg = tid >> 4, tg = tid & 15;
  float acc[4][14];
  #pragma unroll
  for (int i=0;i<4;++i)
    #pragma unroll
    for (int k=0;k<14;++k) acc[i][k]=0.f;
  for (int j = 0; j < 128; ++j){
    uint2 hv = *reinterpret_cast<const uint2*>(&H[j][cg*4]);
    float h[4] = { bfu(hv.x), bfu(hv.x>>16), bfu(hv.y), bfu(hv.y>>16) };
    #pragma unroll
    for (int k = 0; k < 7; ++k){
      if (k < 6 || tg < 2){    // k=6 valid only for tg<2 (t'=192..195)
        unsigned int wv = *reinterpret_cast<const unsigned int*>(&W[j][2*tg + 32*k]);
        float w0 = bfu(wv), w1v = bfu(wv>>16);
        #pragma unroll
        for (int i=0;i<4;++i){
          acc[i][2*k]   += h[i]*w0;
          acc[i][2*k+1] += h[i]*w1v;
        }
      }
    }
  }
  // bias + LN stats over t' (per c-row)
  float psum[4]={0,0,0,0}, psq[4]={0,0,0,0};
  #pragma unroll
  for (int sl=0; sl<14; ++sl){
    int t = 2*tg + 32*(sl>>1) + (sl&1);
    if (t < 196){
      #pragma unroll
      for (int i=0;i<4;++i){
        float y = acc[i][sl] + b2[t];
        acc[i][sl] = y;
        psum[i] += y; psq[i] += y*y;
      }
    }
  }
  #pragma unroll
  for (int i=0;i<4;++i){ red[0][cg*4+i][tg]=psum[i]; red[1][cg*4+i][tg]=psq[i]; }
  __syncthreads();
  float mu4[4], rs4[4];
  #pragma unroll
  for (int i=0;i<4;++i){
    float ssv=0.f, qv=0.f;
    #pragma unroll
    for (int u=0;u<16;++u){ ssv += red[0][cg*4+i][u]; qv += red[1][cg*4+i][u]; }
    float m = ssv*(1.0f/196.0f);
    mu4[i]=m; rs4[i]=rsqrtf(qv*(1.0f/196.0f)-m*m+1e-5f);
  }
  #pragma unroll
  for (int sl=0; sl<14; ++sl){
    int t = 2*tg + 32*(sl>>1) + (sl&1);
    if (t < 196){
      float g = g3[t], bb = b3[t];
      unsigned int o0 = f2b((acc[0][sl]-mu4[0])*rs4[0]*g + bb);
      unsigned int o1 = f2b((acc[1][sl]-mu4[1])*rs4[1]*g + bb);
      unsigned int o2 = f2b((acc[2][sl]-mu4[2])*rs4[2]*g + bb);
      unsigned int o3 = f2b((acc[3][sl]-mu4[3])*rs4[3]*g + bb);
      uint2 pk; pk.x = o0 | (o1<<16); pk.y = o2 | (o3<<16);
      *reinterpret_cast<uint2*>(&Qout[((size_t)b*196 + t)*384 + c0 + cg*4]) = pk;
    }
  }
}

// ---------------- H1: fc4 stage A (one s-half per launch) ----------------
// grid 512*13 (b, t-tile of 16), block 256.
// Z = LN1(x)*Qin as bf16 in LDS (vectorized float4/uint2 loads, branchless tail),
// then GEMM1 384->96 with bf16 weight chunks in LDS (k_fc3a idiom).
// Rounds 1-3: the scalar mixed-stream variant spilled to 256 VGPR (50 GB scratch).
__global__ __launch_bounds__(256, 2) void k_fc4a(
    const float* __restrict__ x,         // fq or fs
    const float* __restrict__ m1_base,   // mlp1 + s*512*384
    const float* __restrict__ mu_s,      // mu + s*100864
    const float* __restrict__ rstd_s,    // rstd + s*100864
    const float* __restrict__ g1, const float* __restrict__ bln1,
    const ushort_t* __restrict__ Qin,    // Qb or Sb
    const float* __restrict__ w1, const float* __restrict__ b1mlp,
    ushort_t* __restrict__ h4s){         // h4 + s*512*196*96
  __shared__ ushort_t Zs[16][392];       // bf16 Z tile, padded stride
  __shared__ ushort_t Wc[96*96];         // bf16 w1 chunk [k][j]
  __shared__ float m1s[384], g1s[384], b1s[384];
  __shared__ float mus[16], rss[16];
  int bid = blockIdx.x;
  int b = bid/13, tt0 = (bid%13)*16;
  int tid = threadIdx.x;
  const float* m1 = m1_base + (size_t)b*384;
  for (int i = tid; i < 384; i += 256){ m1s[i] = m1[i]; g1s[i] = g1[i]; b1s[i] = bln1[i]; }
  if (tid < 16){
    int t = tt0 + tid; int tc = t < 196 ? t : 195;
    int srow = b*197 + tc + 1;
    mus[tid] = mu_s[srow]; rss[tid] = rstd_s[srow];
  }
  __syncthreads();
  // phase 1: vectorized Z build (6 float4 + 6 uint2 loads per thread)
  for (int e = 0; e < 6; ++e){
    int v = e*256 + tid;
    int row = v/96, col4 = v - row*96;   // row<16, col4<96 (4 channels each)
    int t = tt0 + row; int tc = t < 196 ? t : 195;
    float valid = (t < 196) ? 1.f : 0.f;
    float4 xv = *reinterpret_cast<const float4*>(&x[((size_t)b*197 + tc + 1)*384 + col4*4]);
    uint2 qv = *reinterpret_cast<const uint2*>(&Qin[((size_t)b*196 + tc)*384 + col4*4]);
    float muv = mus[row], rsv = rss[row];
    int c = col4*4;
    float z0 = (((xv.x + m1s[c+0]) - muv)*rsv*g1s[c+0] + b1s[c+0]) * bfu(qv.x)      * valid;
    float z1 = (((xv.y + m1s[c+1]) - muv)*rsv*g1s[c+1] + b1s[c+1]) * bfu(qv.x>>16)  * valid;
    float z2 = (((xv.z + m1s[c+2]) - muv)*rsv*g1s[c+2] + b1s[c+2]) * bfu(qv.y)      * valid;
    float z3 = (((xv.w + m1s[c+3]) - muv)*rsv*g1s[c+3] + b1s[c+3]) * bfu(qv.y>>16)  * valid;
    uint2 pk; pk.x = f2b(z0) | (f2b(z1)<<16); pk.y = f2b(z2) | (f2b(z3)<<16);
    *reinterpret_cast<uint2*>(&Zs[row][col4*4]) = pk;
  }
  // phase 2: GEMM1 (K=384 in 4 chunks of 96), thread = (t-row tt, 6 j's at lg*6)
  int tt = tid >> 4, lg = tid & 15;
  float a1[6] = {0,0,0,0,0,0};
  for (int kc = 0; kc < 4; ++kc){
    __syncthreads();
    for (int i = tid; i < 96*96; i += 256) Wc[i] = (ushort_t)f2b(w1[kc*9216 + i]);
    __syncthreads();
    for (int k = 0; k < 96; ++k){
      float z = bfu(Zs[tt][kc*96 + k]);
      const unsigned int* wrow = reinterpret_cast<const unsigned int*>(&Wc[k*96 + lg*6]);
      unsigned int w0 = wrow[0], w1v = wrow[1], w2v = wrow[2];
      a1[0] += z*bfu(w0); a1[1] += z*bfu(w0>>16);
      a1[2] += z*bfu(w1v); a1[3] += z*bfu(w1v>>16);
      a1[4] += z*bfu(w2v); a1[5] += z*bfu(w2v>>16);
    }
  }
  int t = tt0 + tt;
  if (t < 196){
    int j0 = lg*6;
    unsigned int o0 = f2b(geluf(a1[0]+b1mlp[j0+0])) | (f2b(geluf(a1[1]+b1mlp[j0+1]))<<16);
    unsigned int o1 = f2b(geluf(a1[2]+b1mlp[j0+2])) | (f2b(geluf(a1[3]+b1mlp[j0+3]))<<16);
    unsigned int o2 = f2b(geluf(a1[4]+b1mlp[j0+4])) | (f2b(geluf(a1[5]+b1mlp[j0+5]))<<16);
    unsigned int* dst = reinterpret_cast<unsigned int*>(&h4s[((size_t)b*196 + t)*96 + j0]);
    dst[0] = o0; dst[1] = o1; dst[2] = o2;
  }
}

// ---------------- H2: fc4 stage B (one s-half per launch) ----------------
// grid 512*13, block 256: y = h@w2+b2, LN4, +0.5*class, l2norm, center
__global__ __launch_bounds__(256) void k_fc4b(
    const ushort_t* __restrict__ h4s,    // h4 + s*512*196*96
    const float* __restrict__ w2, const float* __restrict__ b2,
    const float* __restrict__ g4, const float* __restrict__ bb4,
    const float* __restrict__ cls_base,  // dout + 1024 + s*196608
    ushort_t* __restrict__ Qo){          // Qb or Sb
  __shared__ float Hs[16][97];
  __shared__ float WS[24*384];
  int bid = blockIdx.x;
  int b = bid/13, tt0 = (bid%13)*16;
  int tid = threadIdx.x;
  // load h tile (invalid rows -> 0; their lanes never write out)
  for (int idx = tid; idx < 16*48; idx += 256){
    int trow = idx / 48, cu = idx % 48;
    int t = tt0 + trow; int tc = t < 196 ? t : 195;
    float valid = (t < 196) ? 1.f : 0.f;
    unsigned int hv = *reinterpret_cast<const unsigned int*>(&h4s[((size_t)b*196 + tc)*96 + cu*2]);
    Hs[trow][cu*2+0] = bfu(hv) * valid;
    Hs[trow][cu*2+1] = bfu(hv>>16) * valid;
  }
  int tt = tid >> 4, lg = tid & 15;
  float a2[24];
  #pragma unroll
  for (int k=0;k<24;++k) a2[k]=0.f;
  for (int n = 0; n < 4; ++n){
    __syncthreads();
    for (int i = tid; i < 24*384; i += 256) WS[i] = w2[(size_t)n*9216 + i];
    __syncthreads();
    for (int jj = 0; jj < 24; ++jj){
      float h = Hs[tt][n*24+jj];
      #pragma unroll
      for (int k=0;k<24;++k) a2[k] += h * WS[jj*384 + lg + 16*k];
    }
  }
  // epilogue: bias, LN4, +0.5*class, l2norm, center; 16-lane shuffle reductions
  int t = tt0 + tt; bool valid = (t < 196);
  float sum=0.f, sq=0.f;
  #pragma unroll
  for (int k=0;k<24;++k){
    int c = lg + 16*k;
    a2[k] += b2[c];
    sum += a2[k]; sq += a2[k]*a2[k];
  }
  #pragma unroll
  for (int o=1;o<16;o<<=1){ sum += __shfl_xor(sum,o); sq += __shfl_xor(sq,o); }
  float m4 = sum*(1.0f/384.0f);
  float rs = rsqrtf(sq*(1.0f/384.0f) - m4*m4 + 1e-5f);
  const float* cls = cls_base + (size_t)b*384;
  float s2 = 0.f;
  #pragma unroll
  for (int k=0;k<24;++k){
    int c = lg + 16*k;
    float v = (a2[k]-m4)*rs*g4[c] + bb4[c];
    v += 0.5f*cls[c];
    a2[k] = v; s2 += v*v;
  }
  #pragma unroll
  for (int o=1;o<16;o<<=1) s2 += __shfl_xor(s2,o);
  float inv = 1.0f/fmaxf(sqrtf(s2), 1e-12f);
  float sm = 0.f;
  #pragma unroll
  for (int k=0;k<24;++k){ a2[k]*=inv; sm += a2[k]; }
  #pragma unroll
  for (int o=1;o<16;o<<=1) sm += __shfl_xor(sm,o);
  sm *= (1.0f/384.0f);
  if (valid){
    #pragma unroll
    for (int k=0;k<24;++k) Qo[((size_t)b*196 + t)*384 + lg + 16*k] = (ushort_t)f2b(a2[k]-sm);
  }
}

// ---------------- I: batched einsum + fused 2x2 pooling ----------------
// grid 512*16 (b, qt, st), block 256
__global__ __launch_bounds__(256) void k_sim(
    const ushort_t* __restrict__ Q, const ushort_t* __restrict__ S,
    float* __restrict__ P){
  __shared__ ushort_t As[32][68];
  __shared__ ushort_t Bs[32][68];
  int bx = blockIdx.x;
  int b = bx >> 4, qt = (bx >> 2) & 3, st = bx & 3;
  int q0 = qt*64, s0 = st*64;
  int tid = threadIdx.x, ty = tid >> 4, tx = tid & 15;
  float acc[4][4];
  #pragma unroll
  for (int i=0;i<4;++i)
    #pragma unroll
    for (int j=0;j<4;++j) acc[i][j]=0.f;
  for (int kc = 0; kc < 384; kc += 32){
    __syncthreads();
    #pragma unroll
    for (int l = 0; l < 2; ++l){
      int idx = tid + l*256;
      int rr = idx >> 3, g = idx & 7;
      uint2 va; va.x=0u; va.y=0u;
      uint2 vb; vb.x=0u; vb.y=0u;
      int q = q0 + rr, ss = s0 + rr;
      if (q  < 196) va = *reinterpret_cast<const uint2*>(&Q[((size_t)b*196+q )*384 + kc + g*4]);
      if (ss < 196) vb = *reinterpret_cast<const uint2*>(&S[((size_t)b*196+ss)*384 + kc + g*4]);
      As[g*4+0][rr] = (ushort_t)(va.x&0xffffu); As[g*4+1][rr]=(ushort_t)(va.x>>16);
      As[g*4+2][rr] = (ushort_t)(va.y&0xffffu); As[g*4+3][rr]=(ushort_t)(va.y>>16);
      Bs[g*4+0][rr] = (ushort_t)(vb.x&0xffffu); Bs[g*4+1][rr]=(ushort_t)(vb.x>>16);
      Bs[g*4+2][rr] = (ushort_t)(vb.y&0xffffu); Bs[g*4+3][rr]=(ushort_t)(vb.y>>16);
    }
    __syncthreads();
    for (int k = 0; k < 32; ++k){
      uint2 ua = *reinterpret_cast<const uint2*>(&As[k][ty*4]);
      uint2 ub = *reinterpret_cast<const uint2*>(&Bs[k][tx*4]);
      float av[4] = {bfu(ua.x),bfu(ua.x>>16),bfu(ua.y),bfu(ua.y>>16)};
      float bv[4] = {bfu(ub.x),bfu(ub.x>>16),bfu(ub.y),bfu(ub.y>>16)};
      #pragma unroll
      for (int i=0;i<4;++i)
        #pragma unroll
        for (int j=0;j<4;++j) acc[i][j] += av[i]*bv[j];
    }
  }
  int qb = q0 + ty*4, sb = s0 + tx*4;
  #pragma unroll
  for (int i=0;i<2;++i)
    #pragma unroll
    for (int j=0;j<2;++j){
      int qp = (qb>>1) + i, sp = (sb>>1) + j;
      if (qp < 98 && sp < 98){
        float v = 0.25f*(acc[2*i][2*j]+acc[2*i][2*j+1]+acc[2*i+1][2*j]+acc[2*i+1][2*j+1]);
        P[((size_t)b*98 + qp)*98 + sp] = v;
      }
    }
}

// ---------------- J: fc2 head (square -> 9604->256 gelu -> 1) ----------------
// grid 64 (8 batch rows each), block 256
__global__ __launch_bounds__(256) void k_fc2(
    const float* __restrict__ P, const float* __restrict__ w1,
    const float* __restrict__ b1, const float* __restrict__ w2,
    const float* __restrict__ b2, float* __restrict__ outp){
  __shared__ float p2[8][257];
  int b0 = blockIdx.x*8, tid = threadIdx.x;
  float acc[8];
  #pragma unroll
  for (int r=0;r<8;++r) acc[r]=0.f;
  for (int ic = 0; ic < 9604; ic += 256){
    __syncthreads();
    int iend = min(256, 9604-ic);
    #pragma unroll
    for (int l=0;l<8;++l){
      float v = 0.f;
      if (tid < iend) v = P[(size_t)(b0+l)*9604 + ic + tid];
      p2[l][tid] = v*v;
    }
    __syncthreads();
    for (int ii=0; ii<iend; ++ii){
      float w = w1[(size_t)(ic+ii)*256 + tid];
      #pragma unroll
      for (int r=0;r<8;++r) acc[r] += p2[r][ii]*w;
    }
  }
  float wv = w2[tid];
  __syncthreads();
  #pragma unroll
  for (int r=0;r<8;++r) p2[r][tid] = geluf(acc[r] + b1[tid]) * wv;
  __syncthreads();
  if (tid < 8){
    float s = b2[0];
    for (int j=0;j<256;++j) s += p2[tid][j];
    outp[b0+tid] = s;
  }
}

// ---------------- launch ----------------
extern "C" void kernel_launch(void* const* d_in, const int* in_sizes, int n_in,
                              void* d_out, int out_size, void* d_ws, size_t ws_size,
                              hipStream_t stream){
  const float* fq  = (const float*)d_in[0];
  const float* fs  = (const float*)d_in[1];
  const float* fqs = (const float*)d_in[2];
  const float* fss = (const float*)d_in[3];
  const float* fc1_w1 = (const float*)d_in[4];
  const float* fc1_b1 = (const float*)d_in[5];
  const float* fc1_w2 = (const float*)d_in[6];
  const float* fc1_b2 = (const float*)d_in[7];
  const float* ln1_g = (const float*)d_in[8];
  const float* ln1_b = (const float*)d_in[9];
  const float* fc3_w1 = (const float*)d_in[10];
  const float* fc3_b1 = (const float*)d_in[11];
  const float* fc3_w2 = (const float*)d_in[12];
  const float* fc3_b2 = (const float*)d_in[13];
  const float* ln3_g = (const float*)d_in[14];
  const float* ln3_b = (const float*)d_in[15];
  const float* fc4_w1 = (const float*)d_in[16];
  const float* fc4_b1 = (const float*)d_in[17];
  const float* fc4_w2 = (const float*)d_in[18];
  const float* fc4_b2 = (const float*)d_in[19];
  const float* ln4_g = (const float*)d_in[20];
  const float* ln4_b = (const float*)d_in[21];
  const float* fc2_w1 = (const float*)d_in[22];
  const float* fc2_b1 = (const float*)d_in[23];
  const float* fc2_w2 = (const float*)d_in[24];
  const float* fc2_b2 = (const float*)d_in[25];
  const float* cs_w1 = (const float*)d_in[26];
  const float* cs_b1 = (const float*)d_in[27];
  const float* cs_w2 = (const float*)d_in[28];
  const float* cs_b2 = (const float*)d_in[29];
  float* out = (float*)d_out;
  char* ws = (char*)d_ws;
  // ws layout (bytes):
  //   meanb f32 @0           (3,145,728)
  //   mlp1  f32 @3145728     (3,145,728)
  //   mu    f32 @6291456     (1,613,824)
  //   rstd  f32 @7905280     (1,613,824)
  //   h3    bf16 @9519104    (50,331,648)  [reused for h4 bf16 38.5MB, then P f32 19.7MB]
  //   Qb    bf16 @59850752   (77,070,336)
  //   Sb    bf16 @136921088  (77,070,336)
  //   total 213,991,424 B
  float* meanb  = (float*)(ws + 0);
  float* mlp1   = (float*)(ws + 3145728);
  float* mu     = (float*)(ws + 6291456);
  float* rstd   = (float*)(ws + 7905280);
  ushort_t* h3  = (ushort_t*)(ws + 9519104);
  ushort_t* h4  = (ushort_t*)(ws + 9519104);  // overlays h3 (dead after 2nd fc3b)
  float* P      = (float*)(ws + 9519104);     // overlays h4 (dead after fc4b)
  ushort_t* Qb  = (ushort_t*)(ws + 59850752);
  ushort_t* Sb  = (ushort_t*)(ws + 136921088);
  const size_t H4S = (size_t)512*196*96;      // per-s-half h4 elements

  k_mean<<<2048, 384, 0, stream>>>(fq, fs, fqs, fss, meanb);
  k_fc1<<<2048, 384, 0, stream>>>(meanb, fc1_w1, fc1_b1, fc1_w2, fc1_b2, mlp1);
  k_stats<<<100864, 256, 0, stream>>>(fq, fs, fqs, fss, mlp1, mu, rstd);
  k_class<<<1024, 384, 0, stream>>>(fq, fs, mlp1, mu, rstd, ln1_g, ln1_b, out);
  k_cosine<<<512, 384, 0, stream>>>(cs_w1, cs_b1, cs_w2, cs_b2, out);
  k_fc3a<<<3072, 256, 0, stream>>>(fqs, mlp1 + (size_t)2*512*384, mu + 2*100864, rstd + 2*100864,
                                   ln1_g, ln1_b, fc3_w1, fc3_b1, h3);
  k_fc3b<<<3072, 256, 0, stream>>>(h3, fc3_w2, fc3_b2, ln3_g, ln3_b, Qb);
  k_fc3a<<<3072, 256, 0, stream>>>(fss, mlp1 + (size_t)3*512*384, mu + 3*100864, rstd + 3*100864,
                                   ln1_g, ln1_b, fc3_w1, fc3_b1, h3);
  k_fc3b<<<3072, 256, 0, stream>>>(h3, fc3_w2, fc3_b2, ln3_g, ln3_b, Sb);
  // fc4 stage A: q then s (pre-offset pointers, no runtime s-select)
  k_fc4a<<<6656, 256, 0, stream>>>(fq, mlp1, mu, rstd, ln1_g, ln1_b,
                                   Qb, fc4_w1, fc4_b1, h4);
  k_fc4a<<<6656, 256, 0, stream>>>(fs, mlp1 + (size_t)512*384, mu + 100864, rstd + 100864,
                                   ln1_g, ln1_b, Sb, fc4_w1, fc4_b1, h4 + H4S);
  // fc4 stage B: q then s (Qb/Sb overwritten in place after their last read)
  k_fc4b<<<6656, 256, 0, stream>>>(h4,       fc4_w2, fc4_b2, ln4_g, ln4_b, out + 1024,          Qb);
  k_fc4b<<<6656, 256, 0, stream>>>(h4 + H4S, fc4_w2, fc4_b2, ln4_g, ln4_b, out + 1024 + 196608, Sb);
  k_sim<<<8192, 256, 0, stream>>>(Qb, Sb, P);
  k_fc2<<<64, 256, 0, stream>>>(P, fc2_w1, fc2_b1, fc2_w2, fc2_b2, out);
}

// Round 5
// 2939.644 us; speedup vs baseline: 11.2558x; 1.3280x over previous
//
#include <hip/hip_runtime.h>
#include <math.h>

typedef unsigned short ushort_t;

// ---------------- helpers ----------------
__device__ __forceinline__ float geluf(float x){
  return 0.5f*x*(1.0f+erff(x*0.70710678118654752440f));
}
__device__ __forceinline__ float bfu(unsigned int u){
  union { unsigned int i; float f; } v; v.i = (u & 0xffffu) << 16; return v.f;
}
__device__ __forceinline__ unsigned int f2b(float f){
  union { float f; unsigned int i; } v; v.f = f;
  unsigned int r = v.i + 0x7fffu + ((v.i >> 16) & 1u);
  return (r >> 16);
}

// Problem constants
// B=512, N=197, C=384, T=196 image tokens
// d_out layout (floats): out[512] | cosine[512] | query_class[512*384] | support_class[512*384]

// ---------------- A: token means (per tensor, b, c) ----------------
__global__ __launch_bounds__(384) void k_mean(
    const float* __restrict__ x0, const float* __restrict__ x1,
    const float* __restrict__ x2, const float* __restrict__ x3,
    float* __restrict__ meanb){
  int s = blockIdx.x >> 9, b = blockIdx.x & 511, c = threadIdx.x;
  const float* x = (s==0)?x0:(s==1)?x1:(s==2)?x2:x3;
  const float* p = x + ((size_t)b*197)*384 + c;
  float acc = 0.f;
  #pragma unroll 4
  for (int t=0;t<197;++t) acc += p[(size_t)t*384];
  meanb[((size_t)s*512+b)*384+c] = acc*(1.0f/197.0f);
}

// ---------------- B: fc1 tiny MLP on means ----------------
__global__ __launch_bounds__(384) void k_fc1(
    const float* __restrict__ meanb, const float* __restrict__ w1,
    const float* __restrict__ b1, const float* __restrict__ w2,
    const float* __restrict__ b2, float* __restrict__ mlp1){
  __shared__ float ms[384];
  __shared__ float hs[96];
  int row = blockIdx.x, tid = threadIdx.x;
  ms[tid] = meanb[(size_t)row*384 + tid];
  __syncthreads();
  if (tid < 96){
    float a = b1[tid];
    for (int c=0;c<384;++c) a += ms[c]*w1[c*96+tid];
    hs[tid] = geluf(a);
  }
  __syncthreads();
  float a = b2[tid];
  for (int j=0;j<96;++j) a += hs[j]*w2[j*384+tid];
  mlp1[(size_t)row*384 + tid] = a;
}

// ---------------- C: per-row LN stats of (x + mlp1) ----------------
__global__ __launch_bounds__(256) void k_stats(
    const float* __restrict__ x0, const float* __restrict__ x1,
    const float* __restrict__ x2, const float* __restrict__ x3,
    const float* __restrict__ mlp1, float* __restrict__ mu, float* __restrict__ rstd){
  int lane = threadIdx.x & 63, w = threadIdx.x >> 6;
  int row = blockIdx.x*4 + w;           // rows = 4*512*197 = 403456, grid exact
  int s = row / 100864;
  int rr = row % 100864;
  int b = rr / 197, t = rr % 197;
  const float* x = (s==0)?x0:(s==1)?x1:(s==2)?x2:x3;
  const float* xp = x + ((size_t)b*197 + t)*384;
  const float* mp = mlp1 + ((size_t)s*512 + b)*384;
  float sum=0.f, sq=0.f;
  for (int i=lane;i<384;i+=64){ float v = xp[i]+mp[i]; sum+=v; sq+=v*v; }
  #pragma unroll
  for (int o=32;o;o>>=1){ sum+=__shfl_down(sum,o); sq+=__shfl_down(sq,o); }
  if (lane==0){
    float m = sum*(1.0f/384.0f);
    mu[row] = m;
    rstd[row] = rsqrtf(sq*(1.0f/384.0f) - m*m + 1e-5f);
  }
}

// ---------------- D: class token rows -> d_out ----------------
__global__ __launch_bounds__(384) void k_class(
    const float* __restrict__ x0, const float* __restrict__ x1,
    const float* __restrict__ mlp1, const float* __restrict__ mu,
    const float* __restrict__ rstd, const float* __restrict__ g1,
    const float* __restrict__ bb1, float* __restrict__ dout){
  int s = blockIdx.x >> 9, b = blockIdx.x & 511, c = threadIdx.x;
  const float* x = s ? x1 : x0;
  int srow = (s*512 + b)*197;
  float v = x[((size_t)b*197)*384 + c] + mlp1[((size_t)s*512+b)*384 + c];
  float y = (v - mu[srow])*rstd[srow]*g1[c] + bb1[c];
  dout[1024 + (size_t)s*196608 + (size_t)b*384 + c] = y;
}

// ---------------- E: cosine head on class tokens ----------------
__global__ __launch_bounds__(384) void k_cosine(
    const float* __restrict__ w1, const float* __restrict__ b1,
    const float* __restrict__ w2, const float* __restrict__ b2,
    float* __restrict__ dout){
  __shared__ float qrow[384], srw[384], hq[96], hs[96];
  __shared__ float rd0[384], rd1[384], rd2[384];
  int b = blockIdx.x, tid = threadIdx.x;
  qrow[tid] = dout[1024   + (size_t)b*384 + tid];
  srw[tid]  = dout[197632 + (size_t)b*384 + tid];
  __syncthreads();
  if (tid < 96){
    float a = b1[tid];
    for (int c=0;c<384;++c) a += qrow[c]*w1[c*96+tid];
    hq[tid] = geluf(a);
  } else if (tid < 192){
    int j = tid - 96;
    float a = b1[j];
    for (int c=0;c<384;++c) a += srw[c]*w1[c*96+j];
    hs[j] = geluf(a);
  }
  __syncthreads();
  float qx = b2[tid], sy = b2[tid];
  for (int j=0;j<96;++j){ qx += hq[j]*w2[j*384+tid]; sy += hs[j]*w2[j*384+tid]; }
  rd0[tid] = qx*sy; rd1[tid] = qx*qx; rd2[tid] = sy*sy;
  __syncthreads();
  if (tid < 64){
    float d=0.f,nq=0.f,ns=0.f;
    for (int i=tid;i<384;i+=64){ d+=rd0[i]; nq+=rd1[i]; ns+=rd2[i]; }
    #pragma unroll
    for (int o=32;o;o>>=1){ d+=__shfl_down(d,o); nq+=__shfl_down(nq,o); ns+=__shfl_down(ns,o); }
    if (tid==0) dout[512 + b] = d / (fmaxf(sqrtf(nq),1e-8f)*fmaxf(sqrtf(ns),1e-8f));
  }
}

// ---------------- F: fc3 GEMM1  h = gelu(X^T @ w1 + b1) ----------------
// grid 512*6 (b, c-tile of 64), block 256
__global__ __launch_bounds__(256) void k_fc3a(
    const float* __restrict__ x, const float* __restrict__ mlp1t,
    const float* __restrict__ mut, const float* __restrict__ rstdt,
    const float* __restrict__ g1, const float* __restrict__ bb1,
    const float* __restrict__ w1, const float* __restrict__ b1,
    ushort_t* __restrict__ h3){
  __shared__ ushort_t A[196][64];     // bf16 LN'd x^T tile [t][c]
  __shared__ ushort_t W[196][128];    // bf16 w1
  int b = blockIdx.x/6, ct = blockIdx.x%6, c0 = ct*64;
  int tid = threadIdx.x;
  for (int i = tid; i < 196*128; i += 256) (&W[0][0])[i] = (ushort_t)f2b(w1[i]);
  {
    int cl = tid & 63, tg = tid >> 6;
    const float* mrow = mlp1t + (size_t)b*384;
    for (int t = tg; t < 196; t += 4){
      int c = c0 + cl;
      int srow = b*197 + (t+1);
      float v = x[((size_t)b*197 + (t+1))*384 + c] + mrow[c];
      float y = (v - mut[srow])*rstdt[srow]*g1[c] + bb1[c];
      A[t][cl] = (ushort_t)f2b(y);
    }
  }
  __syncthreads();
  int ci = tid >> 4, ji = tid & 15;
  float acc[4][8];
  #pragma unroll
  for (int i=0;i<4;++i)
    #pragma unroll
    for (int k=0;k<8;++k) acc[i][k]=0.f;
  for (int t = 0; t < 196; ++t){
    uint2 av = *reinterpret_cast<const uint2*>(&A[t][ci*4]);
    uint4 wv = *reinterpret_cast<const uint4*>(&W[t][ji*8]);
    float a[4] = { bfu(av.x), bfu(av.x>>16), bfu(av.y), bfu(av.y>>16) };
    float w[8] = { bfu(wv.x), bfu(wv.x>>16), bfu(wv.y), bfu(wv.y>>16),
                   bfu(wv.z), bfu(wv.z>>16), bfu(wv.w), bfu(wv.w>>16) };
    #pragma unroll
    for (int i=0;i<4;++i)
      #pragma unroll
      for (int k=0;k<8;++k) acc[i][k] += a[i]*w[k];
  }
  #pragma unroll
  for (int i=0;i<4;++i){
    int c = c0 + ci*4 + i;
    unsigned int hv[8];
    #pragma unroll
    for (int k=0;k<8;++k){
      int j = ji*8+k;
      hv[k] = f2b(geluf(acc[i][k] + b1[j]));
    }
    uint4 pk;
    pk.x = hv[0] | (hv[1]<<16);
    pk.y = hv[2] | (hv[3]<<16);
    pk.z = hv[4] | (hv[5]<<16);
    pk.w = hv[6] | (hv[7]<<16);
    *reinterpret_cast<uint4*>(&h3[((size_t)b*384 + c)*128 + ji*8]) = pk;
  }
}

// ---------------- G: fc3 GEMM2 + LN over t', write transposed ----------------
// grid 512*6 (b, c-tile of 64), block 256
__global__ __launch_bounds__(256) void k_fc3b(
    const ushort_t* __restrict__ h3, const float* __restrict__ w2,
    const float* __restrict__ b2, const float* __restrict__ g3,
    const float* __restrict__ b3, ushort_t* __restrict__ Qout){
  __shared__ ushort_t H[128][68];     // bf16 h transposed [j][c], padded
  __shared__ ushort_t W[128][196];    // bf16 w2
  __shared__ float red[2][64][16];
  int b = blockIdx.x/6, ct = blockIdx.x%6, c0 = ct*64;
  int tid = threadIdx.x;
  for (int i = tid; i < 64*32; i += 256){
    int c = i >> 5, jq = i & 31;
    uint2 v = *reinterpret_cast<const uint2*>(&h3[((size_t)b*384 + c0 + c)*128 + jq*4]);
    H[jq*4+0][c] = (ushort_t)(v.x & 0xffffu);
    H[jq*4+1][c] = (ushort_t)(v.x >> 16);
    H[jq*4+2][c] = (ushort_t)(v.y & 0xffffu);
    H[jq*4+3][c] = (ushort_t)(v.y >> 16);
  }
  for (int i = tid; i < 128*196; i += 256) (&W[0][0])[i] = (ushort_t)f2b(w2[i]);
  __syncthreads();
  int cg = tid >> 4, tg = tid & 15;
  float acc[4][14];
  #pragma unroll
  for (int i=0;i<4;++i)
    #pragma unroll
    for (int k=0;k<14;++k) acc[i][k]=0.f;
  for (int j = 0; j < 128; ++j){
    uint2 hv = *reinterpret_cast<const uint2*>(&H[j][cg*4]);
    float h[4] = { bfu(hv.x), bfu(hv.x>>16), bfu(hv.y), bfu(hv.y>>16) };
    #pragma unroll
    for (int k = 0; k < 7; ++k){
      if (k < 6 || tg < 2){    // k=6 valid only for tg<2 (t'=192..195)
        unsigned int wv = *reinterpret_cast<const unsigned int*>(&W[j][2*tg + 32*k]);
        float w0 = bfu(wv), w1v = bfu(wv>>16);
        #pragma unroll
        for (int i=0;i<4;++i){
          acc[i][2*k]   += h[i]*w0;
          acc[i][2*k+1] += h[i]*w1v;
        }
      }
    }
  }
  // bias + LN stats over t' (per c-row)
  float psum[4]={0,0,0,0}, psq[4]={0,0,0,0};
  #pragma unroll
  for (int sl=0; sl<14; ++sl){
    int t = 2*tg + 32*(sl>>1) + (sl&1);
    if (t < 196){
      #pragma unroll
      for (int i=0;i<4;++i){
        float y = acc[i][sl] + b2[t];
        acc[i][sl] = y;
        psum[i] += y; psq[i] += y*y;
      }
    }
  }
  #pragma unroll
  for (int i=0;i<4;++i){ red[0][cg*4+i][tg]=psum[i]; red[1][cg*4+i][tg]=psq[i]; }
  __syncthreads();
  float mu4[4], rs4[4];
  #pragma unroll
  for (int i=0;i<4;++i){
    float ssv=0.f, qv=0.f;
    #pragma unroll
    for (int u=0;u<16;++u){ ssv += red[0][cg*4+i][u]; qv += red[1][cg*4+i][u]; }
    float m = ssv*(1.0f/196.0f);
    mu4[i]=m; rs4[i]=rsqrtf(qv*(1.0f/196.0f)-m*m+1e-5f);
  }
  #pragma unroll
  for (int sl=0; sl<14; ++sl){
    int t = 2*tg + 32*(sl>>1) + (sl&1);
    if (t < 196){
      float g = g3[t], bb = b3[t];
      unsigned int o0 = f2b((acc[0][sl]-mu4[0])*rs4[0]*g + bb);
      unsigned int o1 = f2b((acc[1][sl]-mu4[1])*rs4[1]*g + bb);
      unsigned int o2 = f2b((acc[2][sl]-mu4[2])*rs4[2]*g + bb);
      unsigned int o3 = f2b((acc[3][sl]-mu4[3])*rs4[3]*g + bb);
      uint2 pk; pk.x = o0 | (o1<<16); pk.y = o2 | (o3<<16);
      *reinterpret_cast<uint2*>(&Qout[((size_t)b*196 + t)*384 + c0 + cg*4]) = pk;
    }
  }
}

// ---------------- H1: fc4 stage A (one s-half per launch) ----------------
// grid 512*13 (b, t-tile of 16), block 256.
// Z = LN1(x)*Qin as bf16 in LDS (vectorized float4/uint2 loads, branchless tail),
// then GEMM1 384->96 with bf16 weight chunks in LDS (k_fc3a idiom).
// Rounds 1-3: the scalar mixed-stream variant spilled to 256 VGPR (50 GB scratch).
__global__ __launch_bounds__(256, 2) void k_fc4a(
    const float* __restrict__ x,         // fq or fs
    const float* __restrict__ m1_base,   // mlp1 + s*512*384
    const float* __restrict__ mu_s,      // mu + s*100864
    const float* __restrict__ rstd_s,    // rstd + s*100864
    const float* __restrict__ g1, const float* __restrict__ bln1,
    const ushort_t* __restrict__ Qin,    // Qb or Sb
    const float* __restrict__ w1, const float* __restrict__ b1mlp,
    ushort_t* __restrict__ h4s){         // h4 + s*512*196*96
  __shared__ ushort_t Zs[16][392];       // bf16 Z tile, padded stride
  __shared__ ushort_t Wc[96*96];         // bf16 w1 chunk [k][j]
  __shared__ float m1s[384], g1s[384], b1s[384];
  __shared__ float mus[16], rss[16];
  int bid = blockIdx.x;
  int b = bid/13, tt0 = (bid%13)*16;
  int tid = threadIdx.x;
  const float* m1 = m1_base + (size_t)b*384;
  for (int i = tid; i < 384; i += 256){ m1s[i] = m1[i]; g1s[i] = g1[i]; b1s[i] = bln1[i]; }
  if (tid < 16){
    int t = tt0 + tid; int tc = t < 196 ? t : 195;
    int srow = b*197 + tc + 1;
    mus[tid] = mu_s[srow]; rss[tid] = rstd_s[srow];
  }
  __syncthreads();
  // phase 1: vectorized Z build (6 float4 + 6 uint2 loads per thread)
  for (int e = 0; e < 6; ++e){
    int v = e*256 + tid;
    int row = v/96, col4 = v - row*96;   // row<16, col4<96 (4 channels each)
    int t = tt0 + row; int tc = t < 196 ? t : 195;
    float valid = (t < 196) ? 1.f : 0.f;
    float4 xv = *reinterpret_cast<const float4*>(&x[((size_t)b*197 + tc + 1)*384 + col4*4]);
    uint2 qv = *reinterpret_cast<const uint2*>(&Qin[((size_t)b*196 + tc)*384 + col4*4]);
    float muv = mus[row], rsv = rss[row];
    int c = col4*4;
    float z0 = (((xv.x + m1s[c+0]) - muv)*rsv*g1s[c+0] + b1s[c+0]) * bfu(qv.x)      * valid;
    float z1 = (((xv.y + m1s[c+1]) - muv)*rsv*g1s[c+1] + b1s[c+1]) * bfu(qv.x>>16)  * valid;
    float z2 = (((xv.z + m1s[c+2]) - muv)*rsv*g1s[c+2] + b1s[c+2]) * bfu(qv.y)      * valid;
    float z3 = (((xv.w + m1s[c+3]) - muv)*rsv*g1s[c+3] + b1s[c+3]) * bfu(qv.y>>16)  * valid;
    uint2 pk; pk.x = f2b(z0) | (f2b(z1)<<16); pk.y = f2b(z2) | (f2b(z3)<<16);
    *reinterpret_cast<uint2*>(&Zs[row][col4*4]) = pk;
  }
  // phase 2: GEMM1 (K=384 in 4 chunks of 96), thread = (t-row tt, 6 j's at lg*6)
  int tt = tid >> 4, lg = tid & 15;
  float a1[6] = {0,0,0,0,0,0};
  for (int kc = 0; kc < 4; ++kc){
    __syncthreads();
    for (int i = tid; i < 96*96; i += 256) Wc[i] = (ushort_t)f2b(w1[kc*9216 + i]);
    __syncthreads();
    for (int k = 0; k < 96; ++k){
      float z = bfu(Zs[tt][kc*96 + k]);
      const unsigned int* wrow = reinterpret_cast<const unsigned int*>(&Wc[k*96 + lg*6]);
      unsigned int w0 = wrow[0], w1v = wrow[1], w2v = wrow[2];
      a1[0] += z*bfu(w0); a1[1] += z*bfu(w0>>16);
      a1[2] += z*bfu(w1v); a1[3] += z*bfu(w1v>>16);
      a1[4] += z*bfu(w2v); a1[5] += z*bfu(w2v>>16);
    }
  }
  int t = tt0 + tt;
  if (t < 196){
    int j0 = lg*6;
    unsigned int o0 = f2b(geluf(a1[0]+b1mlp[j0+0])) | (f2b(geluf(a1[1]+b1mlp[j0+1]))<<16);
    unsigned int o1 = f2b(geluf(a1[2]+b1mlp[j0+2])) | (f2b(geluf(a1[3]+b1mlp[j0+3]))<<16);
    unsigned int o2 = f2b(geluf(a1[4]+b1mlp[j0+4])) | (f2b(geluf(a1[5]+b1mlp[j0+5]))<<16);
    unsigned int* dst = reinterpret_cast<unsigned int*>(&h4s[((size_t)b*196 + t)*96 + j0]);
    dst[0] = o0; dst[1] = o1; dst[2] = o2;
  }
}

// ---------------- H2: fc4 stage B (one s-half per launch) ----------------
// grid 512*13, block 256: y = h@w2+b2, LN4, +0.5*class, l2norm, center
__global__ __launch_bounds__(256) void k_fc4b(
    const ushort_t* __restrict__ h4s,    // h4 + s*512*196*96
    const float* __restrict__ w2, const float* __restrict__ b2,
    const float* __restrict__ g4, const float* __restrict__ bb4,
    const float* __restrict__ cls_base,  // dout + 1024 + s*196608
    ushort_t* __restrict__ Qo){          // Qb or Sb
  __shared__ float Hs[16][97];
  __shared__ float WS[24*384];
  int bid = blockIdx.x;
  int b = bid/13, tt0 = (bid%13)*16;
  int tid = threadIdx.x;
  // load h tile (invalid rows -> 0; their lanes never write out)
  for (int idx = tid; idx < 16*48; idx += 256){
    int trow = idx / 48, cu = idx % 48;
    int t = tt0 + trow; int tc = t < 196 ? t : 195;
    float valid = (t < 196) ? 1.f : 0.f;
    unsigned int hv = *reinterpret_cast<const unsigned int*>(&h4s[((size_t)b*196 + tc)*96 + cu*2]);
    Hs[trow][cu*2+0] = bfu(hv) * valid;
    Hs[trow][cu*2+1] = bfu(hv>>16) * valid;
  }
  int tt = tid >> 4, lg = tid & 15;
  float a2[24];
  #pragma unroll
  for (int k=0;k<24;++k) a2[k]=0.f;
  for (int n = 0; n < 4; ++n){
    __syncthreads();
    for (int i = tid; i < 24*384; i += 256) WS[i] = w2[(size_t)n*9216 + i];
    __syncthreads();
    for (int jj = 0; jj < 24; ++jj){
      float h = Hs[tt][n*24+jj];
      #pragma unroll
      for (int k=0;k<24;++k) a2[k] += h * WS[jj*384 + lg + 16*k];
    }
  }
  // epilogue: bias, LN4, +0.5*class, l2norm, center; 16-lane shuffle reductions
  int t = tt0 + tt; bool valid = (t < 196);
  float sum=0.f, sq=0.f;
  #pragma unroll
  for (int k=0;k<24;++k){
    int c = lg + 16*k;
    a2[k] += b2[c];
    sum += a2[k]; sq += a2[k]*a2[k];
  }
  #pragma unroll
  for (int o=1;o<16;o<<=1){ sum += __shfl_xor(sum,o); sq += __shfl_xor(sq,o); }
  float m4 = sum*(1.0f/384.0f);
  float rs = rsqrtf(sq*(1.0f/384.0f) - m4*m4 + 1e-5f);
  const float* cls = cls_base + (size_t)b*384;
  float s2 = 0.f;
  #pragma unroll
  for (int k=0;k<24;++k){
    int c = lg + 16*k;
    float v = (a2[k]-m4)*rs*g4[c] + bb4[c];
    v += 0.5f*cls[c];
    a2[k] = v; s2 += v*v;
  }
  #pragma unroll
  for (int o=1;o<16;o<<=1) s2 += __shfl_xor(s2,o);
  float inv = 1.0f/fmaxf(sqrtf(s2), 1e-12f);
  float sm = 0.f;
  #pragma unroll
  for (int k=0;k<24;++k){ a2[k]*=inv; sm += a2[k]; }
  #pragma unroll
  for (int o=1;o<16;o<<=1) sm += __shfl_xor(sm,o);
  sm *= (1.0f/384.0f);
  if (valid){
    #pragma unroll
    for (int k=0;k<24;++k) Qo[((size_t)b*196 + t)*384 + lg + 16*k] = (ushort_t)f2b(a2[k]-sm);
  }
}

// ---------------- I: batched einsum + fused 2x2 pooling ----------------
// grid 512*16 (b, qt, st), block 256
__global__ __launch_bounds__(256) void k_sim(
    const ushort_t* __restrict__ Q, const ushort_t* __restrict__ S,
    float* __restrict__ P){
  __shared__ ushort_t As[32][68];
  __shared__ ushort_t Bs[32][68];
  int bx = blockIdx.x;
  int b = bx >> 4, qt = (bx >> 2) & 3, st = bx & 3;
  int q0 = qt*64, s0 = st*64;
  int tid = threadIdx.x, ty = tid >> 4, tx = tid & 15;
  float acc[4][4];
  #pragma unroll
  for (int i=0;i<4;++i)
    #pragma unroll
    for (int j=0;j<4;++j) acc[i][j]=0.f;
  for (int kc = 0; kc < 384; kc += 32){
    __syncthreads();
    #pragma unroll
    for (int l = 0; l < 2; ++l){
      int idx = tid + l*256;
      int rr = idx >> 3, g = idx & 7;
      uint2 va; va.x=0u; va.y=0u;
      uint2 vb; vb.x=0u; vb.y=0u;
      int q = q0 + rr, ss = s0 + rr;
      if (q  < 196) va = *reinterpret_cast<const uint2*>(&Q[((size_t)b*196+q )*384 + kc + g*4]);
      if (ss < 196) vb = *reinterpret_cast<const uint2*>(&S[((size_t)b*196+ss)*384 + kc + g*4]);
      As[g*4+0][rr] = (ushort_t)(va.x&0xffffu); As[g*4+1][rr]=(ushort_t)(va.x>>16);
      As[g*4+2][rr] = (ushort_t)(va.y&0xffffu); As[g*4+3][rr]=(ushort_t)(va.y>>16);
      Bs[g*4+0][rr] = (ushort_t)(vb.x&0xffffu); Bs[g*4+1][rr]=(ushort_t)(vb.x>>16);
      Bs[g*4+2][rr] = (ushort_t)(vb.y&0xffffu); Bs[g*4+3][rr]=(ushort_t)(vb.y>>16);
    }
    __syncthreads();
    for (int k = 0; k < 32; ++k){
      uint2 ua = *reinterpret_cast<const uint2*>(&As[k][ty*4]);
      uint2 ub = *reinterpret_cast<const uint2*>(&Bs[k][tx*4]);
      float av[4] = {bfu(ua.x),bfu(ua.x>>16),bfu(ua.y),bfu(ua.y>>16)};
      float bv[4] = {bfu(ub.x),bfu(ub.x>>16),bfu(ub.y),bfu(ub.y>>16)};
      #pragma unroll
      for (int i=0;i<4;++i)
        #pragma unroll
        for (int j=0;j<4;++j) acc[i][j] += av[i]*bv[j];
    }
  }
  int qb = q0 + ty*4, sb = s0 + tx*4;
  #pragma unroll
  for (int i=0;i<2;++i)
    #pragma unroll
    for (int j=0;j<2;++j){
      int qp = (qb>>1) + i, sp = (sb>>1) + j;
      if (qp < 98 && sp < 98){
        float v = 0.25f*(acc[2*i][2*j]+acc[2*i][2*j+1]+acc[2*i+1][2*j]+acc[2*i+1][2*j+1]);
        P[((size_t)b*98 + qp)*98 + sp] = v;
      }
    }
}

// ---------------- J1: fc2 split-K GEMM  Cpart[ks] = P2-chunk @ w1-chunk ----------------
// grid 64*14 (m-block of 8 rows, k-split of 686), block 256 (= N columns)
__global__ __launch_bounds__(256) void k_fc2a(
    const float* __restrict__ P, const float* __restrict__ w1,
    float* __restrict__ Cpart){
  __shared__ float p2[8][688];
  int bx = blockIdx.x;
  int mb = bx & 63, ks = bx >> 6;      // 14 k-splits of 686 (14*686 = 9604)
  int b0 = mb*8, k0 = ks*686;
  int tid = threadIdx.x;
  for (int idx = tid; idx < 8*686; idx += 256){
    int r = idx / 686, i = idx - r*686;
    float v = P[(size_t)(b0+r)*9604 + k0 + i];
    p2[r][i] = v*v;
  }
  __syncthreads();
  float acc[8];
  #pragma unroll
  for (int r=0;r<8;++r) acc[r]=0.f;
  for (int ii=0; ii<686; ++ii){
    float w = w1[(size_t)(k0+ii)*256 + tid];
    #pragma unroll
    for (int r=0;r<8;++r) acc[r] += p2[r][ii]*w;
  }
  #pragma unroll
  for (int r=0;r<8;++r) Cpart[((size_t)ks*512 + b0 + r)*256 + tid] = acc[r];
}

// ---------------- J2: fc2 reduce + gelu + w2 dot ----------------
// grid 512 (one b each), block 256
__global__ __launch_bounds__(256) void k_fc2b(
    const float* __restrict__ Cpart, const float* __restrict__ b1,
    const float* __restrict__ w2, const float* __restrict__ b2,
    float* __restrict__ outp){
  __shared__ float red[4];
  int b = blockIdx.x, tid = threadIdx.x;
  float s = 0.f;
  for (int ks = 0; ks < 14; ++ks) s += Cpart[((size_t)ks*512 + b)*256 + tid];
  float h = geluf(s + b1[tid]) * w2[tid];
  #pragma unroll
  for (int o=32;o;o>>=1) h += __shfl_down(h,o);
  int w = tid >> 6, lane = tid & 63;
  if (lane==0) red[w] = h;
  __syncthreads();
  if (tid==0) outp[b] = red[0]+red[1]+red[2]+red[3] + b2[0];
}

// ---------------- launch ----------------
extern "C" void kernel_launch(void* const* d_in, const int* in_sizes, int n_in,
                              void* d_out, int out_size, void* d_ws, size_t ws_size,
                              hipStream_t stream){
  const float* fq  = (const float*)d_in[0];
  const float* fs  = (const float*)d_in[1];
  const float* fqs = (const float*)d_in[2];
  const float* fss = (const float*)d_in[3];
  const float* fc1_w1 = (const float*)d_in[4];
  const float* fc1_b1 = (const float*)d_in[5];
  const float* fc1_w2 = (const float*)d_in[6];
  const float* fc1_b2 = (const float*)d_in[7];
  const float* ln1_g = (const float*)d_in[8];
  const float* ln1_b = (const float*)d_in[9];
  const float* fc3_w1 = (const float*)d_in[10];
  const float* fc3_b1 = (const float*)d_in[11];
  const float* fc3_w2 = (const float*)d_in[12];
  const float* fc3_b2 = (const float*)d_in[13];
  const float* ln3_g = (const float*)d_in[14];
  const float* ln3_b = (const float*)d_in[15];
  const float* fc4_w1 = (const float*)d_in[16];
  const float* fc4_b1 = (const float*)d_in[17];
  const float* fc4_w2 = (const float*)d_in[18];
  const float* fc4_b2 = (const float*)d_in[19];
  const float* ln4_g = (const float*)d_in[20];
  const float* ln4_b = (const float*)d_in[21];
  const float* fc2_w1 = (const float*)d_in[22];
  const float* fc2_b1 = (const float*)d_in[23];
  const float* fc2_w2 = (const float*)d_in[24];
  const float* fc2_b2 = (const float*)d_in[25];
  const float* cs_w1 = (const float*)d_in[26];
  const float* cs_b1 = (const float*)d_in[27];
  const float* cs_w2 = (const float*)d_in[28];
  const float* cs_b2 = (const float*)d_in[29];
  float* out = (float*)d_out;
  char* ws = (char*)d_ws;
  // ws layout (bytes):
  //   meanb f32 @0           (3,145,728)
  //   mlp1  f32 @3145728     (3,145,728)
  //   mu    f32 @6291456     (1,613,824)
  //   rstd  f32 @7905280     (1,613,824)
  //   h3    bf16 @9519104    (50,331,648)  [reused for h4 bf16 38.5MB, then P f32 19.7MB]
  //   Cpart f32 @29188096    (7,340,032)   [after P; inside old h3 region]
  //   Qb    bf16 @59850752   (77,070,336)
  //   Sb    bf16 @136921088  (77,070,336)
  //   total 213,991,424 B
  float* meanb  = (float*)(ws + 0);
  float* mlp1   = (float*)(ws + 3145728);
  float* mu     = (float*)(ws + 6291456);
  float* rstd   = (float*)(ws + 7905280);
  ushort_t* h3  = (ushort_t*)(ws + 9519104);
  ushort_t* h4  = (ushort_t*)(ws + 9519104);  // overlays h3 (dead after 2nd fc3b)
  float* P      = (float*)(ws + 9519104);     // overlays h4 (dead after fc4b)
  float* Cpart  = (float*)(ws + 29188096);    // after P, before Qb
  ushort_t* Qb  = (ushort_t*)(ws + 59850752);
  ushort_t* Sb  = (ushort_t*)(ws + 136921088);
  const size_t H4S = (size_t)512*196*96;      // per-s-half h4 elements

  k_mean<<<2048, 384, 0, stream>>>(fq, fs, fqs, fss, meanb);
  k_fc1<<<2048, 384, 0, stream>>>(meanb, fc1_w1, fc1_b1, fc1_w2, fc1_b2, mlp1);
  k_stats<<<100864, 256, 0, stream>>>(fq, fs, fqs, fss, mlp1, mu, rstd);
  k_class<<<1024, 384, 0, stream>>>(fq, fs, mlp1, mu, rstd, ln1_g, ln1_b, out);
  k_cosine<<<512, 384, 0, stream>>>(cs_w1, cs_b1, cs_w2, cs_b2, out);
  k_fc3a<<<3072, 256, 0, stream>>>(fqs, mlp1 + (size_t)2*512*384, mu + 2*100864, rstd + 2*100864,
                                   ln1_g, ln1_b, fc3_w1, fc3_b1, h3);
  k_fc3b<<<3072, 256, 0, stream>>>(h3, fc3_w2, fc3_b2, ln3_g, ln3_b, Qb);
  k_fc3a<<<3072, 256, 0, stream>>>(fss, mlp1 + (size_t)3*512*384, mu + 3*100864, rstd + 3*100864,
                                   ln1_g, ln1_b, fc3_w1, fc3_b1, h3);
  k_fc3b<<<3072, 256, 0, stream>>>(h3, fc3_w2, fc3_b2, ln3_g, ln3_b, Sb);
  // fc4 stage A: q then s (pre-offset pointers, no runtime s-select)
  k_fc4a<<<6656, 256, 0, stream>>>(fq, mlp1, mu, rstd, ln1_g, ln1_b,
                                   Qb, fc4_w1, fc4_b1, h4);
  k_fc4a<<<6656, 256, 0, stream>>>(fs, mlp1 + (size_t)512*384, mu + 100864, rstd + 100864,
                                   ln1_g, ln1_b, Sb, fc4_w1, fc4_b1, h4 + H4S);
  // fc4 stage B: q then s (Qb/Sb overwritten in place after their last read)
  k_fc4b<<<6656, 256, 0, stream>>>(h4,       fc4_w2, fc4_b2, ln4_g, ln4_b, out + 1024,          Qb);
  k_fc4b<<<6656, 256, 0, stream>>>(h4 + H4S, fc4_w2, fc4_b2, ln4_g, ln4_b, out + 1024 + 196608, Sb);
  k_sim<<<8192, 256, 0, stream>>>(Qb, Sb, P);
  // fc2 head: split-K GEMM (896 blocks) + tiny reduce
  k_fc2a<<<896, 256, 0, stream>>>(P, fc2_w1, Cpart);
  k_fc2b<<<512, 256, 0, stream>>>(Cpart, fc2_b1, fc2_w2, fc2_b2, out);
}

// Round 6
// 2686.883 us; speedup vs baseline: 12.3147x; 1.0941x over previous
//
#include <hip/hip_runtime.h>
#include <math.h>

typedef unsigned short ushort_t;
typedef __attribute__((ext_vector_type(8))) short bf16x8;
typedef __attribute__((ext_vector_type(4))) float f32x4;

// ---------------- helpers ----------------
__device__ __forceinline__ float geluf(float x){
  return 0.5f*x*(1.0f+erff(x*0.70710678118654752440f));
}
__device__ __forceinline__ float bfu(unsigned int u){
  union { unsigned int i; float f; } v; v.i = (u & 0xffffu) << 16; return v.f;
}
__device__ __forceinline__ unsigned int f2b(float f){
  union { float f; unsigned int i; } v; v.f = f;
  unsigned int r = v.i + 0x7fffu + ((v.i >> 16) & 1u);
  return (r >> 16);
}

// Problem constants
// B=512, N=197, C=384, T=196 image tokens
// d_out layout (floats): out[512] | cosine[512] | query_class[512*384] | support_class[512*384]

// ---------------- A: token means (per tensor, b, c) ----------------
__global__ __launch_bounds__(384) void k_mean(
    const float* __restrict__ x0, const float* __restrict__ x1,
    const float* __restrict__ x2, const float* __restrict__ x3,
    float* __restrict__ meanb){
  int s = blockIdx.x >> 9, b = blockIdx.x & 511, c = threadIdx.x;
  const float* x = (s==0)?x0:(s==1)?x1:(s==2)?x2:x3;
  const float* p = x + ((size_t)b*197)*384 + c;
  float acc = 0.f;
  #pragma unroll 4
  for (int t=0;t<197;++t) acc += p[(size_t)t*384];
  meanb[((size_t)s*512+b)*384+c] = acc*(1.0f/197.0f);
}

// ---------------- B: fc1 tiny MLP on means ----------------
__global__ __launch_bounds__(384) void k_fc1(
    const float* __restrict__ meanb, const float* __restrict__ w1,
    const float* __restrict__ b1, const float* __restrict__ w2,
    const float* __restrict__ b2, float* __restrict__ mlp1){
  __shared__ float ms[384];
  __shared__ float hs[96];
  int row = blockIdx.x, tid = threadIdx.x;
  ms[tid] = meanb[(size_t)row*384 + tid];
  __syncthreads();
  if (tid < 96){
    float a = b1[tid];
    for (int c=0;c<384;++c) a += ms[c]*w1[c*96+tid];
    hs[tid] = geluf(a);
  }
  __syncthreads();
  float a = b2[tid];
  for (int j=0;j<96;++j) a += hs[j]*w2[j*384+tid];
  mlp1[(size_t)row*384 + tid] = a;
}

// ---------------- C: per-row LN stats of (x + mlp1) ----------------
__global__ __launch_bounds__(256) void k_stats(
    const float* __restrict__ x0, const float* __restrict__ x1,
    const float* __restrict__ x2, const float* __restrict__ x3,
    const float* __restrict__ mlp1, float* __restrict__ mu, float* __restrict__ rstd){
  int lane = threadIdx.x & 63, w = threadIdx.x >> 6;
  int row = blockIdx.x*4 + w;           // rows = 4*512*197 = 403456, grid exact
  int s = row / 100864;
  int rr = row % 100864;
  int b = rr / 197, t = rr % 197;
  const float* x = (s==0)?x0:(s==1)?x1:(s==2)?x2:x3;
  const float* xp = x + ((size_t)b*197 + t)*384;
  const float* mp = mlp1 + ((size_t)s*512 + b)*384;
  float sum=0.f, sq=0.f;
  for (int i=lane;i<384;i+=64){ float v = xp[i]+mp[i]; sum+=v; sq+=v*v; }
  #pragma unroll
  for (int o=32;o;o>>=1){ sum+=__shfl_down(sum,o); sq+=__shfl_down(sq,o); }
  if (lane==0){
    float m = sum*(1.0f/384.0f);
    mu[row] = m;
    rstd[row] = rsqrtf(sq*(1.0f/384.0f) - m*m + 1e-5f);
  }
}

// ---------------- D: class token rows -> d_out ----------------
__global__ __launch_bounds__(384) void k_class(
    const float* __restrict__ x0, const float* __restrict__ x1,
    const float* __restrict__ mlp1, const float* __restrict__ mu,
    const float* __restrict__ rstd, const float* __restrict__ g1,
    const float* __restrict__ bb1, float* __restrict__ dout){
  int s = blockIdx.x >> 9, b = blockIdx.x & 511, c = threadIdx.x;
  const float* x = s ? x1 : x0;
  int srow = (s*512 + b)*197;
  float v = x[((size_t)b*197)*384 + c] + mlp1[((size_t)s*512+b)*384 + c];
  float y = (v - mu[srow])*rstd[srow]*g1[c] + bb1[c];
  dout[1024 + (size_t)s*196608 + (size_t)b*384 + c] = y;
}

// ---------------- E: cosine head on class tokens ----------------
__global__ __launch_bounds__(384) void k_cosine(
    const float* __restrict__ w1, const float* __restrict__ b1,
    const float* __restrict__ w2, const float* __restrict__ b2,
    float* __restrict__ dout){
  __shared__ float qrow[384], srw[384], hq[96], hs[96];
  __shared__ float rd0[384], rd1[384], rd2[384];
  int b = blockIdx.x, tid = threadIdx.x;
  qrow[tid] = dout[1024   + (size_t)b*384 + tid];
  srw[tid]  = dout[197632 + (size_t)b*384 + tid];
  __syncthreads();
  if (tid < 96){
    float a = b1[tid];
    for (int c=0;c<384;++c) a += qrow[c]*w1[c*96+tid];
    hq[tid] = geluf(a);
  } else if (tid < 192){
    int j = tid - 96;
    float a = b1[j];
    for (int c=0;c<384;++c) a += srw[c]*w1[c*96+j];
    hs[j] = geluf(a);
  }
  __syncthreads();
  float qx = b2[tid], sy = b2[tid];
  for (int j=0;j<96;++j){ qx += hq[j]*w2[j*384+tid]; sy += hs[j]*w2[j*384+tid]; }
  rd0[tid] = qx*sy; rd1[tid] = qx*qx; rd2[tid] = sy*sy;
  __syncthreads();
  if (tid < 64){
    float d=0.f,nq=0.f,ns=0.f;
    for (int i=tid;i<384;i+=64){ d+=rd0[i]; nq+=rd1[i]; ns+=rd2[i]; }
    #pragma unroll
    for (int o=32;o;o>>=1){ d+=__shfl_down(d,o); nq+=__shfl_down(nq,o); ns+=__shfl_down(ns,o); }
    if (tid==0) dout[512 + b] = d / (fmaxf(sqrtf(nq),1e-8f)*fmaxf(sqrtf(ns),1e-8f));
  }
}

// ---------------- F: fc3 GEMM1  h = gelu(X^T @ w1 + b1) ----------------
// grid 512*6 (b, c-tile of 64), block 256
__global__ __launch_bounds__(256) void k_fc3a(
    const float* __restrict__ x, const float* __restrict__ mlp1t,
    const float* __restrict__ mut, const float* __restrict__ rstdt,
    const float* __restrict__ g1, const float* __restrict__ bb1,
    const float* __restrict__ w1, const float* __restrict__ b1,
    ushort_t* __restrict__ h3){
  __shared__ ushort_t A[196][64];     // bf16 LN'd x^T tile [t][c]
  __shared__ ushort_t W[196][128];    // bf16 w1
  int b = blockIdx.x/6, ct = blockIdx.x%6, c0 = ct*64;
  int tid = threadIdx.x;
  for (int i = tid; i < 196*128; i += 256) (&W[0][0])[i] = (ushort_t)f2b(w1[i]);
  {
    int cl = tid & 63, tg = tid >> 6;
    const float* mrow = mlp1t + (size_t)b*384;
    for (int t = tg; t < 196; t += 4){
      int c = c0 + cl;
      int srow = b*197 + (t+1);
      float v = x[((size_t)b*197 + (t+1))*384 + c] + mrow[c];
      float y = (v - mut[srow])*rstdt[srow]*g1[c] + bb1[c];
      A[t][cl] = (ushort_t)f2b(y);
    }
  }
  __syncthreads();
  int ci = tid >> 4, ji = tid & 15;
  float acc[4][8];
  #pragma unroll
  for (int i=0;i<4;++i)
    #pragma unroll
    for (int k=0;k<8;++k) acc[i][k]=0.f;
  for (int t = 0; t < 196; ++t){
    uint2 av = *reinterpret_cast<const uint2*>(&A[t][ci*4]);
    uint4 wv = *reinterpret_cast<const uint4*>(&W[t][ji*8]);
    float a[4] = { bfu(av.x), bfu(av.x>>16), bfu(av.y), bfu(av.y>>16) };
    float w[8] = { bfu(wv.x), bfu(wv.x>>16), bfu(wv.y), bfu(wv.y>>16),
                   bfu(wv.z), bfu(wv.z>>16), bfu(wv.w), bfu(wv.w>>16) };
    #pragma unroll
    for (int i=0;i<4;++i)
      #pragma unroll
      for (int k=0;k<8;++k) acc[i][k] += a[i]*w[k];
  }
  #pragma unroll
  for (int i=0;i<4;++i){
    int c = c0 + ci*4 + i;
    unsigned int hv[8];
    #pragma unroll
    for (int k=0;k<8;++k){
      int j = ji*8+k;
      hv[k] = f2b(geluf(acc[i][k] + b1[j]));
    }
    uint4 pk;
    pk.x = hv[0] | (hv[1]<<16);
    pk.y = hv[2] | (hv[3]<<16);
    pk.z = hv[4] | (hv[5]<<16);
    pk.w = hv[6] | (hv[7]<<16);
    *reinterpret_cast<uint4*>(&h3[((size_t)b*384 + c)*128 + ji*8]) = pk;
  }
}

// ---------------- G: fc3 GEMM2 + LN over t', write transposed ----------------
// grid 512*6 (b, c-tile of 64), block 256
__global__ __launch_bounds__(256) void k_fc3b(
    const ushort_t* __restrict__ h3, const float* __restrict__ w2,
    const float* __restrict__ b2, const float* __restrict__ g3,
    const float* __restrict__ b3, ushort_t* __restrict__ Qout){
  __shared__ ushort_t H[128][68];     // bf16 h transposed [j][c], padded
  __shared__ ushort_t W[128][196];    // bf16 w2
  __shared__ float red[2][64][16];
  int b = blockIdx.x/6, ct = blockIdx.x%6, c0 = ct*64;
  int tid = threadIdx.x;
  for (int i = tid; i < 64*32; i += 256){
    int c = i >> 5, jq = i & 31;
    uint2 v = *reinterpret_cast<const uint2*>(&h3[((size_t)b*384 + c0 + c)*128 + jq*4]);
    H[jq*4+0][c] = (ushort_t)(v.x & 0xffffu);
    H[jq*4+1][c] = (ushort_t)(v.x >> 16);
    H[jq*4+2][c] = (ushort_t)(v.y & 0xffffu);
    H[jq*4+3][c] = (ushort_t)(v.y >> 16);
  }
  for (int i = tid; i < 128*196; i += 256) (&W[0][0])[i] = (ushort_t)f2b(w2[i]);
  __syncthreads();
  int cg = tid >> 4, tg = tid & 15;
  float acc[4][14];
  #pragma unroll
  for (int i=0;i<4;++i)
    #pragma unroll
    for (int k=0;k<14;++k) acc[i][k]=0.f;
  for (int j = 0; j < 128; ++j){
    uint2 hv = *reinterpret_cast<const uint2*>(&H[j][cg*4]);
    float h[4] = { bfu(hv.x), bfu(hv.x>>16), bfu(hv.y), bfu(hv.y>>16) };
    #pragma unroll
    for (int k = 0; k < 7; ++k){
      if (k < 6 || tg < 2){    // k=6 valid only for tg<2 (t'=192..195)
        unsigned int wv = *reinterpret_cast<const unsigned int*>(&W[j][2*tg + 32*k]);
        float w0 = bfu(wv), w1v = bfu(wv>>16);
        #pragma unroll
        for (int i=0;i<4;++i){
          acc[i][2*k]   += h[i]*w0;
          acc[i][2*k+1] += h[i]*w1v;
        }
      }
    }
  }
  // bias + LN stats over t' (per c-row)
  float psum[4]={0,0,0,0}, psq[4]={0,0,0,0};
  #pragma unroll
  for (int sl=0; sl<14; ++sl){
    int t = 2*tg + 32*(sl>>1) + (sl&1);
    if (t < 196){
      #pragma unroll
      for (int i=0;i<4;++i){
        float y = acc[i][sl] + b2[t];
        acc[i][sl] = y;
        psum[i] += y; psq[i] += y*y;
      }
    }
  }
  #pragma unroll
  for (int i=0;i<4;++i){ red[0][cg*4+i][tg]=psum[i]; red[1][cg*4+i][tg]=psq[i]; }
  __syncthreads();
  float mu4[4], rs4[4];
  #pragma unroll
  for (int i=0;i<4;++i){
    float ssv=0.f, qv=0.f;
    #pragma unroll
    for (int u=0;u<16;++u){ ssv += red[0][cg*4+i][u]; qv += red[1][cg*4+i][u]; }
    float m = ssv*(1.0f/196.0f);
    mu4[i]=m; rs4[i]=rsqrtf(qv*(1.0f/196.0f)-m*m+1e-5f);
  }
  #pragma unroll
  for (int sl=0; sl<14; ++sl){
    int t = 2*tg + 32*(sl>>1) + (sl&1);
    if (t < 196){
      float g = g3[t], bb = b3[t];
      unsigned int o0 = f2b((acc[0][sl]-mu4[0])*rs4[0]*g + bb);
      unsigned int o1 = f2b((acc[1][sl]-mu4[1])*rs4[1]*g + bb);
      unsigned int o2 = f2b((acc[2][sl]-mu4[2])*rs4[2]*g + bb);
      unsigned int o3 = f2b((acc[3][sl]-mu4[3])*rs4[3]*g + bb);
      uint2 pk; pk.x = o0 | (o1<<16); pk.y = o2 | (o3<<16);
      *reinterpret_cast<uint2*>(&Qout[((size_t)b*196 + t)*384 + c0 + cg*4]) = pk;
    }
  }
}

// ---------------- H1: fc4 stage A (one s-half per launch) ----------------
// grid 512*13 (b, t-tile of 16), block 256.
// Z = LN1(x)*Qin as bf16 in LDS (vectorized float4/uint2 loads, branchless tail),
// then GEMM1 384->96 with bf16 weight chunks in LDS (k_fc3a idiom).
// Rounds 1-3: the scalar mixed-stream variant spilled to 256 VGPR (50 GB scratch).
__global__ __launch_bounds__(256, 2) void k_fc4a(
    const float* __restrict__ x,         // fq or fs
    const float* __restrict__ m1_base,   // mlp1 + s*512*384
    const float* __restrict__ mu_s,      // mu + s*100864
    const float* __restrict__ rstd_s,    // rstd + s*100864
    const float* __restrict__ g1, const float* __restrict__ bln1,
    const ushort_t* __restrict__ Qin,    // Qb or Sb
    const float* __restrict__ w1, const float* __restrict__ b1mlp,
    ushort_t* __restrict__ h4s){         // h4 + s*512*196*96
  __shared__ ushort_t Zs[16][392];       // bf16 Z tile, padded stride
  __shared__ ushort_t Wc[96*96];         // bf16 w1 chunk [k][j]
  __shared__ float m1s[384], g1s[384], b1s[384];
  __shared__ float mus[16], rss[16];
  int bid = blockIdx.x;
  int b = bid/13, tt0 = (bid%13)*16;
  int tid = threadIdx.x;
  const float* m1 = m1_base + (size_t)b*384;
  for (int i = tid; i < 384; i += 256){ m1s[i] = m1[i]; g1s[i] = g1[i]; b1s[i] = bln1[i]; }
  if (tid < 16){
    int t = tt0 + tid; int tc = t < 196 ? t : 195;
    int srow = b*197 + tc + 1;
    mus[tid] = mu_s[srow]; rss[tid] = rstd_s[srow];
  }
  __syncthreads();
  // phase 1: vectorized Z build (6 float4 + 6 uint2 loads per thread)
  for (int e = 0; e < 6; ++e){
    int v = e*256 + tid;
    int row = v/96, col4 = v - row*96;   // row<16, col4<96 (4 channels each)
    int t = tt0 + row; int tc = t < 196 ? t : 195;
    float valid = (t < 196) ? 1.f : 0.f;
    float4 xv = *reinterpret_cast<const float4*>(&x[((size_t)b*197 + tc + 1)*384 + col4*4]);
    uint2 qv = *reinterpret_cast<const uint2*>(&Qin[((size_t)b*196 + tc)*384 + col4*4]);
    float muv = mus[row], rsv = rss[row];
    int c = col4*4;
    float z0 = (((xv.x + m1s[c+0]) - muv)*rsv*g1s[c+0] + b1s[c+0]) * bfu(qv.x)      * valid;
    float z1 = (((xv.y + m1s[c+1]) - muv)*rsv*g1s[c+1] + b1s[c+1]) * bfu(qv.x>>16)  * valid;
    float z2 = (((xv.z + m1s[c+2]) - muv)*rsv*g1s[c+2] + b1s[c+2]) * bfu(qv.y)      * valid;
    float z3 = (((xv.w + m1s[c+3]) - muv)*rsv*g1s[c+3] + b1s[c+3]) * bfu(qv.y>>16)  * valid;
    uint2 pk; pk.x = f2b(z0) | (f2b(z1)<<16); pk.y = f2b(z2) | (f2b(z3)<<16);
    *reinterpret_cast<uint2*>(&Zs[row][col4*4]) = pk;
  }
  // phase 2: GEMM1 (K=384 in 4 chunks of 96), thread = (t-row tt, 6 j's at lg*6)
  int tt = tid >> 4, lg = tid & 15;
  float a1[6] = {0,0,0,0,0,0};
  for (int kc = 0; kc < 4; ++kc){
    __syncthreads();
    for (int i = tid; i < 96*96; i += 256) Wc[i] = (ushort_t)f2b(w1[kc*9216 + i]);
    __syncthreads();
    for (int k = 0; k < 96; ++k){
      float z = bfu(Zs[tt][kc*96 + k]);
      const unsigned int* wrow = reinterpret_cast<const unsigned int*>(&Wc[k*96 + lg*6]);
      unsigned int w0 = wrow[0], w1v = wrow[1], w2v = wrow[2];
      a1[0] += z*bfu(w0); a1[1] += z*bfu(w0>>16);
      a1[2] += z*bfu(w1v); a1[3] += z*bfu(w1v>>16);
      a1[4] += z*bfu(w2v); a1[5] += z*bfu(w2v>>16);
    }
  }
  int t = tt0 + tt;
  if (t < 196){
    int j0 = lg*6;
    unsigned int o0 = f2b(geluf(a1[0]+b1mlp[j0+0])) | (f2b(geluf(a1[1]+b1mlp[j0+1]))<<16);
    unsigned int o1 = f2b(geluf(a1[2]+b1mlp[j0+2])) | (f2b(geluf(a1[3]+b1mlp[j0+3]))<<16);
    unsigned int o2 = f2b(geluf(a1[4]+b1mlp[j0+4])) | (f2b(geluf(a1[5]+b1mlp[j0+5]))<<16);
    unsigned int* dst = reinterpret_cast<unsigned int*>(&h4s[((size_t)b*196 + t)*96 + j0]);
    dst[0] = o0; dst[1] = o1; dst[2] = o2;
  }
}

// ---------------- H2: fc4 stage B (one s-half per launch) ----------------
// grid 512*13, block 256: y = h@w2+b2, LN4, +0.5*class, l2norm, center
__global__ __launch_bounds__(256) void k_fc4b(
    const ushort_t* __restrict__ h4s,    // h4 + s*512*196*96
    const float* __restrict__ w2, const float* __restrict__ b2,
    const float* __restrict__ g4, const float* __restrict__ bb4,
    const float* __restrict__ cls_base,  // dout + 1024 + s*196608
    ushort_t* __restrict__ Qo){          // Qb or Sb
  __shared__ float Hs[16][97];
  __shared__ float WS[24*384];
  int bid = blockIdx.x;
  int b = bid/13, tt0 = (bid%13)*16;
  int tid = threadIdx.x;
  // load h tile (invalid rows -> 0; their lanes never write out)
  for (int idx = tid; idx < 16*48; idx += 256){
    int trow = idx / 48, cu = idx % 48;
    int t = tt0 + trow; int tc = t < 196 ? t : 195;
    float valid = (t < 196) ? 1.f : 0.f;
    unsigned int hv = *reinterpret_cast<const unsigned int*>(&h4s[((size_t)b*196 + tc)*96 + cu*2]);
    Hs[trow][cu*2+0] = bfu(hv) * valid;
    Hs[trow][cu*2+1] = bfu(hv>>16) * valid;
  }
  int tt = tid >> 4, lg = tid & 15;
  float a2[24];
  #pragma unroll
  for (int k=0;k<24;++k) a2[k]=0.f;
  for (int n = 0; n < 4; ++n){
    __syncthreads();
    for (int i = tid; i < 24*384; i += 256) WS[i] = w2[(size_t)n*9216 + i];
    __syncthreads();
    for (int jj = 0; jj < 24; ++jj){
      float h = Hs[tt][n*24+jj];
      #pragma unroll
      for (int k=0;k<24;++k) a2[k] += h * WS[jj*384 + lg + 16*k];
    }
  }
  // epilogue: bias, LN4, +0.5*class, l2norm, center; 16-lane shuffle reductions
  int t = tt0 + tt; bool valid = (t < 196);
  float sum=0.f, sq=0.f;
  #pragma unroll
  for (int k=0;k<24;++k){
    int c = lg + 16*k;
    a2[k] += b2[c];
    sum += a2[k]; sq += a2[k]*a2[k];
  }
  #pragma unroll
  for (int o=1;o<16;o<<=1){ sum += __shfl_xor(sum,o); sq += __shfl_xor(sq,o); }
  float m4 = sum*(1.0f/384.0f);
  float rs = rsqrtf(sq*(1.0f/384.0f) - m4*m4 + 1e-5f);
  const float* cls = cls_base + (size_t)b*384;
  float s2 = 0.f;
  #pragma unroll
  for (int k=0;k<24;++k){
    int c = lg + 16*k;
    float v = (a2[k]-m4)*rs*g4[c] + bb4[c];
    v += 0.5f*cls[c];
    a2[k] = v; s2 += v*v;
  }
  #pragma unroll
  for (int o=1;o<16;o<<=1) s2 += __shfl_xor(s2,o);
  float inv = 1.0f/fmaxf(sqrtf(s2), 1e-12f);
  float sm = 0.f;
  #pragma unroll
  for (int k=0;k<24;++k){ a2[k]*=inv; sm += a2[k]; }
  #pragma unroll
  for (int o=1;o<16;o<<=1) sm += __shfl_xor(sm,o);
  sm *= (1.0f/384.0f);
  if (valid){
    #pragma unroll
    for (int k=0;k<24;++k) Qo[((size_t)b*196 + t)*384 + lg + 16*k] = (ushort_t)f2b(a2[k]-sm);
  }
}

// ---------------- I: batched einsum + fused 2x2 pooling (MFMA) ----------------
// grid 512*16 (b, qt, st), block 256 = 4 waves; wave = 32x32 output tile.
// C = Q S^T via mfma_f32_16x16x32_bf16, fragments loaded straight from global
// (lane l&15 = row, (l>>4)*8 = k offset; rows 16B-aligned). Pooling in-register:
// row pairs live in one lane (C/D row=(lane>>4)*4+reg), col pairs via shfl_xor(1).
__global__ __launch_bounds__(256) void k_sim(
    const ushort_t* __restrict__ Q, const ushort_t* __restrict__ S,
    float* __restrict__ P){
  int bx = blockIdx.x;
  int b = bx >> 4, qt = (bx >> 2) & 3, st = bx & 3;
  int tid = threadIdx.x;
  int w = tid >> 6, lane = tid & 63;
  int wr = w >> 1, wc = w & 1;
  int q0 = qt*64 + wr*32, s0 = st*64 + wc*32;
  int rrow = lane & 15, kg = lane >> 4;
  const ushort_t* Qb_ = Q + (size_t)b*196*384;
  const ushort_t* Sb_ = S + (size_t)b*196*384;
  int qr0 = min(q0 + rrow, 195), qr1 = min(q0 + 16 + rrow, 195);
  int sr0 = min(s0 + rrow, 195), sr1 = min(s0 + 16 + rrow, 195);
  const ushort_t* qp0 = Qb_ + (size_t)qr0*384 + kg*8;
  const ushort_t* qp1 = Qb_ + (size_t)qr1*384 + kg*8;
  const ushort_t* sp0 = Sb_ + (size_t)sr0*384 + kg*8;
  const ushort_t* sp1 = Sb_ + (size_t)sr1*384 + kg*8;
  f32x4 acc00 = {0.f,0.f,0.f,0.f}, acc01 = {0.f,0.f,0.f,0.f};
  f32x4 acc10 = {0.f,0.f,0.f,0.f}, acc11 = {0.f,0.f,0.f,0.f};
  for (int k0 = 0; k0 < 384; k0 += 32){
    bf16x8 a0 = *reinterpret_cast<const bf16x8*>(qp0 + k0);
    bf16x8 a1 = *reinterpret_cast<const bf16x8*>(qp1 + k0);
    bf16x8 b0 = *reinterpret_cast<const bf16x8*>(sp0 + k0);
    bf16x8 b1 = *reinterpret_cast<const bf16x8*>(sp1 + k0);
    acc00 = __builtin_amdgcn_mfma_f32_16x16x32_bf16(a0, b0, acc00, 0, 0, 0);
    acc01 = __builtin_amdgcn_mfma_f32_16x16x32_bf16(a0, b1, acc01, 0, 0, 0);
    acc10 = __builtin_amdgcn_mfma_f32_16x16x32_bf16(a1, b0, acc10, 0, 0, 0);
    acc11 = __builtin_amdgcn_mfma_f32_16x16x32_bf16(a1, b1, acc11, 0, 0, 0);
  }
  int c = lane & 15, g = lane >> 4;
  float* Pb = P + (size_t)b*98*98;
  #pragma unroll
  for (int i = 0; i < 2; ++i){
    #pragma unroll
    for (int j = 0; j < 2; ++j){
      f32x4 v = (i==0) ? (j==0 ? acc00 : acc01) : (j==0 ? acc10 : acc11);
      float p0 = v[0] + v[1];   // rows 4g, 4g+1
      float p1 = v[2] + v[3];   // rows 4g+2, 4g+3
      float t0 = p0 + __shfl_xor(p0, 1);
      float t1 = p1 + __shfl_xor(p1, 1);
      if (!(c & 1)){
        int qp = (q0 + 16*i + 4*g) >> 1;
        int sp = (s0 + 16*j + c) >> 1;
        if (sp < 98){
          if (qp     < 98) Pb[(size_t)(qp    )*98 + sp] = 0.25f*t0;
          if (qp + 1 < 98) Pb[(size_t)(qp + 1)*98 + sp] = 0.25f*t1;
        }
      }
    }
  }
}

// ---------------- J1: fc2 split-K GEMM  Cpart[ks] = P2-chunk @ w1-chunk ----------------
// grid 64*14 (m-block of 8 rows, k-split of 686), block 256 (= N columns)
__global__ __launch_bounds__(256) void k_fc2a(
    const float* __restrict__ P, const float* __restrict__ w1,
    float* __restrict__ Cpart){
  __shared__ float p2[8][688];
  int bx = blockIdx.x;
  int mb = bx & 63, ks = bx >> 6;      // 14 k-splits of 686 (14*686 = 9604)
  int b0 = mb*8, k0 = ks*686;
  int tid = threadIdx.x;
  for (int idx = tid; idx < 8*686; idx += 256){
    int r = idx / 686, i = idx - r*686;
    float v = P[(size_t)(b0+r)*9604 + k0 + i];
    p2[r][i] = v*v;
  }
  __syncthreads();
  float acc[8];
  #pragma unroll
  for (int r=0;r<8;++r) acc[r]=0.f;
  for (int ii=0; ii<686; ++ii){
    float w = w1[(size_t)(k0+ii)*256 + tid];
    #pragma unroll
    for (int r=0;r<8;++r) acc[r] += p2[r][ii]*w;
  }
  #pragma unroll
  for (int r=0;r<8;++r) Cpart[((size_t)ks*512 + b0 + r)*256 + tid] = acc[r];
}

// ---------------- J2: fc2 reduce + gelu + w2 dot ----------------
// grid 512 (one b each), block 256
__global__ __launch_bounds__(256) void k_fc2b(
    const float* __restrict__ Cpart, const float* __restrict__ b1,
    const float* __restrict__ w2, const float* __restrict__ b2,
    float* __restrict__ outp){
  __shared__ float red[4];
  int b = blockIdx.x, tid = threadIdx.x;
  float s = 0.f;
  for (int ks = 0; ks < 14; ++ks) s += Cpart[((size_t)ks*512 + b)*256 + tid];
  float h = geluf(s + b1[tid]) * w2[tid];
  #pragma unroll
  for (int o=32;o;o>>=1) h += __shfl_down(h,o);
  int w = tid >> 6, lane = tid & 63;
  if (lane==0) red[w] = h;
  __syncthreads();
  if (tid==0) outp[b] = red[0]+red[1]+red[2]+red[3] + b2[0];
}

// ---------------- launch ----------------
extern "C" void kernel_launch(void* const* d_in, const int* in_sizes, int n_in,
                              void* d_out, int out_size, void* d_ws, size_t ws_size,
                              hipStream_t stream){
  const float* fq  = (const float*)d_in[0];
  const float* fs  = (const float*)d_in[1];
  const float* fqs = (const float*)d_in[2];
  const float* fss = (const float*)d_in[3];
  const float* fc1_w1 = (const float*)d_in[4];
  const float* fc1_b1 = (const float*)d_in[5];
  const float* fc1_w2 = (const float*)d_in[6];
  const float* fc1_b2 = (const float*)d_in[7];
  const float* ln1_g = (const float*)d_in[8];
  const float* ln1_b = (const float*)d_in[9];
  const float* fc3_w1 = (const float*)d_in[10];
  const float* fc3_b1 = (const float*)d_in[11];
  const float* fc3_w2 = (const float*)d_in[12];
  const float* fc3_b2 = (const float*)d_in[13];
  const float* ln3_g = (const float*)d_in[14];
  const float* ln3_b = (const float*)d_in[15];
  const float* fc4_w1 = (const float*)d_in[16];
  const float* fc4_b1 = (const float*)d_in[17];
  const float* fc4_w2 = (const float*)d_in[18];
  const float* fc4_b2 = (const float*)d_in[19];
  const float* ln4_g = (const float*)d_in[20];
  const float* ln4_b = (const float*)d_in[21];
  const float* fc2_w1 = (const float*)d_in[22];
  const float* fc2_b1 = (const float*)d_in[23];
  const float* fc2_w2 = (const float*)d_in[24];
  const float* fc2_b2 = (const float*)d_in[25];
  const float* cs_w1 = (const float*)d_in[26];
  const float* cs_b1 = (const float*)d_in[27];
  const float* cs_w2 = (const float*)d_in[28];
  const float* cs_b2 = (const float*)d_in[29];
  float* out = (float*)d_out;
  char* ws = (char*)d_ws;
  // ws layout (bytes):
  //   meanb f32 @0           (3,145,728)
  //   mlp1  f32 @3145728     (3,145,728)
  //   mu    f32 @6291456     (1,613,824)
  //   rstd  f32 @7905280     (1,613,824)
  //   h3    bf16 @9519104    (50,331,648)  [reused for h4 bf16 38.5MB, then P f32 19.7MB]
  //   Cpart f32 @29188096    (7,340,032)   [after P; inside old h3 region]
  //   Qb    bf16 @59850752   (77,070,336)
  //   Sb    bf16 @136921088  (77,070,336)
  //   total 213,991,424 B
  float* meanb  = (float*)(ws + 0);
  float* mlp1   = (float*)(ws + 3145728);
  float* mu     = (float*)(ws + 6291456);
  float* rstd   = (float*)(ws + 7905280);
  ushort_t* h3  = (ushort_t*)(ws + 9519104);
  ushort_t* h4  = (ushort_t*)(ws + 9519104);  // overlays h3 (dead after 2nd fc3b)
  float* P      = (float*)(ws + 9519104);     // overlays h4 (dead after fc4b)
  float* Cpart  = (float*)(ws + 29188096);    // after P, before Qb
  ushort_t* Qb  = (ushort_t*)(ws + 59850752);
  ushort_t* Sb  = (ushort_t*)(ws + 136921088);
  const size_t H4S = (size_t)512*196*96;      // per-s-half h4 elements

  k_mean<<<2048, 384, 0, stream>>>(fq, fs, fqs, fss, meanb);
  k_fc1<<<2048, 384, 0, stream>>>(meanb, fc1_w1, fc1_b1, fc1_w2, fc1_b2, mlp1);
  k_stats<<<100864, 256, 0, stream>>>(fq, fs, fqs, fss, mlp1, mu, rstd);
  k_class<<<1024, 384, 0, stream>>>(fq, fs, mlp1, mu, rstd, ln1_g, ln1_b, out);
  k_cosine<<<512, 384, 0, stream>>>(cs_w1, cs_b1, cs_w2, cs_b2, out);
  k_fc3a<<<3072, 256, 0, stream>>>(fqs, mlp1 + (size_t)2*512*384, mu + 2*100864, rstd + 2*100864,
                                   ln1_g, ln1_b, fc3_w1, fc3_b1, h3);
  k_fc3b<<<3072, 256, 0, stream>>>(h3, fc3_w2, fc3_b2, ln3_g, ln3_b, Qb);
  k_fc3a<<<3072, 256, 0, stream>>>(fss, mlp1 + (size_t)3*512*384, mu + 3*100864, rstd + 3*100864,
                                   ln1_g, ln1_b, fc3_w1, fc3_b1, h3);
  k_fc3b<<<3072, 256, 0, stream>>>(h3, fc3_w2, fc3_b2, ln3_g, ln3_b, Sb);
  // fc4 stage A: q then s (pre-offset pointers, no runtime s-select)
  k_fc4a<<<6656, 256, 0, stream>>>(fq, mlp1, mu, rstd, ln1_g, ln1_b,
                                   Qb, fc4_w1, fc4_b1, h4);
  k_fc4a<<<6656, 256, 0, stream>>>(fs, mlp1 + (size_t)512*384, mu + 100864, rstd + 100864,
                                   ln1_g, ln1_b, Sb, fc4_w1, fc4_b1, h4 + H4S);
  // fc4 stage B: q then s (Qb/Sb overwritten in place after their last read)
  k_fc4b<<<6656, 256, 0, stream>>>(h4,       fc4_w2, fc4_b2, ln4_g, ln4_b, out + 1024,          Qb);
  k_fc4b<<<6656, 256, 0, stream>>>(h4 + H4S, fc4_w2, fc4_b2, ln4_g, ln4_b, out + 1024 + 196608, Sb);
  k_sim<<<8192, 256, 0, stream>>>(Qb, Sb, P);
  // fc2 head: split-K GEMM (896 blocks) + tiny reduce
  k_fc2a<<<896, 256, 0, stream>>>(P, fc2_w1, Cpart);
  k_fc2b<<<512, 256, 0, stream>>>(Cpart, fc2_b1, fc2_w2, fc2_b2, out);
}

// Round 7
// 2286.997 us; speedup vs baseline: 14.4679x; 1.1749x over previous
//
#include <hip/hip_runtime.h>
#include <math.h>

typedef unsigned short ushort_t;
typedef __attribute__((ext_vector_type(8))) short bf16x8;
typedef __attribute__((ext_vector_type(4))) float f32x4;

// ---------------- helpers ----------------
__device__ __forceinline__ float geluf(float x){
  return 0.5f*x*(1.0f+erff(x*0.70710678118654752440f));
}
__device__ __forceinline__ float bfu(unsigned int u){
  union { unsigned int i; float f; } v; v.i = (u & 0xffffu) << 16; return v.f;
}
__device__ __forceinline__ unsigned int f2b(float f){
  union { float f; unsigned int i; } v; v.f = f;
  unsigned int r = v.i + 0x7fffu + ((v.i >> 16) & 1u);
  return (r >> 16);
}

// Problem constants
// B=512, N=197, C=384, T=196 image tokens
// d_out layout (floats): out[512] | cosine[512] | query_class[512*384] | support_class[512*384]

// ---------------- A: token means (per tensor, b, c) ----------------
__global__ __launch_bounds__(384) void k_mean(
    const float* __restrict__ x0, const float* __restrict__ x1,
    const float* __restrict__ x2, const float* __restrict__ x3,
    float* __restrict__ meanb){
  int s = blockIdx.x >> 9, b = blockIdx.x & 511, c = threadIdx.x;
  const float* x = (s==0)?x0:(s==1)?x1:(s==2)?x2:x3;
  const float* p = x + ((size_t)b*197)*384 + c;
  float acc = 0.f;
  #pragma unroll 4
  for (int t=0;t<197;++t) acc += p[(size_t)t*384];
  meanb[((size_t)s*512+b)*384+c] = acc*(1.0f/197.0f);
}

// ---------------- B: fc1 tiny MLP on means ----------------
__global__ __launch_bounds__(384) void k_fc1(
    const float* __restrict__ meanb, const float* __restrict__ w1,
    const float* __restrict__ b1, const float* __restrict__ w2,
    const float* __restrict__ b2, float* __restrict__ mlp1){
  __shared__ float ms[384];
  __shared__ float hs[96];
  int row = blockIdx.x, tid = threadIdx.x;
  ms[tid] = meanb[(size_t)row*384 + tid];
  __syncthreads();
  if (tid < 96){
    float a = b1[tid];
    for (int c=0;c<384;++c) a += ms[c]*w1[c*96+tid];
    hs[tid] = geluf(a);
  }
  __syncthreads();
  float a = b2[tid];
  for (int j=0;j<96;++j) a += hs[j]*w2[j*384+tid];
  mlp1[(size_t)row*384 + tid] = a;
}

// ---------------- C: per-row LN stats of (x + mlp1) ----------------
__global__ __launch_bounds__(256) void k_stats(
    const float* __restrict__ x0, const float* __restrict__ x1,
    const float* __restrict__ x2, const float* __restrict__ x3,
    const float* __restrict__ mlp1, float* __restrict__ mu, float* __restrict__ rstd){
  int lane = threadIdx.x & 63, w = threadIdx.x >> 6;
  int row = blockIdx.x*4 + w;           // rows = 4*512*197 = 403456, grid exact
  int s = row / 100864;
  int rr = row % 100864;
  int b = rr / 197, t = rr % 197;
  const float* x = (s==0)?x0:(s==1)?x1:(s==2)?x2:x3;
  const float* xp = x + ((size_t)b*197 + t)*384;
  const float* mp = mlp1 + ((size_t)s*512 + b)*384;
  float sum=0.f, sq=0.f;
  for (int i=lane;i<384;i+=64){ float v = xp[i]+mp[i]; sum+=v; sq+=v*v; }
  #pragma unroll
  for (int o=32;o;o>>=1){ sum+=__shfl_down(sum,o); sq+=__shfl_down(sq,o); }
  if (lane==0){
    float m = sum*(1.0f/384.0f);
    mu[row] = m;
    rstd[row] = rsqrtf(sq*(1.0f/384.0f) - m*m + 1e-5f);
  }
}

// ---------------- D: class token rows -> d_out ----------------
__global__ __launch_bounds__(384) void k_class(
    const float* __restrict__ x0, const float* __restrict__ x1,
    const float* __restrict__ mlp1, const float* __restrict__ mu,
    const float* __restrict__ rstd, const float* __restrict__ g1,
    const float* __restrict__ bb1, float* __restrict__ dout){
  int s = blockIdx.x >> 9, b = blockIdx.x & 511, c = threadIdx.x;
  const float* x = s ? x1 : x0;
  int srow = (s*512 + b)*197;
  float v = x[((size_t)b*197)*384 + c] + mlp1[((size_t)s*512+b)*384 + c];
  float y = (v - mu[srow])*rstd[srow]*g1[c] + bb1[c];
  dout[1024 + (size_t)s*196608 + (size_t)b*384 + c] = y;
}

// ---------------- E: cosine head on class tokens ----------------
__global__ __launch_bounds__(384) void k_cosine(
    const float* __restrict__ w1, const float* __restrict__ b1,
    const float* __restrict__ w2, const float* __restrict__ b2,
    float* __restrict__ dout){
  __shared__ float qrow[384], srw[384], hq[96], hs[96];
  __shared__ float rd0[384], rd1[384], rd2[384];
  int b = blockIdx.x, tid = threadIdx.x;
  qrow[tid] = dout[1024   + (size_t)b*384 + tid];
  srw[tid]  = dout[197632 + (size_t)b*384 + tid];
  __syncthreads();
  if (tid < 96){
    float a = b1[tid];
    for (int c=0;c<384;++c) a += qrow[c]*w1[c*96+tid];
    hq[tid] = geluf(a);
  } else if (tid < 192){
    int j = tid - 96;
    float a = b1[j];
    for (int c=0;c<384;++c) a += srw[c]*w1[c*96+j];
    hs[j] = geluf(a);
  }
  __syncthreads();
  float qx = b2[tid], sy = b2[tid];
  for (int j=0;j<96;++j){ qx += hq[j]*w2[j*384+tid]; sy += hs[j]*w2[j*384+tid]; }
  rd0[tid] = qx*sy; rd1[tid] = qx*qx; rd2[tid] = sy*sy;
  __syncthreads();
  if (tid < 64){
    float d=0.f,nq=0.f,ns=0.f;
    for (int i=tid;i<384;i+=64){ d+=rd0[i]; nq+=rd1[i]; ns+=rd2[i]; }
    #pragma unroll
    for (int o=32;o;o>>=1){ d+=__shfl_down(d,o); nq+=__shfl_down(nq,o); ns+=__shfl_down(ns,o); }
    if (tid==0) dout[512 + b] = d / (fmaxf(sqrtf(nq),1e-8f)*fmaxf(sqrtf(ns),1e-8f));
  }
}

// ---------------- F: fc3 GEMM1  h = gelu(X^T @ w1 + b1) ----------------
// grid 512*6 (b, c-tile of 64), block 256
__global__ __launch_bounds__(256) void k_fc3a(
    const float* __restrict__ x, const float* __restrict__ mlp1t,
    const float* __restrict__ mut, const float* __restrict__ rstdt,
    const float* __restrict__ g1, const float* __restrict__ bb1,
    const float* __restrict__ w1, const float* __restrict__ b1,
    ushort_t* __restrict__ h3){
  __shared__ ushort_t A[196][64];     // bf16 LN'd x^T tile [t][c]
  __shared__ ushort_t W[196][128];    // bf16 w1
  int b = blockIdx.x/6, ct = blockIdx.x%6, c0 = ct*64;
  int tid = threadIdx.x;
  for (int i = tid; i < 196*128; i += 256) (&W[0][0])[i] = (ushort_t)f2b(w1[i]);
  {
    int cl = tid & 63, tg = tid >> 6;
    const float* mrow = mlp1t + (size_t)b*384;
    for (int t = tg; t < 196; t += 4){
      int c = c0 + cl;
      int srow = b*197 + (t+1);
      float v = x[((size_t)b*197 + (t+1))*384 + c] + mrow[c];
      float y = (v - mut[srow])*rstdt[srow]*g1[c] + bb1[c];
      A[t][cl] = (ushort_t)f2b(y);
    }
  }
  __syncthreads();
  int ci = tid >> 4, ji = tid & 15;
  float acc[4][8];
  #pragma unroll
  for (int i=0;i<4;++i)
    #pragma unroll
    for (int k=0;k<8;++k) acc[i][k]=0.f;
  for (int t = 0; t < 196; ++t){
    uint2 av = *reinterpret_cast<const uint2*>(&A[t][ci*4]);
    uint4 wv = *reinterpret_cast<const uint4*>(&W[t][ji*8]);
    float a[4] = { bfu(av.x), bfu(av.x>>16), bfu(av.y), bfu(av.y>>16) };
    float w[8] = { bfu(wv.x), bfu(wv.x>>16), bfu(wv.y), bfu(wv.y>>16),
                   bfu(wv.z), bfu(wv.z>>16), bfu(wv.w), bfu(wv.w>>16) };
    #pragma unroll
    for (int i=0;i<4;++i)
      #pragma unroll
      for (int k=0;k<8;++k) acc[i][k] += a[i]*w[k];
  }
  #pragma unroll
  for (int i=0;i<4;++i){
    int c = c0 + ci*4 + i;
    unsigned int hv[8];
    #pragma unroll
    for (int k=0;k<8;++k){
      int j = ji*8+k;
      hv[k] = f2b(geluf(acc[i][k] + b1[j]));
    }
    uint4 pk;
    pk.x = hv[0] | (hv[1]<<16);
    pk.y = hv[2] | (hv[3]<<16);
    pk.z = hv[4] | (hv[5]<<16);
    pk.w = hv[6] | (hv[7]<<16);
    *reinterpret_cast<uint4*>(&h3[((size_t)b*384 + c)*128 + ji*8]) = pk;
  }
}

// ---------------- G: fc3 GEMM2 + LN over t', write transposed ----------------
// grid 512*6 (b, c-tile of 64), block 256
__global__ __launch_bounds__(256) void k_fc3b(
    const ushort_t* __restrict__ h3, const float* __restrict__ w2,
    const float* __restrict__ b2, const float* __restrict__ g3,
    const float* __restrict__ b3, ushort_t* __restrict__ Qout){
  __shared__ ushort_t H[128][68];     // bf16 h transposed [j][c], padded
  __shared__ ushort_t W[128][196];    // bf16 w2
  __shared__ float red[2][64][16];
  int b = blockIdx.x/6, ct = blockIdx.x%6, c0 = ct*64;
  int tid = threadIdx.x;
  for (int i = tid; i < 64*32; i += 256){
    int c = i >> 5, jq = i & 31;
    uint2 v = *reinterpret_cast<const uint2*>(&h3[((size_t)b*384 + c0 + c)*128 + jq*4]);
    H[jq*4+0][c] = (ushort_t)(v.x & 0xffffu);
    H[jq*4+1][c] = (ushort_t)(v.x >> 16);
    H[jq*4+2][c] = (ushort_t)(v.y & 0xffffu);
    H[jq*4+3][c] = (ushort_t)(v.y >> 16);
  }
  for (int i = tid; i < 128*196; i += 256) (&W[0][0])[i] = (ushort_t)f2b(w2[i]);
  __syncthreads();
  int cg = tid >> 4, tg = tid & 15;
  float acc[4][14];
  #pragma unroll
  for (int i=0;i<4;++i)
    #pragma unroll
    for (int k=0;k<14;++k) acc[i][k]=0.f;
  for (int j = 0; j < 128; ++j){
    uint2 hv = *reinterpret_cast<const uint2*>(&H[j][cg*4]);
    float h[4] = { bfu(hv.x), bfu(hv.x>>16), bfu(hv.y), bfu(hv.y>>16) };
    #pragma unroll
    for (int k = 0; k < 7; ++k){
      if (k < 6 || tg < 2){    // k=6 valid only for tg<2 (t'=192..195)
        unsigned int wv = *reinterpret_cast<const unsigned int*>(&W[j][2*tg + 32*k]);
        float w0 = bfu(wv), w1v = bfu(wv>>16);
        #pragma unroll
        for (int i=0;i<4;++i){
          acc[i][2*k]   += h[i]*w0;
          acc[i][2*k+1] += h[i]*w1v;
        }
      }
    }
  }
  // bias + LN stats over t' (per c-row)
  float psum[4]={0,0,0,0}, psq[4]={0,0,0,0};
  #pragma unroll
  for (int sl=0; sl<14; ++sl){
    int t = 2*tg + 32*(sl>>1) + (sl&1);
    if (t < 196){
      #pragma unroll
      for (int i=0;i<4;++i){
        float y = acc[i][sl] + b2[t];
        acc[i][sl] = y;
        psum[i] += y; psq[i] += y*y;
      }
    }
  }
  #pragma unroll
  for (int i=0;i<4;++i){ red[0][cg*4+i][tg]=psum[i]; red[1][cg*4+i][tg]=psq[i]; }
  __syncthreads();
  float mu4[4], rs4[4];
  #pragma unroll
  for (int i=0;i<4;++i){
    float ssv=0.f, qv=0.f;
    #pragma unroll
    for (int u=0;u<16;++u){ ssv += red[0][cg*4+i][u]; qv += red[1][cg*4+i][u]; }
    float m = ssv*(1.0f/196.0f);
    mu4[i]=m; rs4[i]=rsqrtf(qv*(1.0f/196.0f)-m*m+1e-5f);
  }
  #pragma unroll
  for (int sl=0; sl<14; ++sl){
    int t = 2*tg + 32*(sl>>1) + (sl&1);
    if (t < 196){
      float g = g3[t], bb = b3[t];
      unsigned int o0 = f2b((acc[0][sl]-mu4[0])*rs4[0]*g + bb);
      unsigned int o1 = f2b((acc[1][sl]-mu4[1])*rs4[1]*g + bb);
      unsigned int o2 = f2b((acc[2][sl]-mu4[2])*rs4[2]*g + bb);
      unsigned int o3 = f2b((acc[3][sl]-mu4[3])*rs4[3]*g + bb);
      uint2 pk; pk.x = o0 | (o1<<16); pk.y = o2 | (o3<<16);
      *reinterpret_cast<uint2*>(&Qout[((size_t)b*196 + t)*384 + c0 + cg*4]) = pk;
    }
  }
}

// ---------------- H1: fc4 stage A (one s-half per launch) ----------------
// grid 512*13 (b, t-tile of 16), block 256.
// Z = LN1(x)*Qin as bf16 in LDS (vectorized float4/uint2 loads, branchless tail),
// then GEMM1 384->96 with bf16 weight chunks in LDS (k_fc3a idiom).
// Rounds 1-3: the scalar mixed-stream variant spilled to 256 VGPR (50 GB scratch).
__global__ __launch_bounds__(256, 2) void k_fc4a(
    const float* __restrict__ x,         // fq or fs
    const float* __restrict__ m1_base,   // mlp1 + s*512*384
    const float* __restrict__ mu_s,      // mu + s*100864
    const float* __restrict__ rstd_s,    // rstd + s*100864
    const float* __restrict__ g1, const float* __restrict__ bln1,
    const ushort_t* __restrict__ Qin,    // Qb or Sb
    const float* __restrict__ w1, const float* __restrict__ b1mlp,
    ushort_t* __restrict__ h4s){         // h4 + s*512*196*96
  __shared__ ushort_t Zs[16][392];       // bf16 Z tile, padded stride
  __shared__ ushort_t Wc[96*96];         // bf16 w1 chunk [k][j]
  __shared__ float m1s[384], g1s[384], b1s[384];
  __shared__ float mus[16], rss[16];
  int bid = blockIdx.x;
  int b = bid/13, tt0 = (bid%13)*16;
  int tid = threadIdx.x;
  const float* m1 = m1_base + (size_t)b*384;
  for (int i = tid; i < 384; i += 256){ m1s[i] = m1[i]; g1s[i] = g1[i]; b1s[i] = bln1[i]; }
  if (tid < 16){
    int t = tt0 + tid; int tc = t < 196 ? t : 195;
    int srow = b*197 + tc + 1;
    mus[tid] = mu_s[srow]; rss[tid] = rstd_s[srow];
  }
  __syncthreads();
  // phase 1: vectorized Z build (6 float4 + 6 uint2 loads per thread)
  for (int e = 0; e < 6; ++e){
    int v = e*256 + tid;
    int row = v/96, col4 = v - row*96;   // row<16, col4<96 (4 channels each)
    int t = tt0 + row; int tc = t < 196 ? t : 195;
    float valid = (t < 196) ? 1.f : 0.f;
    float4 xv = *reinterpret_cast<const float4*>(&x[((size_t)b*197 + tc + 1)*384 + col4*4]);
    uint2 qv = *reinterpret_cast<const uint2*>(&Qin[((size_t)b*196 + tc)*384 + col4*4]);
    float muv = mus[row], rsv = rss[row];
    int c = col4*4;
    float z0 = (((xv.x + m1s[c+0]) - muv)*rsv*g1s[c+0] + b1s[c+0]) * bfu(qv.x)      * valid;
    float z1 = (((xv.y + m1s[c+1]) - muv)*rsv*g1s[c+1] + b1s[c+1]) * bfu(qv.x>>16)  * valid;
    float z2 = (((xv.z + m1s[c+2]) - muv)*rsv*g1s[c+2] + b1s[c+2]) * bfu(qv.y)      * valid;
    float z3 = (((xv.w + m1s[c+3]) - muv)*rsv*g1s[c+3] + b1s[c+3]) * bfu(qv.y>>16)  * valid;
    uint2 pk; pk.x = f2b(z0) | (f2b(z1)<<16); pk.y = f2b(z2) | (f2b(z3)<<16);
    *reinterpret_cast<uint2*>(&Zs[row][col4*4]) = pk;
  }
  // phase 2: GEMM1 (K=384 in 4 chunks of 96), thread = (t-row tt, 6 j's at lg*6)
  int tt = tid >> 4, lg = tid & 15;
  float a1[6] = {0,0,0,0,0,0};
  for (int kc = 0; kc < 4; ++kc){
    __syncthreads();
    for (int i = tid; i < 96*96; i += 256) Wc[i] = (ushort_t)f2b(w1[kc*9216 + i]);
    __syncthreads();
    for (int k = 0; k < 96; ++k){
      float z = bfu(Zs[tt][kc*96 + k]);
      const unsigned int* wrow = reinterpret_cast<const unsigned int*>(&Wc[k*96 + lg*6]);
      unsigned int w0 = wrow[0], w1v = wrow[1], w2v = wrow[2];
      a1[0] += z*bfu(w0); a1[1] += z*bfu(w0>>16);
      a1[2] += z*bfu(w1v); a1[3] += z*bfu(w1v>>16);
      a1[4] += z*bfu(w2v); a1[5] += z*bfu(w2v>>16);
    }
  }
  int t = tt0 + tt;
  if (t < 196){
    int j0 = lg*6;
    unsigned int o0 = f2b(geluf(a1[0]+b1mlp[j0+0])) | (f2b(geluf(a1[1]+b1mlp[j0+1]))<<16);
    unsigned int o1 = f2b(geluf(a1[2]+b1mlp[j0+2])) | (f2b(geluf(a1[3]+b1mlp[j0+3]))<<16);
    unsigned int o2 = f2b(geluf(a1[4]+b1mlp[j0+4])) | (f2b(geluf(a1[5]+b1mlp[j0+5]))<<16);
    unsigned int* dst = reinterpret_cast<unsigned int*>(&h4s[((size_t)b*196 + t)*96 + j0]);
    dst[0] = o0; dst[1] = o1; dst[2] = o2;
  }
}

// ---------------- W: transpose fc4_w2 -> bf16 [384 c][96 j] ----------------
// grid 144, block 256
__global__ __launch_bounds__(256) void k_w2t(
    const float* __restrict__ w2, ushort_t* __restrict__ w2t){
  int idx = blockIdx.x*256 + threadIdx.x;   // 144*256 = 36864 exact
  int c = idx / 96, j = idx - c*96;
  w2t[idx] = (ushort_t)f2b(w2[(size_t)j*384 + c]);
}

// ---------------- H2: fc4 stage B (MFMA; one s-half per launch) ----------------
// grid 512*4 (b, t-tile of 64), block 256 = 4 waves; wave = 16 t x 384 c.
// A = w2t rows (c -> C/D row=(lane>>4)*4+reg), B = h4s rows (t -> C/D col=lane&15),
// 24 A-frags x 3 k-steps = 72 MFMA (k_sim-validated fragment recipe).
// Fused epilogue: bias, LN4 (shfl_xor 16/32 across the 4 lanes sharing t),
// +0.5*class, l2norm, center. Coef arrays staged in LDS (broadcast reads).
__global__ __launch_bounds__(256) void k_fc4b(
    const ushort_t* __restrict__ h4s,    // h4 + s*512*196*96
    const ushort_t* __restrict__ w2t,    // [384][96] bf16
    const float* __restrict__ b2, const float* __restrict__ g4,
    const float* __restrict__ bb4,
    const float* __restrict__ cls_base,  // dout + 1024 + s*196608
    ushort_t* __restrict__ Qo){          // Qb or Sb
  __shared__ float b2s[384], g4s[384], b4s[384], cl_s[384];
  int bid = blockIdx.x;
  int b = bid >> 2, ttile = bid & 3;
  int tid = threadIdx.x, w = tid >> 6, lane = tid & 63;
  const float* cls = cls_base + (size_t)b*384;
  for (int i = tid; i < 384; i += 256){
    b2s[i] = b2[i]; g4s[i] = g4[i]; b4s[i] = bb4[i]; cl_s[i] = cls[i];
  }
  __syncthreads();
  int tr = ttile*64 + w*16 + (lane & 15);
  int trc = tr < 196 ? tr : 195;
  int kg = lane >> 4;
  const ushort_t* hp = h4s + ((size_t)b*196 + trc)*96 + kg*8;
  bf16x8 hb0 = *reinterpret_cast<const bf16x8*>(hp);
  bf16x8 hb1 = *reinterpret_cast<const bf16x8*>(hp + 32);
  bf16x8 hb2 = *reinterpret_cast<const bf16x8*>(hp + 64);
  const ushort_t* ap_base = w2t + (size_t)(lane & 15)*96 + kg*8;
  f32x4 acc[24];
  #pragma unroll
  for (int af = 0; af < 24; ++af){
    const ushort_t* ap = ap_base + (size_t)af*16*96;
    bf16x8 a0 = *reinterpret_cast<const bf16x8*>(ap);
    bf16x8 a1 = *reinterpret_cast<const bf16x8*>(ap + 32);
    bf16x8 a2 = *reinterpret_cast<const bf16x8*>(ap + 64);
    f32x4 z = {0.f,0.f,0.f,0.f};
    z = __builtin_amdgcn_mfma_f32_16x16x32_bf16(a0, hb0, z, 0, 0, 0);
    z = __builtin_amdgcn_mfma_f32_16x16x32_bf16(a1, hb1, z, 0, 0, 0);
    z = __builtin_amdgcn_mfma_f32_16x16x32_bf16(a2, hb2, z, 0, 0, 0);
    acc[af] = z;
  }
  // epilogue: lane holds c = af*16 + kg*4 + r  (r=0..3), t = tr (col)
  float sum = 0.f, sq = 0.f;
  #pragma unroll
  for (int af = 0; af < 24; ++af){
    int cb = af*16 + kg*4;
    float4 bv = *reinterpret_cast<const float4*>(&b2s[cb]);
    f32x4 y = acc[af];
    y[0] += bv.x; y[1] += bv.y; y[2] += bv.z; y[3] += bv.w;
    acc[af] = y;
    sum += y[0]+y[1]+y[2]+y[3];
    sq  += y[0]*y[0]+y[1]*y[1]+y[2]*y[2]+y[3]*y[3];
  }
  sum += __shfl_xor(sum, 16); sum += __shfl_xor(sum, 32);
  sq  += __shfl_xor(sq, 16);  sq  += __shfl_xor(sq, 32);
  float m4 = sum*(1.0f/384.0f);
  float rs = rsqrtf(sq*(1.0f/384.0f) - m4*m4 + 1e-5f);
  float s2 = 0.f;
  #pragma unroll
  for (int af = 0; af < 24; ++af){
    int cb = af*16 + kg*4;
    float4 gv = *reinterpret_cast<const float4*>(&g4s[cb]);
    float4 bb = *reinterpret_cast<const float4*>(&b4s[cb]);
    float4 cv = *reinterpret_cast<const float4*>(&cl_s[cb]);
    f32x4 y = acc[af];
    y[0] = (y[0]-m4)*rs*gv.x + bb.x + 0.5f*cv.x;
    y[1] = (y[1]-m4)*rs*gv.y + bb.y + 0.5f*cv.y;
    y[2] = (y[2]-m4)*rs*gv.z + bb.z + 0.5f*cv.z;
    y[3] = (y[3]-m4)*rs*gv.w + bb.w + 0.5f*cv.w;
    acc[af] = y;
    s2 += y[0]*y[0]+y[1]*y[1]+y[2]*y[2]+y[3]*y[3];
  }
  s2 += __shfl_xor(s2, 16); s2 += __shfl_xor(s2, 32);
  float inv = 1.0f/fmaxf(sqrtf(s2), 1e-12f);
  float sm = 0.f;
  #pragma unroll
  for (int af = 0; af < 24; ++af){
    f32x4 y = acc[af];
    y[0]*=inv; y[1]*=inv; y[2]*=inv; y[3]*=inv;
    acc[af] = y;
    sm += y[0]+y[1]+y[2]+y[3];
  }
  sm += __shfl_xor(sm, 16); sm += __shfl_xor(sm, 32);
  sm *= (1.0f/384.0f);
  if (tr < 196){
    ushort_t* dst = Qo + ((size_t)b*196 + tr)*384 + kg*4;
    #pragma unroll
    for (int af = 0; af < 24; ++af){
      f32x4 y = acc[af];
      uint2 pk;
      pk.x = f2b(y[0]-sm) | (f2b(y[1]-sm)<<16);
      pk.y = f2b(y[2]-sm) | (f2b(y[3]-sm)<<16);
      *reinterpret_cast<uint2*>(dst + af*16) = pk;
    }
  }
}

// ---------------- I: batched einsum + fused 2x2 pooling (MFMA) ----------------
// grid 512*16 (b, qt, st), block 256 = 4 waves; wave = 32x32 output tile.
__global__ __launch_bounds__(256) void k_sim(
    const ushort_t* __restrict__ Q, const ushort_t* __restrict__ S,
    float* __restrict__ P){
  int bx = blockIdx.x;
  int b = bx >> 4, qt = (bx >> 2) & 3, st = bx & 3;
  int tid = threadIdx.x;
  int w = tid >> 6, lane = tid & 63;
  int wr = w >> 1, wc = w & 1;
  int q0 = qt*64 + wr*32, s0 = st*64 + wc*32;
  int rrow = lane & 15, kg = lane >> 4;
  const ushort_t* Qb_ = Q + (size_t)b*196*384;
  const ushort_t* Sb_ = S + (size_t)b*196*384;
  int qr0 = min(q0 + rrow, 195), qr1 = min(q0 + 16 + rrow, 195);
  int sr0 = min(s0 + rrow, 195), sr1 = min(s0 + 16 + rrow, 195);
  const ushort_t* qp0 = Qb_ + (size_t)qr0*384 + kg*8;
  const ushort_t* qp1 = Qb_ + (size_t)qr1*384 + kg*8;
  const ushort_t* sp0 = Sb_ + (size_t)sr0*384 + kg*8;
  const ushort_t* sp1 = Sb_ + (size_t)sr1*384 + kg*8;
  f32x4 acc00 = {0.f,0.f,0.f,0.f}, acc01 = {0.f,0.f,0.f,0.f};
  f32x4 acc10 = {0.f,0.f,0.f,0.f}, acc11 = {0.f,0.f,0.f,0.f};
  for (int k0 = 0; k0 < 384; k0 += 32){
    bf16x8 a0 = *reinterpret_cast<const bf16x8*>(qp0 + k0);
    bf16x8 a1 = *reinterpret_cast<const bf16x8*>(qp1 + k0);
    bf16x8 b0 = *reinterpret_cast<const bf16x8*>(sp0 + k0);
    bf16x8 b1 = *reinterpret_cast<const bf16x8*>(sp1 + k0);
    acc00 = __builtin_amdgcn_mfma_f32_16x16x32_bf16(a0, b0, acc00, 0, 0, 0);
    acc01 = __builtin_amdgcn_mfma_f32_16x16x32_bf16(a0, b1, acc01, 0, 0, 0);
    acc10 = __builtin_amdgcn_mfma_f32_16x16x32_bf16(a1, b0, acc10, 0, 0, 0);
    acc11 = __builtin_amdgcn_mfma_f32_16x16x32_bf16(a1, b1, acc11, 0, 0, 0);
  }
  int c = lane & 15, g = lane >> 4;
  float* Pb = P + (size_t)b*98*98;
  #pragma unroll
  for (int i = 0; i < 2; ++i){
    #pragma unroll
    for (int j = 0; j < 2; ++j){
      f32x4 v = (i==0) ? (j==0 ? acc00 : acc01) : (j==0 ? acc10 : acc11);
      float p0 = v[0] + v[1];   // rows 4g, 4g+1
      float p1 = v[2] + v[3];   // rows 4g+2, 4g+3
      float t0 = p0 + __shfl_xor(p0, 1);
      float t1 = p1 + __shfl_xor(p1, 1);
      if (!(c & 1)){
        int qp = (q0 + 16*i + 4*g) >> 1;
        int sp = (s0 + 16*j + c) >> 1;
        if (sp < 98){
          if (qp     < 98) Pb[(size_t)(qp    )*98 + sp] = 0.25f*t0;
          if (qp + 1 < 98) Pb[(size_t)(qp + 1)*98 + sp] = 0.25f*t1;
        }
      }
    }
  }
}

// ---------------- J1: fc2 split-K GEMM  Cpart[ks] = P2-chunk @ w1-chunk ----------------
// grid 64*14 (m-block of 8 rows, k-split of 686), block 256 (= N columns)
__global__ __launch_bounds__(256) void k_fc2a(
    const float* __restrict__ P, const float* __restrict__ w1,
    float* __restrict__ Cpart){
  __shared__ float p2[8][688];
  int bx = blockIdx.x;
  int mb = bx & 63, ks = bx >> 6;      // 14 k-splits of 686 (14*686 = 9604)
  int b0 = mb*8, k0 = ks*686;
  int tid = threadIdx.x;
  for (int idx = tid; idx < 8*686; idx += 256){
    int r = idx / 686, i = idx - r*686;
    float v = P[(size_t)(b0+r)*9604 + k0 + i];
    p2[r][i] = v*v;
  }
  __syncthreads();
  float acc[8];
  #pragma unroll
  for (int r=0;r<8;++r) acc[r]=0.f;
  for (int ii=0; ii<686; ++ii){
    float w = w1[(size_t)(k0+ii)*256 + tid];
    #pragma unroll
    for (int r=0;r<8;++r) acc[r] += p2[r][ii]*w;
  }
  #pragma unroll
  for (int r=0;r<8;++r) Cpart[((size_t)ks*512 + b0 + r)*256 + tid] = acc[r];
}

// ---------------- J2: fc2 reduce + gelu + w2 dot ----------------
// grid 512 (one b each), block 256
__global__ __launch_bounds__(256) void k_fc2b(
    const float* __restrict__ Cpart, const float* __restrict__ b1,
    const float* __restrict__ w2, const float* __restrict__ b2,
    float* __restrict__ outp){
  __shared__ float red[4];
  int b = blockIdx.x, tid = threadIdx.x;
  float s = 0.f;
  for (int ks = 0; ks < 14; ++ks) s += Cpart[((size_t)ks*512 + b)*256 + tid];
  float h = geluf(s + b1[tid]) * w2[tid];
  #pragma unroll
  for (int o=32;o;o>>=1) h += __shfl_down(h,o);
  int w = tid >> 6, lane = tid & 63;
  if (lane==0) red[w] = h;
  __syncthreads();
  if (tid==0) outp[b] = red[0]+red[1]+red[2]+red[3] + b2[0];
}

// ---------------- launch ----------------
extern "C" void kernel_launch(void* const* d_in, const int* in_sizes, int n_in,
                              void* d_out, int out_size, void* d_ws, size_t ws_size,
                              hipStream_t stream){
  const float* fq  = (const float*)d_in[0];
  const float* fs  = (const float*)d_in[1];
  const float* fqs = (const float*)d_in[2];
  const float* fss = (const float*)d_in[3];
  const float* fc1_w1 = (const float*)d_in[4];
  const float* fc1_b1 = (const float*)d_in[5];
  const float* fc1_w2 = (const float*)d_in[6];
  const float* fc1_b2 = (const float*)d_in[7];
  const float* ln1_g = (const float*)d_in[8];
  const float* ln1_b = (const float*)d_in[9];
  const float* fc3_w1 = (const float*)d_in[10];
  const float* fc3_b1 = (const float*)d_in[11];
  const float* fc3_w2 = (const float*)d_in[12];
  const float* fc3_b2 = (const float*)d_in[13];
  const float* ln3_g = (const float*)d_in[14];
  const float* ln3_b = (const float*)d_in[15];
  const float* fc4_w1 = (const float*)d_in[16];
  const float* fc4_b1 = (const float*)d_in[17];
  const float* fc4_w2 = (const float*)d_in[18];
  const float* fc4_b2 = (const float*)d_in[19];
  const float* ln4_g = (const float*)d_in[20];
  const float* ln4_b = (const float*)d_in[21];
  const float* fc2_w1 = (const float*)d_in[22];
  const float* fc2_b1 = (const float*)d_in[23];
  const float* fc2_w2 = (const float*)d_in[24];
  const float* fc2_b2 = (const float*)d_in[25];
  const float* cs_w1 = (const float*)d_in[26];
  const float* cs_b1 = (const float*)d_in[27];
  const float* cs_w2 = (const float*)d_in[28];
  const float* cs_b2 = (const float*)d_in[29];
  float* out = (float*)d_out;
  char* ws = (char*)d_ws;
  // ws layout (bytes):
  //   meanb f32 @0           (3,145,728)
  //   mlp1  f32 @3145728     (3,145,728)
  //   mu    f32 @6291456     (1,613,824)
  //   rstd  f32 @7905280     (1,613,824)
  //   h3    bf16 @9519104    (50,331,648)  [reused for h4 bf16 38.5MB, then P f32 19.7MB]
  //   Cpart f32 @29188096    (7,340,032)   [after P; inside old h3 region]
  //   w2t   bf16 @36528128   (73,728)
  //   Qb    bf16 @59850752   (77,070,336)
  //   Sb    bf16 @136921088  (77,070,336)
  //   total 213,991,424 B
  float* meanb  = (float*)(ws + 0);
  float* mlp1   = (float*)(ws + 3145728);
  float* mu     = (float*)(ws + 6291456);
  float* rstd   = (float*)(ws + 7905280);
  ushort_t* h3  = (ushort_t*)(ws + 9519104);
  ushort_t* h4  = (ushort_t*)(ws + 9519104);  // overlays h3 (dead after 2nd fc3b)
  float* P      = (float*)(ws + 9519104);     // overlays h4 (dead after fc4b)
  float* Cpart  = (float*)(ws + 29188096);    // after P, before Qb
  ushort_t* w2t = (ushort_t*)(ws + 36528128);
  ushort_t* Qb  = (ushort_t*)(ws + 59850752);
  ushort_t* Sb  = (ushort_t*)(ws + 136921088);
  const size_t H4S = (size_t)512*196*96;      // per-s-half h4 elements

  k_w2t<<<144, 256, 0, stream>>>(fc4_w2, w2t);
  k_mean<<<2048, 384, 0, stream>>>(fq, fs, fqs, fss, meanb);
  k_fc1<<<2048, 384, 0, stream>>>(meanb, fc1_w1, fc1_b1, fc1_w2, fc1_b2, mlp1);
  k_stats<<<100864, 256, 0, stream>>>(fq, fs, fqs, fss, mlp1, mu, rstd);
  k_class<<<1024, 384, 0, stream>>>(fq, fs, mlp1, mu, rstd, ln1_g, ln1_b, out);
  k_cosine<<<512, 384, 0, stream>>>(cs_w1, cs_b1, cs_w2, cs_b2, out);
  k_fc3a<<<3072, 256, 0, stream>>>(fqs, mlp1 + (size_t)2*512*384, mu + 2*100864, rstd + 2*100864,
                                   ln1_g, ln1_b, fc3_w1, fc3_b1, h3);
  k_fc3b<<<3072, 256, 0, stream>>>(h3, fc3_w2, fc3_b2, ln3_g, ln3_b, Qb);
  k_fc3a<<<3072, 256, 0, stream>>>(fss, mlp1 + (size_t)3*512*384, mu + 3*100864, rstd + 3*100864,
                                   ln1_g, ln1_b, fc3_w1, fc3_b1, h3);
  k_fc3b<<<3072, 256, 0, stream>>>(h3, fc3_w2, fc3_b2, ln3_g, ln3_b, Sb);
  // fc4 stage A: q then s (pre-offset pointers, no runtime s-select)
  k_fc4a<<<6656, 256, 0, stream>>>(fq, mlp1, mu, rstd, ln1_g, ln1_b,
                                   Qb, fc4_w1, fc4_b1, h4);
  k_fc4a<<<6656, 256, 0, stream>>>(fs, mlp1 + (size_t)512*384, mu + 100864, rstd + 100864,
                                   ln1_g, ln1_b, Sb, fc4_w1, fc4_b1, h4 + H4S);
  // fc4 stage B (MFMA): q then s (Qb/Sb overwritten in place after their last read)
  k_fc4b<<<2048, 256, 0, stream>>>(h4,       w2t, fc4_b2, ln4_g, ln4_b, out + 1024,          Qb);
  k_fc4b<<<2048, 256, 0, stream>>>(h4 + H4S, w2t, fc4_b2, ln4_g, ln4_b, out + 1024 + 196608, Sb);
  k_sim<<<8192, 256, 0, stream>>>(Qb, Sb, P);
  // fc2 head: split-K GEMM (896 blocks) + tiny reduce
  k_fc2a<<<896, 256, 0, stream>>>(P, fc2_w1, Cpart);
  k_fc2b<<<512, 256, 0, stream>>>(Cpart, fc2_b1, fc2_w2, fc2_b2, out);
}

// Round 9
// 2034.540 us; speedup vs baseline: 16.2632x; 1.1241x over previous
//
#include <hip/hip_runtime.h>
#include <math.h>

typedef unsigned short ushort_t;
typedef __attribute__((ext_vector_type(8))) short bf16x8;
typedef __attribute__((ext_vector_type(4))) float f32x4;

// ---------------- helpers ----------------
__device__ __forceinline__ float geluf(float x){
  return 0.5f*x*(1.0f+erff(x*0.70710678118654752440f));
}
__device__ __forceinline__ float bfu(unsigned int u){
  union { unsigned int i; float f; } v; v.i = (u & 0xffffu) << 16; return v.f;
}
__device__ __forceinline__ unsigned int f2b(float f){
  union { float f; unsigned int i; } v; v.f = f;
  unsigned int r = v.i + 0x7fffu + ((v.i >> 16) & 1u);
  return (r >> 16);
}

// Problem constants
// B=512, N=197, C=384, T=196 image tokens
// d_out layout (floats): out[512] | cosine[512] | query_class[512*384] | support_class[512*384]

// ---------------- A: token means (per tensor, b, c) ----------------
__global__ __launch_bounds__(384) void k_mean(
    const float* __restrict__ x0, const float* __restrict__ x1,
    const float* __restrict__ x2, const float* __restrict__ x3,
    float* __restrict__ meanb){
  int s = blockIdx.x >> 9, b = blockIdx.x & 511, c = threadIdx.x;
  const float* x = (s==0)?x0:(s==1)?x1:(s==2)?x2:x3;
  const float* p = x + ((size_t)b*197)*384 + c;
  float acc = 0.f;
  #pragma unroll 4
  for (int t=0;t<197;++t) acc += p[(size_t)t*384];
  meanb[((size_t)s*512+b)*384+c] = acc*(1.0f/197.0f);
}

// ---------------- B: fc1 tiny MLP on means ----------------
__global__ __launch_bounds__(384) void k_fc1(
    const float* __restrict__ meanb, const float* __restrict__ w1,
    const float* __restrict__ b1, const float* __restrict__ w2,
    const float* __restrict__ b2, float* __restrict__ mlp1){
  __shared__ float ms[384];
  __shared__ float hs[96];
  int row = blockIdx.x, tid = threadIdx.x;
  ms[tid] = meanb[(size_t)row*384 + tid];
  __syncthreads();
  if (tid < 96){
    float a = b1[tid];
    for (int c=0;c<384;++c) a += ms[c]*w1[c*96+tid];
    hs[tid] = geluf(a);
  }
  __syncthreads();
  float a = b2[tid];
  for (int j=0;j<96;++j) a += hs[j]*w2[j*384+tid];
  mlp1[(size_t)row*384 + tid] = a;
}

// ---------------- C: per-row LN stats of (x + mlp1) ----------------
__global__ __launch_bounds__(256) void k_stats(
    const float* __restrict__ x0, const float* __restrict__ x1,
    const float* __restrict__ x2, const float* __restrict__ x3,
    const float* __restrict__ mlp1, float* __restrict__ mu, float* __restrict__ rstd){
  int lane = threadIdx.x & 63, w = threadIdx.x >> 6;
  int row = blockIdx.x*4 + w;           // rows = 4*512*197 = 403456, grid exact
  int s = row / 100864;
  int rr = row % 100864;
  int b = rr / 197, t = rr % 197;
  const float* x = (s==0)?x0:(s==1)?x1:(s==2)?x2:x3;
  const float* xp = x + ((size_t)b*197 + t)*384;
  const float* mp = mlp1 + ((size_t)s*512 + b)*384;
  float sum=0.f, sq=0.f;
  for (int i=lane;i<384;i+=64){ float v = xp[i]+mp[i]; sum+=v; sq+=v*v; }
  #pragma unroll
  for (int o=32;o;o>>=1){ sum+=__shfl_down(sum,o); sq+=__shfl_down(sq,o); }
  if (lane==0){
    float m = sum*(1.0f/384.0f);
    mu[row] = m;
    rstd[row] = rsqrtf(sq*(1.0f/384.0f) - m*m + 1e-5f);
  }
}

// ---------------- D: class token rows -> d_out ----------------
__global__ __launch_bounds__(384) void k_class(
    const float* __restrict__ x0, const float* __restrict__ x1,
    const float* __restrict__ mlp1, const float* __restrict__ mu,
    const float* __restrict__ rstd, const float* __restrict__ g1,
    const float* __restrict__ bb1, float* __restrict__ dout){
  int s = blockIdx.x >> 9, b = blockIdx.x & 511, c = threadIdx.x;
  const float* x = s ? x1 : x0;
  int srow = (s*512 + b)*197;
  float v = x[((size_t)b*197)*384 + c] + mlp1[((size_t)s*512+b)*384 + c];
  float y = (v - mu[srow])*rstd[srow]*g1[c] + bb1[c];
  dout[1024 + (size_t)s*196608 + (size_t)b*384 + c] = y;
}

// ---------------- E: cosine head on class tokens ----------------
__global__ __launch_bounds__(384) void k_cosine(
    const float* __restrict__ w1, const float* __restrict__ b1,
    const float* __restrict__ w2, const float* __restrict__ b2,
    float* __restrict__ dout){
  __shared__ float qrow[384], srw[384], hq[96], hs[96];
  __shared__ float rd0[384], rd1[384], rd2[384];
  int b = blockIdx.x, tid = threadIdx.x;
  qrow[tid] = dout[1024   + (size_t)b*384 + tid];
  srw[tid]  = dout[197632 + (size_t)b*384 + tid];
  __syncthreads();
  if (tid < 96){
    float a = b1[tid];
    for (int c=0;c<384;++c) a += qrow[c]*w1[c*96+tid];
    hq[tid] = geluf(a);
  } else if (tid < 192){
    int j = tid - 96;
    float a = b1[j];
    for (int c=0;c<384;++c) a += srw[c]*w1[c*96+j];
    hs[j] = geluf(a);
  }
  __syncthreads();
  float qx = b2[tid], sy = b2[tid];
  for (int j=0;j<96;++j){ qx += hq[j]*w2[j*384+tid]; sy += hs[j]*w2[j*384+tid]; }
  rd0[tid] = qx*sy; rd1[tid] = qx*qx; rd2[tid] = sy*sy;
  __syncthreads();
  if (tid < 64){
    float d=0.f,nq=0.f,ns=0.f;
    for (int i=tid;i<384;i+=64){ d+=rd0[i]; nq+=rd1[i]; ns+=rd2[i]; }
    #pragma unroll
    for (int o=32;o;o>>=1){ d+=__shfl_down(d,o); nq+=__shfl_down(nq,o); ns+=__shfl_down(ns,o); }
    if (tid==0) dout[512 + b] = d / (fmaxf(sqrtf(nq),1e-8f)*fmaxf(sqrtf(ns),1e-8f));
  }
}

// ---------------- F: fc3 GEMM1  h = gelu(X^T @ w1 + b1) ----------------
// grid 512*6 (b, c-tile of 64), block 256
__global__ __launch_bounds__(256) void k_fc3a(
    const float* __restrict__ x, const float* __restrict__ mlp1t,
    const float* __restrict__ mut, const float* __restrict__ rstdt,
    const float* __restrict__ g1, const float* __restrict__ bb1,
    const float* __restrict__ w1, const float* __restrict__ b1,
    ushort_t* __restrict__ h3){
  __shared__ ushort_t A[196][64];     // bf16 LN'd x^T tile [t][c]
  __shared__ ushort_t W[196][128];    // bf16 w1
  int b = blockIdx.x/6, ct = blockIdx.x%6, c0 = ct*64;
  int tid = threadIdx.x;
  for (int i = tid; i < 196*128; i += 256) (&W[0][0])[i] = (ushort_t)f2b(w1[i]);
  {
    int cl = tid & 63, tg = tid >> 6;
    const float* mrow = mlp1t + (size_t)b*384;
    for (int t = tg; t < 196; t += 4){
      int c = c0 + cl;
      int srow = b*197 + (t+1);
      float v = x[((size_t)b*197 + (t+1))*384 + c] + mrow[c];
      float y = (v - mut[srow])*rstdt[srow]*g1[c] + bb1[c];
      A[t][cl] = (ushort_t)f2b(y);
    }
  }
  __syncthreads();
  int ci = tid >> 4, ji = tid & 15;
  float acc[4][8];
  #pragma unroll
  for (int i=0;i<4;++i)
    #pragma unroll
    for (int k=0;k<8;++k) acc[i][k]=0.f;
  for (int t = 0; t < 196; ++t){
    uint2 av = *reinterpret_cast<const uint2*>(&A[t][ci*4]);
    uint4 wv = *reinterpret_cast<const uint4*>(&W[t][ji*8]);
    float a[4] = { bfu(av.x), bfu(av.x>>16), bfu(av.y), bfu(av.y>>16) };
    float w[8] = { bfu(wv.x), bfu(wv.x>>16), bfu(wv.y), bfu(wv.y>>16),
                   bfu(wv.z), bfu(wv.z>>16), bfu(wv.w), bfu(wv.w>>16) };
    #pragma unroll
    for (int i=0;i<4;++i)
      #pragma unroll
      for (int k=0;k<8;++k) acc[i][k] += a[i]*w[k];
  }
  #pragma unroll
  for (int i=0;i<4;++i){
    int c = c0 + ci*4 + i;
    unsigned int hv[8];
    #pragma unroll
    for (int k=0;k<8;++k){
      int j = ji*8+k;
      hv[k] = f2b(geluf(acc[i][k] + b1[j]));
    }
    uint4 pk;
    pk.x = hv[0] | (hv[1]<<16);
    pk.y = hv[2] | (hv[3]<<16);
    pk.z = hv[4] | (hv[5]<<16);
    pk.w = hv[6] | (hv[7]<<16);
    *reinterpret_cast<uint4*>(&h3[((size_t)b*384 + c)*128 + ji*8]) = pk;
  }
}

// ---------------- G: fc3 GEMM2 + LN over t', write transposed ----------------
// grid 512*6 (b, c-tile of 64), block 256
__global__ __launch_bounds__(256) void k_fc3b(
    const ushort_t* __restrict__ h3, const float* __restrict__ w2,
    const float* __restrict__ b2, const float* __restrict__ g3,
    const float* __restrict__ b3, ushort_t* __restrict__ Qout){
  __shared__ ushort_t H[128][68];     // bf16 h transposed [j][c], padded
  __shared__ ushort_t W[128][196];    // bf16 w2
  __shared__ float red[2][64][16];
  int b = blockIdx.x/6, ct = blockIdx.x%6, c0 = ct*64;
  int tid = threadIdx.x;
  for (int i = tid; i < 64*32; i += 256){
    int c = i >> 5, jq = i & 31;
    uint2 v = *reinterpret_cast<const uint2*>(&h3[((size_t)b*384 + c0 + c)*128 + jq*4]);
    H[jq*4+0][c] = (ushort_t)(v.x & 0xffffu);
    H[jq*4+1][c] = (ushort_t)(v.x >> 16);
    H[jq*4+2][c] = (ushort_t)(v.y & 0xffffu);
    H[jq*4+3][c] = (ushort_t)(v.y >> 16);
  }
  for (int i = tid; i < 128*196; i += 256) (&W[0][0])[i] = (ushort_t)f2b(w2[i]);
  __syncthreads();
  int cg = tid >> 4, tg = tid & 15;
  float acc[4][14];
  #pragma unroll
  for (int i=0;i<4;++i)
    #pragma unroll
    for (int k=0;k<14;++k) acc[i][k]=0.f;
  for (int j = 0; j < 128; ++j){
    uint2 hv = *reinterpret_cast<const uint2*>(&H[j][cg*4]);
    float h[4] = { bfu(hv.x), bfu(hv.x>>16), bfu(hv.y), bfu(hv.y>>16) };
    #pragma unroll
    for (int k = 0; k < 7; ++k){
      if (k < 6 || tg < 2){    // k=6 valid only for tg<2 (t'=192..195)
        unsigned int wv = *reinterpret_cast<const unsigned int*>(&W[j][2*tg + 32*k]);
        float w0 = bfu(wv), w1v = bfu(wv>>16);
        #pragma unroll
        for (int i=0;i<4;++i){
          acc[i][2*k]   += h[i]*w0;
          acc[i][2*k+1] += h[i]*w1v;
        }
      }
    }
  }
  // bias + LN stats over t' (per c-row)
  float psum[4]={0,0,0,0}, psq[4]={0,0,0,0};
  #pragma unroll
  for (int sl=0; sl<14; ++sl){
    int t = 2*tg + 32*(sl>>1) + (sl&1);
    if (t < 196){
      #pragma unroll
      for (int i=0;i<4;++i){
        float y = acc[i][sl] + b2[t];
        acc[i][sl] = y;
        psum[i] += y; psq[i] += y*y;
      }
    }
  }
  #pragma unroll
  for (int i=0;i<4;++i){ red[0][cg*4+i][tg]=psum[i]; red[1][cg*4+i][tg]=psq[i]; }
  __syncthreads();
  float mu4[4], rs4[4];
  #pragma unroll
  for (int i=0;i<4;++i){
    float ssv=0.f, qv=0.f;
    #pragma unroll
    for (int u=0;u<16;++u){ ssv += red[0][cg*4+i][u]; qv += red[1][cg*4+i][u]; }
    float m = ssv*(1.0f/196.0f);
    mu4[i]=m; rs4[i]=rsqrtf(qv*(1.0f/196.0f)-m*m+1e-5f);
  }
  #pragma unroll
  for (int sl=0; sl<14; ++sl){
    int t = 2*tg + 32*(sl>>1) + (sl&1);
    if (t < 196){
      float g = g3[t], bb = b3[t];
      unsigned int o0 = f2b((acc[0][sl]-mu4[0])*rs4[0]*g + bb);
      unsigned int o1 = f2b((acc[1][sl]-mu4[1])*rs4[1]*g + bb);
      unsigned int o2 = f2b((acc[2][sl]-mu4[2])*rs4[2]*g + bb);
      unsigned int o3 = f2b((acc[3][sl]-mu4[3])*rs4[3]*g + bb);
      uint2 pk; pk.x = o0 | (o1<<16); pk.y = o2 | (o3<<16);
      *reinterpret_cast<uint2*>(&Qout[((size_t)b*196 + t)*384 + c0 + cg*4]) = pk;
    }
  }
}

// ---------------- W: transpose fc4 weights -> bf16 (w2t [384][96], w1t [96][384]) ----------------
// grid 288, block 256 (288*256 = 73728 = 2*36864).
// NOTE: w1t/w2t live in the DEAD meanb region (ws+0), written AFTER k_fc1's last
// meanb read and never overwritten again. Round-8 bug: they sat inside the
// h3/h4 overlay region and were clobbered by fc3a/fc4a writes (absmax 0.38).
__global__ __launch_bounds__(256) void k_wt(
    const float* __restrict__ w1, const float* __restrict__ w2,
    ushort_t* __restrict__ w1t, ushort_t* __restrict__ w2t){
  int idx = blockIdx.x*256 + threadIdx.x;
  if (idx < 36864){
    int c = idx / 96, j = idx - c*96;
    w2t[idx] = (ushort_t)f2b(w2[(size_t)j*384 + c]);   // w2 [96][384] -> w2t [384][96]
  } else {
    int k = idx - 36864;
    int j = k / 384, c = k - j*384;
    w1t[k] = (ushort_t)f2b(w1[(size_t)c*96 + j]);      // w1 [384][96] -> w1t [96][384]
  }
}

// ---------------- H1: fc4 stage A (MFMA; one s-half per launch) ----------------
// grid 512*4 (b, t-tile of 64), block 256 = 4 waves; wave = 16 t x 96 j.
// Phase 1: Z = LN1(x)*Qin -> bf16 LDS tile [64][392].
// Phase 2: A = w1t rows (j -> D row), B = Z rows (t -> D col), 12 k-steps x 6 j-frags
// = 72 MFMA/wave (k_fc4b-validated fragment recipe). gelu+bias epilogue -> h4 bf16.
__global__ __launch_bounds__(256) void k_fc4a(
    const float* __restrict__ x,         // fq or fs
    const float* __restrict__ m1_base,   // mlp1 + s*512*384
    const float* __restrict__ mu_s,      // mu + s*100864
    const float* __restrict__ rstd_s,    // rstd + s*100864
    const float* __restrict__ g1, const float* __restrict__ bln1,
    const ushort_t* __restrict__ Qin,    // Qb or Sb
    const ushort_t* __restrict__ w1t,    // [96][384] bf16
    const float* __restrict__ b1mlp,
    ushort_t* __restrict__ h4s){         // h4 + s*512*196*96
  __shared__ ushort_t Zs[64][392];       // bf16 Z tile, padded stride
  __shared__ float m1s[384], g1s[384], b1s[384];
  __shared__ float mus[64], rss[64];
  __shared__ float b1m[96];
  int bid = blockIdx.x;
  int b = bid >> 2, tt0 = (bid & 3)*64;
  int tid = threadIdx.x;
  const float* m1 = m1_base + (size_t)b*384;
  for (int i = tid; i < 384; i += 256){ m1s[i] = m1[i]; g1s[i] = g1[i]; b1s[i] = bln1[i]; }
  if (tid < 96) b1m[tid] = b1mlp[tid];
  if (tid < 64){
    int t = tt0 + tid; int tc = t < 196 ? t : 195;
    mus[tid] = mu_s[b*197 + tc + 1]; rss[tid] = rstd_s[b*197 + tc + 1];
  }
  __syncthreads();
  // phase 1: Z build, 64 rows x 96 col4-slots = 6144 slots, 24 per thread
  for (int e = 0; e < 24; ++e){
    int v = e*256 + tid;
    int row = v/96, col4 = v - row*96;
    int t = tt0 + row; int tc = t < 196 ? t : 195;
    float valid = (t < 196) ? 1.f : 0.f;
    float4 xv = *reinterpret_cast<const float4*>(&x[((size_t)b*197 + tc + 1)*384 + col4*4]);
    uint2 qv = *reinterpret_cast<const uint2*>(&Qin[((size_t)b*196 + tc)*384 + col4*4]);
    float muv = mus[row], rsv = rss[row];
    int c = col4*4;
    float z0 = (((xv.x + m1s[c+0]) - muv)*rsv*g1s[c+0] + b1s[c+0]) * bfu(qv.x)      * valid;
    float z1 = (((xv.y + m1s[c+1]) - muv)*rsv*g1s[c+1] + b1s[c+1]) * bfu(qv.x>>16)  * valid;
    float z2 = (((xv.z + m1s[c+2]) - muv)*rsv*g1s[c+2] + b1s[c+2]) * bfu(qv.y)      * valid;
    float z3 = (((xv.w + m1s[c+3]) - muv)*rsv*g1s[c+3] + b1s[c+3]) * bfu(qv.y>>16)  * valid;
    uint2 pk; pk.x = f2b(z0) | (f2b(z1)<<16); pk.y = f2b(z2) | (f2b(z3)<<16);
    *reinterpret_cast<uint2*>(&Zs[row][col4*4]) = pk;
  }
  __syncthreads();
  // phase 2: MFMA GEMM1 (16t x 96j per wave, K=384)
  int w = tid >> 6, lane = tid & 63;
  int tr = tt0 + w*16 + (lane & 15);
  int kg = lane >> 4;
  f32x4 acc0 = {0.f,0.f,0.f,0.f}, acc1 = {0.f,0.f,0.f,0.f}, acc2 = {0.f,0.f,0.f,0.f};
  f32x4 acc3 = {0.f,0.f,0.f,0.f}, acc4 = {0.f,0.f,0.f,0.f}, acc5 = {0.f,0.f,0.f,0.f};
  const ushort_t* arow = w1t + (size_t)(lane & 15)*384 + kg*8;
  const ushort_t* zrow = &Zs[w*16 + (lane & 15)][kg*8];
  for (int kc = 0; kc < 12; ++kc){
    bf16x8 zb = *reinterpret_cast<const bf16x8*>(zrow + kc*32);
    bf16x8 a0 = *reinterpret_cast<const bf16x8*>(arow + kc*32);
    bf16x8 a1 = *reinterpret_cast<const bf16x8*>(arow + kc*32 + 16*384);
    bf16x8 a2 = *reinterpret_cast<const bf16x8*>(arow + kc*32 + 32*384);
    bf16x8 a3 = *reinterpret_cast<const bf16x8*>(arow + kc*32 + 48*384);
    bf16x8 a4 = *reinterpret_cast<const bf16x8*>(arow + kc*32 + 64*384);
    bf16x8 a5 = *reinterpret_cast<const bf16x8*>(arow + kc*32 + 80*384);
    acc0 = __builtin_amdgcn_mfma_f32_16x16x32_bf16(a0, zb, acc0, 0, 0, 0);
    acc1 = __builtin_amdgcn_mfma_f32_16x16x32_bf16(a1, zb, acc1, 0, 0, 0);
    acc2 = __builtin_amdgcn_mfma_f32_16x16x32_bf16(a2, zb, acc2, 0, 0, 0);
    acc3 = __builtin_amdgcn_mfma_f32_16x16x32_bf16(a3, zb, acc3, 0, 0, 0);
    acc4 = __builtin_amdgcn_mfma_f32_16x16x32_bf16(a4, zb, acc4, 0, 0, 0);
    acc5 = __builtin_amdgcn_mfma_f32_16x16x32_bf16(a5, zb, acc5, 0, 0, 0);
  }
  // epilogue: lane holds j = jb*16 + kg*4 + r (D row), t = tr (D col)
  if (tr < 196){
    ushort_t* dst = h4s + ((size_t)b*196 + tr)*96 + kg*4;
    #pragma unroll
    for (int jb = 0; jb < 6; ++jb){
      f32x4 y = (jb==0)?acc0:(jb==1)?acc1:(jb==2)?acc2:(jb==3)?acc3:(jb==4)?acc4:acc5;
      int j0 = jb*16 + kg*4;
      uint2 pk;
      pk.x = f2b(geluf(y[0]+b1m[j0+0])) | (f2b(geluf(y[1]+b1m[j0+1]))<<16);
      pk.y = f2b(geluf(y[2]+b1m[j0+2])) | (f2b(geluf(y[3]+b1m[j0+3]))<<16);
      *reinterpret_cast<uint2*>(dst + jb*16) = pk;
    }
  }
}

// ---------------- H2: fc4 stage B (MFMA; one s-half per launch) ----------------
// grid 512*4 (b, t-tile of 64), block 256 = 4 waves; wave = 16 t x 384 c.
__global__ __launch_bounds__(256) void k_fc4b(
    const ushort_t* __restrict__ h4s,    // h4 + s*512*196*96
    const ushort_t* __restrict__ w2t,    // [384][96] bf16
    const float* __restrict__ b2, const float* __restrict__ g4,
    const float* __restrict__ bb4,
    const float* __restrict__ cls_base,  // dout + 1024 + s*196608
    ushort_t* __restrict__ Qo){          // Qb or Sb
  __shared__ float b2s[384], g4s[384], b4s[384], cl_s[384];
  int bid = blockIdx.x;
  int b = bid >> 2, ttile = bid & 3;
  int tid = threadIdx.x, w = tid >> 6, lane = tid & 63;
  const float* cls = cls_base + (size_t)b*384;
  for (int i = tid; i < 384; i += 256){
    b2s[i] = b2[i]; g4s[i] = g4[i]; b4s[i] = bb4[i]; cl_s[i] = cls[i];
  }
  __syncthreads();
  int tr = ttile*64 + w*16 + (lane & 15);
  int trc = tr < 196 ? tr : 195;
  int kg = lane >> 4;
  const ushort_t* hp = h4s + ((size_t)b*196 + trc)*96 + kg*8;
  bf16x8 hb0 = *reinterpret_cast<const bf16x8*>(hp);
  bf16x8 hb1 = *reinterpret_cast<const bf16x8*>(hp + 32);
  bf16x8 hb2 = *reinterpret_cast<const bf16x8*>(hp + 64);
  const ushort_t* ap_base = w2t + (size_t)(lane & 15)*96 + kg*8;
  f32x4 acc[24];
  #pragma unroll
  for (int af = 0; af < 24; ++af){
    const ushort_t* ap = ap_base + (size_t)af*16*96;
    bf16x8 a0 = *reinterpret_cast<const bf16x8*>(ap);
    bf16x8 a1 = *reinterpret_cast<const bf16x8*>(ap + 32);
    bf16x8 a2 = *reinterpret_cast<const bf16x8*>(ap + 64);
    f32x4 z = {0.f,0.f,0.f,0.f};
    z = __builtin_amdgcn_mfma_f32_16x16x32_bf16(a0, hb0, z, 0, 0, 0);
    z = __builtin_amdgcn_mfma_f32_16x16x32_bf16(a1, hb1, z, 0, 0, 0);
    z = __builtin_amdgcn_mfma_f32_16x16x32_bf16(a2, hb2, z, 0, 0, 0);
    acc[af] = z;
  }
  // epilogue: lane holds c = af*16 + kg*4 + r  (r=0..3), t = tr (col)
  float sum = 0.f, sq = 0.f;
  #pragma unroll
  for (int af = 0; af < 24; ++af){
    int cb = af*16 + kg*4;
    float4 bv = *reinterpret_cast<const float4*>(&b2s[cb]);
    f32x4 y = acc[af];
    y[0] += bv.x; y[1] += bv.y; y[2] += bv.z; y[3] += bv.w;
    acc[af] = y;
    sum += y[0]+y[1]+y[2]+y[3];
    sq  += y[0]*y[0]+y[1]*y[1]+y[2]*y[2]+y[3]*y[3];
  }
  sum += __shfl_xor(sum, 16); sum += __shfl_xor(sum, 32);
  sq  += __shfl_xor(sq, 16);  sq  += __shfl_xor(sq, 32);
  float m4 = sum*(1.0f/384.0f);
  float rs = rsqrtf(sq*(1.0f/384.0f) - m4*m4 + 1e-5f);
  float s2 = 0.f;
  #pragma unroll
  for (int af = 0; af < 24; ++af){
    int cb = af*16 + kg*4;
    float4 gv = *reinterpret_cast<const float4*>(&g4s[cb]);
    float4 bb = *reinterpret_cast<const float4*>(&b4s[cb]);
    float4 cv = *reinterpret_cast<const float4*>(&cl_s[cb]);
    f32x4 y = acc[af];
    y[0] = (y[0]-m4)*rs*gv.x + bb.x + 0.5f*cv.x;
    y[1] = (y[1]-m4)*rs*gv.y + bb.y + 0.5f*cv.y;
    y[2] = (y[2]-m4)*rs*gv.z + bb.z + 0.5f*cv.z;
    y[3] = (y[3]-m4)*rs*gv.w + bb.w + 0.5f*cv.w;
    acc[af] = y;
    s2 += y[0]*y[0]+y[1]*y[1]+y[2]*y[2]+y[3]*y[3];
  }
  s2 += __shfl_xor(s2, 16); s2 += __shfl_xor(s2, 32);
  float inv = 1.0f/fmaxf(sqrtf(s2), 1e-12f);
  float sm = 0.f;
  #pragma unroll
  for (int af = 0; af < 24; ++af){
    f32x4 y = acc[af];
    y[0]*=inv; y[1]*=inv; y[2]*=inv; y[3]*=inv;
    acc[af] = y;
    sm += y[0]+y[1]+y[2]+y[3];
  }
  sm += __shfl_xor(sm, 16); sm += __shfl_xor(sm, 32);
  sm *= (1.0f/384.0f);
  if (tr < 196){
    ushort_t* dst = Qo + ((size_t)b*196 + tr)*384 + kg*4;
    #pragma unroll
    for (int af = 0; af < 24; ++af){
      f32x4 y = acc[af];
      uint2 pk;
      pk.x = f2b(y[0]-sm) | (f2b(y[1]-sm)<<16);
      pk.y = f2b(y[2]-sm) | (f2b(y[3]-sm)<<16);
      *reinterpret_cast<uint2*>(dst + af*16) = pk;
    }
  }
}

// ---------------- I: batched einsum + fused 2x2 pooling (MFMA) ----------------
// grid 512*16 (b, qt, st), block 256 = 4 waves; wave = 32x32 output tile.
__global__ __launch_bounds__(256) void k_sim(
    const ushort_t* __restrict__ Q, const ushort_t* __restrict__ S,
    float* __restrict__ P){
  int bx = blockIdx.x;
  int b = bx >> 4, qt = (bx >> 2) & 3, st = bx & 3;
  int tid = threadIdx.x;
  int w = tid >> 6, lane = tid & 63;
  int wr = w >> 1, wc = w & 1;
  int q0 = qt*64 + wr*32, s0 = st*64 + wc*32;
  int rrow = lane & 15, kg = lane >> 4;
  const ushort_t* Qb_ = Q + (size_t)b*196*384;
  const ushort_t* Sb_ = S + (size_t)b*196*384;
  int qr0 = min(q0 + rrow, 195), qr1 = min(q0 + 16 + rrow, 195);
  int sr0 = min(s0 + rrow, 195), sr1 = min(s0 + 16 + rrow, 195);
  const ushort_t* qp0 = Qb_ + (size_t)qr0*384 + kg*8;
  const ushort_t* qp1 = Qb_ + (size_t)qr1*384 + kg*8;
  const ushort_t* sp0 = Sb_ + (size_t)sr0*384 + kg*8;
  const ushort_t* sp1 = Sb_ + (size_t)sr1*384 + kg*8;
  f32x4 acc00 = {0.f,0.f,0.f,0.f}, acc01 = {0.f,0.f,0.f,0.f};
  f32x4 acc10 = {0.f,0.f,0.f,0.f}, acc11 = {0.f,0.f,0.f,0.f};
  for (int k0 = 0; k0 < 384; k0 += 32){
    bf16x8 a0 = *reinterpret_cast<const bf16x8*>(qp0 + k0);
    bf16x8 a1 = *reinterpret_cast<const bf16x8*>(qp1 + k0);
    bf16x8 b0 = *reinterpret_cast<const bf16x8*>(sp0 + k0);
    bf16x8 b1 = *reinterpret_cast<const bf16x8*>(sp1 + k0);
    acc00 = __builtin_amdgcn_mfma_f32_16x16x32_bf16(a0, b0, acc00, 0, 0, 0);
    acc01 = __builtin_amdgcn_mfma_f32_16x16x32_bf16(a0, b1, acc01, 0, 0, 0);
    acc10 = __builtin_amdgcn_mfma_f32_16x16x32_bf16(a1, b0, acc10, 0, 0, 0);
    acc11 = __builtin_amdgcn_mfma_f32_16x16x32_bf16(a1, b1, acc11, 0, 0, 0);
  }
  int c = lane & 15, g = lane >> 4;
  float* Pb = P + (size_t)b*98*98;
  #pragma unroll
  for (int i = 0; i < 2; ++i){
    #pragma unroll
    for (int j = 0; j < 2; ++j){
      f32x4 v = (i==0) ? (j==0 ? acc00 : acc01) : (j==0 ? acc10 : acc11);
      float p0 = v[0] + v[1];   // rows 4g, 4g+1
      float p1 = v[2] + v[3];   // rows 4g+2, 4g+3
      float t0 = p0 + __shfl_xor(p0, 1);
      float t1 = p1 + __shfl_xor(p1, 1);
      if (!(c & 1)){
        int qp = (q0 + 16*i + 4*g) >> 1;
        int sp = (s0 + 16*j + c) >> 1;
        if (sp < 98){
          if (qp     < 98) Pb[(size_t)(qp    )*98 + sp] = 0.25f*t0;
          if (qp + 1 < 98) Pb[(size_t)(qp + 1)*98 + sp] = 0.25f*t1;
        }
      }
    }
  }
}

// ---------------- J1: fc2 split-K GEMM  Cpart[ks] = P2-chunk @ w1-chunk ----------------
// grid 64*14 (m-block of 8 rows, k-split of 686), block 256 (= N columns)
__global__ __launch_bounds__(256) void k_fc2a(
    const float* __restrict__ P, const float* __restrict__ w1,
    float* __restrict__ Cpart){
  __shared__ float p2[8][688];
  int bx = blockIdx.x;
  int mb = bx & 63, ks = bx >> 6;      // 14 k-splits of 686 (14*686 = 9604)
  int b0 = mb*8, k0 = ks*686;
  int tid = threadIdx.x;
  for (int idx = tid; idx < 8*686; idx += 256){
    int r = idx / 686, i = idx - r*686;
    float v = P[(size_t)(b0+r)*9604 + k0 + i];
    p2[r][i] = v*v;
  }
  __syncthreads();
  float acc[8];
  #pragma unroll
  for (int r=0;r<8;++r) acc[r]=0.f;
  for (int ii=0; ii<686; ++ii){
    float w = w1[(size_t)(k0+ii)*256 + tid];
    #pragma unroll
    for (int r=0;r<8;++r) acc[r] += p2[r][ii]*w;
  }
  #pragma unroll
  for (int r=0;r<8;++r) Cpart[((size_t)ks*512 + b0 + r)*256 + tid] = acc[r];
}

// ---------------- J2: fc2 reduce + gelu + w2 dot ----------------
// grid 512 (one b each), block 256
__global__ __launch_bounds__(256) void k_fc2b(
    const float* __restrict__ Cpart, const float* __restrict__ b1,
    const float* __restrict__ w2, const float* __restrict__ b2,
    float* __restrict__ outp){
  __shared__ float red[4];
  int b = blockIdx.x, tid = threadIdx.x;
  float s = 0.f;
  for (int ks = 0; ks < 14; ++ks) s += Cpart[((size_t)ks*512 + b)*256 + tid];
  float h = geluf(s + b1[tid]) * w2[tid];
  #pragma unroll
  for (int o=32;o;o>>=1) h += __shfl_down(h,o);
  int w = tid >> 6, lane = tid & 63;
  if (lane==0) red[w] = h;
  __syncthreads();
  if (tid==0) outp[b] = red[0]+red[1]+red[2]+red[3] + b2[0];
}

// ---------------- launch ----------------
extern "C" void kernel_launch(void* const* d_in, const int* in_sizes, int n_in,
                              void* d_out, int out_size, void* d_ws, size_t ws_size,
                              hipStream_t stream){
  const float* fq  = (const float*)d_in[0];
  const float* fs  = (const float*)d_in[1];
  const float* fqs = (const float*)d_in[2];
  const float* fss = (const float*)d_in[3];
  const float* fc1_w1 = (const float*)d_in[4];
  const float* fc1_b1 = (const float*)d_in[5];
  const float* fc1_w2 = (const float*)d_in[6];
  const float* fc1_b2 = (const float*)d_in[7];
  const float* ln1_g = (const float*)d_in[8];
  const float* ln1_b = (const float*)d_in[9];
  const float* fc3_w1 = (const float*)d_in[10];
  const float* fc3_b1 = (const float*)d_in[11];
  const float* fc3_w2 = (const float*)d_in[12];
  const float* fc3_b2 = (const float*)d_in[13];
  const float* ln3_g = (const float*)d_in[14];
  const float* ln3_b = (const float*)d_in[15];
  const float* fc4_w1 = (const float*)d_in[16];
  const float* fc4_b1 = (const float*)d_in[17];
  const float* fc4_w2 = (const float*)d_in[18];
  const float* fc4_b2 = (const float*)d_in[19];
  const float* ln4_g = (const float*)d_in[20];
  const float* ln4_b = (const float*)d_in[21];
  const float* fc2_w1 = (const float*)d_in[22];
  const float* fc2_b1 = (const float*)d_in[23];
  const float* fc2_w2 = (const float*)d_in[24];
  const float* fc2_b2 = (const float*)d_in[25];
  const float* cs_w1 = (const float*)d_in[26];
  const float* cs_b1 = (const float*)d_in[27];
  const float* cs_w2 = (const float*)d_in[28];
  const float* cs_b2 = (const float*)d_in[29];
  float* out = (float*)d_out;
  char* ws = (char*)d_ws;
  // ws layout (bytes):
  //   meanb f32 @0           (3,145,728)   [dead after k_fc1; first 147KB reused for w2t/w1t]
  //     w2t bf16 @0          (73,728)      [written by k_wt AFTER k_fc1]
  //     w1t bf16 @73728      (73,728)
  //   mlp1  f32 @3145728     (3,145,728)
  //   mu    f32 @6291456     (1,613,824)
  //   rstd  f32 @7905280     (1,613,824)
  //   h3    bf16 @9519104    (50,331,648)  [reused for h4 bf16 38.5MB, then P f32 + Cpart]
  //   Cpart f32 @29188096    (7,340,032)   [after P; h4 dead by k_fc2a]
  //   Qb    bf16 @59850752   (77,070,336)
  //   Sb    bf16 @136921088  (77,070,336)
  //   total 213,991,424 B
  float* meanb  = (float*)(ws + 0);
  ushort_t* w2t = (ushort_t*)(ws + 0);        // overlays meanb (dead after k_fc1)
  ushort_t* w1t = (ushort_t*)(ws + 73728);
  float* mlp1   = (float*)(ws + 3145728);
  float* mu     = (float*)(ws + 6291456);
  float* rstd   = (float*)(ws + 7905280);
  ushort_t* h3  = (ushort_t*)(ws + 9519104);
  ushort_t* h4  = (ushort_t*)(ws + 9519104);  // overlays h3 (dead after 2nd fc3b)
  float* P      = (float*)(ws + 9519104);     // overlays h4 (dead after fc4b)
  float* Cpart  = (float*)(ws + 29188096);    // after P, before Qb
  ushort_t* Qb  = (ushort_t*)(ws + 59850752);
  ushort_t* Sb  = (ushort_t*)(ws + 136921088);
  const size_t H4S = (size_t)512*196*96;      // per-s-half h4 elements

  k_mean<<<2048, 384, 0, stream>>>(fq, fs, fqs, fss, meanb);
  k_fc1<<<2048, 384, 0, stream>>>(meanb, fc1_w1, fc1_b1, fc1_w2, fc1_b2, mlp1);
  k_wt<<<288, 256, 0, stream>>>(fc4_w1, fc4_w2, w1t, w2t);   // after k_fc1: meanb dead
  k_stats<<<100864, 256, 0, stream>>>(fq, fs, fqs, fss, mlp1, mu, rstd);
  k_class<<<1024, 384, 0, stream>>>(fq, fs, mlp1, mu, rstd, ln1_g, ln1_b, out);
  k_cosine<<<512, 384, 0, stream>>>(cs_w1, cs_b1, cs_w2, cs_b2, out);
  k_fc3a<<<3072, 256, 0, stream>>>(fqs, mlp1 + (size_t)2*512*384, mu + 2*100864, rstd + 2*100864,
                                   ln1_g, ln1_b, fc3_w1, fc3_b1, h3);
  k_fc3b<<<3072, 256, 0, stream>>>(h3, fc3_w2, fc3_b2, ln3_g, ln3_b, Qb);
  k_fc3a<<<3072, 256, 0, stream>>>(fss, mlp1 + (size_t)3*512*384, mu + 3*100864, rstd + 3*100864,
                                   ln1_g, ln1_b, fc3_w1, fc3_b1, h3);
  k_fc3b<<<3072, 256, 0, stream>>>(h3, fc3_w2, fc3_b2, ln3_g, ln3_b, Sb);
  // fc4 stage A (MFMA): q then s (pre-offset pointers, no runtime s-select)
  k_fc4a<<<2048, 256, 0, stream>>>(fq, mlp1, mu, rstd, ln1_g, ln1_b,
                                   Qb, w1t, fc4_b1, h4);
  k_fc4a<<<2048, 256, 0, stream>>>(fs, mlp1 + (size_t)512*384, mu + 100864, rstd + 100864,
                                   ln1_g, ln1_b, Sb, w1t, fc4_b1, h4 + H4S);
  // fc4 stage B (MFMA): q then s (Qb/Sb overwritten in place after their last read)
  k_fc4b<<<2048, 256, 0, stream>>>(h4,       w2t, fc4_b2, ln4_g, ln4_b, out + 1024,          Qb);
  k_fc4b<<<2048, 256, 0, stream>>>(h4 + H4S, w2t, fc4_b2, ln4_g, ln4_b, out + 1024 + 196608, Sb);
  k_sim<<<8192, 256, 0, stream>>>(Qb, Sb, P);
  // fc2 head: split-K GEMM (896 blocks) + tiny reduce
  k_fc2a<<<896, 256, 0, stream>>>(P, fc2_w1, Cpart);
  k_fc2b<<<512, 256, 0, stream>>>(Cpart, fc2_b1, fc2_w2, fc2_b2, out);
}

// Round 10
// 1586.833 us; speedup vs baseline: 20.8516x; 1.2821x over previous
//
#include <hip/hip_runtime.h>
#include <math.h>

typedef unsigned short ushort_t;
typedef __attribute__((ext_vector_type(8))) short bf16x8;
typedef __attribute__((ext_vector_type(4))) float f32x4;

// ---------------- helpers ----------------
__device__ __forceinline__ float geluf(float x){
  return 0.5f*x*(1.0f+erff(x*0.70710678118654752440f));
}
__device__ __forceinline__ float bfu(unsigned int u){
  union { unsigned int i; float f; } v; v.i = (u & 0xffffu) << 16; return v.f;
}
__device__ __forceinline__ unsigned int f2b(float f){
  union { float f; unsigned int i; } v; v.f = f;
  unsigned int r = v.i + 0x7fffu + ((v.i >> 16) & 1u);
  return (r >> 16);
}

// Problem constants
// B=512, N=197, C=384, T=196 image tokens
// d_out layout (floats): out[512] | cosine[512] | query_class[512*384] | support_class[512*384]

// ---------------- A: token means (per tensor, b, c) ----------------
__global__ __launch_bounds__(384) void k_mean(
    const float* __restrict__ x0, const float* __restrict__ x1,
    const float* __restrict__ x2, const float* __restrict__ x3,
    float* __restrict__ meanb){
  int s = blockIdx.x >> 9, b = blockIdx.x & 511, c = threadIdx.x;
  const float* x = (s==0)?x0:(s==1)?x1:(s==2)?x2:x3;
  const float* p = x + ((size_t)b*197)*384 + c;
  float acc = 0.f;
  #pragma unroll 4
  for (int t=0;t<197;++t) acc += p[(size_t)t*384];
  meanb[((size_t)s*512+b)*384+c] = acc*(1.0f/197.0f);
}

// ---------------- B: fc1 tiny MLP on means ----------------
__global__ __launch_bounds__(384) void k_fc1(
    const float* __restrict__ meanb, const float* __restrict__ w1,
    const float* __restrict__ b1, const float* __restrict__ w2,
    const float* __restrict__ b2, float* __restrict__ mlp1){
  __shared__ float ms[384];
  __shared__ float hs[96];
  int row = blockIdx.x, tid = threadIdx.x;
  ms[tid] = meanb[(size_t)row*384 + tid];
  __syncthreads();
  if (tid < 96){
    float a = b1[tid];
    for (int c=0;c<384;++c) a += ms[c]*w1[c*96+tid];
    hs[tid] = geluf(a);
  }
  __syncthreads();
  float a = b2[tid];
  for (int j=0;j<96;++j) a += hs[j]*w2[j*384+tid];
  mlp1[(size_t)row*384 + tid] = a;
}

// ---------------- C: per-row LN stats of (x + mlp1) ----------------
__global__ __launch_bounds__(256) void k_stats(
    const float* __restrict__ x0, const float* __restrict__ x1,
    const float* __restrict__ x2, const float* __restrict__ x3,
    const float* __restrict__ mlp1, float* __restrict__ mu, float* __restrict__ rstd){
  int lane = threadIdx.x & 63, w = threadIdx.x >> 6;
  int row = blockIdx.x*4 + w;           // rows = 4*512*197 = 403456, grid exact
  int s = row / 100864;
  int rr = row % 100864;
  int b = rr / 197, t = rr % 197;
  const float* x = (s==0)?x0:(s==1)?x1:(s==2)?x2:x3;
  const float* xp = x + ((size_t)b*197 + t)*384;
  const float* mp = mlp1 + ((size_t)s*512 + b)*384;
  float sum=0.f, sq=0.f;
  for (int i=lane;i<384;i+=64){ float v = xp[i]+mp[i]; sum+=v; sq+=v*v; }
  #pragma unroll
  for (int o=32;o;o>>=1){ sum+=__shfl_down(sum,o); sq+=__shfl_down(sq,o); }
  if (lane==0){
    float m = sum*(1.0f/384.0f);
    mu[row] = m;
    rstd[row] = rsqrtf(sq*(1.0f/384.0f) - m*m + 1e-5f);
  }
}

// ---------------- D: class token rows -> d_out ----------------
__global__ __launch_bounds__(384) void k_class(
    const float* __restrict__ x0, const float* __restrict__ x1,
    const float* __restrict__ mlp1, const float* __restrict__ mu,
    const float* __restrict__ rstd, const float* __restrict__ g1,
    const float* __restrict__ bb1, float* __restrict__ dout){
  int s = blockIdx.x >> 9, b = blockIdx.x & 511, c = threadIdx.x;
  const float* x = s ? x1 : x0;
  int srow = (s*512 + b)*197;
  float v = x[((size_t)b*197)*384 + c] + mlp1[((size_t)s*512+b)*384 + c];
  float y = (v - mu[srow])*rstd[srow]*g1[c] + bb1[c];
  dout[1024 + (size_t)s*196608 + (size_t)b*384 + c] = y;
}

// ---------------- E: cosine head on class tokens ----------------
__global__ __launch_bounds__(384) void k_cosine(
    const float* __restrict__ w1, const float* __restrict__ b1,
    const float* __restrict__ w2, const float* __restrict__ b2,
    float* __restrict__ dout){
  __shared__ float qrow[384], srw[384], hq[96], hs[96];
  __shared__ float rd0[384], rd1[384], rd2[384];
  int b = blockIdx.x, tid = threadIdx.x;
  qrow[tid] = dout[1024   + (size_t)b*384 + tid];
  srw[tid]  = dout[197632 + (size_t)b*384 + tid];
  __syncthreads();
  if (tid < 96){
    float a = b1[tid];
    for (int c=0;c<384;++c) a += qrow[c]*w1[c*96+tid];
    hq[tid] = geluf(a);
  } else if (tid < 192){
    int j = tid - 96;
    float a = b1[j];
    for (int c=0;c<384;++c) a += srw[c]*w1[c*96+j];
    hs[j] = geluf(a);
  }
  __syncthreads();
  float qx = b2[tid], sy = b2[tid];
  for (int j=0;j<96;++j){ qx += hq[j]*w2[j*384+tid]; sy += hs[j]*w2[j*384+tid]; }
  rd0[tid] = qx*sy; rd1[tid] = qx*qx; rd2[tid] = sy*sy;
  __syncthreads();
  if (tid < 64){
    float d=0.f,nq=0.f,ns=0.f;
    for (int i=tid;i<384;i+=64){ d+=rd0[i]; nq+=rd1[i]; ns+=rd2[i]; }
    #pragma unroll
    for (int o=32;o;o>>=1){ d+=__shfl_down(d,o); nq+=__shfl_down(nq,o); ns+=__shfl_down(ns,o); }
    if (tid==0) dout[512 + b] = d / (fmaxf(sqrtf(nq),1e-8f)*fmaxf(sqrtf(ns),1e-8f));
  }
}

// ---------------- W: weight prep (bf16 transposes, zero-padded) ----------------
// grid 504, block 256 (504*256 = 129024).
//   fc4 w2t  [384][96]   @idx 0..36863        (w2 [96][384] transposed)
//   fc4 w1t  [96][384]   @idx 36864..73727    (w1 [384][96] transposed)
//   fc3 w1t3 [128][224]  @idx 73728..102399   (w1 [196][128] transposed, t-pad 0)
//   fc3 w2t3 [208][128]  @idx 102400..129023  (w2 [128][196] transposed, t'-pad 0)
// All live in the DEAD meanb region (written after k_fc1's last meanb read).
__global__ __launch_bounds__(256) void k_wt(
    const float* __restrict__ w1_4, const float* __restrict__ w2_4,
    const float* __restrict__ w1_3, const float* __restrict__ w2_3,
    ushort_t* __restrict__ w1t, ushort_t* __restrict__ w2t,
    ushort_t* __restrict__ w1t3, ushort_t* __restrict__ w2t3){
  int idx = blockIdx.x*256 + threadIdx.x;
  if (idx < 36864){
    int c = idx / 96, j = idx - c*96;
    w2t[idx] = (ushort_t)f2b(w2_4[(size_t)j*384 + c]);
  } else if (idx < 73728){
    int k = idx - 36864;
    int j = k / 384, c = k - j*384;
    w1t[k] = (ushort_t)f2b(w1_4[(size_t)c*96 + j]);
  } else if (idx < 102400){
    int k = idx - 73728;
    int j = k / 224, t = k - j*224;
    w1t3[k] = (t < 196) ? (ushort_t)f2b(w1_3[(size_t)t*128 + j]) : (ushort_t)0;
  } else {
    int k = idx - 102400;
    int tp = k / 128, j = k - tp*128;
    w2t3[k] = (tp < 196) ? (ushort_t)f2b(w2_3[(size_t)j*196 + tp]) : (ushort_t)0;
  }
}

// ---------------- F: fc3 fused MFMA (one s-half per launch) ----------------
// grid 512*6 (b, c-tile of 64), block 256 = 4 waves; wave = 16 c rows.
// Phase 1: Xs[c][t] = LN1(x)^T bf16 tile (stride 234; zero-pad t in [196,224)).
// GEMM1: A = w1t3 rows j (L2), B = Xs rows c; 8 jfrag x 7 kstep = 56 MFMA;
//        gelu+bias -> Hs[c][j] (D row=j, col=c; 8B packed ds_write).
// GEMM2: A = Hs rows c, B = w2t3 rows t'; 13 tfrag x 4 kstep = 52 MFMA;
//        bias/LN-coef arrays zero-padded so pad-t' contributes 0 to LN sums.
// LN over t' via 13-frag local sums + shfl_xor(1,2,4,8); write Qout[t'][c].
__global__ __launch_bounds__(256) void k_fc3(
    const float* __restrict__ x,         // fqs or fss
    const float* __restrict__ m1_base,   // mlp1 + s*512*384
    const float* __restrict__ mu_s,      // mu + s*100864
    const float* __restrict__ rstd_s,
    const float* __restrict__ g1, const float* __restrict__ bln1,
    const ushort_t* __restrict__ w1t3,   // [128][224] bf16
    const float* __restrict__ b1,        // fc3_b1 [128]
    const ushort_t* __restrict__ w2t3,   // [208][128] bf16
    const float* __restrict__ b2, const float* __restrict__ g3,
    const float* __restrict__ b3,
    ushort_t* __restrict__ Qout){        // Qb or Sb
  __shared__ ushort_t Xs[64][234];
  __shared__ ushort_t Hs[64][136];
  __shared__ float m1s[64], g1s[64], b1s[64];
  __shared__ float mus[196], rss[196];
  __shared__ float b1j[128];
  __shared__ float b2s[208], g3s[208], b3s[208];
  int bid = blockIdx.x;
  int b = bid/6, c0 = (bid%6)*64;
  int tid = threadIdx.x;
  // stage coefficients
  if (tid < 64){
    m1s[tid] = m1_base[(size_t)b*384 + c0 + tid];
    g1s[tid] = g1[c0+tid]; b1s[tid] = bln1[c0+tid];
  }
  if (tid < 128) b1j[tid] = b1[tid];
  if (tid < 196){ mus[tid] = mu_s[b*197 + tid + 1]; rss[tid] = rstd_s[b*197 + tid + 1]; }
  if (tid < 208){
    float bb=0.f, gg=0.f, b3v=0.f;
    if (tid < 196){ bb = b2[tid]; gg = g3[tid]; b3v = b3[tid]; }
    b2s[tid]=bb; g3s[tid]=gg; b3s[tid]=b3v;
  }
  // zero the t-pad of Xs ([196,224); [224,234) never read)
  for (int i = tid; i < 64*28; i += 256){ Xs[i/28][196 + i%28] = 0; }
  __syncthreads();
  // phase 1: stage LN'd X^T tile (196 t x 16 c4-slots = 3136)
  for (int e = 0; e < 13; ++e){
    int idx = e*256 + tid;
    if (idx < 3136){
      int t = idx >> 4, c4 = idx & 15;
      float4 xv = *reinterpret_cast<const float4*>(&x[((size_t)b*197 + t + 1)*384 + c0 + c4*4]);
      float muv = mus[t], rsv = rss[t];
      int c = c4*4;
      Xs[c+0][t] = (ushort_t)f2b(((xv.x + m1s[c+0]) - muv)*rsv*g1s[c+0] + b1s[c+0]);
      Xs[c+1][t] = (ushort_t)f2b(((xv.y + m1s[c+1]) - muv)*rsv*g1s[c+1] + b1s[c+1]);
      Xs[c+2][t] = (ushort_t)f2b(((xv.z + m1s[c+2]) - muv)*rsv*g1s[c+2] + b1s[c+2]);
      Xs[c+3][t] = (ushort_t)f2b(((xv.w + m1s[c+3]) - muv)*rsv*g1s[c+3] + b1s[c+3]);
    }
  }
  __syncthreads();
  int w = tid >> 6, lane = tid & 63;
  int cl = lane & 15, kg = lane >> 4;
  // GEMM1: h = gelu(Xt @ w1 + b1)
  f32x4 hacc[8];
  #pragma unroll
  for (int jf=0;jf<8;++jf){ f32x4 z={0.f,0.f,0.f,0.f}; hacc[jf]=z; }
  const ushort_t* zrow = &Xs[w*16 + cl][kg*8];
  for (int kc = 0; kc < 7; ++kc){
    bf16x8 xb = *reinterpret_cast<const bf16x8*>(zrow + kc*32);
    #pragma unroll
    for (int jf=0;jf<8;++jf){
      const ushort_t* ap = w1t3 + (size_t)(jf*16 + cl)*224 + kg*8 + kc*32;
      hacc[jf] = __builtin_amdgcn_mfma_f32_16x16x32_bf16(
          *reinterpret_cast<const bf16x8*>(ap), xb, hacc[jf], 0, 0, 0);
    }
  }
  // D: row = j = jf*16+kg*4+r, col = c = cl -> Hs[c][j] packed uint2
  #pragma unroll
  for (int jf=0;jf<8;++jf){
    f32x4 y = hacc[jf];
    int j0 = jf*16 + kg*4;
    uint2 pk;
    pk.x = f2b(geluf(y[0]+b1j[j0+0])) | (f2b(geluf(y[1]+b1j[j0+1]))<<16);
    pk.y = f2b(geluf(y[2]+b1j[j0+2])) | (f2b(geluf(y[3]+b1j[j0+3]))<<16);
    *reinterpret_cast<uint2*>(&Hs[w*16 + cl][j0]) = pk;
  }
  __syncthreads();
  // GEMM2: y = h @ w2 (+b2 in epilogue)
  f32x4 yacc[13];
  #pragma unroll
  for (int tf=0;tf<13;++tf){ f32x4 z={0.f,0.f,0.f,0.f}; yacc[tf]=z; }
  const ushort_t* hrow = &Hs[w*16 + cl][kg*8];
  for (int kc = 0; kc < 4; ++kc){
    bf16x8 hb = *reinterpret_cast<const bf16x8*>(hrow + kc*32);
    #pragma unroll
    for (int tf=0;tf<13;++tf){
      const ushort_t* bp = w2t3 + (size_t)(tf*16 + cl)*128 + kg*8 + kc*32;
      yacc[tf] = __builtin_amdgcn_mfma_f32_16x16x32_bf16(
          hb, *reinterpret_cast<const bf16x8*>(bp), yacc[tf], 0, 0, 0);
    }
  }
  // epilogue: lane holds c = c0 + w*16 + kg*4 + r (r=0..3), t' = tf*16 + cl.
  // bias; LN stats over t' (pad t' -> y=0, b2s=0 -> contributes 0)
  float sum0=0.f,sum1=0.f,sum2=0.f,sum3=0.f, sq0=0.f,sq1=0.f,sq2=0.f,sq3=0.f;
  #pragma unroll
  for (int tf=0;tf<13;++tf){
    int tp = tf*16 + cl;
    float bb = b2s[tp];
    f32x4 y = yacc[tf];
    y[0]+=bb; y[1]+=bb; y[2]+=bb; y[3]+=bb;
    yacc[tf] = y;
    sum0+=y[0]; sum1+=y[1]; sum2+=y[2]; sum3+=y[3];
    sq0+=y[0]*y[0]; sq1+=y[1]*y[1]; sq2+=y[2]*y[2]; sq3+=y[3]*y[3];
  }
  #pragma unroll
  for (int o=1;o<16;o<<=1){
    sum0+=__shfl_xor(sum0,o); sum1+=__shfl_xor(sum1,o);
    sum2+=__shfl_xor(sum2,o); sum3+=__shfl_xor(sum3,o);
    sq0+=__shfl_xor(sq0,o); sq1+=__shfl_xor(sq1,o);
    sq2+=__shfl_xor(sq2,o); sq3+=__shfl_xor(sq3,o);
  }
  float m0=sum0*(1.0f/196.0f), m1v=sum1*(1.0f/196.0f), m2=sum2*(1.0f/196.0f), m3=sum3*(1.0f/196.0f);
  float r0=rsqrtf(sq0*(1.0f/196.0f)-m0*m0+1e-5f);
  float r1=rsqrtf(sq1*(1.0f/196.0f)-m1v*m1v+1e-5f);
  float r2=rsqrtf(sq2*(1.0f/196.0f)-m2*m2+1e-5f);
  float r3=rsqrtf(sq3*(1.0f/196.0f)-m3*m3+1e-5f);
  int cbase = c0 + w*16 + kg*4;
  #pragma unroll
  for (int tf=0;tf<13;++tf){
    int tp = tf*16 + cl;
    if (tp < 196){
      float gg = g3s[tp], bb3 = b3s[tp];
      f32x4 y = yacc[tf];
      unsigned int o0 = f2b((y[0]-m0)*r0*gg + bb3);
      unsigned int o1 = f2b((y[1]-m1v)*r1*gg + bb3);
      unsigned int o2 = f2b((y[2]-m2)*r2*gg + bb3);
      unsigned int o3 = f2b((y[3]-m3)*r3*gg + bb3);
      uint2 pk; pk.x = o0 | (o1<<16); pk.y = o2 | (o3<<16);
      *reinterpret_cast<uint2*>(&Qout[((size_t)b*196 + tp)*384 + cbase]) = pk;
    }
  }
}

// ---------------- H1: fc4 stage A (MFMA; one s-half per launch) ----------------
// grid 512*4 (b, t-tile of 64), block 256 = 4 waves; wave = 16 t x 96 j.
__global__ __launch_bounds__(256) void k_fc4a(
    const float* __restrict__ x,         // fq or fs
    const float* __restrict__ m1_base,   // mlp1 + s*512*384
    const float* __restrict__ mu_s,      // mu + s*100864
    const float* __restrict__ rstd_s,    // rstd + s*100864
    const float* __restrict__ g1, const float* __restrict__ bln1,
    const ushort_t* __restrict__ Qin,    // Qb or Sb
    const ushort_t* __restrict__ w1t,    // [96][384] bf16
    const float* __restrict__ b1mlp,
    ushort_t* __restrict__ h4s){         // h4 + s*512*196*96
  __shared__ ushort_t Zs[64][392];       // bf16 Z tile, padded stride
  __shared__ float m1s[384], g1s[384], b1s[384];
  __shared__ float mus[64], rss[64];
  __shared__ float b1m[96];
  int bid = blockIdx.x;
  int b = bid >> 2, tt0 = (bid & 3)*64;
  int tid = threadIdx.x;
  const float* m1 = m1_base + (size_t)b*384;
  for (int i = tid; i < 384; i += 256){ m1s[i] = m1[i]; g1s[i] = g1[i]; b1s[i] = bln1[i]; }
  if (tid < 96) b1m[tid] = b1mlp[tid];
  if (tid < 64){
    int t = tt0 + tid; int tc = t < 196 ? t : 195;
    mus[tid] = mu_s[b*197 + tc + 1]; rss[tid] = rstd_s[b*197 + tc + 1];
  }
  __syncthreads();
  // phase 1: Z build, 64 rows x 96 col4-slots = 6144 slots, 24 per thread
  for (int e = 0; e < 24; ++e){
    int v = e*256 + tid;
    int row = v/96, col4 = v - row*96;
    int t = tt0 + row; int tc = t < 196 ? t : 195;
    float valid = (t < 196) ? 1.f : 0.f;
    float4 xv = *reinterpret_cast<const float4*>(&x[((size_t)b*197 + tc + 1)*384 + col4*4]);
    uint2 qv = *reinterpret_cast<const uint2*>(&Qin[((size_t)b*196 + tc)*384 + col4*4]);
    float muv = mus[row], rsv = rss[row];
    int c = col4*4;
    float z0 = (((xv.x + m1s[c+0]) - muv)*rsv*g1s[c+0] + b1s[c+0]) * bfu(qv.x)      * valid;
    float z1 = (((xv.y + m1s[c+1]) - muv)*rsv*g1s[c+1] + b1s[c+1]) * bfu(qv.x>>16)  * valid;
    float z2 = (((xv.z + m1s[c+2]) - muv)*rsv*g1s[c+2] + b1s[c+2]) * bfu(qv.y)      * valid;
    float z3 = (((xv.w + m1s[c+3]) - muv)*rsv*g1s[c+3] + b1s[c+3]) * bfu(qv.y>>16)  * valid;
    uint2 pk; pk.x = f2b(z0) | (f2b(z1)<<16); pk.y = f2b(z2) | (f2b(z3)<<16);
    *reinterpret_cast<uint2*>(&Zs[row][col4*4]) = pk;
  }
  __syncthreads();
  // phase 2: MFMA GEMM1 (16t x 96j per wave, K=384)
  int w = tid >> 6, lane = tid & 63;
  int tr = tt0 + w*16 + (lane & 15);
  int kg = lane >> 4;
  f32x4 acc0 = {0.f,0.f,0.f,0.f}, acc1 = {0.f,0.f,0.f,0.f}, acc2 = {0.f,0.f,0.f,0.f};
  f32x4 acc3 = {0.f,0.f,0.f,0.f}, acc4 = {0.f,0.f,0.f,0.f}, acc5 = {0.f,0.f,0.f,0.f};
  const ushort_t* arow = w1t + (size_t)(lane & 15)*384 + kg*8;
  const ushort_t* zrow = &Zs[w*16 + (lane & 15)][kg*8];
  for (int kc = 0; kc < 12; ++kc){
    bf16x8 zb = *reinterpret_cast<const bf16x8*>(zrow + kc*32);
    bf16x8 a0 = *reinterpret_cast<const bf16x8*>(arow + kc*32);
    bf16x8 a1 = *reinterpret_cast<const bf16x8*>(arow + kc*32 + 16*384);
    bf16x8 a2 = *reinterpret_cast<const bf16x8*>(arow + kc*32 + 32*384);
    bf16x8 a3 = *reinterpret_cast<const bf16x8*>(arow + kc*32 + 48*384);
    bf16x8 a4 = *reinterpret_cast<const bf16x8*>(arow + kc*32 + 64*384);
    bf16x8 a5 = *reinterpret_cast<const bf16x8*>(arow + kc*32 + 80*384);
    acc0 = __builtin_amdgcn_mfma_f32_16x16x32_bf16(a0, zb, acc0, 0, 0, 0);
    acc1 = __builtin_amdgcn_mfma_f32_16x16x32_bf16(a1, zb, acc1, 0, 0, 0);
    acc2 = __builtin_amdgcn_mfma_f32_16x16x32_bf16(a2, zb, acc2, 0, 0, 0);
    acc3 = __builtin_amdgcn_mfma_f32_16x16x32_bf16(a3, zb, acc3, 0, 0, 0);
    acc4 = __builtin_amdgcn_mfma_f32_16x16x32_bf16(a4, zb, acc4, 0, 0, 0);
    acc5 = __builtin_amdgcn_mfma_f32_16x16x32_bf16(a5, zb, acc5, 0, 0, 0);
  }
  // epilogue: lane holds j = jb*16 + kg*4 + r (D row), t = tr (D col)
  if (tr < 196){
    ushort_t* dst = h4s + ((size_t)b*196 + tr)*96 + kg*4;
    #pragma unroll
    for (int jb = 0; jb < 6; ++jb){
      f32x4 y = (jb==0)?acc0:(jb==1)?acc1:(jb==2)?acc2:(jb==3)?acc3:(jb==4)?acc4:acc5;
      int j0 = jb*16 + kg*4;
      uint2 pk;
      pk.x = f2b(geluf(y[0]+b1m[j0+0])) | (f2b(geluf(y[1]+b1m[j0+1]))<<16);
      pk.y = f2b(geluf(y[2]+b1m[j0+2])) | (f2b(geluf(y[3]+b1m[j0+3]))<<16);
      *reinterpret_cast<uint2*>(dst + jb*16) = pk;
    }
  }
}

// ---------------- H2: fc4 stage B (MFMA; one s-half per launch) ----------------
// grid 512*4 (b, t-tile of 64), block 256 = 4 waves; wave = 16 t x 384 c.
__global__ __launch_bounds__(256) void k_fc4b(
    const ushort_t* __restrict__ h4s,    // h4 + s*512*196*96
    const ushort_t* __restrict__ w2t,    // [384][96] bf16
    const float* __restrict__ b2, const float* __restrict__ g4,
    const float* __restrict__ bb4,
    const float* __restrict__ cls_base,  // dout + 1024 + s*196608
    ushort_t* __restrict__ Qo){          // Qb or Sb
  __shared__ float b2s[384], g4s[384], b4s[384], cl_s[384];
  int bid = blockIdx.x;
  int b = bid >> 2, ttile = bid & 3;
  int tid = threadIdx.x, w = tid >> 6, lane = tid & 63;
  const float* cls = cls_base + (size_t)b*384;
  for (int i = tid; i < 384; i += 256){
    b2s[i] = b2[i]; g4s[i] = g4[i]; b4s[i] = bb4[i]; cl_s[i] = cls[i];
  }
  __syncthreads();
  int tr = ttile*64 + w*16 + (lane & 15);
  int trc = tr < 196 ? tr : 195;
  int kg = lane >> 4;
  const ushort_t* hp = h4s + ((size_t)b*196 + trc)*96 + kg*8;
  bf16x8 hb0 = *reinterpret_cast<const bf16x8*>(hp);
  bf16x8 hb1 = *reinterpret_cast<const bf16x8*>(hp + 32);
  bf16x8 hb2 = *reinterpret_cast<const bf16x8*>(hp + 64);
  const ushort_t* ap_base = w2t + (size_t)(lane & 15)*96 + kg*8;
  f32x4 acc[24];
  #pragma unroll
  for (int af = 0; af < 24; ++af){
    const ushort_t* ap = ap_base + (size_t)af*16*96;
    bf16x8 a0 = *reinterpret_cast<const bf16x8*>(ap);
    bf16x8 a1 = *reinterpret_cast<const bf16x8*>(ap + 32);
    bf16x8 a2 = *reinterpret_cast<const bf16x8*>(ap + 64);
    f32x4 z = {0.f,0.f,0.f,0.f};
    z = __builtin_amdgcn_mfma_f32_16x16x32_bf16(a0, hb0, z, 0, 0, 0);
    z = __builtin_amdgcn_mfma_f32_16x16x32_bf16(a1, hb1, z, 0, 0, 0);
    z = __builtin_amdgcn_mfma_f32_16x16x32_bf16(a2, hb2, z, 0, 0, 0);
    acc[af] = z;
  }
  // epilogue: lane holds c = af*16 + kg*4 + r  (r=0..3), t = tr (col)
  float sum = 0.f, sq = 0.f;
  #pragma unroll
  for (int af = 0; af < 24; ++af){
    int cb = af*16 + kg*4;
    float4 bv = *reinterpret_cast<const float4*>(&b2s[cb]);
    f32x4 y = acc[af];
    y[0] += bv.x; y[1] += bv.y; y[2] += bv.z; y[3] += bv.w;
    acc[af] = y;
    sum += y[0]+y[1]+y[2]+y[3];
    sq  += y[0]*y[0]+y[1]*y[1]+y[2]*y[2]+y[3]*y[3];
  }
  sum += __shfl_xor(sum, 16); sum += __shfl_xor(sum, 32);
  sq  += __shfl_xor(sq, 16);  sq  += __shfl_xor(sq, 32);
  float m4 = sum*(1.0f/384.0f);
  float rs = rsqrtf(sq*(1.0f/384.0f) - m4*m4 + 1e-5f);
  float s2 = 0.f;
  #pragma unroll
  for (int af = 0; af < 24; ++af){
    int cb = af*16 + kg*4;
    float4 gv = *reinterpret_cast<const float4*>(&g4s[cb]);
    float4 bb = *reinterpret_cast<const float4*>(&b4s[cb]);
    float4 cv = *reinterpret_cast<const float4*>(&cl_s[cb]);
    f32x4 y = acc[af];
    y[0] = (y[0]-m4)*rs*gv.x + bb.x + 0.5f*cv.x;
    y[1] = (y[1]-m4)*rs*gv.y + bb.y + 0.5f*cv.y;
    y[2] = (y[2]-m4)*rs*gv.z + bb.z + 0.5f*cv.z;
    y[3] = (y[3]-m4)*rs*gv.w + bb.w + 0.5f*cv.w;
    acc[af] = y;
    s2 += y[0]*y[0]+y[1]*y[1]+y[2]*y[2]+y[3]*y[3];
  }
  s2 += __shfl_xor(s2, 16); s2 += __shfl_xor(s2, 32);
  float inv = 1.0f/fmaxf(sqrtf(s2), 1e-12f);
  float sm = 0.f;
  #pragma unroll
  for (int af = 0; af < 24; ++af){
    f32x4 y = acc[af];
    y[0]*=inv; y[1]*=inv; y[2]*=inv; y[3]*=inv;
    acc[af] = y;
    sm += y[0]+y[1]+y[2]+y[3];
  }
  sm += __shfl_xor(sm, 16); sm += __shfl_xor(sm, 32);
  sm *= (1.0f/384.0f);
  if (tr < 196){
    ushort_t* dst = Qo + ((size_t)b*196 + tr)*384 + kg*4;
    #pragma unroll
    for (int af = 0; af < 24; ++af){
      f32x4 y = acc[af];
      uint2 pk;
      pk.x = f2b(y[0]-sm) | (f2b(y[1]-sm)<<16);
      pk.y = f2b(y[2]-sm) | (f2b(y[3]-sm)<<16);
      *reinterpret_cast<uint2*>(dst + af*16) = pk;
    }
  }
}

// ---------------- I: batched einsum + fused 2x2 pooling (MFMA) ----------------
// grid 512*16 (b, qt, st), block 256 = 4 waves; wave = 32x32 output tile.
__global__ __launch_bounds__(256) void k_sim(
    const ushort_t* __restrict__ Q, const ushort_t* __restrict__ S,
    float* __restrict__ P){
  int bx = blockIdx.x;
  int b = bx >> 4, qt = (bx >> 2) & 3, st = bx & 3;
  int tid = threadIdx.x;
  int w = tid >> 6, lane = tid & 63;
  int wr = w >> 1, wc = w & 1;
  int q0 = qt*64 + wr*32, s0 = st*64 + wc*32;
  int rrow = lane & 15, kg = lane >> 4;
  const ushort_t* Qb_ = Q + (size_t)b*196*384;
  const ushort_t* Sb_ = S + (size_t)b*196*384;
  int qr0 = min(q0 + rrow, 195), qr1 = min(q0 + 16 + rrow, 195);
  int sr0 = min(s0 + rrow, 195), sr1 = min(s0 + 16 + rrow, 195);
  const ushort_t* qp0 = Qb_ + (size_t)qr0*384 + kg*8;
  const ushort_t* qp1 = Qb_ + (size_t)qr1*384 + kg*8;
  const ushort_t* sp0 = Sb_ + (size_t)sr0*384 + kg*8;
  const ushort_t* sp1 = Sb_ + (size_t)sr1*384 + kg*8;
  f32x4 acc00 = {0.f,0.f,0.f,0.f}, acc01 = {0.f,0.f,0.f,0.f};
  f32x4 acc10 = {0.f,0.f,0.f,0.f}, acc11 = {0.f,0.f,0.f,0.f};
  for (int k0 = 0; k0 < 384; k0 += 32){
    bf16x8 a0 = *reinterpret_cast<const bf16x8*>(qp0 + k0);
    bf16x8 a1 = *reinterpret_cast<const bf16x8*>(qp1 + k0);
    bf16x8 b0 = *reinterpret_cast<const bf16x8*>(sp0 + k0);
    bf16x8 b1 = *reinterpret_cast<const bf16x8*>(sp1 + k0);
    acc00 = __builtin_amdgcn_mfma_f32_16x16x32_bf16(a0, b0, acc00, 0, 0, 0);
    acc01 = __builtin_amdgcn_mfma_f32_16x16x32_bf16(a0, b1, acc01, 0, 0, 0);
    acc10 = __builtin_amdgcn_mfma_f32_16x16x32_bf16(a1, b0, acc10, 0, 0, 0);
    acc11 = __builtin_amdgcn_mfma_f32_16x16x32_bf16(a1, b1, acc11, 0, 0, 0);
  }
  int c = lane & 15, g = lane >> 4;
  float* Pb = P + (size_t)b*98*98;
  #pragma unroll
  for (int i = 0; i < 2; ++i){
    #pragma unroll
    for (int j = 0; j < 2; ++j){
      f32x4 v = (i==0) ? (j==0 ? acc00 : acc01) : (j==0 ? acc10 : acc11);
      float p0 = v[0] + v[1];   // rows 4g, 4g+1
      float p1 = v[2] + v[3];   // rows 4g+2, 4g+3
      float t0 = p0 + __shfl_xor(p0, 1);
      float t1 = p1 + __shfl_xor(p1, 1);
      if (!(c & 1)){
        int qp = (q0 + 16*i + 4*g) >> 1;
        int sp = (s0 + 16*j + c) >> 1;
        if (sp < 98){
          if (qp     < 98) Pb[(size_t)(qp    )*98 + sp] = 0.25f*t0;
          if (qp + 1 < 98) Pb[(size_t)(qp + 1)*98 + sp] = 0.25f*t1;
        }
      }
    }
  }
}

// ---------------- J1: fc2 split-K GEMM  Cpart[ks] = P2-chunk @ w1-chunk ----------------
// grid 64*14 (m-block of 8 rows, k-split of 686), block 256 (= N columns)
__global__ __launch_bounds__(256) void k_fc2a(
    const float* __restrict__ P, const float* __restrict__ w1,
    float* __restrict__ Cpart){
  __shared__ float p2[8][688];
  int bx = blockIdx.x;
  int mb = bx & 63, ks = bx >> 6;      // 14 k-splits of 686 (14*686 = 9604)
  int b0 = mb*8, k0 = ks*686;
  int tid = threadIdx.x;
  for (int idx = tid; idx < 8*686; idx += 256){
    int r = idx / 686, i = idx - r*686;
    float v = P[(size_t)(b0+r)*9604 + k0 + i];
    p2[r][i] = v*v;
  }
  __syncthreads();
  float acc[8];
  #pragma unroll
  for (int r=0;r<8;++r) acc[r]=0.f;
  for (int ii=0; ii<686; ++ii){
    float w = w1[(size_t)(k0+ii)*256 + tid];
    #pragma unroll
    for (int r=0;r<8;++r) acc[r] += p2[r][ii]*w;
  }
  #pragma unroll
  for (int r=0;r<8;++r) Cpart[((size_t)ks*512 + b0 + r)*256 + tid] = acc[r];
}

// ---------------- J2: fc2 reduce + gelu + w2 dot ----------------
// grid 512 (one b each), block 256
__global__ __launch_bounds__(256) void k_fc2b(
    const float* __restrict__ Cpart, const float* __restrict__ b1,
    const float* __restrict__ w2, const float* __restrict__ b2,
    float* __restrict__ outp){
  __shared__ float red[4];
  int b = blockIdx.x, tid = threadIdx.x;
  float s = 0.f;
  for (int ks = 0; ks < 14; ++ks) s += Cpart[((size_t)ks*512 + b)*256 + tid];
  float h = geluf(s + b1[tid]) * w2[tid];
  #pragma unroll
  for (int o=32;o;o>>=1) h += __shfl_down(h,o);
  int w = tid >> 6, lane = tid & 63;
  if (lane==0) red[w] = h;
  __syncthreads();
  if (tid==0) outp[b] = red[0]+red[1]+red[2]+red[3] + b2[0];
}

// ---------------- launch ----------------
extern "C" void kernel_launch(void* const* d_in, const int* in_sizes, int n_in,
                              void* d_out, int out_size, void* d_ws, size_t ws_size,
                              hipStream_t stream){
  const float* fq  = (const float*)d_in[0];
  const float* fs  = (const float*)d_in[1];
  const float* fqs = (const float*)d_in[2];
  const float* fss = (const float*)d_in[3];
  const float* fc1_w1 = (const float*)d_in[4];
  const float* fc1_b1 = (const float*)d_in[5];
  const float* fc1_w2 = (const float*)d_in[6];
  const float* fc1_b2 = (const float*)d_in[7];
  const float* ln1_g = (const float*)d_in[8];
  const float* ln1_b = (const float*)d_in[9];
  const float* fc3_w1 = (const float*)d_in[10];
  const float* fc3_b1 = (const float*)d_in[11];
  const float* fc3_w2 = (const float*)d_in[12];
  const float* fc3_b2 = (const float*)d_in[13];
  const float* ln3_g = (const float*)d_in[14];
  const float* ln3_b = (const float*)d_in[15];
  const float* fc4_w1 = (const float*)d_in[16];
  const float* fc4_b1 = (const float*)d_in[17];
  const float* fc4_w2 = (const float*)d_in[18];
  const float* fc4_b2 = (const float*)d_in[19];
  const float* ln4_g = (const float*)d_in[20];
  const float* ln4_b = (const float*)d_in[21];
  const float* fc2_w1 = (const float*)d_in[22];
  const float* fc2_b1 = (const float*)d_in[23];
  const float* fc2_w2 = (const float*)d_in[24];
  const float* fc2_b2 = (const float*)d_in[25];
  const float* cs_w1 = (const float*)d_in[26];
  const float* cs_b1 = (const float*)d_in[27];
  const float* cs_w2 = (const float*)d_in[28];
  const float* cs_b2 = (const float*)d_in[29];
  float* out = (float*)d_out;
  char* ws = (char*)d_ws;
  // ws layout (bytes):
  //   meanb f32 @0           (3,145,728)   [dead after k_fc1; head reused for weight prep]
  //     w2t  bf16 @0         (73,728)      [fc4 w2^T; written by k_wt AFTER k_fc1]
  //     w1t  bf16 @73728     (73,728)      [fc4 w1^T]
  //     w1t3 bf16 @147456    (57,344)      [fc3 w1^T, t-pad 224]
  //     w2t3 bf16 @204800    (53,248)      [fc3 w2^T, t'-pad 208]
  //   mlp1  f32 @3145728     (3,145,728)
  //   mu    f32 @6291456     (1,613,824)
  //   rstd  f32 @7905280     (1,613,824)
  //   h4    bf16 @9519104    (38,535,168)  [then P f32 + Cpart overlay]
  //   P     f32 @9519104     (19,668,992)  [overlays h4 (dead after fc4b)]
  //   Cpart f32 @29188096    (7,340,032)
  //   Qb    bf16 @59850752   (77,070,336)
  //   Sb    bf16 @136921088  (77,070,336)
  //   total 213,991,424 B
  float* meanb  = (float*)(ws + 0);
  ushort_t* w2t  = (ushort_t*)(ws + 0);       // overlays meanb (dead after k_fc1)
  ushort_t* w1t  = (ushort_t*)(ws + 73728);
  ushort_t* w1t3 = (ushort_t*)(ws + 147456);
  ushort_t* w2t3 = (ushort_t*)(ws + 204800);
  float* mlp1   = (float*)(ws + 3145728);
  float* mu     = (float*)(ws + 6291456);
  float* rstd   = (float*)(ws + 7905280);
  ushort_t* h4  = (ushort_t*)(ws + 9519104);
  float* P      = (float*)(ws + 9519104);     // overlays h4 (dead after fc4b)
  float* Cpart  = (float*)(ws + 29188096);    // after P, before Qb
  ushort_t* Qb  = (ushort_t*)(ws + 59850752);
  ushort_t* Sb  = (ushort_t*)(ws + 136921088);
  const size_t H4S = (size_t)512*196*96;      // per-s-half h4 elements

  k_mean<<<2048, 384, 0, stream>>>(fq, fs, fqs, fss, meanb);
  k_fc1<<<2048, 384, 0, stream>>>(meanb, fc1_w1, fc1_b1, fc1_w2, fc1_b2, mlp1);
  k_wt<<<504, 256, 0, stream>>>(fc4_w1, fc4_w2, fc3_w1, fc3_w2,
                                w1t, w2t, w1t3, w2t3);      // after k_fc1: meanb dead
  k_stats<<<100864, 256, 0, stream>>>(fq, fs, fqs, fss, mlp1, mu, rstd);
  k_class<<<1024, 384, 0, stream>>>(fq, fs, mlp1, mu, rstd, ln1_g, ln1_b, out);
  k_cosine<<<512, 384, 0, stream>>>(cs_w1, cs_b1, cs_w2, cs_b2, out);
  // fc3 fused MFMA: q-start then s-start
  k_fc3<<<3072, 256, 0, stream>>>(fqs, mlp1 + (size_t)2*512*384, mu + 2*100864, rstd + 2*100864,
                                  ln1_g, ln1_b, w1t3, fc3_b1, w2t3, fc3_b2, ln3_g, ln3_b, Qb);
  k_fc3<<<3072, 256, 0, stream>>>(fss, mlp1 + (size_t)3*512*384, mu + 3*100864, rstd + 3*100864,
                                  ln1_g, ln1_b, w1t3, fc3_b1, w2t3, fc3_b2, ln3_g, ln3_b, Sb);
  // fc4 stage A (MFMA): q then s (pre-offset pointers, no runtime s-select)
  k_fc4a<<<2048, 256, 0, stream>>>(fq, mlp1, mu, rstd, ln1_g, ln1_b,
                                   Qb, w1t, fc4_b1, h4);
  k_fc4a<<<2048, 256, 0, stream>>>(fs, mlp1 + (size_t)512*384, mu + 100864, rstd + 100864,
                                   ln1_g, ln1_b, Sb, w1t, fc4_b1, h4 + H4S);
  // fc4 stage B (MFMA): q then s (Qb/Sb overwritten in place after their last read)
  k_fc4b<<<2048, 256, 0, stream>>>(h4,       w2t, fc4_b2, ln4_g, ln4_b, out + 1024,          Qb);
  k_fc4b<<<2048, 256, 0, stream>>>(h4 + H4S, w2t, fc4_b2, ln4_g, ln4_b, out + 1024 + 196608, Sb);
  k_sim<<<8192, 256, 0, stream>>>(Qb, Sb, P);
  // fc2 head: split-K GEMM (896 blocks) + tiny reduce
  k_fc2a<<<896, 256, 0, stream>>>(P, fc2_w1, Cpart);
  k_fc2b<<<512, 256, 0, stream>>>(Cpart, fc2_b1, fc2_w2, fc2_b2, out);
}

// Round 11
// 1555.900 us; speedup vs baseline: 21.2662x; 1.0199x over previous
//
#include <hip/hip_runtime.h>
#include <math.h>

typedef unsigned short ushort_t;
typedef __attribute__((ext_vector_type(8))) short bf16x8;
typedef __attribute__((ext_vector_type(4))) float f32x4;

// ---------------- helpers ----------------
__device__ __forceinline__ float geluf(float x){
  return 0.5f*x*(1.0f+erff(x*0.70710678118654752440f));
}
__device__ __forceinline__ float bfu(unsigned int u){
  union { unsigned int i; float f; } v; v.i = (u & 0xffffu) << 16; return v.f;
}
__device__ __forceinline__ unsigned int f2b(float f){
  union { float f; unsigned int i; } v; v.f = f;
  unsigned int r = v.i + 0x7fffu + ((v.i >> 16) & 1u);
  return (r >> 16);
}

// Problem constants
// B=512, N=197, C=384, T=196 image tokens
// d_out layout (floats): out[512] | cosine[512] | query_class[512*384] | support_class[512*384]

// ---------------- A: token means (per tensor, b, c) ----------------
__global__ __launch_bounds__(384) void k_mean(
    const float* __restrict__ x0, const float* __restrict__ x1,
    const float* __restrict__ x2, const float* __restrict__ x3,
    float* __restrict__ meanb){
  int s = blockIdx.x >> 9, b = blockIdx.x & 511, c = threadIdx.x;
  const float* x = (s==0)?x0:(s==1)?x1:(s==2)?x2:x3;
  const float* p = x + ((size_t)b*197)*384 + c;
  float acc = 0.f;
  #pragma unroll 4
  for (int t=0;t<197;++t) acc += p[(size_t)t*384];
  meanb[((size_t)s*512+b)*384+c] = acc*(1.0f/197.0f);
}

// ---------------- B: fc1 tiny MLP on means ----------------
__global__ __launch_bounds__(384) void k_fc1(
    const float* __restrict__ meanb, const float* __restrict__ w1,
    const float* __restrict__ b1, const float* __restrict__ w2,
    const float* __restrict__ b2, float* __restrict__ mlp1){
  __shared__ float ms[384];
  __shared__ float hs[96];
  int row = blockIdx.x, tid = threadIdx.x;
  ms[tid] = meanb[(size_t)row*384 + tid];
  __syncthreads();
  if (tid < 96){
    float a = b1[tid];
    for (int c=0;c<384;++c) a += ms[c]*w1[c*96+tid];
    hs[tid] = geluf(a);
  }
  __syncthreads();
  float a = b2[tid];
  for (int j=0;j<96;++j) a += hs[j]*w2[j*384+tid];
  mlp1[(size_t)row*384 + tid] = a;
}

// ---------------- C: per-row LN stats of (x + mlp1) ----------------
__global__ __launch_bounds__(256) void k_stats(
    const float* __restrict__ x0, const float* __restrict__ x1,
    const float* __restrict__ x2, const float* __restrict__ x3,
    const float* __restrict__ mlp1, float* __restrict__ mu, float* __restrict__ rstd){
  int lane = threadIdx.x & 63, w = threadIdx.x >> 6;
  int row = blockIdx.x*4 + w;           // rows = 4*512*197 = 403456, grid exact
  int s = row / 100864;
  int rr = row % 100864;
  int b = rr / 197, t = rr % 197;
  const float* x = (s==0)?x0:(s==1)?x1:(s==2)?x2:x3;
  const float* xp = x + ((size_t)b*197 + t)*384;
  const float* mp = mlp1 + ((size_t)s*512 + b)*384;
  float sum=0.f, sq=0.f;
  for (int i=lane;i<384;i+=64){ float v = xp[i]+mp[i]; sum+=v; sq+=v*v; }
  #pragma unroll
  for (int o=32;o;o>>=1){ sum+=__shfl_down(sum,o); sq+=__shfl_down(sq,o); }
  if (lane==0){
    float m = sum*(1.0f/384.0f);
    mu[row] = m;
    rstd[row] = rsqrtf(sq*(1.0f/384.0f) - m*m + 1e-5f);
  }
}

// ---------------- D: class token rows -> d_out ----------------
__global__ __launch_bounds__(384) void k_class(
    const float* __restrict__ x0, const float* __restrict__ x1,
    const float* __restrict__ mlp1, const float* __restrict__ mu,
    const float* __restrict__ rstd, const float* __restrict__ g1,
    const float* __restrict__ bb1, float* __restrict__ dout){
  int s = blockIdx.x >> 9, b = blockIdx.x & 511, c = threadIdx.x;
  const float* x = s ? x1 : x0;
  int srow = (s*512 + b)*197;
  float v = x[((size_t)b*197)*384 + c] + mlp1[((size_t)s*512+b)*384 + c];
  float y = (v - mu[srow])*rstd[srow]*g1[c] + bb1[c];
  dout[1024 + (size_t)s*196608 + (size_t)b*384 + c] = y;
}

// ---------------- E: cosine head on class tokens ----------------
__global__ __launch_bounds__(384) void k_cosine(
    const float* __restrict__ w1, const float* __restrict__ b1,
    const float* __restrict__ w2, const float* __restrict__ b2,
    float* __restrict__ dout){
  __shared__ float qrow[384], srw[384], hq[96], hs[96];
  __shared__ float rd0[384], rd1[384], rd2[384];
  int b = blockIdx.x, tid = threadIdx.x;
  qrow[tid] = dout[1024   + (size_t)b*384 + tid];
  srw[tid]  = dout[197632 + (size_t)b*384 + tid];
  __syncthreads();
  if (tid < 96){
    float a = b1[tid];
    for (int c=0;c<384;++c) a += qrow[c]*w1[c*96+tid];
    hq[tid] = geluf(a);
  } else if (tid < 192){
    int j = tid - 96;
    float a = b1[j];
    for (int c=0;c<384;++c) a += srw[c]*w1[c*96+j];
    hs[j] = geluf(a);
  }
  __syncthreads();
  float qx = b2[tid], sy = b2[tid];
  for (int j=0;j<96;++j){ qx += hq[j]*w2[j*384+tid]; sy += hs[j]*w2[j*384+tid]; }
  rd0[tid] = qx*sy; rd1[tid] = qx*qx; rd2[tid] = sy*sy;
  __syncthreads();
  if (tid < 64){
    float d=0.f,nq=0.f,ns=0.f;
    for (int i=tid;i<384;i+=64){ d+=rd0[i]; nq+=rd1[i]; ns+=rd2[i]; }
    #pragma unroll
    for (int o=32;o;o>>=1){ d+=__shfl_down(d,o); nq+=__shfl_down(nq,o); ns+=__shfl_down(ns,o); }
    if (tid==0) dout[512 + b] = d / (fmaxf(sqrtf(nq),1e-8f)*fmaxf(sqrtf(ns),1e-8f));
  }
}

// ---------------- W: weight prep (bf16 transposes, zero-padded) ----------------
// grid 504, block 256 (504*256 = 129024).
//   fc4 w2t  [384][96]   @idx 0..36863        (w2 [96][384] transposed)
//   fc4 w1t  [96][384]   @idx 36864..73727    (w1 [384][96] transposed)
//   fc3 w1t3 [128][224]  @idx 73728..102399   (w1 [196][128] transposed, t-pad 0)
//   fc3 w2t3 [208][128]  @idx 102400..129023  (w2 [128][196] transposed, t'-pad 0)
// All live in the DEAD meanb region (written after k_fc1's last meanb read).
__global__ __launch_bounds__(256) void k_wt(
    const float* __restrict__ w1_4, const float* __restrict__ w2_4,
    const float* __restrict__ w1_3, const float* __restrict__ w2_3,
    ushort_t* __restrict__ w1t, ushort_t* __restrict__ w2t,
    ushort_t* __restrict__ w1t3, ushort_t* __restrict__ w2t3){
  int idx = blockIdx.x*256 + threadIdx.x;
  if (idx < 36864){
    int c = idx / 96, j = idx - c*96;
    w2t[idx] = (ushort_t)f2b(w2_4[(size_t)j*384 + c]);
  } else if (idx < 73728){
    int k = idx - 36864;
    int j = k / 384, c = k - j*384;
    w1t[k] = (ushort_t)f2b(w1_4[(size_t)c*96 + j]);
  } else if (idx < 102400){
    int k = idx - 73728;
    int j = k / 224, t = k - j*224;
    w1t3[k] = (t < 196) ? (ushort_t)f2b(w1_3[(size_t)t*128 + j]) : (ushort_t)0;
  } else {
    int k = idx - 102400;
    int tp = k / 128, j = k - tp*128;
    w2t3[k] = (tp < 196) ? (ushort_t)f2b(w2_3[(size_t)j*196 + tp]) : (ushort_t)0;
  }
}

// ---------------- F: fc3 fused MFMA (one s-half per launch) ----------------
// grid 512*6 (b, c-tile of 64), block 256 = 4 waves; wave = 16 c rows.
// Xs[64][232]: row stride 464 B = 29x16 -> every row 16B-aligned (true ds_read_b128;
// the round-10 stride 234 made odd rows 4B-aligned -> split b32 reads, latency-bound).
// Phase 1 stages by t-PAIRS: 2 row-adjacent float4 loads -> 4 packed uint LDS stores
// ({bf16(t),bf16(t+1)} contiguous in Xs[c][t]) — half the store count, all 4B-aligned.
// GEMM1: A = w1t3 rows j (L2), B = Xs rows c; 56 MFMA; gelu+bias -> Hs OVERLAID on
// the wave's OWN Xs rows (j=0..127) — wave-local rows + in-order per-wave DS ops
// make this safe with NO barrier. GEMM2: A = Hs rows c, B = w2t3 rows t'; 52 MFMA.
// LN over t' via 13-frag local sums + shfl_xor(1..8); write Qout[t'][c].
__global__ __launch_bounds__(256) void k_fc3(
    const float* __restrict__ x,         // fqs or fss
    const float* __restrict__ m1_base,   // mlp1 + s*512*384
    const float* __restrict__ mu_s,      // mu + s*100864
    const float* __restrict__ rstd_s,
    const float* __restrict__ g1, const float* __restrict__ bln1,
    const ushort_t* __restrict__ w1t3,   // [128][224] bf16
    const float* __restrict__ b1,        // fc3_b1 [128]
    const ushort_t* __restrict__ w2t3,   // [208][128] bf16
    const float* __restrict__ b2, const float* __restrict__ g3,
    const float* __restrict__ b3,
    ushort_t* __restrict__ Qout){        // Qb or Sb
  __shared__ ushort_t Xs[64][232];       // X^T tile; Hs overlays cols [0,128) per wave
  __shared__ float m1s[64], g1s[64], b1s[64];
  __shared__ float mus[196], rss[196];
  __shared__ float b1j[128];
  __shared__ float b2s[208], g3s[208], b3s[208];
  int bid = blockIdx.x;
  int b = bid/6, c0 = (bid%6)*64;
  int tid = threadIdx.x;
  // stage coefficients
  if (tid < 64){
    m1s[tid] = m1_base[(size_t)b*384 + c0 + tid];
    g1s[tid] = g1[c0+tid]; b1s[tid] = bln1[c0+tid];
  }
  if (tid < 128) b1j[tid] = b1[tid];
  if (tid < 196){ mus[tid] = mu_s[b*197 + tid + 1]; rss[tid] = rstd_s[b*197 + tid + 1]; }
  if (tid < 208){
    float bb=0.f, gg=0.f, b3v=0.f;
    if (tid < 196){ bb = b2[tid]; gg = g3[tid]; b3v = b3[tid]; }
    b2s[tid]=bb; g3s[tid]=gg; b3s[tid]=b3v;
  }
  // zero the t-pad of Xs ([196,224) as uints; [224,232) never read)
  for (int i = tid; i < 64*14; i += 256){
    *reinterpret_cast<unsigned int*>(&Xs[i/14][196 + 2*(i%14)]) = 0u;
  }
  __syncthreads();
  // phase 1: stage LN'd X^T tile by t-pairs (98 tpairs x 16 c4-slots = 1568)
  for (int e = 0; e < 7; ++e){
    int idx = e*256 + tid;
    if (idx < 1568){
      int t2 = idx >> 4, c4 = idx & 15;
      int t0 = t2*2;
      const float* xr = &x[((size_t)b*197 + t0 + 1)*384 + c0 + c4*4];
      float4 xv0 = *reinterpret_cast<const float4*>(xr);
      float4 xv1 = *reinterpret_cast<const float4*>(xr + 384);
      float mu0 = mus[t0], rs0 = rss[t0], mu1 = mus[t0+1], rs1 = rss[t0+1];
      int c = c4*4;
      unsigned int u0 = f2b(((xv0.x + m1s[c+0]) - mu0)*rs0*g1s[c+0] + b1s[c+0])
                      | (f2b(((xv1.x + m1s[c+0]) - mu1)*rs1*g1s[c+0] + b1s[c+0]) << 16);
      unsigned int u1 = f2b(((xv0.y + m1s[c+1]) - mu0)*rs0*g1s[c+1] + b1s[c+1])
                      | (f2b(((xv1.y + m1s[c+1]) - mu1)*rs1*g1s[c+1] + b1s[c+1]) << 16);
      unsigned int u2 = f2b(((xv0.z + m1s[c+2]) - mu0)*rs0*g1s[c+2] + b1s[c+2])
                      | (f2b(((xv1.z + m1s[c+2]) - mu1)*rs1*g1s[c+2] + b1s[c+2]) << 16);
      unsigned int u3 = f2b(((xv0.w + m1s[c+3]) - mu0)*rs0*g1s[c+3] + b1s[c+3])
                      | (f2b(((xv1.w + m1s[c+3]) - mu1)*rs1*g1s[c+3] + b1s[c+3]) << 16);
      *reinterpret_cast<unsigned int*>(&Xs[c+0][t0]) = u0;
      *reinterpret_cast<unsigned int*>(&Xs[c+1][t0]) = u1;
      *reinterpret_cast<unsigned int*>(&Xs[c+2][t0]) = u2;
      *reinterpret_cast<unsigned int*>(&Xs[c+3][t0]) = u3;
    }
  }
  __syncthreads();
  int w = tid >> 6, lane = tid & 63;
  int cl = lane & 15, kg = lane >> 4;
  // GEMM1: h = gelu(Xt @ w1 + b1)
  f32x4 hacc[8];
  #pragma unroll
  for (int jf=0;jf<8;++jf){ f32x4 z={0.f,0.f,0.f,0.f}; hacc[jf]=z; }
  const ushort_t* zrow = &Xs[w*16 + cl][kg*8];
  for (int kc = 0; kc < 7; ++kc){
    bf16x8 xb = *reinterpret_cast<const bf16x8*>(zrow + kc*32);
    #pragma unroll
    for (int jf=0;jf<8;++jf){
      const ushort_t* ap = w1t3 + (size_t)(jf*16 + cl)*224 + kg*8 + kc*32;
      hacc[jf] = __builtin_amdgcn_mfma_f32_16x16x32_bf16(
          *reinterpret_cast<const bf16x8*>(ap), xb, hacc[jf], 0, 0, 0);
    }
  }
  // D: row = j = jf*16+kg*4+r, col = c = cl -> overlay into the wave's OWN Xs rows.
  // Wave-local (each row w*16+cl is read/written only by lanes of this wave) and
  // per-wave DS ops are in-order -> no __syncthreads needed.
  #pragma unroll
  for (int jf=0;jf<8;++jf){
    f32x4 y = hacc[jf];
    int j0 = jf*16 + kg*4;
    uint2 pk;
    pk.x = f2b(geluf(y[0]+b1j[j0+0])) | (f2b(geluf(y[1]+b1j[j0+1]))<<16);
    pk.y = f2b(geluf(y[2]+b1j[j0+2])) | (f2b(geluf(y[3]+b1j[j0+3]))<<16);
    *reinterpret_cast<uint2*>(&Xs[w*16 + cl][j0]) = pk;
  }
  // GEMM2: y = h @ w2 (+b2 in epilogue)
  f32x4 yacc[13];
  #pragma unroll
  for (int tf=0;tf<13;++tf){ f32x4 z={0.f,0.f,0.f,0.f}; yacc[tf]=z; }
  const ushort_t* hrow = &Xs[w*16 + cl][kg*8];
  for (int kc = 0; kc < 4; ++kc){
    bf16x8 hb = *reinterpret_cast<const bf16x8*>(hrow + kc*32);
    #pragma unroll
    for (int tf=0;tf<13;++tf){
      const ushort_t* bp = w2t3 + (size_t)(tf*16 + cl)*128 + kg*8 + kc*32;
      yacc[tf] = __builtin_amdgcn_mfma_f32_16x16x32_bf16(
          hb, *reinterpret_cast<const bf16x8*>(bp), yacc[tf], 0, 0, 0);
    }
  }
  // epilogue: lane holds c = c0 + w*16 + kg*4 + r (r=0..3), t' = tf*16 + cl.
  // bias; LN stats over t' (pad t' -> y=0, b2s=0 -> contributes 0)
  float sum0=0.f,sum1=0.f,sum2=0.f,sum3=0.f, sq0=0.f,sq1=0.f,sq2=0.f,sq3=0.f;
  #pragma unroll
  for (int tf=0;tf<13;++tf){
    int tp = tf*16 + cl;
    float bb = b2s[tp];
    f32x4 y = yacc[tf];
    y[0]+=bb; y[1]+=bb; y[2]+=bb; y[3]+=bb;
    yacc[tf] = y;
    sum0+=y[0]; sum1+=y[1]; sum2+=y[2]; sum3+=y[3];
    sq0+=y[0]*y[0]; sq1+=y[1]*y[1]; sq2+=y[2]*y[2]; sq3+=y[3]*y[3];
  }
  #pragma unroll
  for (int o=1;o<16;o<<=1){
    sum0+=__shfl_xor(sum0,o); sum1+=__shfl_xor(sum1,o);
    sum2+=__shfl_xor(sum2,o); sum3+=__shfl_xor(sum3,o);
    sq0+=__shfl_xor(sq0,o); sq1+=__shfl_xor(sq1,o);
    sq2+=__shfl_xor(sq2,o); sq3+=__shfl_xor(sq3,o);
  }
  float m0=sum0*(1.0f/196.0f), m1v=sum1*(1.0f/196.0f), m2=sum2*(1.0f/196.0f), m3=sum3*(1.0f/196.0f);
  float r0=rsqrtf(sq0*(1.0f/196.0f)-m0*m0+1e-5f);
  float r1=rsqrtf(sq1*(1.0f/196.0f)-m1v*m1v+1e-5f);
  float r2=rsqrtf(sq2*(1.0f/196.0f)-m2*m2+1e-5f);
  float r3=rsqrtf(sq3*(1.0f/196.0f)-m3*m3+1e-5f);
  int cbase = c0 + w*16 + kg*4;
  #pragma unroll
  for (int tf=0;tf<13;++tf){
    int tp = tf*16 + cl;
    if (tp < 196){
      float gg = g3s[tp], bb3 = b3s[tp];
      f32x4 y = yacc[tf];
      unsigned int o0 = f2b((y[0]-m0)*r0*gg + bb3);
      unsigned int o1 = f2b((y[1]-m1v)*r1*gg + bb3);
      unsigned int o2 = f2b((y[2]-m2)*r2*gg + bb3);
      unsigned int o3 = f2b((y[3]-m3)*r3*gg + bb3);
      uint2 pk; pk.x = o0 | (o1<<16); pk.y = o2 | (o3<<16);
      *reinterpret_cast<uint2*>(&Qout[((size_t)b*196 + tp)*384 + cbase]) = pk;
    }
  }
}

// ---------------- H1: fc4 stage A (MFMA; one s-half per launch) ----------------
// grid 512*4 (b, t-tile of 64), block 256 = 4 waves; wave = 16 t x 96 j.
__global__ __launch_bounds__(256) void k_fc4a(
    const float* __restrict__ x,         // fq or fs
    const float* __restrict__ m1_base,   // mlp1 + s*512*384
    const float* __restrict__ mu_s,      // mu + s*100864
    const float* __restrict__ rstd_s,    // rstd + s*100864
    const float* __restrict__ g1, const float* __restrict__ bln1,
    const ushort_t* __restrict__ Qin,    // Qb or Sb
    const ushort_t* __restrict__ w1t,    // [96][384] bf16
    const float* __restrict__ b1mlp,
    ushort_t* __restrict__ h4s){         // h4 + s*512*196*96
  __shared__ ushort_t Zs[64][392];       // bf16 Z tile, padded stride
  __shared__ float m1s[384], g1s[384], b1s[384];
  __shared__ float mus[64], rss[64];
  __shared__ float b1m[96];
  int bid = blockIdx.x;
  int b = bid >> 2, tt0 = (bid & 3)*64;
  int tid = threadIdx.x;
  const float* m1 = m1_base + (size_t)b*384;
  for (int i = tid; i < 384; i += 256){ m1s[i] = m1[i]; g1s[i] = g1[i]; b1s[i] = bln1[i]; }
  if (tid < 96) b1m[tid] = b1mlp[tid];
  if (tid < 64){
    int t = tt0 + tid; int tc = t < 196 ? t : 195;
    mus[tid] = mu_s[b*197 + tc + 1]; rss[tid] = rstd_s[b*197 + tc + 1];
  }
  __syncthreads();
  // phase 1: Z build, 64 rows x 96 col4-slots = 6144 slots, 24 per thread
  for (int e = 0; e < 24; ++e){
    int v = e*256 + tid;
    int row = v/96, col4 = v - row*96;
    int t = tt0 + row; int tc = t < 196 ? t : 195;
    float valid = (t < 196) ? 1.f : 0.f;
    float4 xv = *reinterpret_cast<const float4*>(&x[((size_t)b*197 + tc + 1)*384 + col4*4]);
    uint2 qv = *reinterpret_cast<const uint2*>(&Qin[((size_t)b*196 + tc)*384 + col4*4]);
    float muv = mus[row], rsv = rss[row];
    int c = col4*4;
    float z0 = (((xv.x + m1s[c+0]) - muv)*rsv*g1s[c+0] + b1s[c+0]) * bfu(qv.x)      * valid;
    float z1 = (((xv.y + m1s[c+1]) - muv)*rsv*g1s[c+1] + b1s[c+1]) * bfu(qv.x>>16)  * valid;
    float z2 = (((xv.z + m1s[c+2]) - muv)*rsv*g1s[c+2] + b1s[c+2]) * bfu(qv.y)      * valid;
    float z3 = (((xv.w + m1s[c+3]) - muv)*rsv*g1s[c+3] + b1s[c+3]) * bfu(qv.y>>16)  * valid;
    uint2 pk; pk.x = f2b(z0) | (f2b(z1)<<16); pk.y = f2b(z2) | (f2b(z3)<<16);
    *reinterpret_cast<uint2*>(&Zs[row][col4*4]) = pk;
  }
  __syncthreads();
  // phase 2: MFMA GEMM1 (16t x 96j per wave, K=384)
  int w = tid >> 6, lane = tid & 63;
  int tr = tt0 + w*16 + (lane & 15);
  int kg = lane >> 4;
  f32x4 acc0 = {0.f,0.f,0.f,0.f}, acc1 = {0.f,0.f,0.f,0.f}, acc2 = {0.f,0.f,0.f,0.f};
  f32x4 acc3 = {0.f,0.f,0.f,0.f}, acc4 = {0.f,0.f,0.f,0.f}, acc5 = {0.f,0.f,0.f,0.f};
  const ushort_t* arow = w1t + (size_t)(lane & 15)*384 + kg*8;
  const ushort_t* zrow = &Zs[w*16 + (lane & 15)][kg*8];
  for (int kc = 0; kc < 12; ++kc){
    bf16x8 zb = *reinterpret_cast<const bf16x8*>(zrow + kc*32);
    bf16x8 a0 = *reinterpret_cast<const bf16x8*>(arow + kc*32);
    bf16x8 a1 = *reinterpret_cast<const bf16x8*>(arow + kc*32 + 16*384);
    bf16x8 a2 = *reinterpret_cast<const bf16x8*>(arow + kc*32 + 32*384);
    bf16x8 a3 = *reinterpret_cast<const bf16x8*>(arow + kc*32 + 48*384);
    bf16x8 a4 = *reinterpret_cast<const bf16x8*>(arow + kc*32 + 64*384);
    bf16x8 a5 = *reinterpret_cast<const bf16x8*>(arow + kc*32 + 80*384);
    acc0 = __builtin_amdgcn_mfma_f32_16x16x32_bf16(a0, zb, acc0, 0, 0, 0);
    acc1 = __builtin_amdgcn_mfma_f32_16x16x32_bf16(a1, zb, acc1, 0, 0, 0);
    acc2 = __builtin_amdgcn_mfma_f32_16x16x32_bf16(a2, zb, acc2, 0, 0, 0);
    acc3 = __builtin_amdgcn_mfma_f32_16x16x32_bf16(a3, zb, acc3, 0, 0, 0);
    acc4 = __builtin_amdgcn_mfma_f32_16x16x32_bf16(a4, zb, acc4, 0, 0, 0);
    acc5 = __builtin_amdgcn_mfma_f32_16x16x32_bf16(a5, zb, acc5, 0, 0, 0);
  }
  // epilogue: lane holds j = jb*16 + kg*4 + r (D row), t = tr (D col)
  if (tr < 196){
    ushort_t* dst = h4s + ((size_t)b*196 + tr)*96 + kg*4;
    #pragma unroll
    for (int jb = 0; jb < 6; ++jb){
      f32x4 y = (jb==0)?acc0:(jb==1)?acc1:(jb==2)?acc2:(jb==3)?acc3:(jb==4)?acc4:acc5;
      int j0 = jb*16 + kg*4;
      uint2 pk;
      pk.x = f2b(geluf(y[0]+b1m[j0+0])) | (f2b(geluf(y[1]+b1m[j0+1]))<<16);
      pk.y = f2b(geluf(y[2]+b1m[j0+2])) | (f2b(geluf(y[3]+b1m[j0+3]))<<16);
      *reinterpret_cast<uint2*>(dst + jb*16) = pk;
    }
  }
}

// ---------------- H2: fc4 stage B (MFMA; one s-half per launch) ----------------
// grid 512*4 (b, t-tile of 64), block 256 = 4 waves; wave = 16 t x 384 c.
__global__ __launch_bounds__(256) void k_fc4b(
    const ushort_t* __restrict__ h4s,    // h4 + s*512*196*96
    const ushort_t* __restrict__ w2t,    // [384][96] bf16
    const float* __restrict__ b2, const float* __restrict__ g4,
    const float* __restrict__ bb4,
    const float* __restrict__ cls_base,  // dout + 1024 + s*196608
    ushort_t* __restrict__ Qo){          // Qb or Sb
  __shared__ float b2s[384], g4s[384], b4s[384], cl_s[384];
  int bid = blockIdx.x;
  int b = bid >> 2, ttile = bid & 3;
  int tid = threadIdx.x, w = tid >> 6, lane = tid & 63;
  const float* cls = cls_base + (size_t)b*384;
  for (int i = tid; i < 384; i += 256){
    b2s[i] = b2[i]; g4s[i] = g4[i]; b4s[i] = bb4[i]; cl_s[i] = cls[i];
  }
  __syncthreads();
  int tr = ttile*64 + w*16 + (lane & 15);
  int trc = tr < 196 ? tr : 195;
  int kg = lane >> 4;
  const ushort_t* hp = h4s + ((size_t)b*196 + trc)*96 + kg*8;
  bf16x8 hb0 = *reinterpret_cast<const bf16x8*>(hp);
  bf16x8 hb1 = *reinterpret_cast<const bf16x8*>(hp + 32);
  bf16x8 hb2 = *reinterpret_cast<const bf16x8*>(hp + 64);
  const ushort_t* ap_base = w2t + (size_t)(lane & 15)*96 + kg*8;
  f32x4 acc[24];
  #pragma unroll
  for (int af = 0; af < 24; ++af){
    const ushort_t* ap = ap_base + (size_t)af*16*96;
    bf16x8 a0 = *reinterpret_cast<const bf16x8*>(ap);
    bf16x8 a1 = *reinterpret_cast<const bf16x8*>(ap + 32);
    bf16x8 a2 = *reinterpret_cast<const bf16x8*>(ap + 64);
    f32x4 z = {0.f,0.f,0.f,0.f};
    z = __builtin_amdgcn_mfma_f32_16x16x32_bf16(a0, hb0, z, 0, 0, 0);
    z = __builtin_amdgcn_mfma_f32_16x16x32_bf16(a1, hb1, z, 0, 0, 0);
    z = __builtin_amdgcn_mfma_f32_16x16x32_bf16(a2, hb2, z, 0, 0, 0);
    acc[af] = z;
  }
  // epilogue: lane holds c = af*16 + kg*4 + r  (r=0..3), t = tr (col)
  float sum = 0.f, sq = 0.f;
  #pragma unroll
  for (int af = 0; af < 24; ++af){
    int cb = af*16 + kg*4;
    float4 bv = *reinterpret_cast<const float4*>(&b2s[cb]);
    f32x4 y = acc[af];
    y[0] += bv.x; y[1] += bv.y; y[2] += bv.z; y[3] += bv.w;
    acc[af] = y;
    sum += y[0]+y[1]+y[2]+y[3];
    sq  += y[0]*y[0]+y[1]*y[1]+y[2]*y[2]+y[3]*y[3];
  }
  sum += __shfl_xor(sum, 16); sum += __shfl_xor(sum, 32);
  sq  += __shfl_xor(sq, 16);  sq  += __shfl_xor(sq, 32);
  float m4 = sum*(1.0f/384.0f);
  float rs = rsqrtf(sq*(1.0f/384.0f) - m4*m4 + 1e-5f);
  float s2 = 0.f;
  #pragma unroll
  for (int af = 0; af < 24; ++af){
    int cb = af*16 + kg*4;
    float4 gv = *reinterpret_cast<const float4*>(&g4s[cb]);
    float4 bb = *reinterpret_cast<const float4*>(&b4s[cb]);
    float4 cv = *reinterpret_cast<const float4*>(&cl_s[cb]);
    f32x4 y = acc[af];
    y[0] = (y[0]-m4)*rs*gv.x + bb.x + 0.5f*cv.x;
    y[1] = (y[1]-m4)*rs*gv.y + bb.y + 0.5f*cv.y;
    y[2] = (y[2]-m4)*rs*gv.z + bb.z + 0.5f*cv.z;
    y[3] = (y[3]-m4)*rs*gv.w + bb.w + 0.5f*cv.w;
    acc[af] = y;
    s2 += y[0]*y[0]+y[1]*y[1]+y[2]*y[2]+y[3]*y[3];
  }
  s2 += __shfl_xor(s2, 16); s2 += __shfl_xor(s2, 32);
  float inv = 1.0f/fmaxf(sqrtf(s2), 1e-12f);
  float sm = 0.f;
  #pragma unroll
  for (int af = 0; af < 24; ++af){
    f32x4 y = acc[af];
    y[0]*=inv; y[1]*=inv; y[2]*=inv; y[3]*=inv;
    acc[af] = y;
    sm += y[0]+y[1]+y[2]+y[3];
  }
  sm += __shfl_xor(sm, 16); sm += __shfl_xor(sm, 32);
  sm *= (1.0f/384.0f);
  if (tr < 196){
    ushort_t* dst = Qo + ((size_t)b*196 + tr)*384 + kg*4;
    #pragma unroll
    for (int af = 0; af < 24; ++af){
      f32x4 y = acc[af];
      uint2 pk;
      pk.x = f2b(y[0]-sm) | (f2b(y[1]-sm)<<16);
      pk.y = f2b(y[2]-sm) | (f2b(y[3]-sm)<<16);
      *reinterpret_cast<uint2*>(dst + af*16) = pk;
    }
  }
}

// ---------------- I: batched einsum + fused 2x2 pooling (MFMA) ----------------
// grid 512*16 (b, qt, st), block 256 = 4 waves; wave = 32x32 output tile.
__global__ __launch_bounds__(256) void k_sim(
    const ushort_t* __restrict__ Q, const ushort_t* __restrict__ S,
    float* __restrict__ P){
  int bx = blockIdx.x;
  int b = bx >> 4, qt = (bx >> 2) & 3, st = bx & 3;
  int tid = threadIdx.x;
  int w = tid >> 6, lane = tid & 63;
  int wr = w >> 1, wc = w & 1;
  int q0 = qt*64 + wr*32, s0 = st*64 + wc*32;
  int rrow = lane & 15, kg = lane >> 4;
  const ushort_t* Qb_ = Q + (size_t)b*196*384;
  const ushort_t* Sb_ = S + (size_t)b*196*384;
  int qr0 = min(q0 + rrow, 195), qr1 = min(q0 + 16 + rrow, 195);
  int sr0 = min(s0 + rrow, 195), sr1 = min(s0 + 16 + rrow, 195);
  const ushort_t* qp0 = Qb_ + (size_t)qr0*384 + kg*8;
  const ushort_t* qp1 = Qb_ + (size_t)qr1*384 + kg*8;
  const ushort_t* sp0 = Sb_ + (size_t)sr0*384 + kg*8;
  const ushort_t* sp1 = Sb_ + (size_t)sr1*384 + kg*8;
  f32x4 acc00 = {0.f,0.f,0.f,0.f}, acc01 = {0.f,0.f,0.f,0.f};
  f32x4 acc10 = {0.f,0.f,0.f,0.f}, acc11 = {0.f,0.f,0.f,0.f};
  for (int k0 = 0; k0 < 384; k0 += 32){
    bf16x8 a0 = *reinterpret_cast<const bf16x8*>(qp0 + k0);
    bf16x8 a1 = *reinterpret_cast<const bf16x8*>(qp1 + k0);
    bf16x8 b0 = *reinterpret_cast<const bf16x8*>(sp0 + k0);
    bf16x8 b1 = *reinterpret_cast<const bf16x8*>(sp1 + k0);
    acc00 = __builtin_amdgcn_mfma_f32_16x16x32_bf16(a0, b0, acc00, 0, 0, 0);
    acc01 = __builtin_amdgcn_mfma_f32_16x16x32_bf16(a0, b1, acc01, 0, 0, 0);
    acc10 = __builtin_amdgcn_mfma_f32_16x16x32_bf16(a1, b0, acc10, 0, 0, 0);
    acc11 = __builtin_amdgcn_mfma_f32_16x16x32_bf16(a1, b1, acc11, 0, 0, 0);
  }
  int c = lane & 15, g = lane >> 4;
  float* Pb = P + (size_t)b*98*98;
  #pragma unroll
  for (int i = 0; i < 2; ++i){
    #pragma unroll
    for (int j = 0; j < 2; ++j){
      f32x4 v = (i==0) ? (j==0 ? acc00 : acc01) : (j==0 ? acc10 : acc11);
      float p0 = v[0] + v[1];   // rows 4g, 4g+1
      float p1 = v[2] + v[3];   // rows 4g+2, 4g+3
      float t0 = p0 + __shfl_xor(p0, 1);
      float t1 = p1 + __shfl_xor(p1, 1);
      if (!(c & 1)){
        int qp = (q0 + 16*i + 4*g) >> 1;
        int sp = (s0 + 16*j + c) >> 1;
        if (sp < 98){
          if (qp     < 98) Pb[(size_t)(qp    )*98 + sp] = 0.25f*t0;
          if (qp + 1 < 98) Pb[(size_t)(qp + 1)*98 + sp] = 0.25f*t1;
        }
      }
    }
  }
}

// ---------------- J1: fc2 split-K GEMM  Cpart[ks] = P2-chunk @ w1-chunk ----------------
// grid 64*14 (m-block of 8 rows, k-split of 686), block 256 (= N columns)
__global__ __launch_bounds__(256) void k_fc2a(
    const float* __restrict__ P, const float* __restrict__ w1,
    float* __restrict__ Cpart){
  __shared__ float p2[8][688];
  int bx = blockIdx.x;
  int mb = bx & 63, ks = bx >> 6;      // 14 k-splits of 686 (14*686 = 9604)
  int b0 = mb*8, k0 = ks*686;
  int tid = threadIdx.x;
  for (int idx = tid; idx < 8*686; idx += 256){
    int r = idx / 686, i = idx - r*686;
    float v = P[(size_t)(b0+r)*9604 + k0 + i];
    p2[r][i] = v*v;
  }
  __syncthreads();
  float acc[8];
  #pragma unroll
  for (int r=0;r<8;++r) acc[r]=0.f;
  for (int ii=0; ii<686; ++ii){
    float w = w1[(size_t)(k0+ii)*256 + tid];
    #pragma unroll
    for (int r=0;r<8;++r) acc[r] += p2[r][ii]*w;
  }
  #pragma unroll
  for (int r=0;r<8;++r) Cpart[((size_t)ks*512 + b0 + r)*256 + tid] = acc[r];
}

// ---------------- J2: fc2 reduce + gelu + w2 dot ----------------
// grid 512 (one b each), block 256
__global__ __launch_bounds__(256) void k_fc2b(
    const float* __restrict__ Cpart, const float* __restrict__ b1,
    const float* __restrict__ w2, const float* __restrict__ b2,
    float* __restrict__ outp){
  __shared__ float red[4];
  int b = blockIdx.x, tid = threadIdx.x;
  float s = 0.f;
  for (int ks = 0; ks < 14; ++ks) s += Cpart[((size_t)ks*512 + b)*256 + tid];
  float h = geluf(s + b1[tid]) * w2[tid];
  #pragma unroll
  for (int o=32;o;o>>=1) h += __shfl_down(h,o);
  int w = tid >> 6, lane = tid & 63;
  if (lane==0) red[w] = h;
  __syncthreads();
  if (tid==0) outp[b] = red[0]+red[1]+red[2]+red[3] + b2[0];
}

// ---------------- launch ----------------
extern "C" void kernel_launch(void* const* d_in, const int* in_sizes, int n_in,
                              void* d_out, int out_size, void* d_ws, size_t ws_size,
                              hipStream_t stream){
  const float* fq  = (const float*)d_in[0];
  const float* fs  = (const float*)d_in[1];
  const float* fqs = (const float*)d_in[2];
  const float* fss = (const float*)d_in[3];
  const float* fc1_w1 = (const float*)d_in[4];
  const float* fc1_b1 = (const float*)d_in[5];
  const float* fc1_w2 = (const float*)d_in[6];
  const float* fc1_b2 = (const float*)d_in[7];
  const float* ln1_g = (const float*)d_in[8];
  const float* ln1_b = (const float*)d_in[9];
  const float* fc3_w1 = (const float*)d_in[10];
  const float* fc3_b1 = (const float*)d_in[11];
  const float* fc3_w2 = (const float*)d_in[12];
  const float* fc3_b2 = (const float*)d_in[13];
  const float* ln3_g = (const float*)d_in[14];
  const float* ln3_b = (const float*)d_in[15];
  const float* fc4_w1 = (const float*)d_in[16];
  const float* fc4_b1 = (const float*)d_in[17];
  const float* fc4_w2 = (const float*)d_in[18];
  const float* fc4_b2 = (const float*)d_in[19];
  const float* ln4_g = (const float*)d_in[20];
  const float* ln4_b = (const float*)d_in[21];
  const float* fc2_w1 = (const float*)d_in[22];
  const float* fc2_b1 = (const float*)d_in[23];
  const float* fc2_w2 = (const float*)d_in[24];
  const float* fc2_b2 = (const float*)d_in[25];
  const float* cs_w1 = (const float*)d_in[26];
  const float* cs_b1 = (const float*)d_in[27];
  const float* cs_w2 = (const float*)d_in[28];
  const float* cs_b2 = (const float*)d_in[29];
  float* out = (float*)d_out;
  char* ws = (char*)d_ws;
  // ws layout (bytes):
  //   meanb f32 @0           (3,145,728)   [dead after k_fc1; head reused for weight prep]
  //     w2t  bf16 @0         (73,728)      [fc4 w2^T; written by k_wt AFTER k_fc1]
  //     w1t  bf16 @73728     (73,728)      [fc4 w1^T]
  //     w1t3 bf16 @147456    (57,344)      [fc3 w1^T, t-pad 224]
  //     w2t3 bf16 @204800    (53,248)      [fc3 w2^T, t'-pad 208]
  //   mlp1  f32 @3145728     (3,145,728)
  //   mu    f32 @6291456     (1,613,824)
  //   rstd  f32 @7905280     (1,613,824)
  //   h4    bf16 @9519104    (38,535,168)  [then P f32 + Cpart overlay]
  //   P     f32 @9519104     (19,668,992)  [overlays h4 (dead after fc4b)]
  //   Cpart f32 @29188096    (7,340,032)
  //   Qb    bf16 @59850752   (77,070,336)
  //   Sb    bf16 @136921088  (77,070,336)
  //   total 213,991,424 B
  float* meanb  = (float*)(ws + 0);
  ushort_t* w2t  = (ushort_t*)(ws + 0);       // overlays meanb (dead after k_fc1)
  ushort_t* w1t  = (ushort_t*)(ws + 73728);
  ushort_t* w1t3 = (ushort_t*)(ws + 147456);
  ushort_t* w2t3 = (ushort_t*)(ws + 204800);
  float* mlp1   = (float*)(ws + 3145728);
  float* mu     = (float*)(ws + 6291456);
  float* rstd   = (float*)(ws + 7905280);
  ushort_t* h4  = (ushort_t*)(ws + 9519104);
  float* P      = (float*)(ws + 9519104);     // overlays h4 (dead after fc4b)
  float* Cpart  = (float*)(ws + 29188096);    // after P, before Qb
  ushort_t* Qb  = (ushort_t*)(ws + 59850752);
  ushort_t* Sb  = (ushort_t*)(ws + 136921088);
  const size_t H4S = (size_t)512*196*96;      // per-s-half h4 elements

  k_mean<<<2048, 384, 0, stream>>>(fq, fs, fqs, fss, meanb);
  k_fc1<<<2048, 384, 0, stream>>>(meanb, fc1_w1, fc1_b1, fc1_w2, fc1_b2, mlp1);
  k_wt<<<504, 256, 0, stream>>>(fc4_w1, fc4_w2, fc3_w1, fc3_w2,
                                w1t, w2t, w1t3, w2t3);      // after k_fc1: meanb dead
  k_stats<<<100864, 256, 0, stream>>>(fq, fs, fqs, fss, mlp1, mu, rstd);
  k_class<<<1024, 384, 0, stream>>>(fq, fs, mlp1, mu, rstd, ln1_g, ln1_b, out);
  k_cosine<<<512, 384, 0, stream>>>(cs_w1, cs_b1, cs_w2, cs_b2, out);
  // fc3 fused MFMA: q-start then s-start
  k_fc3<<<3072, 256, 0, stream>>>(fqs, mlp1 + (size_t)2*512*384, mu + 2*100864, rstd + 2*100864,
                                  ln1_g, ln1_b, w1t3, fc3_b1, w2t3, fc3_b2, ln3_g, ln3_b, Qb);
  k_fc3<<<3072, 256, 0, stream>>>(fss, mlp1 + (size_t)3*512*384, mu + 3*100864, rstd + 3*100864,
                                  ln1_g, ln1_b, w1t3, fc3_b1, w2t3, fc3_b2, ln3_g, ln3_b, Sb);
  // fc4 stage A (MFMA): q then s (pre-offset pointers, no runtime s-select)
  k_fc4a<<<2048, 256, 0, stream>>>(fq, mlp1, mu, rstd, ln1_g, ln1_b,
                                   Qb, w1t, fc4_b1, h4);
  k_fc4a<<<2048, 256, 0, stream>>>(fs, mlp1 + (size_t)512*384, mu + 100864, rstd + 100864,
                                   ln1_g, ln1_b, Sb, w1t, fc4_b1, h4 + H4S);
  // fc4 stage B (MFMA): q then s (Qb/Sb overwritten in place after their last read)
  k_fc4b<<<2048, 256, 0, stream>>>(h4,       w2t, fc4_b2, ln4_g, ln4_b, out + 1024,          Qb);
  k_fc4b<<<2048, 256, 0, stream>>>(h4 + H4S, w2t, fc4_b2, ln4_g, ln4_b, out + 1024 + 196608, Sb);
  k_sim<<<8192, 256, 0, stream>>>(Qb, Sb, P);
  // fc2 head: split-K GEMM (896 blocks) + tiny reduce
  k_fc2a<<<896, 256, 0, stream>>>(P, fc2_w1, Cpart);
  k_fc2b<<<512, 256, 0, stream>>>(Cpart, fc2_b1, fc2_w2, fc2_b2, out);
}

// Round 12
// 1475.449 us; speedup vs baseline: 22.4258x; 1.0545x over previous
//
#include <hip/hip_runtime.h>
#include <math.h>

typedef unsigned short ushort_t;
typedef __attribute__((ext_vector_type(8))) short bf16x8;
typedef __attribute__((ext_vector_type(4))) float f32x4;

// ---------------- helpers ----------------
__device__ __forceinline__ float geluf(float x){
  return 0.5f*x*(1.0f+erff(x*0.70710678118654752440f));
}
__device__ __forceinline__ float bfu(unsigned int u){
  union { unsigned int i; float f; } v; v.i = (u & 0xffffu) << 16; return v.f;
}
__device__ __forceinline__ unsigned int f2b(float f){
  union { float f; unsigned int i; } v; v.f = f;
  unsigned int r = v.i + 0x7fffu + ((v.i >> 16) & 1u);
  return (r >> 16);
}

// Problem constants
// B=512, N=197, C=384, T=196 image tokens
// d_out layout (floats): out[512] | cosine[512] | query_class[512*384] | support_class[512*384]

// ---------------- A: token means (per tensor, b, c) ----------------
__global__ __launch_bounds__(384) void k_mean(
    const float* __restrict__ x0, const float* __restrict__ x1,
    const float* __restrict__ x2, const float* __restrict__ x3,
    float* __restrict__ meanb){
  int s = blockIdx.x >> 9, b = blockIdx.x & 511, c = threadIdx.x;
  const float* x = (s==0)?x0:(s==1)?x1:(s==2)?x2:x3;
  const float* p = x + ((size_t)b*197)*384 + c;
  float acc = 0.f;
  #pragma unroll 4
  for (int t=0;t<197;++t) acc += p[(size_t)t*384];
  meanb[((size_t)s*512+b)*384+c] = acc*(1.0f/197.0f);
}

// ---------------- B: fc1 tiny MLP on means ----------------
__global__ __launch_bounds__(384) void k_fc1(
    const float* __restrict__ meanb, const float* __restrict__ w1,
    const float* __restrict__ b1, const float* __restrict__ w2,
    const float* __restrict__ b2, float* __restrict__ mlp1){
  __shared__ float ms[384];
  __shared__ float hs[96];
  int row = blockIdx.x, tid = threadIdx.x;
  ms[tid] = meanb[(size_t)row*384 + tid];
  __syncthreads();
  if (tid < 96){
    float a = b1[tid];
    for (int c=0;c<384;++c) a += ms[c]*w1[c*96+tid];
    hs[tid] = geluf(a);
  }
  __syncthreads();
  float a = b2[tid];
  for (int j=0;j<96;++j) a += hs[j]*w2[j*384+tid];
  mlp1[(size_t)row*384 + tid] = a;
}

// ---------------- C: per-row LN stats of (x + mlp1) ----------------
// grid 2048 (s*512+b), block 256 = 4 waves; 16-lane groups process 4 rows/wave.
// Lane register-caches its 24 mlp1 channels ONCE (kills the 619MB mlp1 re-read
// and per-row address arith that made the old version issue-bound at 1.6TB/s).
__global__ __launch_bounds__(256) void k_stats(
    const float* __restrict__ x0, const float* __restrict__ x1,
    const float* __restrict__ x2, const float* __restrict__ x3,
    const float* __restrict__ mlp1, float* __restrict__ mu, float* __restrict__ rstd){
  int sb = blockIdx.x;          // s*512 + b
  int s = sb >> 9, b = sb & 511;
  const float* x = (s==0)?x0:(s==1)?x1:(s==2)?x2:x3;
  const float* mp = mlp1 + (size_t)sb*384;
  int tid = threadIdx.x, w = tid >> 6, lane = tid & 63;
  int g = lane >> 4, il = lane & 15;
  float4 mreg[6];
  #pragma unroll
  for (int it = 0; it < 6; ++it)
    mreg[it] = *reinterpret_cast<const float4*>(&mp[il*4 + 64*it]);
  for (int t0 = 0; t0 < 208; t0 += 16){
    int t = t0 + w*4 + g;
    if (t < 197){
      const float* xp = x + ((size_t)b*197 + t)*384 + il*4;
      float sum = 0.f, sq = 0.f;
      #pragma unroll
      for (int it = 0; it < 6; ++it){
        float4 v = *reinterpret_cast<const float4*>(xp + 64*it);
        float a0 = v.x + mreg[it].x, a1 = v.y + mreg[it].y;
        float a2 = v.z + mreg[it].z, a3 = v.w + mreg[it].w;
        sum += a0+a1+a2+a3;
        sq  += a0*a0+a1*a1+a2*a2+a3*a3;
      }
      #pragma unroll
      for (int o=1;o<16;o<<=1){ sum += __shfl_xor(sum,o); sq += __shfl_xor(sq,o); }
      if (il == 0){
        int row = sb*197 + t;
        float m = sum*(1.0f/384.0f);
        mu[row] = m;
        rstd[row] = rsqrtf(sq*(1.0f/384.0f) - m*m + 1e-5f);
      }
    }
  }
}

// ---------------- D: class token rows -> d_out ----------------
__global__ __launch_bounds__(384) void k_class(
    const float* __restrict__ x0, const float* __restrict__ x1,
    const float* __restrict__ mlp1, const float* __restrict__ mu,
    const float* __restrict__ rstd, const float* __restrict__ g1,
    const float* __restrict__ bb1, float* __restrict__ dout){
  int s = blockIdx.x >> 9, b = blockIdx.x & 511, c = threadIdx.x;
  const float* x = s ? x1 : x0;
  int srow = (s*512 + b)*197;
  float v = x[((size_t)b*197)*384 + c] + mlp1[((size_t)s*512+b)*384 + c];
  float y = (v - mu[srow])*rstd[srow]*g1[c] + bb1[c];
  dout[1024 + (size_t)s*196608 + (size_t)b*384 + c] = y;
}

// ---------------- E: cosine head on class tokens ----------------
__global__ __launch_bounds__(384) void k_cosine(
    const float* __restrict__ w1, const float* __restrict__ b1,
    const float* __restrict__ w2, const float* __restrict__ b2,
    float* __restrict__ dout){
  __shared__ float qrow[384], srw[384], hq[96], hs[96];
  __shared__ float rd0[384], rd1[384], rd2[384];
  int b = blockIdx.x, tid = threadIdx.x;
  qrow[tid] = dout[1024   + (size_t)b*384 + tid];
  srw[tid]  = dout[197632 + (size_t)b*384 + tid];
  __syncthreads();
  if (tid < 96){
    float a = b1[tid];
    for (int c=0;c<384;++c) a += qrow[c]*w1[c*96+tid];
    hq[tid] = geluf(a);
  } else if (tid < 192){
    int j = tid - 96;
    float a = b1[j];
    for (int c=0;c<384;++c) a += srw[c]*w1[c*96+j];
    hs[j] = geluf(a);
  }
  __syncthreads();
  float qx = b2[tid], sy = b2[tid];
  for (int j=0;j<96;++j){ qx += hq[j]*w2[j*384+tid]; sy += hs[j]*w2[j*384+tid]; }
  rd0[tid] = qx*sy; rd1[tid] = qx*qx; rd2[tid] = sy*sy;
  __syncthreads();
  if (tid < 64){
    float d=0.f,nq=0.f,ns=0.f;
    for (int i=tid;i<384;i+=64){ d+=rd0[i]; nq+=rd1[i]; ns+=rd2[i]; }
    #pragma unroll
    for (int o=32;o;o>>=1){ d+=__shfl_down(d,o); nq+=__shfl_down(nq,o); ns+=__shfl_down(ns,o); }
    if (tid==0) dout[512 + b] = d / (fmaxf(sqrtf(nq),1e-8f)*fmaxf(sqrtf(ns),1e-8f));
  }
}

// ---------------- W: weight prep (bf16 transposes, zero-padded) ----------------
// grid 504, block 256 (504*256 = 129024).
__global__ __launch_bounds__(256) void k_wt(
    const float* __restrict__ w1_4, const float* __restrict__ w2_4,
    const float* __restrict__ w1_3, const float* __restrict__ w2_3,
    ushort_t* __restrict__ w1t, ushort_t* __restrict__ w2t,
    ushort_t* __restrict__ w1t3, ushort_t* __restrict__ w2t3){
  int idx = blockIdx.x*256 + threadIdx.x;
  if (idx < 36864){
    int c = idx / 96, j = idx - c*96;
    w2t[idx] = (ushort_t)f2b(w2_4[(size_t)j*384 + c]);
  } else if (idx < 73728){
    int k = idx - 36864;
    int j = k / 384, c = k - j*384;
    w1t[k] = (ushort_t)f2b(w1_4[(size_t)c*96 + j]);
  } else if (idx < 102400){
    int k = idx - 73728;
    int j = k / 224, t = k - j*224;
    w1t3[k] = (t < 196) ? (ushort_t)f2b(w1_3[(size_t)t*128 + j]) : (ushort_t)0;
  } else {
    int k = idx - 102400;
    int tp = k / 128, j = k - tp*128;
    w2t3[k] = (tp < 196) ? (ushort_t)f2b(w2_3[(size_t)j*196 + tp]) : (ushort_t)0;
  }
}

// ---------------- F: fc3 fused MFMA (one s-half per launch) ----------------
// grid 512*6 (b, c-tile of 64), block 256 = 4 waves; wave = 16 c rows.
__global__ __launch_bounds__(256) void k_fc3(
    const float* __restrict__ x,         // fqs or fss
    const float* __restrict__ m1_base,   // mlp1 + s*512*384
    const float* __restrict__ mu_s,      // mu + s*100864
    const float* __restrict__ rstd_s,
    const float* __restrict__ g1, const float* __restrict__ bln1,
    const ushort_t* __restrict__ w1t3,   // [128][224] bf16
    const float* __restrict__ b1,        // fc3_b1 [128]
    const ushort_t* __restrict__ w2t3,   // [208][128] bf16
    const float* __restrict__ b2, const float* __restrict__ g3,
    const float* __restrict__ b3,
    ushort_t* __restrict__ Qout){        // Qb or Sb
  __shared__ ushort_t Xs[64][232];       // X^T tile; Hs overlays cols [0,128) per wave
  __shared__ float m1s[64], g1s[64], b1s[64];
  __shared__ float mus[196], rss[196];
  __shared__ float b1j[128];
  __shared__ float b2s[208], g3s[208], b3s[208];
  int bid = blockIdx.x;
  int b = bid/6, c0 = (bid%6)*64;
  int tid = threadIdx.x;
  // stage coefficients
  if (tid < 64){
    m1s[tid] = m1_base[(size_t)b*384 + c0 + tid];
    g1s[tid] = g1[c0+tid]; b1s[tid] = bln1[c0+tid];
  }
  if (tid < 128) b1j[tid] = b1[tid];
  if (tid < 196){ mus[tid] = mu_s[b*197 + tid + 1]; rss[tid] = rstd_s[b*197 + tid + 1]; }
  if (tid < 208){
    float bb=0.f, gg=0.f, b3v=0.f;
    if (tid < 196){ bb = b2[tid]; gg = g3[tid]; b3v = b3[tid]; }
    b2s[tid]=bb; g3s[tid]=gg; b3s[tid]=b3v;
  }
  // zero the t-pad of Xs ([196,224) as uints; [224,232) never read)
  for (int i = tid; i < 64*14; i += 256){
    *reinterpret_cast<unsigned int*>(&Xs[i/14][196 + 2*(i%14)]) = 0u;
  }
  __syncthreads();
  // phase 1: stage LN'd X^T tile by t-pairs (98 tpairs x 16 c4-slots = 1568)
  for (int e = 0; e < 7; ++e){
    int idx = e*256 + tid;
    if (idx < 1568){
      int t2 = idx >> 4, c4 = idx & 15;
      int t0 = t2*2;
      const float* xr = &x[((size_t)b*197 + t0 + 1)*384 + c0 + c4*4];
      float4 xv0 = *reinterpret_cast<const float4*>(xr);
      float4 xv1 = *reinterpret_cast<const float4*>(xr + 384);
      float mu0 = mus[t0], rs0 = rss[t0], mu1 = mus[t0+1], rs1 = rss[t0+1];
      int c = c4*4;
      unsigned int u0 = f2b(((xv0.x + m1s[c+0]) - mu0)*rs0*g1s[c+0] + b1s[c+0])
                      | (f2b(((xv1.x + m1s[c+0]) - mu1)*rs1*g1s[c+0] + b1s[c+0]) << 16);
      unsigned int u1 = f2b(((xv0.y + m1s[c+1]) - mu0)*rs0*g1s[c+1] + b1s[c+1])
                      | (f2b(((xv1.y + m1s[c+1]) - mu1)*rs1*g1s[c+1] + b1s[c+1]) << 16);
      unsigned int u2 = f2b(((xv0.z + m1s[c+2]) - mu0)*rs0*g1s[c+2] + b1s[c+2])
                      | (f2b(((xv1.z + m1s[c+2]) - mu1)*rs1*g1s[c+2] + b1s[c+2]) << 16);
      unsigned int u3 = f2b(((xv0.w + m1s[c+3]) - mu0)*rs0*g1s[c+3] + b1s[c+3])
                      | (f2b(((xv1.w + m1s[c+3]) - mu1)*rs1*g1s[c+3] + b1s[c+3]) << 16);
      *reinterpret_cast<unsigned int*>(&Xs[c+0][t0]) = u0;
      *reinterpret_cast<unsigned int*>(&Xs[c+1][t0]) = u1;
      *reinterpret_cast<unsigned int*>(&Xs[c+2][t0]) = u2;
      *reinterpret_cast<unsigned int*>(&Xs[c+3][t0]) = u3;
    }
  }
  __syncthreads();
  int w = tid >> 6, lane = tid & 63;
  int cl = lane & 15, kg = lane >> 4;
  // GEMM1: h = gelu(Xt @ w1 + b1)
  f32x4 hacc[8];
  #pragma unroll
  for (int jf=0;jf<8;++jf){ f32x4 z={0.f,0.f,0.f,0.f}; hacc[jf]=z; }
  const ushort_t* zrow = &Xs[w*16 + cl][kg*8];
  for (int kc = 0; kc < 7; ++kc){
    bf16x8 xb = *reinterpret_cast<const bf16x8*>(zrow + kc*32);
    #pragma unroll
    for (int jf=0;jf<8;++jf){
      const ushort_t* ap = w1t3 + (size_t)(jf*16 + cl)*224 + kg*8 + kc*32;
      hacc[jf] = __builtin_amdgcn_mfma_f32_16x16x32_bf16(
          *reinterpret_cast<const bf16x8*>(ap), xb, hacc[jf], 0, 0, 0);
    }
  }
  // D: row = j = jf*16+kg*4+r, col = c = cl -> overlay into the wave's OWN Xs rows.
  #pragma unroll
  for (int jf=0;jf<8;++jf){
    f32x4 y = hacc[jf];
    int j0 = jf*16 + kg*4;
    uint2 pk;
    pk.x = f2b(geluf(y[0]+b1j[j0+0])) | (f2b(geluf(y[1]+b1j[j0+1]))<<16);
    pk.y = f2b(geluf(y[2]+b1j[j0+2])) | (f2b(geluf(y[3]+b1j[j0+3]))<<16);
    *reinterpret_cast<uint2*>(&Xs[w*16 + cl][j0]) = pk;
  }
  // GEMM2: y = h @ w2 (+b2 in epilogue)
  f32x4 yacc[13];
  #pragma unroll
  for (int tf=0;tf<13;++tf){ f32x4 z={0.f,0.f,0.f,0.f}; yacc[tf]=z; }
  const ushort_t* hrow = &Xs[w*16 + cl][kg*8];
  for (int kc = 0; kc < 4; ++kc){
    bf16x8 hb = *reinterpret_cast<const bf16x8*>(hrow + kc*32);
    #pragma unroll
    for (int tf=0;tf<13;++tf){
      const ushort_t* bp = w2t3 + (size_t)(tf*16 + cl)*128 + kg*8 + kc*32;
      yacc[tf] = __builtin_amdgcn_mfma_f32_16x16x32_bf16(
          hb, *reinterpret_cast<const bf16x8*>(bp), yacc[tf], 0, 0, 0);
    }
  }
  // epilogue: lane holds c = c0 + w*16 + kg*4 + r (r=0..3), t' = tf*16 + cl.
  float sum0=0.f,sum1=0.f,sum2=0.f,sum3=0.f, sq0=0.f,sq1=0.f,sq2=0.f,sq3=0.f;
  #pragma unroll
  for (int tf=0;tf<13;++tf){
    int tp = tf*16 + cl;
    float bb = b2s[tp];
    f32x4 y = yacc[tf];
    y[0]+=bb; y[1]+=bb; y[2]+=bb; y[3]+=bb;
    yacc[tf] = y;
    sum0+=y[0]; sum1+=y[1]; sum2+=y[2]; sum3+=y[3];
    sq0+=y[0]*y[0]; sq1+=y[1]*y[1]; sq2+=y[2]*y[2]; sq3+=y[3]*y[3];
  }
  #pragma unroll
  for (int o=1;o<16;o<<=1){
    sum0+=__shfl_xor(sum0,o); sum1+=__shfl_xor(sum1,o);
    sum2+=__shfl_xor(sum2,o); sum3+=__shfl_xor(sum3,o);
    sq0+=__shfl_xor(sq0,o); sq1+=__shfl_xor(sq1,o);
    sq2+=__shfl_xor(sq2,o); sq3+=__shfl_xor(sq3,o);
  }
  float m0=sum0*(1.0f/196.0f), m1v=sum1*(1.0f/196.0f), m2=sum2*(1.0f/196.0f), m3=sum3*(1.0f/196.0f);
  float r0=rsqrtf(sq0*(1.0f/196.0f)-m0*m0+1e-5f);
  float r1=rsqrtf(sq1*(1.0f/196.0f)-m1v*m1v+1e-5f);
  float r2=rsqrtf(sq2*(1.0f/196.0f)-m2*m2+1e-5f);
  float r3=rsqrtf(sq3*(1.0f/196.0f)-m3*m3+1e-5f);
  int cbase = c0 + w*16 + kg*4;
  #pragma unroll
  for (int tf=0;tf<13;++tf){
    int tp = tf*16 + cl;
    if (tp < 196){
      float gg = g3s[tp], bb3 = b3s[tp];
      f32x4 y = yacc[tf];
      unsigned int o0 = f2b((y[0]-m0)*r0*gg + bb3);
      unsigned int o1 = f2b((y[1]-m1v)*r1*gg + bb3);
      unsigned int o2 = f2b((y[2]-m2)*r2*gg + bb3);
      unsigned int o3 = f2b((y[3]-m3)*r3*gg + bb3);
      uint2 pk; pk.x = o0 | (o1<<16); pk.y = o2 | (o3<<16);
      *reinterpret_cast<uint2*>(&Qout[((size_t)b*196 + tp)*384 + cbase]) = pk;
    }
  }
}

// ---------------- H1: fc4 stage A (MFMA; one s-half per launch) ----------------
// grid 512*4 (b, t-tile of 64), block 256 = 4 waves; wave = 16 t x 96 j.
__global__ __launch_bounds__(256) void k_fc4a(
    const float* __restrict__ x,         // fq or fs
    const float* __restrict__ m1_base,   // mlp1 + s*512*384
    const float* __restrict__ mu_s,      // mu + s*100864
    const float* __restrict__ rstd_s,    // rstd + s*100864
    const float* __restrict__ g1, const float* __restrict__ bln1,
    const ushort_t* __restrict__ Qin,    // Qb or Sb
    const ushort_t* __restrict__ w1t,    // [96][384] bf16
    const float* __restrict__ b1mlp,
    ushort_t* __restrict__ h4s){         // h4 + s*512*196*96
  __shared__ ushort_t Zs[64][392];       // bf16 Z tile, padded stride
  __shared__ float m1s[384], g1s[384], b1s[384];
  __shared__ float mus[64], rss[64];
  __shared__ float b1m[96];
  int bid = blockIdx.x;
  int b = bid >> 2, tt0 = (bid & 3)*64;
  int tid = threadIdx.x;
  const float* m1 = m1_base + (size_t)b*384;
  for (int i = tid; i < 384; i += 256){ m1s[i] = m1[i]; g1s[i] = g1[i]; b1s[i] = bln1[i]; }
  if (tid < 96) b1m[tid] = b1mlp[tid];
  if (tid < 64){
    int t = tt0 + tid; int tc = t < 196 ? t : 195;
    mus[tid] = mu_s[b*197 + tc + 1]; rss[tid] = rstd_s[b*197 + tc + 1];
  }
  __syncthreads();
  // phase 1: Z build, 64 rows x 96 col4-slots = 6144 slots, 24 per thread
  for (int e = 0; e < 24; ++e){
    int v = e*256 + tid;
    int row = v/96, col4 = v - row*96;
    int t = tt0 + row; int tc = t < 196 ? t : 195;
    float valid = (t < 196) ? 1.f : 0.f;
    float4 xv = *reinterpret_cast<const float4*>(&x[((size_t)b*197 + tc + 1)*384 + col4*4]);
    uint2 qv = *reinterpret_cast<const uint2*>(&Qin[((size_t)b*196 + tc)*384 + col4*4]);
    float muv = mus[row], rsv = rss[row];
    int c = col4*4;
    float z0 = (((xv.x + m1s[c+0]) - muv)*rsv*g1s[c+0] + b1s[c+0]) * bfu(qv.x)      * valid;
    float z1 = (((xv.y + m1s[c+1]) - muv)*rsv*g1s[c+1] + b1s[c+1]) * bfu(qv.x>>16)  * valid;
    float z2 = (((xv.z + m1s[c+2]) - muv)*rsv*g1s[c+2] + b1s[c+2]) * bfu(qv.y)      * valid;
    float z3 = (((xv.w + m1s[c+3]) - muv)*rsv*g1s[c+3] + b1s[c+3]) * bfu(qv.y>>16)  * valid;
    uint2 pk; pk.x = f2b(z0) | (f2b(z1)<<16); pk.y = f2b(z2) | (f2b(z3)<<16);
    *reinterpret_cast<uint2*>(&Zs[row][col4*4]) = pk;
  }
  __syncthreads();
  // phase 2: MFMA GEMM1 (16t x 96j per wave, K=384)
  int w = tid >> 6, lane = tid & 63;
  int tr = tt0 + w*16 + (lane & 15);
  int kg = lane >> 4;
  f32x4 acc0 = {0.f,0.f,0.f,0.f}, acc1 = {0.f,0.f,0.f,0.f}, acc2 = {0.f,0.f,0.f,0.f};
  f32x4 acc3 = {0.f,0.f,0.f,0.f}, acc4 = {0.f,0.f,0.f,0.f}, acc5 = {0.f,0.f,0.f,0.f};
  const ushort_t* arow = w1t + (size_t)(lane & 15)*384 + kg*8;
  const ushort_t* zrow = &Zs[w*16 + (lane & 15)][kg*8];
  for (int kc = 0; kc < 12; ++kc){
    bf16x8 zb = *reinterpret_cast<const bf16x8*>(zrow + kc*32);
    bf16x8 a0 = *reinterpret_cast<const bf16x8*>(arow + kc*32);
    bf16x8 a1 = *reinterpret_cast<const bf16x8*>(arow + kc*32 + 16*384);
    bf16x8 a2 = *reinterpret_cast<const bf16x8*>(arow + kc*32 + 32*384);
    bf16x8 a3 = *reinterpret_cast<const bf16x8*>(arow + kc*32 + 48*384);
    bf16x8 a4 = *reinterpret_cast<const bf16x8*>(arow + kc*32 + 64*384);
    bf16x8 a5 = *reinterpret_cast<const bf16x8*>(arow + kc*32 + 80*384);
    acc0 = __builtin_amdgcn_mfma_f32_16x16x32_bf16(a0, zb, acc0, 0, 0, 0);
    acc1 = __builtin_amdgcn_mfma_f32_16x16x32_bf16(a1, zb, acc1, 0, 0, 0);
    acc2 = __builtin_amdgcn_mfma_f32_16x16x32_bf16(a2, zb, acc2, 0, 0, 0);
    acc3 = __builtin_amdgcn_mfma_f32_16x16x32_bf16(a3, zb, acc3, 0, 0, 0);
    acc4 = __builtin_amdgcn_mfma_f32_16x16x32_bf16(a4, zb, acc4, 0, 0, 0);
    acc5 = __builtin_amdgcn_mfma_f32_16x16x32_bf16(a5, zb, acc5, 0, 0, 0);
  }
  // epilogue: lane holds j = jb*16 + kg*4 + r (D row), t = tr (D col)
  if (tr < 196){
    ushort_t* dst = h4s + ((size_t)b*196 + tr)*96 + kg*4;
    #pragma unroll
    for (int jb = 0; jb < 6; ++jb){
      f32x4 y = (jb==0)?acc0:(jb==1)?acc1:(jb==2)?acc2:(jb==3)?acc3:(jb==4)?acc4:acc5;
      int j0 = jb*16 + kg*4;
      uint2 pk;
      pk.x = f2b(geluf(y[0]+b1m[j0+0])) | (f2b(geluf(y[1]+b1m[j0+1]))<<16);
      pk.y = f2b(geluf(y[2]+b1m[j0+2])) | (f2b(geluf(y[3]+b1m[j0+3]))<<16);
      *reinterpret_cast<uint2*>(dst + jb*16) = pk;
    }
  }
}

// ---------------- H2: fc4 stage B (MFMA; one s-half per launch) ----------------
// grid 512*4 (b, t-tile of 64), block 256 = 4 waves; wave = 16 t x 384 c.
__global__ __launch_bounds__(256) void k_fc4b(
    const ushort_t* __restrict__ h4s,    // h4 + s*512*196*96
    const ushort_t* __restrict__ w2t,    // [384][96] bf16
    const float* __restrict__ b2, const float* __restrict__ g4,
    const float* __restrict__ bb4,
    const float* __restrict__ cls_base,  // dout + 1024 + s*196608
    ushort_t* __restrict__ Qo){          // Qb or Sb
  __shared__ float b2s[384], g4s[384], b4s[384], cl_s[384];
  int bid = blockIdx.x;
  int b = bid >> 2, ttile = bid & 3;
  int tid = threadIdx.x, w = tid >> 6, lane = tid & 63;
  const float* cls = cls_base + (size_t)b*384;
  for (int i = tid; i < 384; i += 256){
    b2s[i] = b2[i]; g4s[i] = g4[i]; b4s[i] = bb4[i]; cl_s[i] = cls[i];
  }
  __syncthreads();
  int tr = ttile*64 + w*16 + (lane & 15);
  int trc = tr < 196 ? tr : 195;
  int kg = lane >> 4;
  const ushort_t* hp = h4s + ((size_t)b*196 + trc)*96 + kg*8;
  bf16x8 hb0 = *reinterpret_cast<const bf16x8*>(hp);
  bf16x8 hb1 = *reinterpret_cast<const bf16x8*>(hp + 32);
  bf16x8 hb2 = *reinterpret_cast<const bf16x8*>(hp + 64);
  const ushort_t* ap_base = w2t + (size_t)(lane & 15)*96 + kg*8;
  f32x4 acc[24];
  #pragma unroll
  for (int af = 0; af < 24; ++af){
    const ushort_t* ap = ap_base + (size_t)af*16*96;
    bf16x8 a0 = *reinterpret_cast<const bf16x8*>(ap);
    bf16x8 a1 = *reinterpret_cast<const bf16x8*>(ap + 32);
    bf16x8 a2 = *reinterpret_cast<const bf16x8*>(ap + 64);
    f32x4 z = {0.f,0.f,0.f,0.f};
    z = __builtin_amdgcn_mfma_f32_16x16x32_bf16(a0, hb0, z, 0, 0, 0);
    z = __builtin_amdgcn_mfma_f32_16x16x32_bf16(a1, hb1, z, 0, 0, 0);
    z = __builtin_amdgcn_mfma_f32_16x16x32_bf16(a2, hb2, z, 0, 0, 0);
    acc[af] = z;
  }
  // epilogue: lane holds c = af*16 + kg*4 + r  (r=0..3), t = tr (col)
  float sum = 0.f, sq = 0.f;
  #pragma unroll
  for (int af = 0; af < 24; ++af){
    int cb = af*16 + kg*4;
    float4 bv = *reinterpret_cast<const float4*>(&b2s[cb]);
    f32x4 y = acc[af];
    y[0] += bv.x; y[1] += bv.y; y[2] += bv.z; y[3] += bv.w;
    acc[af] = y;
    sum += y[0]+y[1]+y[2]+y[3];
    sq  += y[0]*y[0]+y[1]*y[1]+y[2]*y[2]+y[3]*y[3];
  }
  sum += __shfl_xor(sum, 16); sum += __shfl_xor(sum, 32);
  sq  += __shfl_xor(sq, 16);  sq  += __shfl_xor(sq, 32);
  float m4 = sum*(1.0f/384.0f);
  float rs = rsqrtf(sq*(1.0f/384.0f) - m4*m4 + 1e-5f);
  float s2 = 0.f;
  #pragma unroll
  for (int af = 0; af < 24; ++af){
    int cb = af*16 + kg*4;
    float4 gv = *reinterpret_cast<const float4*>(&g4s[cb]);
    float4 bb = *reinterpret_cast<const float4*>(&b4s[cb]);
    float4 cv = *reinterpret_cast<const float4*>(&cl_s[cb]);
    f32x4 y = acc[af];
    y[0] = (y[0]-m4)*rs*gv.x + bb.x + 0.5f*cv.x;
    y[1] = (y[1]-m4)*rs*gv.y + bb.y + 0.5f*cv.y;
    y[2] = (y[2]-m4)*rs*gv.z + bb.z + 0.5f*cv.z;
    y[3] = (y[3]-m4)*rs*gv.w + bb.w + 0.5f*cv.w;
    acc[af] = y;
    s2 += y[0]*y[0]+y[1]*y[1]+y[2]*y[2]+y[3]*y[3];
  }
  s2 += __shfl_xor(s2, 16); s2 += __shfl_xor(s2, 32);
  float inv = 1.0f/fmaxf(sqrtf(s2), 1e-12f);
  float sm = 0.f;
  #pragma unroll
  for (int af = 0; af < 24; ++af){
    f32x4 y = acc[af];
    y[0]*=inv; y[1]*=inv; y[2]*=inv; y[3]*=inv;
    acc[af] = y;
    sm += y[0]+y[1]+y[2]+y[3];
  }
  sm += __shfl_xor(sm, 16); sm += __shfl_xor(sm, 32);
  sm *= (1.0f/384.0f);
  if (tr < 196){
    ushort_t* dst = Qo + ((size_t)b*196 + tr)*384 + kg*4;
    #pragma unroll
    for (int af = 0; af < 24; ++af){
      f32x4 y = acc[af];
      uint2 pk;
      pk.x = f2b(y[0]-sm) | (f2b(y[1]-sm)<<16);
      pk.y = f2b(y[2]-sm) | (f2b(y[3]-sm)<<16);
      *reinterpret_cast<uint2*>(dst + af*16) = pk;
    }
  }
}

// ---------------- I: batched einsum + fused 2x2 pooling (MFMA) ----------------
// grid 512*16 (b, qt, st), block 256 = 4 waves; wave = 32x32 output tile.
__global__ __launch_bounds__(256) void k_sim(
    const ushort_t* __restrict__ Q, const ushort_t* __restrict__ S,
    float* __restrict__ P){
  int bx = blockIdx.x;
  int b = bx >> 4, qt = (bx >> 2) & 3, st = bx & 3;
  int tid = threadIdx.x;
  int w = tid >> 6, lane = tid & 63;
  int wr = w >> 1, wc = w & 1;
  int q0 = qt*64 + wr*32, s0 = st*64 + wc*32;
  int rrow = lane & 15, kg = lane >> 4;
  const ushort_t* Qb_ = Q + (size_t)b*196*384;
  const ushort_t* Sb_ = S + (size_t)b*196*384;
  int qr0 = min(q0 + rrow, 195), qr1 = min(q0 + 16 + rrow, 195);
  int sr0 = min(s0 + rrow, 195), sr1 = min(s0 + 16 + rrow, 195);
  const ushort_t* qp0 = Qb_ + (size_t)qr0*384 + kg*8;
  const ushort_t* qp1 = Qb_ + (size_t)qr1*384 + kg*8;
  const ushort_t* sp0 = Sb_ + (size_t)sr0*384 + kg*8;
  const ushort_t* sp1 = Sb_ + (size_t)sr1*384 + kg*8;
  f32x4 acc00 = {0.f,0.f,0.f,0.f}, acc01 = {0.f,0.f,0.f,0.f};
  f32x4 acc10 = {0.f,0.f,0.f,0.f}, acc11 = {0.f,0.f,0.f,0.f};
  for (int k0 = 0; k0 < 384; k0 += 32){
    bf16x8 a0 = *reinterpret_cast<const bf16x8*>(qp0 + k0);
    bf16x8 a1 = *reinterpret_cast<const bf16x8*>(qp1 + k0);
    bf16x8 b0 = *reinterpret_cast<const bf16x8*>(sp0 + k0);
    bf16x8 b1 = *reinterpret_cast<const bf16x8*>(sp1 + k0);
    acc00 = __builtin_amdgcn_mfma_f32_16x16x32_bf16(a0, b0, acc00, 0, 0, 0);
    acc01 = __builtin_amdgcn_mfma_f32_16x16x32_bf16(a0, b1, acc01, 0, 0, 0);
    acc10 = __builtin_amdgcn_mfma_f32_16x16x32_bf16(a1, b0, acc10, 0, 0, 0);
    acc11 = __builtin_amdgcn_mfma_f32_16x16x32_bf16(a1, b1, acc11, 0, 0, 0);
  }
  int c = lane & 15, g = lane >> 4;
  float* Pb = P + (size_t)b*98*98;
  #pragma unroll
  for (int i = 0; i < 2; ++i){
    #pragma unroll
    for (int j = 0; j < 2; ++j){
      f32x4 v = (i==0) ? (j==0 ? acc00 : acc01) : (j==0 ? acc10 : acc11);
      float p0 = v[0] + v[1];   // rows 4g, 4g+1
      float p1 = v[2] + v[3];   // rows 4g+2, 4g+3
      float t0 = p0 + __shfl_xor(p0, 1);
      float t1 = p1 + __shfl_xor(p1, 1);
      if (!(c & 1)){
        int qp = (q0 + 16*i + 4*g) >> 1;
        int sp = (s0 + 16*j + c) >> 1;
        if (sp < 98){
          if (qp     < 98) Pb[(size_t)(qp    )*98 + sp] = 0.25f*t0;
          if (qp + 1 < 98) Pb[(size_t)(qp + 1)*98 + sp] = 0.25f*t1;
        }
      }
    }
  }
}

// ---------------- J1: fc2 split-K GEMM  Cpart[ks] = P2-chunk @ w1-chunk ----------------
// grid 64*14 (m-block of 8 rows, k-split of 686), block 256 (= N columns)
__global__ __launch_bounds__(256) void k_fc2a(
    const float* __restrict__ P, const float* __restrict__ w1,
    float* __restrict__ Cpart){
  __shared__ float p2[8][688];
  int bx = blockIdx.x;
  int mb = bx & 63, ks = bx >> 6;      // 14 k-splits of 686 (14*686 = 9604)
  int b0 = mb*8, k0 = ks*686;
  int tid = threadIdx.x;
  for (int idx = tid; idx < 8*686; idx += 256){
    int r = idx / 686, i = idx - r*686;
    float v = P[(size_t)(b0+r)*9604 + k0 + i];
    p2[r][i] = v*v;
  }
  __syncthreads();
  float acc[8];
  #pragma unroll
  for (int r=0;r<8;++r) acc[r]=0.f;
  for (int ii=0; ii<686; ++ii){
    float w = w1[(size_t)(k0+ii)*256 + tid];
    #pragma unroll
    for (int r=0;r<8;++r) acc[r] += p2[r][ii]*w;
  }
  #pragma unroll
  for (int r=0;r<8;++r) Cpart[((size_t)ks*512 + b0 + r)*256 + tid] = acc[r];
}

// ---------------- J2: fc2 reduce + gelu + w2 dot ----------------
// grid 512 (one b each), block 256
__global__ __launch_bounds__(256) void k_fc2b(
    const float* __restrict__ Cpart, const float* __restrict__ b1,
    const float* __restrict__ w2, const float* __restrict__ b2,
    float* __restrict__ outp){
  __shared__ float red[4];
  int b = blockIdx.x, tid = threadIdx.x;
  float s = 0.f;
  for (int ks = 0; ks < 14; ++ks) s += Cpart[((size_t)ks*512 + b)*256 + tid];
  float h = geluf(s + b1[tid]) * w2[tid];
  #pragma unroll
  for (int o=32;o;o>>=1) h += __shfl_down(h,o);
  int w = tid >> 6, lane = tid & 63;
  if (lane==0) red[w] = h;
  __syncthreads();
  if (tid==0) outp[b] = red[0]+red[1]+red[2]+red[3] + b2[0];
}

// ---------------- launch ----------------
extern "C" void kernel_launch(void* const* d_in, const int* in_sizes, int n_in,
                              void* d_out, int out_size, void* d_ws, size_t ws_size,
                              hipStream_t stream){
  const float* fq  = (const float*)d_in[0];
  const float* fs  = (const float*)d_in[1];
  const float* fqs = (const float*)d_in[2];
  const float* fss = (const float*)d_in[3];
  const float* fc1_w1 = (const float*)d_in[4];
  const float* fc1_b1 = (const float*)d_in[5];
  const float* fc1_w2 = (const float*)d_in[6];
  const float* fc1_b2 = (const float*)d_in[7];
  const float* ln1_g = (const float*)d_in[8];
  const float* ln1_b = (const float*)d_in[9];
  const float* fc3_w1 = (const float*)d_in[10];
  const float* fc3_b1 = (const float*)d_in[11];
  const float* fc3_w2 = (const float*)d_in[12];
  const float* fc3_b2 = (const float*)d_in[13];
  const float* ln3_g = (const float*)d_in[14];
  const float* ln3_b = (const float*)d_in[15];
  const float* fc4_w1 = (const float*)d_in[16];
  const float* fc4_b1 = (const float*)d_in[17];
  const float* fc4_w2 = (const float*)d_in[18];
  const float* fc4_b2 = (const float*)d_in[19];
  const float* ln4_g = (const float*)d_in[20];
  const float* ln4_b = (const float*)d_in[21];
  const float* fc2_w1 = (const float*)d_in[22];
  const float* fc2_b1 = (const float*)d_in[23];
  const float* fc2_w2 = (const float*)d_in[24];
  const float* fc2_b2 = (const float*)d_in[25];
  const float* cs_w1 = (const float*)d_in[26];
  const float* cs_b1 = (const float*)d_in[27];
  const float* cs_w2 = (const float*)d_in[28];
  const float* cs_b2 = (const float*)d_in[29];
  float* out = (float*)d_out;
  char* ws = (char*)d_ws;
  // ws layout (bytes):
  //   meanb f32 @0           (3,145,728)   [dead after k_fc1; head reused for weight prep]
  //     w2t  bf16 @0         (73,728)      [fc4 w2^T; written by k_wt AFTER k_fc1]
  //     w1t  bf16 @73728     (73,728)      [fc4 w1^T]
  //     w1t3 bf16 @147456    (57,344)      [fc3 w1^T, t-pad 224]
  //     w2t3 bf16 @204800    (53,248)      [fc3 w2^T, t'-pad 208]
  //   mlp1  f32 @3145728     (3,145,728)
  //   mu    f32 @6291456     (1,613,824)
  //   rstd  f32 @7905280     (1,613,824)
  //   h4    bf16 @9519104    (38,535,168)  [then P f32 + Cpart overlay]
  //   P     f32 @9519104     (19,668,992)  [overlays h4 (dead after fc4b)]
  //   Cpart f32 @29188096    (7,340,032)
  //   Qb    bf16 @59850752   (77,070,336)
  //   Sb    bf16 @136921088  (77,070,336)
  //   total 213,991,424 B
  float* meanb  = (float*)(ws + 0);
  ushort_t* w2t  = (ushort_t*)(ws + 0);       // overlays meanb (dead after k_fc1)
  ushort_t* w1t  = (ushort_t*)(ws + 73728);
  ushort_t* w1t3 = (ushort_t*)(ws + 147456);
  ushort_t* w2t3 = (ushort_t*)(ws + 204800);
  float* mlp1   = (float*)(ws + 3145728);
  float* mu     = (float*)(ws + 6291456);
  float* rstd   = (float*)(ws + 7905280);
  ushort_t* h4  = (ushort_t*)(ws + 9519104);
  float* P      = (float*)(ws + 9519104);     // overlays h4 (dead after fc4b)
  float* Cpart  = (float*)(ws + 29188096);    // after P, before Qb
  ushort_t* Qb  = (ushort_t*)(ws + 59850752);
  ushort_t* Sb  = (ushort_t*)(ws + 136921088);
  const size_t H4S = (size_t)512*196*96;      // per-s-half h4 elements

  k_mean<<<2048, 384, 0, stream>>>(fq, fs, fqs, fss, meanb);
  k_fc1<<<2048, 384, 0, stream>>>(meanb, fc1_w1, fc1_b1, fc1_w2, fc1_b2, mlp1);
  k_wt<<<504, 256, 0, stream>>>(fc4_w1, fc4_w2, fc3_w1, fc3_w2,
                                w1t, w2t, w1t3, w2t3);      // after k_fc1: meanb dead
  k_stats<<<2048, 256, 0, stream>>>(fq, fs, fqs, fss, mlp1, mu, rstd);
  k_class<<<1024, 384, 0, stream>>>(fq, fs, mlp1, mu, rstd, ln1_g, ln1_b, out);
  k_cosine<<<512, 384, 0, stream>>>(cs_w1, cs_b1, cs_w2, cs_b2, out);
  // fc3 fused MFMA: q-start then s-start
  k_fc3<<<3072, 256, 0, stream>>>(fqs, mlp1 + (size_t)2*512*384, mu + 2*100864, rstd + 2*100864,
                                  ln1_g, ln1_b, w1t3, fc3_b1, w2t3, fc3_b2, ln3_g, ln3_b, Qb);
  k_fc3<<<3072, 256, 0, stream>>>(fss, mlp1 + (size_t)3*512*384, mu + 3*100864, rstd + 3*100864,
                                  ln1_g, ln1_b, w1t3, fc3_b1, w2t3, fc3_b2, ln3_g, ln3_b, Sb);
  // fc4 stage A (MFMA): q then s (pre-offset pointers, no runtime s-select)
  k_fc4a<<<2048, 256, 0, stream>>>(fq, mlp1, mu, rstd, ln1_g, ln1_b,
                                   Qb, w1t, fc4_b1, h4);
  k_fc4a<<<2048, 256, 0, stream>>>(fs, mlp1 + (size_t)512*384, mu + 100864, rstd + 100864,
                                   ln1_g, ln1_b, Sb, w1t, fc4_b1, h4 + H4S);
  // fc4 stage B (MFMA): q then s (Qb/Sb overwritten in place after their last read)
  k_fc4b<<<2048, 256, 0, stream>>>(h4,       w2t, fc4_b2, ln4_g, ln4_b, out + 1024,          Qb);
  k_fc4b<<<2048, 256, 0, stream>>>(h4 + H4S, w2t, fc4_b2, ln4_g, ln4_b, out + 1024 + 196608, Sb);
  k_sim<<<8192, 256, 0, stream>>>(Qb, Sb, P);
  // fc2 head: split-K GEMM (896 blocks) + tiny reduce
  k_fc2a<<<896, 256, 0, stream>>>(P, fc2_w1, Cpart);
  k_fc2b<<<512, 256, 0, stream>>>(Cpart, fc2_b1, fc2_w2, fc2_b2, out);
}

// Round 13
// 1400.721 us; speedup vs baseline: 23.6222x; 1.0533x over previous
//
#include <hip/hip_runtime.h>
#include <math.h>

typedef unsigned short ushort_t;
typedef __attribute__((ext_vector_type(8))) short bf16x8;
typedef __attribute__((ext_vector_type(4))) float f32x4;

// ---------------- helpers ----------------
__device__ __forceinline__ float geluf(float x){
  return 0.5f*x*(1.0f+erff(x*0.70710678118654752440f));
}
__device__ __forceinline__ float bfu(unsigned int u){
  union { unsigned int i; float f; } v; v.i = (u & 0xffffu) << 16; return v.f;
}
__device__ __forceinline__ unsigned int f2b(float f){
  union { float f; unsigned int i; } v; v.f = f;
  unsigned int r = v.i + 0x7fffu + ((v.i >> 16) & 1u);
  return (r >> 16);
}

// Problem constants
// B=512, N=197, C=384, T=196 image tokens
// d_out layout (floats): out[512] | cosine[512] | query_class[512*384] | support_class[512*384]

// ---------------- A: token means (per tensor, b, c) ----------------
__global__ __launch_bounds__(384) void k_mean(
    const float* __restrict__ x0, const float* __restrict__ x1,
    const float* __restrict__ x2, const float* __restrict__ x3,
    float* __restrict__ meanb){
  int s = blockIdx.x >> 9, b = blockIdx.x & 511, c = threadIdx.x;
  const float* x = (s==0)?x0:(s==1)?x1:(s==2)?x2:x3;
  const float* p = x + ((size_t)b*197)*384 + c;
  float acc = 0.f;
  #pragma unroll 4
  for (int t=0;t<197;++t) acc += p[(size_t)t*384];
  meanb[((size_t)s*512+b)*384+c] = acc*(1.0f/197.0f);
}

// ---------------- B: fc1 tiny MLP on means ----------------
__global__ __launch_bounds__(384) void k_fc1(
    const float* __restrict__ meanb, const float* __restrict__ w1,
    const float* __restrict__ b1, const float* __restrict__ w2,
    const float* __restrict__ b2, float* __restrict__ mlp1){
  __shared__ float ms[384];
  __shared__ float hs[96];
  int row = blockIdx.x, tid = threadIdx.x;
  ms[tid] = meanb[(size_t)row*384 + tid];
  __syncthreads();
  if (tid < 96){
    float a = b1[tid];
    for (int c=0;c<384;++c) a += ms[c]*w1[c*96+tid];
    hs[tid] = geluf(a);
  }
  __syncthreads();
  float a = b2[tid];
  for (int j=0;j<96;++j) a += hs[j]*w2[j*384+tid];
  mlp1[(size_t)row*384 + tid] = a;
}

// ---------------- C: per-row LN stats of (x + mlp1) ----------------
// grid 2048 (s*512+b), block 256 = 4 waves; 16-lane groups process 4 rows/wave.
__global__ __launch_bounds__(256) void k_stats(
    const float* __restrict__ x0, const float* __restrict__ x1,
    const float* __restrict__ x2, const float* __restrict__ x3,
    const float* __restrict__ mlp1, float* __restrict__ mu, float* __restrict__ rstd){
  int sb = blockIdx.x;          // s*512 + b
  int s = sb >> 9, b = sb & 511;
  const float* x = (s==0)?x0:(s==1)?x1:(s==2)?x2:x3;
  const float* mp = mlp1 + (size_t)sb*384;
  int tid = threadIdx.x, w = tid >> 6, lane = tid & 63;
  int g = lane >> 4, il = lane & 15;
  float4 mreg[6];
  #pragma unroll
  for (int it = 0; it < 6; ++it)
    mreg[it] = *reinterpret_cast<const float4*>(&mp[il*4 + 64*it]);
  for (int t0 = 0; t0 < 208; t0 += 16){
    int t = t0 + w*4 + g;
    if (t < 197){
      const float* xp = x + ((size_t)b*197 + t)*384 + il*4;
      float sum = 0.f, sq = 0.f;
      #pragma unroll
      for (int it = 0; it < 6; ++it){
        float4 v = *reinterpret_cast<const float4*>(xp + 64*it);
        float a0 = v.x + mreg[it].x, a1 = v.y + mreg[it].y;
        float a2 = v.z + mreg[it].z, a3 = v.w + mreg[it].w;
        sum += a0+a1+a2+a3;
        sq  += a0*a0+a1*a1+a2*a2+a3*a3;
      }
      #pragma unroll
      for (int o=1;o<16;o<<=1){ sum += __shfl_xor(sum,o); sq += __shfl_xor(sq,o); }
      if (il == 0){
        int row = sb*197 + t;
        float m = sum*(1.0f/384.0f);
        mu[row] = m;
        rstd[row] = rsqrtf(sq*(1.0f/384.0f) - m*m + 1e-5f);
      }
    }
  }
}

// ---------------- D: class token rows -> d_out ----------------
__global__ __launch_bounds__(384) void k_class(
    const float* __restrict__ x0, const float* __restrict__ x1,
    const float* __restrict__ mlp1, const float* __restrict__ mu,
    const float* __restrict__ rstd, const float* __restrict__ g1,
    const float* __restrict__ bb1, float* __restrict__ dout){
  int s = blockIdx.x >> 9, b = blockIdx.x & 511, c = threadIdx.x;
  const float* x = s ? x1 : x0;
  int srow = (s*512 + b)*197;
  float v = x[((size_t)b*197)*384 + c] + mlp1[((size_t)s*512+b)*384 + c];
  float y = (v - mu[srow])*rstd[srow]*g1[c] + bb1[c];
  dout[1024 + (size_t)s*196608 + (size_t)b*384 + c] = y;
}

// ---------------- E: cosine head on class tokens ----------------
__global__ __launch_bounds__(384) void k_cosine(
    const float* __restrict__ w1, const float* __restrict__ b1,
    const float* __restrict__ w2, const float* __restrict__ b2,
    float* __restrict__ dout){
  __shared__ float qrow[384], srw[384], hq[96], hs[96];
  __shared__ float rd0[384], rd1[384], rd2[384];
  int b = blockIdx.x, tid = threadIdx.x;
  qrow[tid] = dout[1024   + (size_t)b*384 + tid];
  srw[tid]  = dout[197632 + (size_t)b*384 + tid];
  __syncthreads();
  if (tid < 96){
    float a = b1[tid];
    for (int c=0;c<384;++c) a += qrow[c]*w1[c*96+tid];
    hq[tid] = geluf(a);
  } else if (tid < 192){
    int j = tid - 96;
    float a = b1[j];
    for (int c=0;c<384;++c) a += srw[c]*w1[c*96+j];
    hs[j] = geluf(a);
  }
  __syncthreads();
  float qx = b2[tid], sy = b2[tid];
  for (int j=0;j<96;++j){ qx += hq[j]*w2[j*384+tid]; sy += hs[j]*w2[j*384+tid]; }
  rd0[tid] = qx*sy; rd1[tid] = qx*qx; rd2[tid] = sy*sy;
  __syncthreads();
  if (tid < 64){
    float d=0.f,nq=0.f,ns=0.f;
    for (int i=tid;i<384;i+=64){ d+=rd0[i]; nq+=rd1[i]; ns+=rd2[i]; }
    #pragma unroll
    for (int o=32;o;o>>=1){ d+=__shfl_down(d,o); nq+=__shfl_down(nq,o); ns+=__shfl_down(ns,o); }
    if (tid==0) dout[512 + b] = d / (fmaxf(sqrtf(nq),1e-8f)*fmaxf(sqrtf(ns),1e-8f));
  }
}

// ---------------- W: weight prep (bf16 transposes, zero-padded) ----------------
// grid 504, block 256 (504*256 = 129024).
__global__ __launch_bounds__(256) void k_wt(
    const float* __restrict__ w1_4, const float* __restrict__ w2_4,
    const float* __restrict__ w1_3, const float* __restrict__ w2_3,
    ushort_t* __restrict__ w1t, ushort_t* __restrict__ w2t,
    ushort_t* __restrict__ w1t3, ushort_t* __restrict__ w2t3){
  int idx = blockIdx.x*256 + threadIdx.x;
  if (idx < 36864){
    int c = idx / 96, j = idx - c*96;
    w2t[idx] = (ushort_t)f2b(w2_4[(size_t)j*384 + c]);
  } else if (idx < 73728){
    int k = idx - 36864;
    int j = k / 384, c = k - j*384;
    w1t[k] = (ushort_t)f2b(w1_4[(size_t)c*96 + j]);
  } else if (idx < 102400){
    int k = idx - 73728;
    int j = k / 224, t = k - j*224;
    w1t3[k] = (t < 196) ? (ushort_t)f2b(w1_3[(size_t)t*128 + j]) : (ushort_t)0;
  } else {
    int k = idx - 102400;
    int tp = k / 128, j = k - tp*128;
    w2t3[k] = (tp < 196) ? (ushort_t)f2b(w2_3[(size_t)j*196 + tp]) : (ushort_t)0;
  }
}

// ---------------- F: fc3 fused MFMA (one s-half per launch) ----------------
// grid 512*6 (b, c-tile of 64), block 256 = 4 waves; wave = 16 c rows.
// Round-12 profile: latency-bound (MfmaUtil 4%, VALU 19%, nothing saturated) —
// 108 per-lane L2 weight loads per wave serialized against MFMAs, 4x redundant
// per block. Fixes: (1) w2t3 staged in LDS (W2s, 2 halves: rows 0-111 then
// 112-207) -> GEMM2 B-frags become ds_read_b128, block w2-traffic 208->53 KB;
// (2) GEMM1 A-frags register double-buffered (aC/aN, kc+1 loads issued before
// kc's MFMAs) -> 8 loads always in flight.
__global__ __launch_bounds__(256) void k_fc3(
    const float* __restrict__ x,         // fqs or fss
    const float* __restrict__ m1_base,   // mlp1 + s*512*384
    const float* __restrict__ mu_s,      // mu + s*100864
    const float* __restrict__ rstd_s,
    const float* __restrict__ g1, const float* __restrict__ bln1,
    const ushort_t* __restrict__ w1t3,   // [128][224] bf16
    const float* __restrict__ b1,        // fc3_b1 [128]
    const ushort_t* __restrict__ w2t3,   // [208][128] bf16
    const float* __restrict__ b2, const float* __restrict__ g3,
    const float* __restrict__ b3,
    ushort_t* __restrict__ Qout){        // Qb or Sb
  __shared__ ushort_t Xs[64][232];       // X^T tile; Hs overlays cols [0,128) per wave
  __shared__ ushort_t W2s[112][136];     // w2t3 half (17x16B stride: bank-safe)
  __shared__ float m1s[64], g1s[64], b1s[64];
  __shared__ float mus[196], rss[196];
  __shared__ float b1j[128];
  __shared__ float b2s[208], g3s[208], b3s[208];
  int bid = blockIdx.x;
  int b = bid/6, c0 = (bid%6)*64;
  int tid = threadIdx.x;
  // stage coefficients
  if (tid < 64){
    m1s[tid] = m1_base[(size_t)b*384 + c0 + tid];
    g1s[tid] = g1[c0+tid]; b1s[tid] = bln1[c0+tid];
  }
  if (tid < 128) b1j[tid] = b1[tid];
  if (tid < 196){ mus[tid] = mu_s[b*197 + tid + 1]; rss[tid] = rstd_s[b*197 + tid + 1]; }
  if (tid < 208){
    float bb=0.f, gg=0.f, b3v=0.f;
    if (tid < 196){ bb = b2[tid]; gg = g3[tid]; b3v = b3[tid]; }
    b2s[tid]=bb; g3s[tid]=gg; b3s[tid]=b3v;
  }
  // stage W2s part 1 (w2t3 rows 0..111)
  for (int i = tid; i < 112*16; i += 256){
    int r = i >> 4, q = i & 15;
    *reinterpret_cast<uint4*>(&W2s[r][q*8]) =
        *reinterpret_cast<const uint4*>(&w2t3[(size_t)r*128 + q*8]);
  }
  // zero the t-pad of Xs ([196,224) as uints; [224,232) never read)
  for (int i = tid; i < 64*14; i += 256){
    *reinterpret_cast<unsigned int*>(&Xs[i/14][196 + 2*(i%14)]) = 0u;
  }
  __syncthreads();
  // phase 1: stage LN'd X^T tile by t-pairs (98 tpairs x 16 c4-slots = 1568)
  for (int e = 0; e < 7; ++e){
    int idx = e*256 + tid;
    if (idx < 1568){
      int t2 = idx >> 4, c4 = idx & 15;
      int t0 = t2*2;
      const float* xr = &x[((size_t)b*197 + t0 + 1)*384 + c0 + c4*4];
      float4 xv0 = *reinterpret_cast<const float4*>(xr);
      float4 xv1 = *reinterpret_cast<const float4*>(xr + 384);
      float mu0 = mus[t0], rs0 = rss[t0], mu1 = mus[t0+1], rs1 = rss[t0+1];
      int c = c4*4;
      unsigned int u0 = f2b(((xv0.x + m1s[c+0]) - mu0)*rs0*g1s[c+0] + b1s[c+0])
                      | (f2b(((xv1.x + m1s[c+0]) - mu1)*rs1*g1s[c+0] + b1s[c+0]) << 16);
      unsigned int u1 = f2b(((xv0.y + m1s[c+1]) - mu0)*rs0*g1s[c+1] + b1s[c+1])
                      | (f2b(((xv1.y + m1s[c+1]) - mu1)*rs1*g1s[c+1] + b1s[c+1]) << 16);
      unsigned int u2 = f2b(((xv0.z + m1s[c+2]) - mu0)*rs0*g1s[c+2] + b1s[c+2])
                      | (f2b(((xv1.z + m1s[c+2]) - mu1)*rs1*g1s[c+2] + b1s[c+2]) << 16);
      unsigned int u3 = f2b(((xv0.w + m1s[c+3]) - mu0)*rs0*g1s[c+3] + b1s[c+3])
                      | (f2b(((xv1.w + m1s[c+3]) - mu1)*rs1*g1s[c+3] + b1s[c+3]) << 16);
      *reinterpret_cast<unsigned int*>(&Xs[c+0][t0]) = u0;
      *reinterpret_cast<unsigned int*>(&Xs[c+1][t0]) = u1;
      *reinterpret_cast<unsigned int*>(&Xs[c+2][t0]) = u2;
      *reinterpret_cast<unsigned int*>(&Xs[c+3][t0]) = u3;
    }
  }
  __syncthreads();
  int w = tid >> 6, lane = tid & 63;
  int cl = lane & 15, kg = lane >> 4;
  // GEMM1: h = gelu(Xt @ w1 + b1); A register double-buffered
  f32x4 hacc[8];
  #pragma unroll
  for (int jf=0;jf<8;++jf){ f32x4 z={0.f,0.f,0.f,0.f}; hacc[jf]=z; }
  const ushort_t* zrow = &Xs[w*16 + cl][kg*8];
  const ushort_t* abase = w1t3 + (size_t)cl*224 + kg*8;
  bf16x8 aC[8], aN[8];
  #pragma unroll
  for (int jf=0;jf<8;++jf)
    aC[jf] = *reinterpret_cast<const bf16x8*>(abase + jf*16*224);
  for (int kc = 0; kc < 7; ++kc){
    bf16x8 xb = *reinterpret_cast<const bf16x8*>(zrow + kc*32);
    if (kc < 6){
      #pragma unroll
      for (int jf=0;jf<8;++jf)
        aN[jf] = *reinterpret_cast<const bf16x8*>(abase + jf*16*224 + (kc+1)*32);
    }
    #pragma unroll
    for (int jf=0;jf<8;++jf)
      hacc[jf] = __builtin_amdgcn_mfma_f32_16x16x32_bf16(aC[jf], xb, hacc[jf], 0, 0, 0);
    #pragma unroll
    for (int jf=0;jf<8;++jf) aC[jf] = aN[jf];
  }
  // D: row = j = jf*16+kg*4+r, col = c = cl -> overlay into the wave's OWN Xs rows.
  #pragma unroll
  for (int jf=0;jf<8;++jf){
    f32x4 y = hacc[jf];
    int j0 = jf*16 + kg*4;
    uint2 pk;
    pk.x = f2b(geluf(y[0]+b1j[j0+0])) | (f2b(geluf(y[1]+b1j[j0+1]))<<16);
    pk.y = f2b(geluf(y[2]+b1j[j0+2])) | (f2b(geluf(y[3]+b1j[j0+3]))<<16);
    *reinterpret_cast<uint2*>(&Xs[w*16 + cl][j0]) = pk;
  }
  // GEMM2: y = h @ w2 (+b2 in epilogue); B from LDS in two halves
  f32x4 yacc[13];
  #pragma unroll
  for (int tf=0;tf<13;++tf){ f32x4 z={0.f,0.f,0.f,0.f}; yacc[tf]=z; }
  const ushort_t* hrow = &Xs[w*16 + cl][kg*8];
  // part A: tf 0..6 (t' rows 0..111 in W2s)
  for (int kc = 0; kc < 4; ++kc){
    bf16x8 hb = *reinterpret_cast<const bf16x8*>(hrow + kc*32);
    #pragma unroll
    for (int tf=0;tf<7;++tf){
      const ushort_t* bp = &W2s[tf*16 + cl][kg*8 + kc*32];
      yacc[tf] = __builtin_amdgcn_mfma_f32_16x16x32_bf16(
          hb, *reinterpret_cast<const bf16x8*>(bp), yacc[tf], 0, 0, 0);
    }
  }
  __syncthreads();
  // restage W2s with w2t3 rows 112..207 (96 rows)
  for (int i = tid; i < 96*16; i += 256){
    int r = i >> 4, q = i & 15;
    *reinterpret_cast<uint4*>(&W2s[r][q*8]) =
        *reinterpret_cast<const uint4*>(&w2t3[(size_t)(112 + r)*128 + q*8]);
  }
  __syncthreads();
  // part B: tf 7..12 (t' rows 112..207 -> W2s rows tf*16+cl-112)
  for (int kc = 0; kc < 4; ++kc){
    bf16x8 hb = *reinterpret_cast<const bf16x8*>(hrow + kc*32);
    #pragma unroll
    for (int tf=7;tf<13;++tf){
      const ushort_t* bp = &W2s[tf*16 + cl - 112][kg*8 + kc*32];
      yacc[tf] = __builtin_amdgcn_mfma_f32_16x16x32_bf16(
          hb, *reinterpret_cast<const bf16x8*>(bp), yacc[tf], 0, 0, 0);
    }
  }
  // epilogue: lane holds c = c0 + w*16 + kg*4 + r (r=0..3), t' = tf*16 + cl.
  float sum0=0.f,sum1=0.f,sum2=0.f,sum3=0.f, sq0=0.f,sq1=0.f,sq2=0.f,sq3=0.f;
  #pragma unroll
  for (int tf=0;tf<13;++tf){
    int tp = tf*16 + cl;
    float bb = b2s[tp];
    f32x4 y = yacc[tf];
    y[0]+=bb; y[1]+=bb; y[2]+=bb; y[3]+=bb;
    yacc[tf] = y;
    sum0+=y[0]; sum1+=y[1]; sum2+=y[2]; sum3+=y[3];
    sq0+=y[0]*y[0]; sq1+=y[1]*y[1]; sq2+=y[2]*y[2]; sq3+=y[3]*y[3];
  }
  #pragma unroll
  for (int o=1;o<16;o<<=1){
    sum0+=__shfl_xor(sum0,o); sum1+=__shfl_xor(sum1,o);
    sum2+=__shfl_xor(sum2,o); sum3+=__shfl_xor(sum3,o);
    sq0+=__shfl_xor(sq0,o); sq1+=__shfl_xor(sq1,o);
    sq2+=__shfl_xor(sq2,o); sq3+=__shfl_xor(sq3,o);
  }
  float m0=sum0*(1.0f/196.0f), m1v=sum1*(1.0f/196.0f), m2=sum2*(1.0f/196.0f), m3=sum3*(1.0f/196.0f);
  float r0=rsqrtf(sq0*(1.0f/196.0f)-m0*m0+1e-5f);
  float r1=rsqrtf(sq1*(1.0f/196.0f)-m1v*m1v+1e-5f);
  float r2=rsqrtf(sq2*(1.0f/196.0f)-m2*m2+1e-5f);
  float r3=rsqrtf(sq3*(1.0f/196.0f)-m3*m3+1e-5f);
  int cbase = c0 + w*16 + kg*4;
  #pragma unroll
  for (int tf=0;tf<13;++tf){
    int tp = tf*16 + cl;
    if (tp < 196){
      float gg = g3s[tp], bb3 = b3s[tp];
      f32x4 y = yacc[tf];
      unsigned int o0 = f2b((y[0]-m0)*r0*gg + bb3);
      unsigned int o1 = f2b((y[1]-m1v)*r1*gg + bb3);
      unsigned int o2 = f2b((y[2]-m2)*r2*gg + bb3);
      unsigned int o3 = f2b((y[3]-m3)*r3*gg + bb3);
      uint2 pk; pk.x = o0 | (o1<<16); pk.y = o2 | (o3<<16);
      *reinterpret_cast<uint2*>(&Qout[((size_t)b*196 + tp)*384 + cbase]) = pk;
    }
  }
}

// ---------------- H1: fc4 stage A (MFMA; one s-half per launch) ----------------
// grid 512*4 (b, t-tile of 64), block 256 = 4 waves; wave = 16 t x 96 j.
__global__ __launch_bounds__(256) void k_fc4a(
    const float* __restrict__ x,         // fq or fs
    const float* __restrict__ m1_base,   // mlp1 + s*512*384
    const float* __restrict__ mu_s,      // mu + s*100864
    const float* __restrict__ rstd_s,    // rstd + s*100864
    const float* __restrict__ g1, const float* __restrict__ bln1,
    const ushort_t* __restrict__ Qin,    // Qb or Sb
    const ushort_t* __restrict__ w1t,    // [96][384] bf16
    const float* __restrict__ b1mlp,
    ushort_t* __restrict__ h4s){         // h4 + s*512*196*96
  __shared__ ushort_t Zs[64][392];       // bf16 Z tile, padded stride
  __shared__ float m1s[384], g1s[384], b1s[384];
  __shared__ float mus[64], rss[64];
  __shared__ float b1m[96];
  int bid = blockIdx.x;
  int b = bid >> 2, tt0 = (bid & 3)*64;
  int tid = threadIdx.x;
  const float* m1 = m1_base + (size_t)b*384;
  for (int i = tid; i < 384; i += 256){ m1s[i] = m1[i]; g1s[i] = g1[i]; b1s[i] = bln1[i]; }
  if (tid < 96) b1m[tid] = b1mlp[tid];
  if (tid < 64){
    int t = tt0 + tid; int tc = t < 196 ? t : 195;
    mus[tid] = mu_s[b*197 + tc + 1]; rss[tid] = rstd_s[b*197 + tc + 1];
  }
  __syncthreads();
  // phase 1: Z build, 64 rows x 96 col4-slots = 6144 slots, 24 per thread
  for (int e = 0; e < 24; ++e){
    int v = e*256 + tid;
    int row = v/96, col4 = v - row*96;
    int t = tt0 + row; int tc = t < 196 ? t : 195;
    float valid = (t < 196) ? 1.f : 0.f;
    float4 xv = *reinterpret_cast<const float4*>(&x[((size_t)b*197 + tc + 1)*384 + col4*4]);
    uint2 qv = *reinterpret_cast<const uint2*>(&Qin[((size_t)b*196 + tc)*384 + col4*4]);
    float muv = mus[row], rsv = rss[row];
    int c = col4*4;
    float z0 = (((xv.x + m1s[c+0]) - muv)*rsv*g1s[c+0] + b1s[c+0]) * bfu(qv.x)      * valid;
    float z1 = (((xv.y + m1s[c+1]) - muv)*rsv*g1s[c+1] + b1s[c+1]) * bfu(qv.x>>16)  * valid;
    float z2 = (((xv.z + m1s[c+2]) - muv)*rsv*g1s[c+2] + b1s[c+2]) * bfu(qv.y)      * valid;
    float z3 = (((xv.w + m1s[c+3]) - muv)*rsv*g1s[c+3] + b1s[c+3]) * bfu(qv.y>>16)  * valid;
    uint2 pk; pk.x = f2b(z0) | (f2b(z1)<<16); pk.y = f2b(z2) | (f2b(z3)<<16);
    *reinterpret_cast<uint2*>(&Zs[row][col4*4]) = pk;
  }
  __syncthreads();
  // phase 2: MFMA GEMM1 (16t x 96j per wave, K=384)
  int w = tid >> 6, lane = tid & 63;
  int tr = tt0 + w*16 + (lane & 15);
  int kg = lane >> 4;
  f32x4 acc0 = {0.f,0.f,0.f,0.f}, acc1 = {0.f,0.f,0.f,0.f}, acc2 = {0.f,0.f,0.f,0.f};
  f32x4 acc3 = {0.f,0.f,0.f,0.f}, acc4 = {0.f,0.f,0.f,0.f}, acc5 = {0.f,0.f,0.f,0.f};
  const ushort_t* arow = w1t + (size_t)(lane & 15)*384 + kg*8;
  const ushort_t* zrow = &Zs[w*16 + (lane & 15)][kg*8];
  for (int kc = 0; kc < 12; ++kc){
    bf16x8 zb = *reinterpret_cast<const bf16x8*>(zrow + kc*32);
    bf16x8 a0 = *reinterpret_cast<const bf16x8*>(arow + kc*32);
    bf16x8 a1 = *reinterpret_cast<const bf16x8*>(arow + kc*32 + 16*384);
    bf16x8 a2 = *reinterpret_cast<const bf16x8*>(arow + kc*32 + 32*384);
    bf16x8 a3 = *reinterpret_cast<const bf16x8*>(arow + kc*32 + 48*384);
    bf16x8 a4 = *reinterpret_cast<const bf16x8*>(arow + kc*32 + 64*384);
    bf16x8 a5 = *reinterpret_cast<const bf16x8*>(arow + kc*32 + 80*384);
    acc0 = __builtin_amdgcn_mfma_f32_16x16x32_bf16(a0, zb, acc0, 0, 0, 0);
    acc1 = __builtin_amdgcn_mfma_f32_16x16x32_bf16(a1, zb, acc1, 0, 0, 0);
    acc2 = __builtin_amdgcn_mfma_f32_16x16x32_bf16(a2, zb, acc2, 0, 0, 0);
    acc3 = __builtin_amdgcn_mfma_f32_16x16x32_bf16(a3, zb, acc3, 0, 0, 0);
    acc4 = __builtin_amdgcn_mfma_f32_16x16x32_bf16(a4, zb, acc4, 0, 0, 0);
    acc5 = __builtin_amdgcn_mfma_f32_16x16x32_bf16(a5, zb, acc5, 0, 0, 0);
  }
  // epilogue: lane holds j = jb*16 + kg*4 + r (D row), t = tr (D col)
  if (tr < 196){
    ushort_t* dst = h4s + ((size_t)b*196 + tr)*96 + kg*4;
    #pragma unroll
    for (int jb = 0; jb < 6; ++jb){
      f32x4 y = (jb==0)?acc0:(jb==1)?acc1:(jb==2)?acc2:(jb==3)?acc3:(jb==4)?acc4:acc5;
      int j0 = jb*16 + kg*4;
      uint2 pk;
      pk.x = f2b(geluf(y[0]+b1m[j0+0])) | (f2b(geluf(y[1]+b1m[j0+1]))<<16);
      pk.y = f2b(geluf(y[2]+b1m[j0+2])) | (f2b(geluf(y[3]+b1m[j0+3]))<<16);
      *reinterpret_cast<uint2*>(dst + jb*16) = pk;
    }
  }
}

// ---------------- H2: fc4 stage B (MFMA; one s-half per launch) ----------------
// grid 512*4 (b, t-tile of 64), block 256 = 4 waves; wave = 16 t x 384 c.
__global__ __launch_bounds__(256) void k_fc4b(
    const ushort_t* __restrict__ h4s,    // h4 + s*512*196*96
    const ushort_t* __restrict__ w2t,    // [384][96] bf16
    const float* __restrict__ b2, const float* __restrict__ g4,
    const float* __restrict__ bb4,
    const float* __restrict__ cls_base,  // dout + 1024 + s*196608
    ushort_t* __restrict__ Qo){          // Qb or Sb
  __shared__ float b2s[384], g4s[384], b4s[384], cl_s[384];
  int bid = blockIdx.x;
  int b = bid >> 2, ttile = bid & 3;
  int tid = threadIdx.x, w = tid >> 6, lane = tid & 63;
  const float* cls = cls_base + (size_t)b*384;
  for (int i = tid; i < 384; i += 256){
    b2s[i] = b2[i]; g4s[i] = g4[i]; b4s[i] = bb4[i]; cl_s[i] = cls[i];
  }
  __syncthreads();
  int tr = ttile*64 + w*16 + (lane & 15);
  int trc = tr < 196 ? tr : 195;
  int kg = lane >> 4;
  const ushort_t* hp = h4s + ((size_t)b*196 + trc)*96 + kg*8;
  bf16x8 hb0 = *reinterpret_cast<const bf16x8*>(hp);
  bf16x8 hb1 = *reinterpret_cast<const bf16x8*>(hp + 32);
  bf16x8 hb2 = *reinterpret_cast<const bf16x8*>(hp + 64);
  const ushort_t* ap_base = w2t + (size_t)(lane & 15)*96 + kg*8;
  f32x4 acc[24];
  #pragma unroll
  for (int af = 0; af < 24; ++af){
    const ushort_t* ap = ap_base + (size_t)af*16*96;
    bf16x8 a0 = *reinterpret_cast<const bf16x8*>(ap);
    bf16x8 a1 = *reinterpret_cast<const bf16x8*>(ap + 32);
    bf16x8 a2 = *reinterpret_cast<const bf16x8*>(ap + 64);
    f32x4 z = {0.f,0.f,0.f,0.f};
    z = __builtin_amdgcn_mfma_f32_16x16x32_bf16(a0, hb0, z, 0, 0, 0);
    z = __builtin_amdgcn_mfma_f32_16x16x32_bf16(a1, hb1, z, 0, 0, 0);
    z = __builtin_amdgcn_mfma_f32_16x16x32_bf16(a2, hb2, z, 0, 0, 0);
    acc[af] = z;
  }
  // epilogue: lane holds c = af*16 + kg*4 + r  (r=0..3), t = tr (col)
  float sum = 0.f, sq = 0.f;
  #pragma unroll
  for (int af = 0; af < 24; ++af){
    int cb = af*16 + kg*4;
    float4 bv = *reinterpret_cast<const float4*>(&b2s[cb]);
    f32x4 y = acc[af];
    y[0] += bv.x; y[1] += bv.y; y[2] += bv.z; y[3] += bv.w;
    acc[af] = y;
    sum += y[0]+y[1]+y[2]+y[3];
    sq  += y[0]*y[0]+y[1]*y[1]+y[2]*y[2]+y[3]*y[3];
  }
  sum += __shfl_xor(sum, 16); sum += __shfl_xor(sum, 32);
  sq  += __shfl_xor(sq, 16);  sq  += __shfl_xor(sq, 32);
  float m4 = sum*(1.0f/384.0f);
  float rs = rsqrtf(sq*(1.0f/384.0f) - m4*m4 + 1e-5f);
  float s2 = 0.f;
  #pragma unroll
  for (int af = 0; af < 24; ++af){
    int cb = af*16 + kg*4;
    float4 gv = *reinterpret_cast<const float4*>(&g4s[cb]);
    float4 bb = *reinterpret_cast<const float4*>(&b4s[cb]);
    float4 cv = *reinterpret_cast<const float4*>(&cl_s[cb]);
    f32x4 y = acc[af];
    y[0] = (y[0]-m4)*rs*gv.x + bb.x + 0.5f*cv.x;
    y[1] = (y[1]-m4)*rs*gv.y + bb.y + 0.5f*cv.y;
    y[2] = (y[2]-m4)*rs*gv.z + bb.z + 0.5f*cv.z;
    y[3] = (y[3]-m4)*rs*gv.w + bb.w + 0.5f*cv.w;
    acc[af] = y;
    s2 += y[0]*y[0]+y[1]*y[1]+y[2]*y[2]+y[3]*y[3];
  }
  s2 += __shfl_xor(s2, 16); s2 += __shfl_xor(s2, 32);
  float inv = 1.0f/fmaxf(sqrtf(s2), 1e-12f);
  float sm = 0.f;
  #pragma unroll
  for (int af = 0; af < 24; ++af){
    f32x4 y = acc[af];
    y[0]*=inv; y[1]*=inv; y[2]*=inv; y[3]*=inv;
    acc[af] = y;
    sm += y[0]+y[1]+y[2]+y[3];
  }
  sm += __shfl_xor(sm, 16); sm += __shfl_xor(sm, 32);
  sm *= (1.0f/384.0f);
  if (tr < 196){
    ushort_t* dst = Qo + ((size_t)b*196 + tr)*384 + kg*4;
    #pragma unroll
    for (int af = 0; af < 24; ++af){
      f32x4 y = acc[af];
      uint2 pk;
      pk.x = f2b(y[0]-sm) | (f2b(y[1]-sm)<<16);
      pk.y = f2b(y[2]-sm) | (f2b(y[3]-sm)<<16);
      *reinterpret_cast<uint2*>(dst + af*16) = pk;
    }
  }
}

// ---------------- I: batched einsum + fused 2x2 pooling (MFMA) ----------------
// grid 512*16 (b, qt, st), block 256 = 4 waves; wave = 32x32 output tile.
__global__ __launch_bounds__(256) void k_sim(
    const ushort_t* __restrict__ Q, const ushort_t* __restrict__ S,
    float* __restrict__ P){
  int bx = blockIdx.x;
  int b = bx >> 4, qt = (bx >> 2) & 3, st = bx & 3;
  int tid = threadIdx.x;
  int w = tid >> 6, lane = tid & 63;
  int wr = w >> 1, wc = w & 1;
  int q0 = qt*64 + wr*32, s0 = st*64 + wc*32;
  int rrow = lane & 15, kg = lane >> 4;
  const ushort_t* Qb_ = Q + (size_t)b*196*384;
  const ushort_t* Sb_ = S + (size_t)b*196*384;
  int qr0 = min(q0 + rrow, 195), qr1 = min(q0 + 16 + rrow, 195);
  int sr0 = min(s0 + rrow, 195), sr1 = min(s0 + 16 + rrow, 195);
  const ushort_t* qp0 = Qb_ + (size_t)qr0*384 + kg*8;
  const ushort_t* qp1 = Qb_ + (size_t)qr1*384 + kg*8;
  const ushort_t* sp0 = Sb_ + (size_t)sr0*384 + kg*8;
  const ushort_t* sp1 = Sb_ + (size_t)sr1*384 + kg*8;
  f32x4 acc00 = {0.f,0.f,0.f,0.f}, acc01 = {0.f,0.f,0.f,0.f};
  f32x4 acc10 = {0.f,0.f,0.f,0.f}, acc11 = {0.f,0.f,0.f,0.f};
  for (int k0 = 0; k0 < 384; k0 += 32){
    bf16x8 a0 = *reinterpret_cast<const bf16x8*>(qp0 + k0);
    bf16x8 a1 = *reinterpret_cast<const bf16x8*>(qp1 + k0);
    bf16x8 b0 = *reinterpret_cast<const bf16x8*>(sp0 + k0);
    bf16x8 b1 = *reinterpret_cast<const bf16x8*>(sp1 + k0);
    acc00 = __builtin_amdgcn_mfma_f32_16x16x32_bf16(a0, b0, acc00, 0, 0, 0);
    acc01 = __builtin_amdgcn_mfma_f32_16x16x32_bf16(a0, b1, acc01, 0, 0, 0);
    acc10 = __builtin_amdgcn_mfma_f32_16x16x32_bf16(a1, b0, acc10, 0, 0, 0);
    acc11 = __builtin_amdgcn_mfma_f32_16x16x32_bf16(a1, b1, acc11, 0, 0, 0);
  }
  int c = lane & 15, g = lane >> 4;
  float* Pb = P + (size_t)b*98*98;
  #pragma unroll
  for (int i = 0; i < 2; ++i){
    #pragma unroll
    for (int j = 0; j < 2; ++j){
      f32x4 v = (i==0) ? (j==0 ? acc00 : acc01) : (j==0 ? acc10 : acc11);
      float p0 = v[0] + v[1];   // rows 4g, 4g+1
      float p1 = v[2] + v[3];   // rows 4g+2, 4g+3
      float t0 = p0 + __shfl_xor(p0, 1);
      float t1 = p1 + __shfl_xor(p1, 1);
      if (!(c & 1)){
        int qp = (q0 + 16*i + 4*g) >> 1;
        int sp = (s0 + 16*j + c) >> 1;
        if (sp < 98){
          if (qp     < 98) Pb[(size_t)(qp    )*98 + sp] = 0.25f*t0;
          if (qp + 1 < 98) Pb[(size_t)(qp + 1)*98 + sp] = 0.25f*t1;
        }
      }
    }
  }
}

// ---------------- J1: fc2 split-K GEMM  Cpart[ks] = P2-chunk @ w1-chunk ----------------
// grid 64*14 (m-block of 8 rows, k-split of 686), block 256 (= N columns)
__global__ __launch_bounds__(256) void k_fc2a(
    const float* __restrict__ P, const float* __restrict__ w1,
    float* __restrict__ Cpart){
  __shared__ float p2[8][688];
  int bx = blockIdx.x;
  int mb = bx & 63, ks = bx >> 6;      // 14 k-splits of 686 (14*686 = 9604)
  int b0 = mb*8, k0 = ks*686;
  int tid = threadIdx.x;
  for (int idx = tid; idx < 8*686; idx += 256){
    int r = idx / 686, i = idx - r*686;
    float v = P[(size_t)(b0+r)*9604 + k0 + i];
    p2[r][i] = v*v;
  }
  __syncthreads();
  float acc[8];
  #pragma unroll
  for (int r=0;r<8;++r) acc[r]=0.f;
  for (int ii=0; ii<686; ++ii){
    float w = w1[(size_t)(k0+ii)*256 + tid];
    #pragma unroll
    for (int r=0;r<8;++r) acc[r] += p2[r][ii]*w;
  }
  #pragma unroll
  for (int r=0;r<8;++r) Cpart[((size_t)ks*512 + b0 + r)*256 + tid] = acc[r];
}

// ---------------- J2: fc2 reduce + gelu + w2 dot ----------------
// grid 512 (one b each), block 256
__global__ __launch_bounds__(256) void k_fc2b(
    const float* __restrict__ Cpart, const float* __restrict__ b1,
    const float* __restrict__ w2, const float* __restrict__ b2,
    float* __restrict__ outp){
  __shared__ float red[4];
  int b = blockIdx.x, tid = threadIdx.x;
  float s = 0.f;
  for (int ks = 0; ks < 14; ++ks) s += Cpart[((size_t)ks*512 + b)*256 + tid];
  float h = geluf(s + b1[tid]) * w2[tid];
  #pragma unroll
  for (int o=32;o;o>>=1) h += __shfl_down(h,o);
  int w = tid >> 6, lane = tid & 63;
  if (lane==0) red[w] = h;
  __syncthreads();
  if (tid==0) outp[b] = red[0]+red[1]+red[2]+red[3] + b2[0];
}

// ---------------- launch ----------------
extern "C" void kernel_launch(void* const* d_in, const int* in_sizes, int n_in,
                              void* d_out, int out_size, void* d_ws, size_t ws_size,
                              hipStream_t stream){
  const float* fq  = (const float*)d_in[0];
  const float* fs  = (const float*)d_in[1];
  const float* fqs = (const float*)d_in[2];
  const float* fss = (const float*)d_in[3];
  const float* fc1_w1 = (const float*)d_in[4];
  const float* fc1_b1 = (const float*)d_in[5];
  const float* fc1_w2 = (const float*)d_in[6];
  const float* fc1_b2 = (const float*)d_in[7];
  const float* ln1_g = (const float*)d_in[8];
  const float* ln1_b = (const float*)d_in[9];
  const float* fc3_w1 = (const float*)d_in[10];
  const float* fc3_b1 = (const float*)d_in[11];
  const float* fc3_w2 = (const float*)d_in[12];
  const float* fc3_b2 = (const float*)d_in[13];
  const float* ln3_g = (const float*)d_in[14];
  const float* ln3_b = (const float*)d_in[15];
  const float* fc4_w1 = (const float*)d_in[16];
  const float* fc4_b1 = (const float*)d_in[17];
  const float* fc4_w2 = (const float*)d_in[18];
  const float* fc4_b2 = (const float*)d_in[19];
  const float* ln4_g = (const float*)d_in[20];
  const float* ln4_b = (const float*)d_in[21];
  const float* fc2_w1 = (const float*)d_in[22];
  const float* fc2_b1 = (const float*)d_in[23];
  const float* fc2_w2 = (const float*)d_in[24];
  const float* fc2_b2 = (const float*)d_in[25];
  const float* cs_w1 = (const float*)d_in[26];
  const float* cs_b1 = (const float*)d_in[27];
  const float* cs_w2 = (const float*)d_in[28];
  const float* cs_b2 = (const float*)d_in[29];
  float* out = (float*)d_out;
  char* ws = (char*)d_ws;
  // ws layout (bytes):
  //   meanb f32 @0           (3,145,728)   [dead after k_fc1; head reused for weight prep]
  //     w2t  bf16 @0         (73,728)      [fc4 w2^T; written by k_wt AFTER k_fc1]
  //     w1t  bf16 @73728     (73,728)      [fc4 w1^T]
  //     w1t3 bf16 @147456    (57,344)      [fc3 w1^T, t-pad 224]
  //     w2t3 bf16 @204800    (53,248)      [fc3 w2^T, t'-pad 208]
  //   mlp1  f32 @3145728     (3,145,728)
  //   mu    f32 @6291456     (1,613,824)
  //   rstd  f32 @7905280     (1,613,824)
  //   h4    bf16 @9519104    (38,535,168)  [then P f32 + Cpart overlay]
  //   P     f32 @9519104     (19,668,992)  [overlays h4 (dead after fc4b)]
  //   Cpart f32 @29188096    (7,340,032)
  //   Qb    bf16 @59850752   (77,070,336)
  //   Sb    bf16 @136921088  (77,070,336)
  //   total 213,991,424 B
  float* meanb  = (float*)(ws + 0);
  ushort_t* w2t  = (ushort_t*)(ws + 0);       // overlays meanb (dead after k_fc1)
  ushort_t* w1t  = (ushort_t*)(ws + 73728);
  ushort_t* w1t3 = (ushort_t*)(ws + 147456);
  ushort_t* w2t3 = (ushort_t*)(ws + 204800);
  float* mlp1   = (float*)(ws + 3145728);
  float* mu     = (float*)(ws + 6291456);
  float* rstd   = (float*)(ws + 7905280);
  ushort_t* h4  = (ushort_t*)(ws + 9519104);
  float* P      = (float*)(ws + 9519104);     // overlays h4 (dead after fc4b)
  float* Cpart  = (float*)(ws + 29188096);    // after P, before Qb
  ushort_t* Qb  = (ushort_t*)(ws + 59850752);
  ushort_t* Sb  = (ushort_t*)(ws + 136921088);
  const size_t H4S = (size_t)512*196*96;      // per-s-half h4 elements

  k_mean<<<2048, 384, 0, stream>>>(fq, fs, fqs, fss, meanb);
  k_fc1<<<2048, 384, 0, stream>>>(meanb, fc1_w1, fc1_b1, fc1_w2, fc1_b2, mlp1);
  k_wt<<<504, 256, 0, stream>>>(fc4_w1, fc4_w2, fc3_w1, fc3_w2,
                                w1t, w2t, w1t3, w2t3);      // after k_fc1: meanb dead
  k_stats<<<2048, 256, 0, stream>>>(fq, fs, fqs, fss, mlp1, mu, rstd);
  k_class<<<1024, 384, 0, stream>>>(fq, fs, mlp1, mu, rstd, ln1_g, ln1_b, out);
  k_cosine<<<512, 384, 0, stream>>>(cs_w1, cs_b1, cs_w2, cs_b2, out);
  // fc3 fused MFMA: q-start then s-start
  k_fc3<<<3072, 256, 0, stream>>>(fqs, mlp1 + (size_t)2*512*384, mu + 2*100864, rstd + 2*100864,
                                  ln1_g, ln1_b, w1t3, fc3_b1, w2t3, fc3_b2, ln3_g, ln3_b, Qb);
  k_fc3<<<3072, 256, 0, stream>>>(fss, mlp1 + (size_t)3*512*384, mu + 3*100864, rstd + 3*100864,
                                  ln1_g, ln1_b, w1t3, fc3_b1, w2t3, fc3_b2, ln3_g, ln3_b, Sb);
  // fc4 stage A (MFMA): q then s (pre-offset pointers, no runtime s-select)
  k_fc4a<<<2048, 256, 0, stream>>>(fq, mlp1, mu, rstd, ln1_g, ln1_b,
                                   Qb, w1t, fc4_b1, h4);
  k_fc4a<<<2048, 256, 0, stream>>>(fs, mlp1 + (size_t)512*384, mu + 100864, rstd + 100864,
                                   ln1_g, ln1_b, Sb, w1t, fc4_b1, h4 + H4S);
  // fc4 stage B (MFMA): q then s (Qb/Sb overwritten in place after their last read)
  k_fc4b<<<2048, 256, 0, stream>>>(h4,       w2t, fc4_b2, ln4_g, ln4_b, out + 1024,          Qb);
  k_fc4b<<<2048, 256, 0, stream>>>(h4 + H4S, w2t, fc4_b2, ln4_g, ln4_b, out + 1024 + 196608, Sb);
  k_sim<<<8192, 256, 0, stream>>>(Qb, Sb, P);
  // fc2 head: split-K GEMM (896 blocks) + tiny reduce
  k_fc2a<<<896, 256, 0, stream>>>(P, fc2_w1, Cpart);
  k_fc2b<<<512, 256, 0, stream>>>(Cpart, fc2_b1, fc2_w2, fc2_b2, out);
}

// Round 14
// 1383.380 us; speedup vs baseline: 23.9183x; 1.0125x over previous
//
#include <hip/hip_runtime.h>
#include <math.h>

typedef unsigned short ushort_t;
typedef __attribute__((ext_vector_type(8))) short bf16x8;
typedef __attribute__((ext_vector_type(4))) float f32x4;

// ---------------- helpers ----------------
__device__ __forceinline__ float geluf(float x){
  return 0.5f*x*(1.0f+erff(x*0.70710678118654752440f));
}
__device__ __forceinline__ float bfu(unsigned int u){
  union { unsigned int i; float f; } v; v.i = (u & 0xffffu) << 16; return v.f;
}
__device__ __forceinline__ unsigned int f2b(float f){
  union { float f; unsigned int i; } v; v.f = f;
  unsigned int r = v.i + 0x7fffu + ((v.i >> 16) & 1u);
  return (r >> 16);
}

// Problem constants
// B=512, N=197, C=384, T=196 image tokens
// d_out layout (floats): out[512] | cosine[512] | query_class[512*384] | support_class[512*384]

// ---------------- A: token means (vectorized; one block per (s,b)) ----------------
// block 384 = 4 row-groups x 96 float4-slots; each iteration moves 4 contiguous
// rows (6 KB, 16B/lane). Round-13 profile: scalar version ran at 3.3 TB/s eff.
__global__ __launch_bounds__(384) void k_mean(
    const float* __restrict__ x0, const float* __restrict__ x1,
    const float* __restrict__ x2, const float* __restrict__ x3,
    float* __restrict__ meanb){
  __shared__ float4 red[4][96];
  int sb = blockIdx.x;
  int s = sb >> 9, b = sb & 511;
  const float* x = (s==0)?x0:(s==1)?x1:(s==2)?x2:x3;
  int tid = threadIdx.x;
  int c4 = tid % 96, g = tid / 96;    // 4 groups of 96
  const float* p = x + ((size_t)b*197)*384 + c4*4;
  float4 acc = {0.f,0.f,0.f,0.f};
  for (int t = g; t < 197; t += 4){
    float4 v = *reinterpret_cast<const float4*>(p + (size_t)t*384);
    acc.x += v.x; acc.y += v.y; acc.z += v.z; acc.w += v.w;
  }
  red[g][c4] = acc;
  __syncthreads();
  if (tid < 96){
    float4 a = red[0][tid], bb = red[1][tid], c = red[2][tid], d = red[3][tid];
    float4 o;
    o.x = (a.x+bb.x+c.x+d.x)*(1.0f/197.0f);
    o.y = (a.y+bb.y+c.y+d.y)*(1.0f/197.0f);
    o.z = (a.z+bb.z+c.z+d.z)*(1.0f/197.0f);
    o.w = (a.w+bb.w+c.w+d.w)*(1.0f/197.0f);
    *reinterpret_cast<float4*>(&meanb[(size_t)sb*384 + tid*4]) = o;
  }
}

// ---------------- B: fc1 tiny MLP on means ----------------
__global__ __launch_bounds__(384) void k_fc1(
    const float* __restrict__ meanb, const float* __restrict__ w1,
    const float* __restrict__ b1, const float* __restrict__ w2,
    const float* __restrict__ b2, float* __restrict__ mlp1){
  __shared__ float ms[384];
  __shared__ float hs[96];
  int row = blockIdx.x, tid = threadIdx.x;
  ms[tid] = meanb[(size_t)row*384 + tid];
  __syncthreads();
  if (tid < 96){
    float a = b1[tid];
    for (int c=0;c<384;++c) a += ms[c]*w1[c*96+tid];
    hs[tid] = geluf(a);
  }
  __syncthreads();
  float a = b2[tid];
  for (int j=0;j<96;++j) a += hs[j]*w2[j*384+tid];
  mlp1[(size_t)row*384 + tid] = a;
}

// ---------------- C: per-row LN stats of (x + mlp1) ----------------
// grid 2048 (s*512+b), block 256 = 4 waves; 16-lane groups process 4 rows/wave.
__global__ __launch_bounds__(256) void k_stats(
    const float* __restrict__ x0, const float* __restrict__ x1,
    const float* __restrict__ x2, const float* __restrict__ x3,
    const float* __restrict__ mlp1, float* __restrict__ mu, float* __restrict__ rstd){
  int sb = blockIdx.x;          // s*512 + b
  int s = sb >> 9, b = sb & 511;
  const float* x = (s==0)?x0:(s==1)?x1:(s==2)?x2:x3;
  const float* mp = mlp1 + (size_t)sb*384;
  int tid = threadIdx.x, w = tid >> 6, lane = tid & 63;
  int g = lane >> 4, il = lane & 15;
  float4 mreg[6];
  #pragma unroll
  for (int it = 0; it < 6; ++it)
    mreg[it] = *reinterpret_cast<const float4*>(&mp[il*4 + 64*it]);
  for (int t0 = 0; t0 < 208; t0 += 16){
    int t = t0 + w*4 + g;
    if (t < 197){
      const float* xp = x + ((size_t)b*197 + t)*384 + il*4;
      float sum = 0.f, sq = 0.f;
      #pragma unroll
      for (int it = 0; it < 6; ++it){
        float4 v = *reinterpret_cast<const float4*>(xp + 64*it);
        float a0 = v.x + mreg[it].x, a1 = v.y + mreg[it].y;
        float a2 = v.z + mreg[it].z, a3 = v.w + mreg[it].w;
        sum += a0+a1+a2+a3;
        sq  += a0*a0+a1*a1+a2*a2+a3*a3;
      }
      #pragma unroll
      for (int o=1;o<16;o<<=1){ sum += __shfl_xor(sum,o); sq += __shfl_xor(sq,o); }
      if (il == 0){
        int row = sb*197 + t;
        float m = sum*(1.0f/384.0f);
        mu[row] = m;
        rstd[row] = rsqrtf(sq*(1.0f/384.0f) - m*m + 1e-5f);
      }
    }
  }
}

// ---------------- D: class token rows -> d_out ----------------
__global__ __launch_bounds__(384) void k_class(
    const float* __restrict__ x0, const float* __restrict__ x1,
    const float* __restrict__ mlp1, const float* __restrict__ mu,
    const float* __restrict__ rstd, const float* __restrict__ g1,
    const float* __restrict__ bb1, float* __restrict__ dout){
  int s = blockIdx.x >> 9, b = blockIdx.x & 511, c = threadIdx.x;
  const float* x = s ? x1 : x0;
  int srow = (s*512 + b)*197;
  float v = x[((size_t)b*197)*384 + c] + mlp1[((size_t)s*512+b)*384 + c];
  float y = (v - mu[srow])*rstd[srow]*g1[c] + bb1[c];
  dout[1024 + (size_t)s*196608 + (size_t)b*384 + c] = y;
}

// ---------------- E: cosine head on class tokens ----------------
__global__ __launch_bounds__(384) void k_cosine(
    const float* __restrict__ w1, const float* __restrict__ b1,
    const float* __restrict__ w2, const float* __restrict__ b2,
    float* __restrict__ dout){
  __shared__ float qrow[384], srw[384], hq[96], hs[96];
  __shared__ float rd0[384], rd1[384], rd2[384];
  int b = blockIdx.x, tid = threadIdx.x;
  qrow[tid] = dout[1024   + (size_t)b*384 + tid];
  srw[tid]  = dout[197632 + (size_t)b*384 + tid];
  __syncthreads();
  if (tid < 96){
    float a = b1[tid];
    for (int c=0;c<384;++c) a += qrow[c]*w1[c*96+tid];
    hq[tid] = geluf(a);
  } else if (tid < 192){
    int j = tid - 96;
    float a = b1[j];
    for (int c=0;c<384;++c) a += srw[c]*w1[c*96+j];
    hs[j] = geluf(a);
  }
  __syncthreads();
  float qx = b2[tid], sy = b2[tid];
  for (int j=0;j<96;++j){ qx += hq[j]*w2[j*384+tid]; sy += hs[j]*w2[j*384+tid]; }
  rd0[tid] = qx*sy; rd1[tid] = qx*qx; rd2[tid] = sy*sy;
  __syncthreads();
  if (tid < 64){
    float d=0.f,nq=0.f,ns=0.f;
    for (int i=tid;i<384;i+=64){ d+=rd0[i]; nq+=rd1[i]; ns+=rd2[i]; }
    #pragma unroll
    for (int o=32;o;o>>=1){ d+=__shfl_down(d,o); nq+=__shfl_down(nq,o); ns+=__shfl_down(ns,o); }
    if (tid==0) dout[512 + b] = d / (fmaxf(sqrtf(nq),1e-8f)*fmaxf(sqrtf(ns),1e-8f));
  }
}

// ---------------- W: weight prep (bf16 transposes, zero-padded) ----------------
// grid 504, block 256 (504*256 = 129024).
__global__ __launch_bounds__(256) void k_wt(
    const float* __restrict__ w1_4, const float* __restrict__ w2_4,
    const float* __restrict__ w1_3, const float* __restrict__ w2_3,
    ushort_t* __restrict__ w1t, ushort_t* __restrict__ w2t,
    ushort_t* __restrict__ w1t3, ushort_t* __restrict__ w2t3){
  int idx = blockIdx.x*256 + threadIdx.x;
  if (idx < 36864){
    int c = idx / 96, j = idx - c*96;
    w2t[idx] = (ushort_t)f2b(w2_4[(size_t)j*384 + c]);
  } else if (idx < 73728){
    int k = idx - 36864;
    int j = k / 384, c = k - j*384;
    w1t[k] = (ushort_t)f2b(w1_4[(size_t)c*96 + j]);
  } else if (idx < 102400){
    int k = idx - 73728;
    int j = k / 224, t = k - j*224;
    w1t3[k] = (t < 196) ? (ushort_t)f2b(w1_3[(size_t)t*128 + j]) : (ushort_t)0;
  } else {
    int k = idx - 102400;
    int tp = k / 128, j = k - tp*128;
    w2t3[k] = (tp < 196) ? (ushort_t)f2b(w2_3[(size_t)j*196 + tp]) : (ushort_t)0;
  }
}

// ---------------- F: fc3 fused MFMA (one s-half per launch) ----------------
// grid 512*6 (b, c-tile of 64), block 256 = 4 waves; wave = 16 c rows.
// (1) w2t3 staged in LDS (W2s, 2 halves); (2) GEMM1 A-frags register
// double-buffered (aC/aN).
__global__ __launch_bounds__(256) void k_fc3(
    const float* __restrict__ x,         // fqs or fss
    const float* __restrict__ m1_base,   // mlp1 + s*512*384
    const float* __restrict__ mu_s,      // mu + s*100864
    const float* __restrict__ rstd_s,
    const float* __restrict__ g1, const float* __restrict__ bln1,
    const ushort_t* __restrict__ w1t3,   // [128][224] bf16
    const float* __restrict__ b1,        // fc3_b1 [128]
    const ushort_t* __restrict__ w2t3,   // [208][128] bf16
    const float* __restrict__ b2, const float* __restrict__ g3,
    const float* __restrict__ b3,
    ushort_t* __restrict__ Qout){        // Qb or Sb
  __shared__ ushort_t Xs[64][232];       // X^T tile; Hs overlays cols [0,128) per wave
  __shared__ ushort_t W2s[112][136];     // w2t3 half (17x16B stride: bank-safe)
  __shared__ float m1s[64], g1s[64], b1s[64];
  __shared__ float mus[196], rss[196];
  __shared__ float b1j[128];
  __shared__ float b2s[208], g3s[208], b3s[208];
  int bid = blockIdx.x;
  int b = bid/6, c0 = (bid%6)*64;
  int tid = threadIdx.x;
  // stage coefficients
  if (tid < 64){
    m1s[tid] = m1_base[(size_t)b*384 + c0 + tid];
    g1s[tid] = g1[c0+tid]; b1s[tid] = bln1[c0+tid];
  }
  if (tid < 128) b1j[tid] = b1[tid];
  if (tid < 196){ mus[tid] = mu_s[b*197 + tid + 1]; rss[tid] = rstd_s[b*197 + tid + 1]; }
  if (tid < 208){
    float bb=0.f, gg=0.f, b3v=0.f;
    if (tid < 196){ bb = b2[tid]; gg = g3[tid]; b3v = b3[tid]; }
    b2s[tid]=bb; g3s[tid]=gg; b3s[tid]=b3v;
  }
  // stage W2s part 1 (w2t3 rows 0..111)
  for (int i = tid; i < 112*16; i += 256){
    int r = i >> 4, q = i & 15;
    *reinterpret_cast<uint4*>(&W2s[r][q*8]) =
        *reinterpret_cast<const uint4*>(&w2t3[(size_t)r*128 + q*8]);
  }
  // zero the t-pad of Xs ([196,224) as uints; [224,232) never read)
  for (int i = tid; i < 64*14; i += 256){
    *reinterpret_cast<unsigned int*>(&Xs[i/14][196 + 2*(i%14)]) = 0u;
  }
  __syncthreads();
  // phase 1: stage LN'd X^T tile by t-pairs (98 tpairs x 16 c4-slots = 1568)
  for (int e = 0; e < 7; ++e){
    int idx = e*256 + tid;
    if (idx < 1568){
      int t2 = idx >> 4, c4 = idx & 15;
      int t0 = t2*2;
      const float* xr = &x[((size_t)b*197 + t0 + 1)*384 + c0 + c4*4];
      float4 xv0 = *reinterpret_cast<const float4*>(xr);
      float4 xv1 = *reinterpret_cast<const float4*>(xr + 384);
      float mu0 = mus[t0], rs0 = rss[t0], mu1 = mus[t0+1], rs1 = rss[t0+1];
      int c = c4*4;
      unsigned int u0 = f2b(((xv0.x + m1s[c+0]) - mu0)*rs0*g1s[c+0] + b1s[c+0])
                      | (f2b(((xv1.x + m1s[c+0]) - mu1)*rs1*g1s[c+0] + b1s[c+0]) << 16);
      unsigned int u1 = f2b(((xv0.y + m1s[c+1]) - mu0)*rs0*g1s[c+1] + b1s[c+1])
                      | (f2b(((xv1.y + m1s[c+1]) - mu1)*rs1*g1s[c+1] + b1s[c+1]) << 16);
      unsigned int u2 = f2b(((xv0.z + m1s[c+2]) - mu0)*rs0*g1s[c+2] + b1s[c+2])
                      | (f2b(((xv1.z + m1s[c+2]) - mu1)*rs1*g1s[c+2] + b1s[c+2]) << 16);
      unsigned int u3 = f2b(((xv0.w + m1s[c+3]) - mu0)*rs0*g1s[c+3] + b1s[c+3])
                      | (f2b(((xv1.w + m1s[c+3]) - mu1)*rs1*g1s[c+3] + b1s[c+3]) << 16);
      *reinterpret_cast<unsigned int*>(&Xs[c+0][t0]) = u0;
      *reinterpret_cast<unsigned int*>(&Xs[c+1][t0]) = u1;
      *reinterpret_cast<unsigned int*>(&Xs[c+2][t0]) = u2;
      *reinterpret_cast<unsigned int*>(&Xs[c+3][t0]) = u3;
    }
  }
  __syncthreads();
  int w = tid >> 6, lane = tid & 63;
  int cl = lane & 15, kg = lane >> 4;
  // GEMM1: h = gelu(Xt @ w1 + b1); A register double-buffered
  f32x4 hacc[8];
  #pragma unroll
  for (int jf=0;jf<8;++jf){ f32x4 z={0.f,0.f,0.f,0.f}; hacc[jf]=z; }
  const ushort_t* zrow = &Xs[w*16 + cl][kg*8];
  const ushort_t* abase = w1t3 + (size_t)cl*224 + kg*8;
  bf16x8 aC[8], aN[8];
  #pragma unroll
  for (int jf=0;jf<8;++jf)
    aC[jf] = *reinterpret_cast<const bf16x8*>(abase + jf*16*224);
  for (int kc = 0; kc < 7; ++kc){
    bf16x8 xb = *reinterpret_cast<const bf16x8*>(zrow + kc*32);
    if (kc < 6){
      #pragma unroll
      for (int jf=0;jf<8;++jf)
        aN[jf] = *reinterpret_cast<const bf16x8*>(abase + jf*16*224 + (kc+1)*32);
    }
    #pragma unroll
    for (int jf=0;jf<8;++jf)
      hacc[jf] = __builtin_amdgcn_mfma_f32_16x16x32_bf16(aC[jf], xb, hacc[jf], 0, 0, 0);
    #pragma unroll
    for (int jf=0;jf<8;++jf) aC[jf] = aN[jf];
  }
  // D: row = j = jf*16+kg*4+r, col = c = cl -> overlay into the wave's OWN Xs rows.
  #pragma unroll
  for (int jf=0;jf<8;++jf){
    f32x4 y = hacc[jf];
    int j0 = jf*16 + kg*4;
    uint2 pk;
    pk.x = f2b(geluf(y[0]+b1j[j0+0])) | (f2b(geluf(y[1]+b1j[j0+1]))<<16);
    pk.y = f2b(geluf(y[2]+b1j[j0+2])) | (f2b(geluf(y[3]+b1j[j0+3]))<<16);
    *reinterpret_cast<uint2*>(&Xs[w*16 + cl][j0]) = pk;
  }
  // GEMM2: y = h @ w2 (+b2 in epilogue); B from LDS in two halves
  f32x4 yacc[13];
  #pragma unroll
  for (int tf=0;tf<13;++tf){ f32x4 z={0.f,0.f,0.f,0.f}; yacc[tf]=z; }
  const ushort_t* hrow = &Xs[w*16 + cl][kg*8];
  // part A: tf 0..6 (t' rows 0..111 in W2s)
  for (int kc = 0; kc < 4; ++kc){
    bf16x8 hb = *reinterpret_cast<const bf16x8*>(hrow + kc*32);
    #pragma unroll
    for (int tf=0;tf<7;++tf){
      const ushort_t* bp = &W2s[tf*16 + cl][kg*8 + kc*32];
      yacc[tf] = __builtin_amdgcn_mfma_f32_16x16x32_bf16(
          hb, *reinterpret_cast<const bf16x8*>(bp), yacc[tf], 0, 0, 0);
    }
  }
  __syncthreads();
  // restage W2s with w2t3 rows 112..207 (96 rows)
  for (int i = tid; i < 96*16; i += 256){
    int r = i >> 4, q = i & 15;
    *reinterpret_cast<uint4*>(&W2s[r][q*8]) =
        *reinterpret_cast<const uint4*>(&w2t3[(size_t)(112 + r)*128 + q*8]);
  }
  __syncthreads();
  // part B: tf 7..12 (t' rows 112..207 -> W2s rows tf*16+cl-112)
  for (int kc = 0; kc < 4; ++kc){
    bf16x8 hb = *reinterpret_cast<const bf16x8*>(hrow + kc*32);
    #pragma unroll
    for (int tf=7;tf<13;++tf){
      const ushort_t* bp = &W2s[tf*16 + cl - 112][kg*8 + kc*32];
      yacc[tf] = __builtin_amdgcn_mfma_f32_16x16x32_bf16(
          hb, *reinterpret_cast<const bf16x8*>(bp), yacc[tf], 0, 0, 0);
    }
  }
  // epilogue: lane holds c = c0 + w*16 + kg*4 + r (r=0..3), t' = tf*16 + cl.
  float sum0=0.f,sum1=0.f,sum2=0.f,sum3=0.f, sq0=0.f,sq1=0.f,sq2=0.f,sq3=0.f;
  #pragma unroll
  for (int tf=0;tf<13;++tf){
    int tp = tf*16 + cl;
    float bb = b2s[tp];
    f32x4 y = yacc[tf];
    y[0]+=bb; y[1]+=bb; y[2]+=bb; y[3]+=bb;
    yacc[tf] = y;
    sum0+=y[0]; sum1+=y[1]; sum2+=y[2]; sum3+=y[3];
    sq0+=y[0]*y[0]; sq1+=y[1]*y[1]; sq2+=y[2]*y[2]; sq3+=y[3]*y[3];
  }
  #pragma unroll
  for (int o=1;o<16;o<<=1){
    sum0+=__shfl_xor(sum0,o); sum1+=__shfl_xor(sum1,o);
    sum2+=__shfl_xor(sum2,o); sum3+=__shfl_xor(sum3,o);
    sq0+=__shfl_xor(sq0,o); sq1+=__shfl_xor(sq1,o);
    sq2+=__shfl_xor(sq2,o); sq3+=__shfl_xor(sq3,o);
  }
  float m0=sum0*(1.0f/196.0f), m1v=sum1*(1.0f/196.0f), m2=sum2*(1.0f/196.0f), m3=sum3*(1.0f/196.0f);
  float r0=rsqrtf(sq0*(1.0f/196.0f)-m0*m0+1e-5f);
  float r1=rsqrtf(sq1*(1.0f/196.0f)-m1v*m1v+1e-5f);
  float r2=rsqrtf(sq2*(1.0f/196.0f)-m2*m2+1e-5f);
  float r3=rsqrtf(sq3*(1.0f/196.0f)-m3*m3+1e-5f);
  int cbase = c0 + w*16 + kg*4;
  #pragma unroll
  for (int tf=0;tf<13;++tf){
    int tp = tf*16 + cl;
    if (tp < 196){
      float gg = g3s[tp], bb3 = b3s[tp];
      f32x4 y = yacc[tf];
      unsigned int o0 = f2b((y[0]-m0)*r0*gg + bb3);
      unsigned int o1 = f2b((y[1]-m1v)*r1*gg + bb3);
      unsigned int o2 = f2b((y[2]-m2)*r2*gg + bb3);
      unsigned int o3 = f2b((y[3]-m3)*r3*gg + bb3);
      uint2 pk; pk.x = o0 | (o1<<16); pk.y = o2 | (o3<<16);
      *reinterpret_cast<uint2*>(&Qout[((size_t)b*196 + tp)*384 + cbase]) = pk;
    }
  }
}

// ---------------- H1: fc4 stage A (MFMA; one s-half per launch) ----------------
// grid 512*4 (b, t-tile of 64), block 256 = 4 waves; wave = 16 t x 96 j.
__global__ __launch_bounds__(256) void k_fc4a(
    const float* __restrict__ x,         // fq or fs
    const float* __restrict__ m1_base,   // mlp1 + s*512*384
    const float* __restrict__ mu_s,      // mu + s*100864
    const float* __restrict__ rstd_s,    // rstd + s*100864
    const float* __restrict__ g1, const float* __restrict__ bln1,
    const ushort_t* __restrict__ Qin,    // Qb or Sb
    const ushort_t* __restrict__ w1t,    // [96][384] bf16
    const float* __restrict__ b1mlp,
    ushort_t* __restrict__ h4s){         // h4 + s*512*196*96
  __shared__ ushort_t Zs[64][392];       // bf16 Z tile, padded stride
  __shared__ float m1s[384], g1s[384], b1s[384];
  __shared__ float mus[64], rss[64];
  __shared__ float b1m[96];
  int bid = blockIdx.x;
  int b = bid >> 2, tt0 = (bid & 3)*64;
  int tid = threadIdx.x;
  const float* m1 = m1_base + (size_t)b*384;
  for (int i = tid; i < 384; i += 256){ m1s[i] = m1[i]; g1s[i] = g1[i]; b1s[i] = bln1[i]; }
  if (tid < 96) b1m[tid] = b1mlp[tid];
  if (tid < 64){
    int t = tt0 + tid; int tc = t < 196 ? t : 195;
    mus[tid] = mu_s[b*197 + tc + 1]; rss[tid] = rstd_s[b*197 + tc + 1];
  }
  __syncthreads();
  // phase 1: Z build, 64 rows x 96 col4-slots = 6144 slots, 24 per thread
  for (int e = 0; e < 24; ++e){
    int v = e*256 + tid;
    int row = v/96, col4 = v - row*96;
    int t = tt0 + row; int tc = t < 196 ? t : 195;
    float valid = (t < 196) ? 1.f : 0.f;
    float4 xv = *reinterpret_cast<const float4*>(&x[((size_t)b*197 + tc + 1)*384 + col4*4]);
    uint2 qv = *reinterpret_cast<const uint2*>(&Qin[((size_t)b*196 + tc)*384 + col4*4]);
    float muv = mus[row], rsv = rss[row];
    int c = col4*4;
    float z0 = (((xv.x + m1s[c+0]) - muv)*rsv*g1s[c+0] + b1s[c+0]) * bfu(qv.x)      * valid;
    float z1 = (((xv.y + m1s[c+1]) - muv)*rsv*g1s[c+1] + b1s[c+1]) * bfu(qv.x>>16)  * valid;
    float z2 = (((xv.z + m1s[c+2]) - muv)*rsv*g1s[c+2] + b1s[c+2]) * bfu(qv.y)      * valid;
    float z3 = (((xv.w + m1s[c+3]) - muv)*rsv*g1s[c+3] + b1s[c+3]) * bfu(qv.y>>16)  * valid;
    uint2 pk; pk.x = f2b(z0) | (f2b(z1)<<16); pk.y = f2b(z2) | (f2b(z3)<<16);
    *reinterpret_cast<uint2*>(&Zs[row][col4*4]) = pk;
  }
  __syncthreads();
  // phase 2: MFMA GEMM1 (16t x 96j per wave, K=384)
  int w = tid >> 6, lane = tid & 63;
  int tr = tt0 + w*16 + (lane & 15);
  int kg = lane >> 4;
  f32x4 acc0 = {0.f,0.f,0.f,0.f}, acc1 = {0.f,0.f,0.f,0.f}, acc2 = {0.f,0.f,0.f,0.f};
  f32x4 acc3 = {0.f,0.f,0.f,0.f}, acc4 = {0.f,0.f,0.f,0.f}, acc5 = {0.f,0.f,0.f,0.f};
  const ushort_t* arow = w1t + (size_t)(lane & 15)*384 + kg*8;
  const ushort_t* zrow = &Zs[w*16 + (lane & 15)][kg*8];
  for (int kc = 0; kc < 12; ++kc){
    bf16x8 zb = *reinterpret_cast<const bf16x8*>(zrow + kc*32);
    bf16x8 a0 = *reinterpret_cast<const bf16x8*>(arow + kc*32);
    bf16x8 a1 = *reinterpret_cast<const bf16x8*>(arow + kc*32 + 16*384);
    bf16x8 a2 = *reinterpret_cast<const bf16x8*>(arow + kc*32 + 32*384);
    bf16x8 a3 = *reinterpret_cast<const bf16x8*>(arow + kc*32 + 48*384);
    bf16x8 a4 = *reinterpret_cast<const bf16x8*>(arow + kc*32 + 64*384);
    bf16x8 a5 = *reinterpret_cast<const bf16x8*>(arow + kc*32 + 80*384);
    acc0 = __builtin_amdgcn_mfma_f32_16x16x32_bf16(a0, zb, acc0, 0, 0, 0);
    acc1 = __builtin_amdgcn_mfma_f32_16x16x32_bf16(a1, zb, acc1, 0, 0, 0);
    acc2 = __builtin_amdgcn_mfma_f32_16x16x32_bf16(a2, zb, acc2, 0, 0, 0);
    acc3 = __builtin_amdgcn_mfma_f32_16x16x32_bf16(a3, zb, acc3, 0, 0, 0);
    acc4 = __builtin_amdgcn_mfma_f32_16x16x32_bf16(a4, zb, acc4, 0, 0, 0);
    acc5 = __builtin_amdgcn_mfma_f32_16x16x32_bf16(a5, zb, acc5, 0, 0, 0);
  }
  // epilogue: lane holds j = jb*16 + kg*4 + r (D row), t = tr (D col)
  if (tr < 196){
    ushort_t* dst = h4s + ((size_t)b*196 + tr)*96 + kg*4;
    #pragma unroll
    for (int jb = 0; jb < 6; ++jb){
      f32x4 y = (jb==0)?acc0:(jb==1)?acc1:(jb==2)?acc2:(jb==3)?acc3:(jb==4)?acc4:acc5;
      int j0 = jb*16 + kg*4;
      uint2 pk;
      pk.x = f2b(geluf(y[0]+b1m[j0+0])) | (f2b(geluf(y[1]+b1m[j0+1]))<<16);
      pk.y = f2b(geluf(y[2]+b1m[j0+2])) | (f2b(geluf(y[3]+b1m[j0+3]))<<16);
      *reinterpret_cast<uint2*>(dst + jb*16) = pk;
    }
  }
}

// ---------------- H2: fc4 stage B (MFMA; one s-half per launch) ----------------
// grid 512*4 (b, t-tile of 64), block 256 = 4 waves; wave = 16 t x 384 c.
__global__ __launch_bounds__(256) void k_fc4b(
    const ushort_t* __restrict__ h4s,    // h4 + s*512*196*96
    const ushort_t* __restrict__ w2t,    // [384][96] bf16
    const float* __restrict__ b2, const float* __restrict__ g4,
    const float* __restrict__ bb4,
    const float* __restrict__ cls_base,  // dout + 1024 + s*196608
    ushort_t* __restrict__ Qo){          // Qb or Sb
  __shared__ float b2s[384], g4s[384], b4s[384], cl_s[384];
  int bid = blockIdx.x;
  int b = bid >> 2, ttile = bid & 3;
  int tid = threadIdx.x, w = tid >> 6, lane = tid & 63;
  const float* cls = cls_base + (size_t)b*384;
  for (int i = tid; i < 384; i += 256){
    b2s[i] = b2[i]; g4s[i] = g4[i]; b4s[i] = bb4[i]; cl_s[i] = cls[i];
  }
  __syncthreads();
  int tr = ttile*64 + w*16 + (lane & 15);
  int trc = tr < 196 ? tr : 195;
  int kg = lane >> 4;
  const ushort_t* hp = h4s + ((size_t)b*196 + trc)*96 + kg*8;
  bf16x8 hb0 = *reinterpret_cast<const bf16x8*>(hp);
  bf16x8 hb1 = *reinterpret_cast<const bf16x8*>(hp + 32);
  bf16x8 hb2 = *reinterpret_cast<const bf16x8*>(hp + 64);
  const ushort_t* ap_base = w2t + (size_t)(lane & 15)*96 + kg*8;
  f32x4 acc[24];
  #pragma unroll
  for (int af = 0; af < 24; ++af){
    const ushort_t* ap = ap_base + (size_t)af*16*96;
    bf16x8 a0 = *reinterpret_cast<const bf16x8*>(ap);
    bf16x8 a1 = *reinterpret_cast<const bf16x8*>(ap + 32);
    bf16x8 a2 = *reinterpret_cast<const bf16x8*>(ap + 64);
    f32x4 z = {0.f,0.f,0.f,0.f};
    z = __builtin_amdgcn_mfma_f32_16x16x32_bf16(a0, hb0, z, 0, 0, 0);
    z = __builtin_amdgcn_mfma_f32_16x16x32_bf16(a1, hb1, z, 0, 0, 0);
    z = __builtin_amdgcn_mfma_f32_16x16x32_bf16(a2, hb2, z, 0, 0, 0);
    acc[af] = z;
  }
  // epilogue: lane holds c = af*16 + kg*4 + r  (r=0..3), t = tr (col)
  float sum = 0.f, sq = 0.f;
  #pragma unroll
  for (int af = 0; af < 24; ++af){
    int cb = af*16 + kg*4;
    float4 bv = *reinterpret_cast<const float4*>(&b2s[cb]);
    f32x4 y = acc[af];
    y[0] += bv.x; y[1] += bv.y; y[2] += bv.z; y[3] += bv.w;
    acc[af] = y;
    sum += y[0]+y[1]+y[2]+y[3];
    sq  += y[0]*y[0]+y[1]*y[1]+y[2]*y[2]+y[3]*y[3];
  }
  sum += __shfl_xor(sum, 16); sum += __shfl_xor(sum, 32);
  sq  += __shfl_xor(sq, 16);  sq  += __shfl_xor(sq, 32);
  float m4 = sum*(1.0f/384.0f);
  float rs = rsqrtf(sq*(1.0f/384.0f) - m4*m4 + 1e-5f);
  float s2 = 0.f;
  #pragma unroll
  for (int af = 0; af < 24; ++af){
    int cb = af*16 + kg*4;
    float4 gv = *reinterpret_cast<const float4*>(&g4s[cb]);
    float4 bb = *reinterpret_cast<const float4*>(&b4s[cb]);
    float4 cv = *reinterpret_cast<const float4*>(&cl_s[cb]);
    f32x4 y = acc[af];
    y[0] = (y[0]-m4)*rs*gv.x + bb.x + 0.5f*cv.x;
    y[1] = (y[1]-m4)*rs*gv.y + bb.y + 0.5f*cv.y;
    y[2] = (y[2]-m4)*rs*gv.z + bb.z + 0.5f*cv.z;
    y[3] = (y[3]-m4)*rs*gv.w + bb.w + 0.5f*cv.w;
    acc[af] = y;
    s2 += y[0]*y[0]+y[1]*y[1]+y[2]*y[2]+y[3]*y[3];
  }
  s2 += __shfl_xor(s2, 16); s2 += __shfl_xor(s2, 32);
  float inv = 1.0f/fmaxf(sqrtf(s2), 1e-12f);
  float sm = 0.f;
  #pragma unroll
  for (int af = 0; af < 24; ++af){
    f32x4 y = acc[af];
    y[0]*=inv; y[1]*=inv; y[2]*=inv; y[3]*=inv;
    acc[af] = y;
    sm += y[0]+y[1]+y[2]+y[3];
  }
  sm += __shfl_xor(sm, 16); sm += __shfl_xor(sm, 32);
  sm *= (1.0f/384.0f);
  if (tr < 196){
    ushort_t* dst = Qo + ((size_t)b*196 + tr)*384 + kg*4;
    #pragma unroll
    for (int af = 0; af < 24; ++af){
      f32x4 y = acc[af];
      uint2 pk;
      pk.x = f2b(y[0]-sm) | (f2b(y[1]-sm)<<16);
      pk.y = f2b(y[2]-sm) | (f2b(y[3]-sm)<<16);
      *reinterpret_cast<uint2*>(dst + af*16) = pk;
    }
  }
}

// ---------------- I: batched einsum + fused 2x2 pooling (MFMA) ----------------
// grid 512*16 (b, qt, st), block 256 = 4 waves; wave = 32x32 output tile.
__global__ __launch_bounds__(256) void k_sim(
    const ushort_t* __restrict__ Q, const ushort_t* __restrict__ S,
    float* __restrict__ P){
  int bx = blockIdx.x;
  int b = bx >> 4, qt = (bx >> 2) & 3, st = bx & 3;
  int tid = threadIdx.x;
  int w = tid >> 6, lane = tid & 63;
  int wr = w >> 1, wc = w & 1;
  int q0 = qt*64 + wr*32, s0 = st*64 + wc*32;
  int rrow = lane & 15, kg = lane >> 4;
  const ushort_t* Qb_ = Q + (size_t)b*196*384;
  const ushort_t* Sb_ = S + (size_t)b*196*384;
  int qr0 = min(q0 + rrow, 195), qr1 = min(q0 + 16 + rrow, 195);
  int sr0 = min(s0 + rrow, 195), sr1 = min(s0 + 16 + rrow, 195);
  const ushort_t* qp0 = Qb_ + (size_t)qr0*384 + kg*8;
  const ushort_t* qp1 = Qb_ + (size_t)qr1*384 + kg*8;
  const ushort_t* sp0 = Sb_ + (size_t)sr0*384 + kg*8;
  const ushort_t* sp1 = Sb_ + (size_t)sr1*384 + kg*8;
  f32x4 acc00 = {0.f,0.f,0.f,0.f}, acc01 = {0.f,0.f,0.f,0.f};
  f32x4 acc10 = {0.f,0.f,0.f,0.f}, acc11 = {0.f,0.f,0.f,0.f};
  for (int k0 = 0; k0 < 384; k0 += 32){
    bf16x8 a0 = *reinterpret_cast<const bf16x8*>(qp0 + k0);
    bf16x8 a1 = *reinterpret_cast<const bf16x8*>(qp1 + k0);
    bf16x8 b0 = *reinterpret_cast<const bf16x8*>(sp0 + k0);
    bf16x8 b1 = *reinterpret_cast<const bf16x8*>(sp1 + k0);
    acc00 = __builtin_amdgcn_mfma_f32_16x16x32_bf16(a0, b0, acc00, 0, 0, 0);
    acc01 = __builtin_amdgcn_mfma_f32_16x16x32_bf16(a0, b1, acc01, 0, 0, 0);
    acc10 = __builtin_amdgcn_mfma_f32_16x16x32_bf16(a1, b0, acc10, 0, 0, 0);
    acc11 = __builtin_amdgcn_mfma_f32_16x16x32_bf16(a1, b1, acc11, 0, 0, 0);
  }
  int c = lane & 15, g = lane >> 4;
  float* Pb = P + (size_t)b*98*98;
  #pragma unroll
  for (int i = 0; i < 2; ++i){
    #pragma unroll
    for (int j = 0; j < 2; ++j){
      f32x4 v = (i==0) ? (j==0 ? acc00 : acc01) : (j==0 ? acc10 : acc11);
      float p0 = v[0] + v[1];   // rows 4g, 4g+1
      float p1 = v[2] + v[3];   // rows 4g+2, 4g+3
      float t0 = p0 + __shfl_xor(p0, 1);
      float t1 = p1 + __shfl_xor(p1, 1);
      if (!(c & 1)){
        int qp = (q0 + 16*i + 4*g) >> 1;
        int sp = (s0 + 16*j + c) >> 1;
        if (sp < 98){
          if (qp     < 98) Pb[(size_t)(qp    )*98 + sp] = 0.25f*t0;
          if (qp + 1 < 98) Pb[(size_t)(qp + 1)*98 + sp] = 0.25f*t1;
        }
      }
    }
  }
}

// ---------------- J1: fc2 split-K GEMM  Cpart[ks] = P2-chunk @ w1-chunk ----------------
// grid 64*14 (m-block of 8 rows, k-split of 686), block 256 (= N columns)
__global__ __launch_bounds__(256) void k_fc2a(
    const float* __restrict__ P, const float* __restrict__ w1,
    float* __restrict__ Cpart){
  __shared__ float p2[8][688];
  int bx = blockIdx.x;
  int mb = bx & 63, ks = bx >> 6;      // 14 k-splits of 686 (14*686 = 9604)
  int b0 = mb*8, k0 = ks*686;
  int tid = threadIdx.x;
  for (int idx = tid; idx < 8*686; idx += 256){
    int r = idx / 686, i = idx - r*686;
    float v = P[(size_t)(b0+r)*9604 + k0 + i];
    p2[r][i] = v*v;
  }
  __syncthreads();
  float acc[8];
  #pragma unroll
  for (int r=0;r<8;++r) acc[r]=0.f;
  for (int ii=0; ii<686; ++ii){
    float w = w1[(size_t)(k0+ii)*256 + tid];
    #pragma unroll
    for (int r=0;r<8;++r) acc[r] += p2[r][ii]*w;
  }
  #pragma unroll
  for (int r=0;r<8;++r) Cpart[((size_t)ks*512 + b0 + r)*256 + tid] = acc[r];
}

// ---------------- J2: fc2 reduce + gelu + w2 dot ----------------
// grid 512 (one b each), block 256
__global__ __launch_bounds__(256) void k_fc2b(
    const float* __restrict__ Cpart, const float* __restrict__ b1,
    const float* __restrict__ w2, const float* __restrict__ b2,
    float* __restrict__ outp){
  __shared__ float red[4];
  int b = blockIdx.x, tid = threadIdx.x;
  float s = 0.f;
  for (int ks = 0; ks < 14; ++ks) s += Cpart[((size_t)ks*512 + b)*256 + tid];
  float h = geluf(s + b1[tid]) * w2[tid];
  #pragma unroll
  for (int o=32;o;o>>=1) h += __shfl_down(h,o);
  int w = tid >> 6, lane = tid & 63;
  if (lane==0) red[w] = h;
  __syncthreads();
  if (tid==0) outp[b] = red[0]+red[1]+red[2]+red[3] + b2[0];
}

// ---------------- launch ----------------
extern "C" void kernel_launch(void* const* d_in, const int* in_sizes, int n_in,
                              void* d_out, int out_size, void* d_ws, size_t ws_size,
                              hipStream_t stream){
  const float* fq  = (const float*)d_in[0];
  const float* fs  = (const float*)d_in[1];
  const float* fqs = (const float*)d_in[2];
  const float* fss = (const float*)d_in[3];
  const float* fc1_w1 = (const float*)d_in[4];
  const float* fc1_b1 = (const float*)d_in[5];
  const float* fc1_w2 = (const float*)d_in[6];
  const float* fc1_b2 = (const float*)d_in[7];
  const float* ln1_g = (const float*)d_in[8];
  const float* ln1_b = (const float*)d_in[9];
  const float* fc3_w1 = (const float*)d_in[10];
  const float* fc3_b1 = (const float*)d_in[11];
  const float* fc3_w2 = (const float*)d_in[12];
  const float* fc3_b2 = (const float*)d_in[13];
  const float* ln3_g = (const float*)d_in[14];
  const float* ln3_b = (const float*)d_in[15];
  const float* fc4_w1 = (const float*)d_in[16];
  const float* fc4_b1 = (const float*)d_in[17];
  const float* fc4_w2 = (const float*)d_in[18];
  const float* fc4_b2 = (const float*)d_in[19];
  const float* ln4_g = (const float*)d_in[20];
  const float* ln4_b = (const float*)d_in[21];
  const float* fc2_w1 = (const float*)d_in[22];
  const float* fc2_b1 = (const float*)d_in[23];
  const float* fc2_w2 = (const float*)d_in[24];
  const float* fc2_b2 = (const float*)d_in[25];
  const float* cs_w1 = (const float*)d_in[26];
  const float* cs_b1 = (const float*)d_in[27];
  const float* cs_w2 = (const float*)d_in[28];
  const float* cs_b2 = (const float*)d_in[29];
  float* out = (float*)d_out;
  char* ws = (char*)d_ws;
  // ws layout (bytes):
  //   meanb f32 @0           (3,145,728)   [dead after k_fc1; head reused for weight prep]
  //     w2t  bf16 @0         (73,728)      [fc4 w2^T; written by k_wt AFTER k_fc1]
  //     w1t  bf16 @73728     (73,728)      [fc4 w1^T]
  //     w1t3 bf16 @147456    (57,344)      [fc3 w1^T, t-pad 224]
  //     w2t3 bf16 @204800    (53,248)      [fc3 w2^T, t'-pad 208]
  //   mlp1  f32 @3145728     (3,145,728)
  //   mu    f32 @6291456     (1,613,824)
  //   rstd  f32 @7905280     (1,613,824)
  //   h4    bf16 @9519104    (38,535,168)  [then P f32 + Cpart overlay]
  //   P     f32 @9519104     (19,668,992)  [overlays h4 (dead after fc4b)]
  //   Cpart f32 @29188096    (7,340,032)
  //   Qb    bf16 @59850752   (77,070,336)
  //   Sb    bf16 @136921088  (77,070,336)
  //   total 213,991,424 B
  float* meanb  = (float*)(ws + 0);
  ushort_t* w2t  = (ushort_t*)(ws + 0);       // overlays meanb (dead after k_fc1)
  ushort_t* w1t  = (ushort_t*)(ws + 73728);
  ushort_t* w1t3 = (ushort_t*)(ws + 147456);
  ushort_t* w2t3 = (ushort_t*)(ws + 204800);
  float* mlp1   = (float*)(ws + 3145728);
  float* mu     = (float*)(ws + 6291456);
  float* rstd   = (float*)(ws + 7905280);
  ushort_t* h4  = (ushort_t*)(ws + 9519104);
  float* P      = (float*)(ws + 9519104);     // overlays h4 (dead after fc4b)
  float* Cpart  = (float*)(ws + 29188096);    // after P, before Qb
  ushort_t* Qb  = (ushort_t*)(ws + 59850752);
  ushort_t* Sb  = (ushort_t*)(ws + 136921088);
  const size_t H4S = (size_t)512*196*96;      // per-s-half h4 elements

  k_mean<<<2048, 384, 0, stream>>>(fq, fs, fqs, fss, meanb);
  k_fc1<<<2048, 384, 0, stream>>>(meanb, fc1_w1, fc1_b1, fc1_w2, fc1_b2, mlp1);
  k_wt<<<504, 256, 0, stream>>>(fc4_w1, fc4_w2, fc3_w1, fc3_w2,
                                w1t, w2t, w1t3, w2t3);      // after k_fc1: meanb dead
  k_stats<<<2048, 256, 0, stream>>>(fq, fs, fqs, fss, mlp1, mu, rstd);
  k_class<<<1024, 384, 0, stream>>>(fq, fs, mlp1, mu, rstd, ln1_g, ln1_b, out);
  k_cosine<<<512, 384, 0, stream>>>(cs_w1, cs_b1, cs_w2, cs_b2, out);
  // fc3 fused MFMA: q-start then s-start
  k_fc3<<<3072, 256, 0, stream>>>(fqs, mlp1 + (size_t)2*512*384, mu + 2*100864, rstd + 2*100864,
                                  ln1_g, ln1_b, w1t3, fc3_b1, w2t3, fc3_b2, ln3_g, ln3_b, Qb);
  k_fc3<<<3072, 256, 0, stream>>>(fss, mlp1 + (size_t)3*512*384, mu + 3*100864, rstd + 3*100864,
                                  ln1_g, ln1_b, w1t3, fc3_b1, w2t3, fc3_b2, ln3_g, ln3_b, Sb);
  // fc4 stage A (MFMA): q then s (pre-offset pointers, no runtime s-select)
  k_fc4a<<<2048, 256, 0, stream>>>(fq, mlp1, mu, rstd, ln1_g, ln1_b,
                                   Qb, w1t, fc4_b1, h4);
  k_fc4a<<<2048, 256, 0, stream>>>(fs, mlp1 + (size_t)512*384, mu + 100864, rstd + 100864,
                                   ln1_g, ln1_b, Sb, w1t, fc4_b1, h4 + H4S);
  // fc4 stage B (MFMA): q then s (Qb/Sb overwritten in place after their last read)
  k_fc4b<<<2048, 256, 0, stream>>>(h4,       w2t, fc4_b2, ln4_g, ln4_b, out + 1024,          Qb);
  k_fc4b<<<2048, 256, 0, stream>>>(h4 + H4S, w2t, fc4_b2, ln4_g, ln4_b, out + 1024 + 196608, Sb);
  k_sim<<<8192, 256, 0, stream>>>(Qb, Sb, P);
  // fc2 head: split-K GEMM (896 blocks) + tiny reduce
  k_fc2a<<<896, 256, 0, stream>>>(P, fc2_w1, Cpart);
  k_fc2b<<<512, 256, 0, stream>>>(Cpart, fc2_b1, fc2_w2, fc2_b2, out);
}

// Round 15
// 1372.123 us; speedup vs baseline: 24.1145x; 1.0082x over previous
//
#include <hip/hip_runtime.h>
#include <math.h>

typedef unsigned short ushort_t;
typedef __attribute__((ext_vector_type(8))) short bf16x8;
typedef __attribute__((ext_vector_type(4))) float f32x4;

// ---------------- helpers ----------------
__device__ __forceinline__ float geluf(float x){
  return 0.5f*x*(1.0f+erff(x*0.70710678118654752440f));
}
__device__ __forceinline__ float bfu(unsigned int u){
  union { unsigned int i; float f; } v; v.i = (u & 0xffffu) << 16; return v.f;
}
__device__ __forceinline__ unsigned int f2b(float f){
  union { float f; unsigned int i; } v; v.f = f;
  unsigned int r = v.i + 0x7fffu + ((v.i >> 16) & 1u);
  return (r >> 16);
}

// Problem constants
// B=512, N=197, C=384, T=196 image tokens
// d_out layout (floats): out[512] | cosine[512] | query_class[512*384] | support_class[512*384]

// ---------------- A: token means (vectorized; one block per (s,b)) ----------------
__global__ __launch_bounds__(384) void k_mean(
    const float* __restrict__ x0, const float* __restrict__ x1,
    const float* __restrict__ x2, const float* __restrict__ x3,
    float* __restrict__ meanb){
  __shared__ float4 red[4][96];
  int sb = blockIdx.x;
  int s = sb >> 9, b = sb & 511;
  const float* x = (s==0)?x0:(s==1)?x1:(s==2)?x2:x3;
  int tid = threadIdx.x;
  int c4 = tid % 96, g = tid / 96;    // 4 groups of 96
  const float* p = x + ((size_t)b*197)*384 + c4*4;
  float4 acc = {0.f,0.f,0.f,0.f};
  for (int t = g; t < 197; t += 4){
    float4 v = *reinterpret_cast<const float4*>(p + (size_t)t*384);
    acc.x += v.x; acc.y += v.y; acc.z += v.z; acc.w += v.w;
  }
  red[g][c4] = acc;
  __syncthreads();
  if (tid < 96){
    float4 a = red[0][tid], bb = red[1][tid], c = red[2][tid], d = red[3][tid];
    float4 o;
    o.x = (a.x+bb.x+c.x+d.x)*(1.0f/197.0f);
    o.y = (a.y+bb.y+c.y+d.y)*(1.0f/197.0f);
    o.z = (a.z+bb.z+c.z+d.z)*(1.0f/197.0f);
    o.w = (a.w+bb.w+c.w+d.w)*(1.0f/197.0f);
    *reinterpret_cast<float4*>(&meanb[(size_t)sb*384 + tid*4]) = o;
  }
}

// ---------------- B: fc1 tiny MLP on means ----------------
__global__ __launch_bounds__(384) void k_fc1(
    const float* __restrict__ meanb, const float* __restrict__ w1,
    const float* __restrict__ b1, const float* __restrict__ w2,
    const float* __restrict__ b2, float* __restrict__ mlp1){
  __shared__ float ms[384];
  __shared__ float hs[96];
  int row = blockIdx.x, tid = threadIdx.x;
  ms[tid] = meanb[(size_t)row*384 + tid];
  __syncthreads();
  if (tid < 96){
    float a = b1[tid];
    for (int c=0;c<384;++c) a += ms[c]*w1[c*96+tid];
    hs[tid] = geluf(a);
  }
  __syncthreads();
  float a = b2[tid];
  for (int j=0;j<96;++j) a += hs[j]*w2[j*384+tid];
  mlp1[(size_t)row*384 + tid] = a;
}

// ---------------- C: per-row LN stats of (x + mlp1) ----------------
// grid 2048 (s*512+b), block 256 = 4 waves; 16-lane groups process 4 rows/wave.
__global__ __launch_bounds__(256) void k_stats(
    const float* __restrict__ x0, const float* __restrict__ x1,
    const float* __restrict__ x2, const float* __restrict__ x3,
    const float* __restrict__ mlp1, float* __restrict__ mu, float* __restrict__ rstd){
  int sb = blockIdx.x;          // s*512 + b
  int s = sb >> 9, b = sb & 511;
  const float* x = (s==0)?x0:(s==1)?x1:(s==2)?x2:x3;
  const float* mp = mlp1 + (size_t)sb*384;
  int tid = threadIdx.x, w = tid >> 6, lane = tid & 63;
  int g = lane >> 4, il = lane & 15;
  float4 mreg[6];
  #pragma unroll
  for (int it = 0; it < 6; ++it)
    mreg[it] = *reinterpret_cast<const float4*>(&mp[il*4 + 64*it]);
  for (int t0 = 0; t0 < 208; t0 += 16){
    int t = t0 + w*4 + g;
    if (t < 197){
      const float* xp = x + ((size_t)b*197 + t)*384 + il*4;
      float sum = 0.f, sq = 0.f;
      #pragma unroll
      for (int it = 0; it < 6; ++it){
        float4 v = *reinterpret_cast<const float4*>(xp + 64*it);
        float a0 = v.x + mreg[it].x, a1 = v.y + mreg[it].y;
        float a2 = v.z + mreg[it].z, a3 = v.w + mreg[it].w;
        sum += a0+a1+a2+a3;
        sq  += a0*a0+a1*a1+a2*a2+a3*a3;
      }
      #pragma unroll
      for (int o=1;o<16;o<<=1){ sum += __shfl_xor(sum,o); sq += __shfl_xor(sq,o); }
      if (il == 0){
        int row = sb*197 + t;
        float m = sum*(1.0f/384.0f);
        mu[row] = m;
        rstd[row] = rsqrtf(sq*(1.0f/384.0f) - m*m + 1e-5f);
      }
    }
  }
}

// ---------------- D: class token rows -> d_out ----------------
__global__ __launch_bounds__(384) void k_class(
    const float* __restrict__ x0, const float* __restrict__ x1,
    const float* __restrict__ mlp1, const float* __restrict__ mu,
    const float* __restrict__ rstd, const float* __restrict__ g1,
    const float* __restrict__ bb1, float* __restrict__ dout){
  int s = blockIdx.x >> 9, b = blockIdx.x & 511, c = threadIdx.x;
  const float* x = s ? x1 : x0;
  int srow = (s*512 + b)*197;
  float v = x[((size_t)b*197)*384 + c] + mlp1[((size_t)s*512+b)*384 + c];
  float y = (v - mu[srow])*rstd[srow]*g1[c] + bb1[c];
  dout[1024 + (size_t)s*196608 + (size_t)b*384 + c] = y;
}

// ---------------- E: cosine head on class tokens ----------------
__global__ __launch_bounds__(384) void k_cosine(
    const float* __restrict__ w1, const float* __restrict__ b1,
    const float* __restrict__ w2, const float* __restrict__ b2,
    float* __restrict__ dout){
  __shared__ float qrow[384], srw[384], hq[96], hs[96];
  __shared__ float rd0[384], rd1[384], rd2[384];
  int b = blockIdx.x, tid = threadIdx.x;
  qrow[tid] = dout[1024   + (size_t)b*384 + tid];
  srw[tid]  = dout[197632 + (size_t)b*384 + tid];
  __syncthreads();
  if (tid < 96){
    float a = b1[tid];
    for (int c=0;c<384;++c) a += qrow[c]*w1[c*96+tid];
    hq[tid] = geluf(a);
  } else if (tid < 192){
    int j = tid - 96;
    float a = b1[j];
    for (int c=0;c<384;++c) a += srw[c]*w1[c*96+j];
    hs[j] = geluf(a);
  }
  __syncthreads();
  float qx = b2[tid], sy = b2[tid];
  for (int j=0;j<96;++j){ qx += hq[j]*w2[j*384+tid]; sy += hs[j]*w2[j*384+tid]; }
  rd0[tid] = qx*sy; rd1[tid] = qx*qx; rd2[tid] = sy*sy;
  __syncthreads();
  if (tid < 64){
    float d=0.f,nq=0.f,ns=0.f;
    for (int i=tid;i<384;i+=64){ d+=rd0[i]; nq+=rd1[i]; ns+=rd2[i]; }
    #pragma unroll
    for (int o=32;o;o>>=1){ d+=__shfl_down(d,o); nq+=__shfl_down(nq,o); ns+=__shfl_down(ns,o); }
    if (tid==0) dout[512 + b] = d / (fmaxf(sqrtf(nq),1e-8f)*fmaxf(sqrtf(ns),1e-8f));
  }
}

// ---------------- W: weight prep (bf16 transposes, zero-padded) ----------------
// grid 504, block 256 (504*256 = 129024).
__global__ __launch_bounds__(256) void k_wt(
    const float* __restrict__ w1_4, const float* __restrict__ w2_4,
    const float* __restrict__ w1_3, const float* __restrict__ w2_3,
    ushort_t* __restrict__ w1t, ushort_t* __restrict__ w2t,
    ushort_t* __restrict__ w1t3, ushort_t* __restrict__ w2t3){
  int idx = blockIdx.x*256 + threadIdx.x;
  if (idx < 36864){
    int c = idx / 96, j = idx - c*96;
    w2t[idx] = (ushort_t)f2b(w2_4[(size_t)j*384 + c]);
  } else if (idx < 73728){
    int k = idx - 36864;
    int j = k / 384, c = k - j*384;
    w1t[k] = (ushort_t)f2b(w1_4[(size_t)c*96 + j]);
  } else if (idx < 102400){
    int k = idx - 73728;
    int j = k / 224, t = k - j*224;
    w1t3[k] = (t < 196) ? (ushort_t)f2b(w1_3[(size_t)t*128 + j]) : (ushort_t)0;
  } else {
    int k = idx - 102400;
    int tp = k / 128, j = k - tp*128;
    w2t3[k] = (tp < 196) ? (ushort_t)f2b(w2_3[(size_t)j*196 + tp]) : (ushort_t)0;
  }
}

// ---------------- F: fc3 fused MFMA (one s-half per launch) ----------------
// grid 512*6 (b, c-tile of 64), block 256 = 4 waves; wave = 16 c rows.
__global__ __launch_bounds__(256) void k_fc3(
    const float* __restrict__ x,         // fqs or fss
    const float* __restrict__ m1_base,   // mlp1 + s*512*384
    const float* __restrict__ mu_s,      // mu + s*100864
    const float* __restrict__ rstd_s,
    const float* __restrict__ g1, const float* __restrict__ bln1,
    const ushort_t* __restrict__ w1t3,   // [128][224] bf16
    const float* __restrict__ b1,        // fc3_b1 [128]
    const ushort_t* __restrict__ w2t3,   // [208][128] bf16
    const float* __restrict__ b2, const float* __restrict__ g3,
    const float* __restrict__ b3,
    ushort_t* __restrict__ Qout){        // Qb or Sb
  __shared__ ushort_t Xs[64][232];       // X^T tile; Hs overlays cols [0,128) per wave
  __shared__ ushort_t W2s[112][136];     // w2t3 half (17x16B stride: bank-safe)
  __shared__ float m1s[64], g1s[64], b1s[64];
  __shared__ float mus[196], rss[196];
  __shared__ float b1j[128];
  __shared__ float b2s[208], g3s[208], b3s[208];
  int bid = blockIdx.x;
  int b = bid/6, c0 = (bid%6)*64;
  int tid = threadIdx.x;
  // stage coefficients
  if (tid < 64){
    m1s[tid] = m1_base[(size_t)b*384 + c0 + tid];
    g1s[tid] = g1[c0+tid]; b1s[tid] = bln1[c0+tid];
  }
  if (tid < 128) b1j[tid] = b1[tid];
  if (tid < 196){ mus[tid] = mu_s[b*197 + tid + 1]; rss[tid] = rstd_s[b*197 + tid + 1]; }
  if (tid < 208){
    float bb=0.f, gg=0.f, b3v=0.f;
    if (tid < 196){ bb = b2[tid]; gg = g3[tid]; b3v = b3[tid]; }
    b2s[tid]=bb; g3s[tid]=gg; b3s[tid]=b3v;
  }
  // stage W2s part 1 (w2t3 rows 0..111)
  for (int i = tid; i < 112*16; i += 256){
    int r = i >> 4, q = i & 15;
    *reinterpret_cast<uint4*>(&W2s[r][q*8]) =
        *reinterpret_cast<const uint4*>(&w2t3[(size_t)r*128 + q*8]);
  }
  // zero the t-pad of Xs ([196,224) as uints; [224,232) never read)
  for (int i = tid; i < 64*14; i += 256){
    *reinterpret_cast<unsigned int*>(&Xs[i/14][196 + 2*(i%14)]) = 0u;
  }
  __syncthreads();
  // phase 1: stage LN'd X^T tile by t-pairs (98 tpairs x 16 c4-slots = 1568)
  for (int e = 0; e < 7; ++e){
    int idx = e*256 + tid;
    if (idx < 1568){
      int t2 = idx >> 4, c4 = idx & 15;
      int t0 = t2*2;
      const float* xr = &x[((size_t)b*197 + t0 + 1)*384 + c0 + c4*4];
      float4 xv0 = *reinterpret_cast<const float4*>(xr);
      float4 xv1 = *reinterpret_cast<const float4*>(xr + 384);
      float mu0 = mus[t0], rs0 = rss[t0], mu1 = mus[t0+1], rs1 = rss[t0+1];
      int c = c4*4;
      unsigned int u0 = f2b(((xv0.x + m1s[c+0]) - mu0)*rs0*g1s[c+0] + b1s[c+0])
                      | (f2b(((xv1.x + m1s[c+0]) - mu1)*rs1*g1s[c+0] + b1s[c+0]) << 16);
      unsigned int u1 = f2b(((xv0.y + m1s[c+1]) - mu0)*rs0*g1s[c+1] + b1s[c+1])
                      | (f2b(((xv1.y + m1s[c+1]) - mu1)*rs1*g1s[c+1] + b1s[c+1]) << 16);
      unsigned int u2 = f2b(((xv0.z + m1s[c+2]) - mu0)*rs0*g1s[c+2] + b1s[c+2])
                      | (f2b(((xv1.z + m1s[c+2]) - mu1)*rs1*g1s[c+2] + b1s[c+2]) << 16);
      unsigned int u3 = f2b(((xv0.w + m1s[c+3]) - mu0)*rs0*g1s[c+3] + b1s[c+3])
                      | (f2b(((xv1.w + m1s[c+3]) - mu1)*rs1*g1s[c+3] + b1s[c+3]) << 16);
      *reinterpret_cast<unsigned int*>(&Xs[c+0][t0]) = u0;
      *reinterpret_cast<unsigned int*>(&Xs[c+1][t0]) = u1;
      *reinterpret_cast<unsigned int*>(&Xs[c+2][t0]) = u2;
      *reinterpret_cast<unsigned int*>(&Xs[c+3][t0]) = u3;
    }
  }
  __syncthreads();
  int w = tid >> 6, lane = tid & 63;
  int cl = lane & 15, kg = lane >> 4;
  // GEMM1: h = gelu(Xt @ w1 + b1); A register double-buffered
  f32x4 hacc[8];
  #pragma unroll
  for (int jf=0;jf<8;++jf){ f32x4 z={0.f,0.f,0.f,0.f}; hacc[jf]=z; }
  const ushort_t* zrow = &Xs[w*16 + cl][kg*8];
  const ushort_t* abase = w1t3 + (size_t)cl*224 + kg*8;
  bf16x8 aC[8], aN[8];
  #pragma unroll
  for (int jf=0;jf<8;++jf)
    aC[jf] = *reinterpret_cast<const bf16x8*>(abase + jf*16*224);
  for (int kc = 0; kc < 7; ++kc){
    bf16x8 xb = *reinterpret_cast<const bf16x8*>(zrow + kc*32);
    if (kc < 6){
      #pragma unroll
      for (int jf=0;jf<8;++jf)
        aN[jf] = *reinterpret_cast<const bf16x8*>(abase + jf*16*224 + (kc+1)*32);
    }
    #pragma unroll
    for (int jf=0;jf<8;++jf)
      hacc[jf] = __builtin_amdgcn_mfma_f32_16x16x32_bf16(aC[jf], xb, hacc[jf], 0, 0, 0);
    #pragma unroll
    for (int jf=0;jf<8;++jf) aC[jf] = aN[jf];
  }
  // D: row = j = jf*16+kg*4+r, col = c = cl -> overlay into the wave's OWN Xs rows.
  #pragma unroll
  for (int jf=0;jf<8;++jf){
    f32x4 y = hacc[jf];
    int j0 = jf*16 + kg*4;
    uint2 pk;
    pk.x = f2b(geluf(y[0]+b1j[j0+0])) | (f2b(geluf(y[1]+b1j[j0+1]))<<16);
    pk.y = f2b(geluf(y[2]+b1j[j0+2])) | (f2b(geluf(y[3]+b1j[j0+3]))<<16);
    *reinterpret_cast<uint2*>(&Xs[w*16 + cl][j0]) = pk;
  }
  // GEMM2: y = h @ w2 (+b2 in epilogue); B from LDS in two halves
  f32x4 yacc[13];
  #pragma unroll
  for (int tf=0;tf<13;++tf){ f32x4 z={0.f,0.f,0.f,0.f}; yacc[tf]=z; }
  const ushort_t* hrow = &Xs[w*16 + cl][kg*8];
  // part A: tf 0..6 (t' rows 0..111 in W2s)
  for (int kc = 0; kc < 4; ++kc){
    bf16x8 hb = *reinterpret_cast<const bf16x8*>(hrow + kc*32);
    #pragma unroll
    for (int tf=0;tf<7;++tf){
      const ushort_t* bp = &W2s[tf*16 + cl][kg*8 + kc*32];
      yacc[tf] = __builtin_amdgcn_mfma_f32_16x16x32_bf16(
          hb, *reinterpret_cast<const bf16x8*>(bp), yacc[tf], 0, 0, 0);
    }
  }
  __syncthreads();
  // restage W2s with w2t3 rows 112..207 (96 rows)
  for (int i = tid; i < 96*16; i += 256){
    int r = i >> 4, q = i & 15;
    *reinterpret_cast<uint4*>(&W2s[r][q*8]) =
        *reinterpret_cast<const uint4*>(&w2t3[(size_t)(112 + r)*128 + q*8]);
  }
  __syncthreads();
  // part B: tf 7..12 (t' rows 112..207 -> W2s rows tf*16+cl-112)
  for (int kc = 0; kc < 4; ++kc){
    bf16x8 hb = *reinterpret_cast<const bf16x8*>(hrow + kc*32);
    #pragma unroll
    for (int tf=7;tf<13;++tf){
      const ushort_t* bp = &W2s[tf*16 + cl - 112][kg*8 + kc*32];
      yacc[tf] = __builtin_amdgcn_mfma_f32_16x16x32_bf16(
          hb, *reinterpret_cast<const bf16x8*>(bp), yacc[tf], 0, 0, 0);
    }
  }
  // epilogue: lane holds c = c0 + w*16 + kg*4 + r (r=0..3), t' = tf*16 + cl.
  float sum0=0.f,sum1=0.f,sum2=0.f,sum3=0.f, sq0=0.f,sq1=0.f,sq2=0.f,sq3=0.f;
  #pragma unroll
  for (int tf=0;tf<13;++tf){
    int tp = tf*16 + cl;
    float bb = b2s[tp];
    f32x4 y = yacc[tf];
    y[0]+=bb; y[1]+=bb; y[2]+=bb; y[3]+=bb;
    yacc[tf] = y;
    sum0+=y[0]; sum1+=y[1]; sum2+=y[2]; sum3+=y[3];
    sq0+=y[0]*y[0]; sq1+=y[1]*y[1]; sq2+=y[2]*y[2]; sq3+=y[3]*y[3];
  }
  #pragma unroll
  for (int o=1;o<16;o<<=1){
    sum0+=__shfl_xor(sum0,o); sum1+=__shfl_xor(sum1,o);
    sum2+=__shfl_xor(sum2,o); sum3+=__shfl_xor(sum3,o);
    sq0+=__shfl_xor(sq0,o); sq1+=__shfl_xor(sq1,o);
    sq2+=__shfl_xor(sq2,o); sq3+=__shfl_xor(sq3,o);
  }
  float m0=sum0*(1.0f/196.0f), m1v=sum1*(1.0f/196.0f), m2=sum2*(1.0f/196.0f), m3=sum3*(1.0f/196.0f);
  float r0=rsqrtf(sq0*(1.0f/196.0f)-m0*m0+1e-5f);
  float r1=rsqrtf(sq1*(1.0f/196.0f)-m1v*m1v+1e-5f);
  float r2=rsqrtf(sq2*(1.0f/196.0f)-m2*m2+1e-5f);
  float r3=rsqrtf(sq3*(1.0f/196.0f)-m3*m3+1e-5f);
  int cbase = c0 + w*16 + kg*4;
  #pragma unroll
  for (int tf=0;tf<13;++tf){
    int tp = tf*16 + cl;
    if (tp < 196){
      float gg = g3s[tp], bb3 = b3s[tp];
      f32x4 y = yacc[tf];
      unsigned int o0 = f2b((y[0]-m0)*r0*gg + bb3);
      unsigned int o1 = f2b((y[1]-m1v)*r1*gg + bb3);
      unsigned int o2 = f2b((y[2]-m2)*r2*gg + bb3);
      unsigned int o3 = f2b((y[3]-m3)*r3*gg + bb3);
      uint2 pk; pk.x = o0 | (o1<<16); pk.y = o2 | (o3<<16);
      *reinterpret_cast<uint2*>(&Qout[((size_t)b*196 + tp)*384 + cbase]) = pk;
    }
  }
}

// ---------------- H1: fc4 stage A (MFMA; one s-half per launch) ----------------
// grid 512*4 (b, t-tile of 64), block 256 = 4 waves; wave = 16 t x 96 j.
__global__ __launch_bounds__(256) void k_fc4a(
    const float* __restrict__ x,         // fq or fs
    const float* __restrict__ m1_base,   // mlp1 + s*512*384
    const float* __restrict__ mu_s,      // mu + s*100864
    const float* __restrict__ rstd_s,    // rstd + s*100864
    const float* __restrict__ g1, const float* __restrict__ bln1,
    const ushort_t* __restrict__ Qin,    // Qb or Sb
    const ushort_t* __restrict__ w1t,    // [96][384] bf16
    const float* __restrict__ b1mlp,
    ushort_t* __restrict__ h4s){         // h4 + s*512*196*96
  __shared__ ushort_t Zs[64][392];       // bf16 Z tile, padded stride
  __shared__ float m1s[384], g1s[384], b1s[384];
  __shared__ float mus[64], rss[64];
  __shared__ float b1m[96];
  int bid = blockIdx.x;
  int b = bid >> 2, tt0 = (bid & 3)*64;
  int tid = threadIdx.x;
  const float* m1 = m1_base + (size_t)b*384;
  for (int i = tid; i < 384; i += 256){ m1s[i] = m1[i]; g1s[i] = g1[i]; b1s[i] = bln1[i]; }
  if (tid < 96) b1m[tid] = b1mlp[tid];
  if (tid < 64){
    int t = tt0 + tid; int tc = t < 196 ? t : 195;
    mus[tid] = mu_s[b*197 + tc + 1]; rss[tid] = rstd_s[b*197 + tc + 1];
  }
  __syncthreads();
  // phase 1: Z build, 64 rows x 96 col4-slots = 6144 slots, 24 per thread
  for (int e = 0; e < 24; ++e){
    int v = e*256 + tid;
    int row = v/96, col4 = v - row*96;
    int t = tt0 + row; int tc = t < 196 ? t : 195;
    float valid = (t < 196) ? 1.f : 0.f;
    float4 xv = *reinterpret_cast<const float4*>(&x[((size_t)b*197 + tc + 1)*384 + col4*4]);
    uint2 qv = *reinterpret_cast<const uint2*>(&Qin[((size_t)b*196 + tc)*384 + col4*4]);
    float muv = mus[row], rsv = rss[row];
    int c = col4*4;
    float z0 = (((xv.x + m1s[c+0]) - muv)*rsv*g1s[c+0] + b1s[c+0]) * bfu(qv.x)      * valid;
    float z1 = (((xv.y + m1s[c+1]) - muv)*rsv*g1s[c+1] + b1s[c+1]) * bfu(qv.x>>16)  * valid;
    float z2 = (((xv.z + m1s[c+2]) - muv)*rsv*g1s[c+2] + b1s[c+2]) * bfu(qv.y)      * valid;
    float z3 = (((xv.w + m1s[c+3]) - muv)*rsv*g1s[c+3] + b1s[c+3]) * bfu(qv.y>>16)  * valid;
    uint2 pk; pk.x = f2b(z0) | (f2b(z1)<<16); pk.y = f2b(z2) | (f2b(z3)<<16);
    *reinterpret_cast<uint2*>(&Zs[row][col4*4]) = pk;
  }
  __syncthreads();
  // phase 2: MFMA GEMM1 (16t x 96j per wave, K=384)
  int w = tid >> 6, lane = tid & 63;
  int tr = tt0 + w*16 + (lane & 15);
  int kg = lane >> 4;
  f32x4 acc0 = {0.f,0.f,0.f,0.f}, acc1 = {0.f,0.f,0.f,0.f}, acc2 = {0.f,0.f,0.f,0.f};
  f32x4 acc3 = {0.f,0.f,0.f,0.f}, acc4 = {0.f,0.f,0.f,0.f}, acc5 = {0.f,0.f,0.f,0.f};
  const ushort_t* arow = w1t + (size_t)(lane & 15)*384 + kg*8;
  const ushort_t* zrow = &Zs[w*16 + (lane & 15)][kg*8];
  for (int kc = 0; kc < 12; ++kc){
    bf16x8 zb = *reinterpret_cast<const bf16x8*>(zrow + kc*32);
    bf16x8 a0 = *reinterpret_cast<const bf16x8*>(arow + kc*32);
    bf16x8 a1 = *reinterpret_cast<const bf16x8*>(arow + kc*32 + 16*384);
    bf16x8 a2 = *reinterpret_cast<const bf16x8*>(arow + kc*32 + 32*384);
    bf16x8 a3 = *reinterpret_cast<const bf16x8*>(arow + kc*32 + 48*384);
    bf16x8 a4 = *reinterpret_cast<const bf16x8*>(arow + kc*32 + 64*384);
    bf16x8 a5 = *reinterpret_cast<const bf16x8*>(arow + kc*32 + 80*384);
    acc0 = __builtin_amdgcn_mfma_f32_16x16x32_bf16(a0, zb, acc0, 0, 0, 0);
    acc1 = __builtin_amdgcn_mfma_f32_16x16x32_bf16(a1, zb, acc1, 0, 0, 0);
    acc2 = __builtin_amdgcn_mfma_f32_16x16x32_bf16(a2, zb, acc2, 0, 0, 0);
    acc3 = __builtin_amdgcn_mfma_f32_16x16x32_bf16(a3, zb, acc3, 0, 0, 0);
    acc4 = __builtin_amdgcn_mfma_f32_16x16x32_bf16(a4, zb, acc4, 0, 0, 0);
    acc5 = __builtin_amdgcn_mfma_f32_16x16x32_bf16(a5, zb, acc5, 0, 0, 0);
  }
  // epilogue: lane holds j = jb*16 + kg*4 + r (D row), t = tr (D col)
  if (tr < 196){
    ushort_t* dst = h4s + ((size_t)b*196 + tr)*96 + kg*4;
    #pragma unroll
    for (int jb = 0; jb < 6; ++jb){
      f32x4 y = (jb==0)?acc0:(jb==1)?acc1:(jb==2)?acc2:(jb==3)?acc3:(jb==4)?acc4:acc5;
      int j0 = jb*16 + kg*4;
      uint2 pk;
      pk.x = f2b(geluf(y[0]+b1m[j0+0])) | (f2b(geluf(y[1]+b1m[j0+1]))<<16);
      pk.y = f2b(geluf(y[2]+b1m[j0+2])) | (f2b(geluf(y[3]+b1m[j0+3]))<<16);
      *reinterpret_cast<uint2*>(dst + jb*16) = pk;
    }
  }
}

// ---------------- H2: fc4 stage B (MFMA; one s-half per launch) ----------------
// grid 512*4 (b, t-tile of 64), block 256 = 4 waves; wave = 16 t x 384 c.
__global__ __launch_bounds__(256) void k_fc4b(
    const ushort_t* __restrict__ h4s,    // h4 + s*512*196*96
    const ushort_t* __restrict__ w2t,    // [384][96] bf16
    const float* __restrict__ b2, const float* __restrict__ g4,
    const float* __restrict__ bb4,
    const float* __restrict__ cls_base,  // dout + 1024 + s*196608
    ushort_t* __restrict__ Qo){          // Qb or Sb
  __shared__ float b2s[384], g4s[384], b4s[384], cl_s[384];
  int bid = blockIdx.x;
  int b = bid >> 2, ttile = bid & 3;
  int tid = threadIdx.x, w = tid >> 6, lane = tid & 63;
  const float* cls = cls_base + (size_t)b*384;
  for (int i = tid; i < 384; i += 256){
    b2s[i] = b2[i]; g4s[i] = g4[i]; b4s[i] = bb4[i]; cl_s[i] = cls[i];
  }
  __syncthreads();
  int tr = ttile*64 + w*16 + (lane & 15);
  int trc = tr < 196 ? tr : 195;
  int kg = lane >> 4;
  const ushort_t* hp = h4s + ((size_t)b*196 + trc)*96 + kg*8;
  bf16x8 hb0 = *reinterpret_cast<const bf16x8*>(hp);
  bf16x8 hb1 = *reinterpret_cast<const bf16x8*>(hp + 32);
  bf16x8 hb2 = *reinterpret_cast<const bf16x8*>(hp + 64);
  const ushort_t* ap_base = w2t + (size_t)(lane & 15)*96 + kg*8;
  f32x4 acc[24];
  #pragma unroll
  for (int af = 0; af < 24; ++af){
    const ushort_t* ap = ap_base + (size_t)af*16*96;
    bf16x8 a0 = *reinterpret_cast<const bf16x8*>(ap);
    bf16x8 a1 = *reinterpret_cast<const bf16x8*>(ap + 32);
    bf16x8 a2 = *reinterpret_cast<const bf16x8*>(ap + 64);
    f32x4 z = {0.f,0.f,0.f,0.f};
    z = __builtin_amdgcn_mfma_f32_16x16x32_bf16(a0, hb0, z, 0, 0, 0);
    z = __builtin_amdgcn_mfma_f32_16x16x32_bf16(a1, hb1, z, 0, 0, 0);
    z = __builtin_amdgcn_mfma_f32_16x16x32_bf16(a2, hb2, z, 0, 0, 0);
    acc[af] = z;
  }
  // epilogue: lane holds c = af*16 + kg*4 + r  (r=0..3), t = tr (col)
  float sum = 0.f, sq = 0.f;
  #pragma unroll
  for (int af = 0; af < 24; ++af){
    int cb = af*16 + kg*4;
    float4 bv = *reinterpret_cast<const float4*>(&b2s[cb]);
    f32x4 y = acc[af];
    y[0] += bv.x; y[1] += bv.y; y[2] += bv.z; y[3] += bv.w;
    acc[af] = y;
    sum += y[0]+y[1]+y[2]+y[3];
    sq  += y[0]*y[0]+y[1]*y[1]+y[2]*y[2]+y[3]*y[3];
  }
  sum += __shfl_xor(sum, 16); sum += __shfl_xor(sum, 32);
  sq  += __shfl_xor(sq, 16);  sq  += __shfl_xor(sq, 32);
  float m4 = sum*(1.0f/384.0f);
  float rs = rsqrtf(sq*(1.0f/384.0f) - m4*m4 + 1e-5f);
  float s2 = 0.f;
  #pragma unroll
  for (int af = 0; af < 24; ++af){
    int cb = af*16 + kg*4;
    float4 gv = *reinterpret_cast<const float4*>(&g4s[cb]);
    float4 bb = *reinterpret_cast<const float4*>(&b4s[cb]);
    float4 cv = *reinterpret_cast<const float4*>(&cl_s[cb]);
    f32x4 y = acc[af];
    y[0] = (y[0]-m4)*rs*gv.x + bb.x + 0.5f*cv.x;
    y[1] = (y[1]-m4)*rs*gv.y + bb.y + 0.5f*cv.y;
    y[2] = (y[2]-m4)*rs*gv.z + bb.z + 0.5f*cv.z;
    y[3] = (y[3]-m4)*rs*gv.w + bb.w + 0.5f*cv.w;
    acc[af] = y;
    s2 += y[0]*y[0]+y[1]*y[1]+y[2]*y[2]+y[3]*y[3];
  }
  s2 += __shfl_xor(s2, 16); s2 += __shfl_xor(s2, 32);
  float inv = 1.0f/fmaxf(sqrtf(s2), 1e-12f);
  float sm = 0.f;
  #pragma unroll
  for (int af = 0; af < 24; ++af){
    f32x4 y = acc[af];
    y[0]*=inv; y[1]*=inv; y[2]*=inv; y[3]*=inv;
    acc[af] = y;
    sm += y[0]+y[1]+y[2]+y[3];
  }
  sm += __shfl_xor(sm, 16); sm += __shfl_xor(sm, 32);
  sm *= (1.0f/384.0f);
  if (tr < 196){
    ushort_t* dst = Qo + ((size_t)b*196 + tr)*384 + kg*4;
    #pragma unroll
    for (int af = 0; af < 24; ++af){
      f32x4 y = acc[af];
      uint2 pk;
      pk.x = f2b(y[0]-sm) | (f2b(y[1]-sm)<<16);
      pk.y = f2b(y[2]-sm) | (f2b(y[3]-sm)<<16);
      *reinterpret_cast<uint2*>(dst + af*16) = pk;
    }
  }
}

// ---------------- I: batched einsum + fused 2x2 pooling (MFMA) ----------------
// grid 512*16 (b, qt, st), block 256 = 4 waves; wave = 32x32 output tile.
// Round-14 profile: 265MB FETCH vs 154MB logical (XCD L2 fragmentation) +
// serialized frag loads. Fixes: (1) XCD-chunked bijective swizzle
// (8192 = 8*1024: XCD i handles b in [64i,64i+64), working set fits 4MB L2);
// (2) register double-buffer on the 4 fragments (prefetch k+1, peel last).
__global__ __launch_bounds__(256) void k_sim(
    const ushort_t* __restrict__ Q, const ushort_t* __restrict__ S,
    float* __restrict__ P){
  int bid0 = blockIdx.x;
  int bx = (bid0 & 7)*1024 + (bid0 >> 3);   // bijective: consecutive work-b per XCD
  int b = bx >> 4, qt = (bx >> 2) & 3, st = bx & 3;
  int tid = threadIdx.x;
  int w = tid >> 6, lane = tid & 63;
  int wr = w >> 1, wc = w & 1;
  int q0 = qt*64 + wr*32, s0 = st*64 + wc*32;
  int rrow = lane & 15, kg = lane >> 4;
  const ushort_t* Qb_ = Q + (size_t)b*196*384;
  const ushort_t* Sb_ = S + (size_t)b*196*384;
  int qr0 = min(q0 + rrow, 195), qr1 = min(q0 + 16 + rrow, 195);
  int sr0 = min(s0 + rrow, 195), sr1 = min(s0 + 16 + rrow, 195);
  const ushort_t* qp0 = Qb_ + (size_t)qr0*384 + kg*8;
  const ushort_t* qp1 = Qb_ + (size_t)qr1*384 + kg*8;
  const ushort_t* sp0 = Sb_ + (size_t)sr0*384 + kg*8;
  const ushort_t* sp1 = Sb_ + (size_t)sr1*384 + kg*8;
  f32x4 acc00 = {0.f,0.f,0.f,0.f}, acc01 = {0.f,0.f,0.f,0.f};
  f32x4 acc10 = {0.f,0.f,0.f,0.f}, acc11 = {0.f,0.f,0.f,0.f};
  bf16x8 qa0 = *reinterpret_cast<const bf16x8*>(qp0);
  bf16x8 qa1 = *reinterpret_cast<const bf16x8*>(qp1);
  bf16x8 sa0 = *reinterpret_cast<const bf16x8*>(sp0);
  bf16x8 sa1 = *reinterpret_cast<const bf16x8*>(sp1);
  for (int kc = 0; kc < 11; ++kc){
    int koff = (kc+1)*32;
    bf16x8 nq0 = *reinterpret_cast<const bf16x8*>(qp0 + koff);
    bf16x8 nq1 = *reinterpret_cast<const bf16x8*>(qp1 + koff);
    bf16x8 ns0 = *reinterpret_cast<const bf16x8*>(sp0 + koff);
    bf16x8 ns1 = *reinterpret_cast<const bf16x8*>(sp1 + koff);
    acc00 = __builtin_amdgcn_mfma_f32_16x16x32_bf16(qa0, sa0, acc00, 0, 0, 0);
    acc01 = __builtin_amdgcn_mfma_f32_16x16x32_bf16(qa0, sa1, acc01, 0, 0, 0);
    acc10 = __builtin_amdgcn_mfma_f32_16x16x32_bf16(qa1, sa0, acc10, 0, 0, 0);
    acc11 = __builtin_amdgcn_mfma_f32_16x16x32_bf16(qa1, sa1, acc11, 0, 0, 0);
    qa0 = nq0; qa1 = nq1; sa0 = ns0; sa1 = ns1;
  }
  acc00 = __builtin_amdgcn_mfma_f32_16x16x32_bf16(qa0, sa0, acc00, 0, 0, 0);
  acc01 = __builtin_amdgcn_mfma_f32_16x16x32_bf16(qa0, sa1, acc01, 0, 0, 0);
  acc10 = __builtin_amdgcn_mfma_f32_16x16x32_bf16(qa1, sa0, acc10, 0, 0, 0);
  acc11 = __builtin_amdgcn_mfma_f32_16x16x32_bf16(qa1, sa1, acc11, 0, 0, 0);
  int c = lane & 15, g = lane >> 4;
  float* Pb = P + (size_t)b*98*98;
  #pragma unroll
  for (int i = 0; i < 2; ++i){
    #pragma unroll
    for (int j = 0; j < 2; ++j){
      f32x4 v = (i==0) ? (j==0 ? acc00 : acc01) : (j==0 ? acc10 : acc11);
      float p0 = v[0] + v[1];   // rows 4g, 4g+1
      float p1 = v[2] + v[3];   // rows 4g+2, 4g+3
      float t0 = p0 + __shfl_xor(p0, 1);
      float t1 = p1 + __shfl_xor(p1, 1);
      if (!(c & 1)){
        int qp = (q0 + 16*i + 4*g) >> 1;
        int sp = (s0 + 16*j + c) >> 1;
        if (sp < 98){
          if (qp     < 98) Pb[(size_t)(qp    )*98 + sp] = 0.25f*t0;
          if (qp + 1 < 98) Pb[(size_t)(qp + 1)*98 + sp] = 0.25f*t1;
        }
      }
    }
  }
}

// ---------------- J1: fc2 split-K GEMM  Cpart[ks] = P2-chunk @ w1-chunk ----------------
// grid 64*14 (m-block of 8 rows, k-split of 686), block 256 (= N columns)
__global__ __launch_bounds__(256) void k_fc2a(
    const float* __restrict__ P, const float* __restrict__ w1,
    float* __restrict__ Cpart){
  __shared__ float p2[8][688];
  int bx = blockIdx.x;
  int mb = bx & 63, ks = bx >> 6;      // 14 k-splits of 686 (14*686 = 9604)
  int b0 = mb*8, k0 = ks*686;
  int tid = threadIdx.x;
  for (int idx = tid; idx < 8*686; idx += 256){
    int r = idx / 686, i = idx - r*686;
    float v = P[(size_t)(b0+r)*9604 + k0 + i];
    p2[r][i] = v*v;
  }
  __syncthreads();
  float acc[8];
  #pragma unroll
  for (int r=0;r<8;++r) acc[r]=0.f;
  for (int ii=0; ii<686; ++ii){
    float w = w1[(size_t)(k0+ii)*256 + tid];
    #pragma unroll
    for (int r=0;r<8;++r) acc[r] += p2[r][ii]*w;
  }
  #pragma unroll
  for (int r=0;r<8;++r) Cpart[((size_t)ks*512 + b0 + r)*256 + tid] = acc[r];
}

// ---------------- J2: fc2 reduce + gelu + w2 dot ----------------
// grid 512 (one b each), block 256
__global__ __launch_bounds__(256) void k_fc2b(
    const float* __restrict__ Cpart, const float* __restrict__ b1,
    const float* __restrict__ w2, const float* __restrict__ b2,
    float* __restrict__ outp){
  __shared__ float red[4];
  int b = blockIdx.x, tid = threadIdx.x;
  float s = 0.f;
  for (int ks = 0; ks < 14; ++ks) s += Cpart[((size_t)ks*512 + b)*256 + tid];
  float h = geluf(s + b1[tid]) * w2[tid];
  #pragma unroll
  for (int o=32;o;o>>=1) h += __shfl_down(h,o);
  int w = tid >> 6, lane = tid & 63;
  if (lane==0) red[w] = h;
  __syncthreads();
  if (tid==0) outp[b] = red[0]+red[1]+red[2]+red[3] + b2[0];
}

// ---------------- launch ----------------
extern "C" void kernel_launch(void* const* d_in, const int* in_sizes, int n_in,
                              void* d_out, int out_size, void* d_ws, size_t ws_size,
                              hipStream_t stream){
  const float* fq  = (const float*)d_in[0];
  const float* fs  = (const float*)d_in[1];
  const float* fqs = (const float*)d_in[2];
  const float* fss = (const float*)d_in[3];
  const float* fc1_w1 = (const float*)d_in[4];
  const float* fc1_b1 = (const float*)d_in[5];
  const float* fc1_w2 = (const float*)d_in[6];
  const float* fc1_b2 = (const float*)d_in[7];
  const float* ln1_g = (const float*)d_in[8];
  const float* ln1_b = (const float*)d_in[9];
  const float* fc3_w1 = (const float*)d_in[10];
  const float* fc3_b1 = (const float*)d_in[11];
  const float* fc3_w2 = (const float*)d_in[12];
  const float* fc3_b2 = (const float*)d_in[13];
  const float* ln3_g = (const float*)d_in[14];
  const float* ln3_b = (const float*)d_in[15];
  const float* fc4_w1 = (const float*)d_in[16];
  const float* fc4_b1 = (const float*)d_in[17];
  const float* fc4_w2 = (const float*)d_in[18];
  const float* fc4_b2 = (const float*)d_in[19];
  const float* ln4_g = (const float*)d_in[20];
  const float* ln4_b = (const float*)d_in[21];
  const float* fc2_w1 = (const float*)d_in[22];
  const float* fc2_b1 = (const float*)d_in[23];
  const float* fc2_w2 = (const float*)d_in[24];
  const float* fc2_b2 = (const float*)d_in[25];
  const float* cs_w1 = (const float*)d_in[26];
  const float* cs_b1 = (const float*)d_in[27];
  const float* cs_w2 = (const float*)d_in[28];
  const float* cs_b2 = (const float*)d_in[29];
  float* out = (float*)d_out;
  char* ws = (char*)d_ws;
  // ws layout (bytes):
  //   meanb f32 @0           (3,145,728)   [dead after k_fc1; head reused for weight prep]
  //     w2t  bf16 @0         (73,728)      [fc4 w2^T; written by k_wt AFTER k_fc1]
  //     w1t  bf16 @73728     (73,728)      [fc4 w1^T]
  //     w1t3 bf16 @147456    (57,344)      [fc3 w1^T, t-pad 224]
  //     w2t3 bf16 @204800    (53,248)      [fc3 w2^T, t'-pad 208]
  //   mlp1  f32 @3145728     (3,145,728)
  //   mu    f32 @6291456     (1,613,824)
  //   rstd  f32 @7905280     (1,613,824)
  //   h4    bf16 @9519104    (38,535,168)  [then P f32 + Cpart overlay]
  //   P     f32 @9519104     (19,668,992)  [overlays h4 (dead after fc4b)]
  //   Cpart f32 @29188096    (7,340,032)
  //   Qb    bf16 @59850752   (77,070,336)
  //   Sb    bf16 @136921088  (77,070,336)
  //   total 213,991,424 B
  float* meanb  = (float*)(ws + 0);
  ushort_t* w2t  = (ushort_t*)(ws + 0);       // overlays meanb (dead after k_fc1)
  ushort_t* w1t  = (ushort_t*)(ws + 73728);
  ushort_t* w1t3 = (ushort_t*)(ws + 147456);
  ushort_t* w2t3 = (ushort_t*)(ws + 204800);
  float* mlp1   = (float*)(ws + 3145728);
  float* mu     = (float*)(ws + 6291456);
  float* rstd   = (float*)(ws + 7905280);
  ushort_t* h4  = (ushort_t*)(ws + 9519104);
  float* P      = (float*)(ws + 9519104);     // overlays h4 (dead after fc4b)
  float* Cpart  = (float*)(ws + 29188096);    // after P, before Qb
  ushort_t* Qb  = (ushort_t*)(ws + 59850752);
  ushort_t* Sb  = (ushort_t*)(ws + 136921088);
  const size_t H4S = (size_t)512*196*96;      // per-s-half h4 elements

  k_mean<<<2048, 384, 0, stream>>>(fq, fs, fqs, fss, meanb);
  k_fc1<<<2048, 384, 0, stream>>>(meanb, fc1_w1, fc1_b1, fc1_w2, fc1_b2, mlp1);
  k_wt<<<504, 256, 0, stream>>>(fc4_w1, fc4_w2, fc3_w1, fc3_w2,
                                w1t, w2t, w1t3, w2t3);      // after k_fc1: meanb dead
  k_stats<<<2048, 256, 0, stream>>>(fq, fs, fqs, fss, mlp1, mu, rstd);
  k_class<<<1024, 384, 0, stream>>>(fq, fs, mlp1, mu, rstd, ln1_g, ln1_b, out);
  k_cosine<<<512, 384, 0, stream>>>(cs_w1, cs_b1, cs_w2, cs_b2, out);
  // fc3 fused MFMA: q-start then s-start
  k_fc3<<<3072, 256, 0, stream>>>(fqs, mlp1 + (size_t)2*512*384, mu + 2*100864, rstd + 2*100864,
                                  ln1_g, ln1_b, w1t3, fc3_b1, w2t3, fc3_b2, ln3_g, ln3_b, Qb);
  k_fc3<<<3072, 256, 0, stream>>>(fss, mlp1 + (size_t)3*512*384, mu + 3*100864, rstd + 3*100864,
                                  ln1_g, ln1_b, w1t3, fc3_b1, w2t3, fc3_b2, ln3_g, ln3_b, Sb);
  // fc4 stage A (MFMA): q then s (pre-offset pointers, no runtime s-select)
  k_fc4a<<<2048, 256, 0, stream>>>(fq, mlp1, mu, rstd, ln1_g, ln1_b,
                                   Qb, w1t, fc4_b1, h4);
  k_fc4a<<<2048, 256, 0, stream>>>(fs, mlp1 + (size_t)512*384, mu + 100864, rstd + 100864,
                                   ln1_g, ln1_b, Sb, w1t, fc4_b1, h4 + H4S);
  // fc4 stage B (MFMA): q then s (Qb/Sb overwritten in place after their last read)
  k_fc4b<<<2048, 256, 0, stream>>>(h4,       w2t, fc4_b2, ln4_g, ln4_b, out + 1024,          Qb);
  k_fc4b<<<2048, 256, 0, stream>>>(h4 + H4S, w2t, fc4_b2, ln4_g, ln4_b, out + 1024 + 196608, Sb);
  k_sim<<<8192, 256, 0, stream>>>(Qb, Sb, P);
  // fc2 head: split-K GEMM (896 blocks) + tiny reduce
  k_fc2a<<<896, 256, 0, stream>>>(P, fc2_w1, Cpart);
  k_fc2b<<<512, 256, 0, stream>>>(Cpart, fc2_b1, fc2_w2, fc2_b2, out);
}